// Round 2
// baseline (6394.692 us; speedup 1.0000x reference)
//
#include <hip/hip_runtime.h>
#include <math.h>

#define HW 65536
#define NPIX 262144

// ---- workspace layout (float offsets) ----
#define OFF_FFTW 0            // 64x64 spatial fft kernel
#define OFF_FLAG 4096         // 1
#define OFF_GSUM 4097         // 1   (zeroed in k0)
#define OFF_POOL 4098         // 128 (zeroed in k0)
#define OFF_GRAM 4226         // 1280 (zeroed in k0)
#define OFF_THR  5506         // 32  (zeroed in k0)
#define OFF_A    5538         // 1024
#define OFF_CW   6562         // 128
#define OFF_QKVL 8192         // 96ch * 65536 = 25165824 floats (end 100.7 MB)
#define T_PLANE  9216         // 36 rows * 256 cols
#define T_STRIDE 9437184      // 4b * 256ch * T_PLANE
#define OFF_T0   8192         // overlaps QKVL (disjoint lifetime)
#define OFF_T1   (OFF_T0 + T_STRIDE)
#define OFF_Z    (OFF_T1 + T_STRIDE)   // 4b*64ch*32rows*256 = 2097152 floats
// peak ws usage = max(QKVL end, Z end) = 25174016 floats = 100.7 MB

__device__ __forceinline__ float sigm(float v) { return 1.f / (1.f + expf(-v)); }
__device__ __forceinline__ float wredsum(float v) {
#pragma unroll
  for (int off = 32; off >= 1; off >>= 1) v += __shfl_xor(v, off);
  return v;
}

// ---------------- K0: zero accumulators + fft spatial kernel + identity flag ----------------
__global__ __launch_bounds__(256) void k0_setup(
    const float* __restrict__ fft_W, float* __restrict__ ws)
{
  __shared__ float ct8[8];
  const int tid = threadIdx.x;
  if (tid < 8) ct8[tid] = cosf((float)tid * 0.78539816339744831f); // cos(k*pi/4)
  for (int i = tid; i < 1441; i += 256) ws[OFF_GSUM + i] = 0.f;    // gsum,pool,gram,thr
  __syncthreads();
  // effective full-spectrum multiplier (real), accounting for irfft2 semantics:
  //  v in 1..3: W[u][v];  v in 5..7: W[(8-u)%8][8-v];
  //  v = 0,4 (self-conjugate): (W[u][v] + W[(8-u)%8][v]) / 2
  for (int i = tid; i < 64 * 64; i += 256) {
    int ch = i >> 6, ab = i & 63;
    int a = ab >> 3, b2 = ab & 7;
    float s = 0.f;
    for (int u = 0; u < 8; ++u)
      for (int v = 0; v < 8; ++v) {
        float Wf;
        if (v == 0 || v == 4)
          Wf = 0.5f * (fft_W[ch * 40 + u * 5 + v] + fft_W[ch * 40 + ((8 - u) & 7) * 5 + v]);
        else if (v < 5)
          Wf = fft_W[ch * 40 + u * 5 + v];
        else
          Wf = fft_W[ch * 40 + ((8 - u) & 7) * 5 + (8 - v)];
        s += Wf * ct8[(u * a + v * b2) & 7];
      }
    ws[OFF_FFTW + i] = s * (1.f / 64.f);
  }
  __syncthreads();
  if (tid == 0) {
    float ok = 1.f;
    for (int i2 = 0; i2 < 4096; ++i2) {
      float expect = ((i2 & 63) == 0) ? 1.f : 0.f;
      if (fabsf(ws[OFF_FFTW + i2] - expect) > 1e-4f) { ok = 0.f; break; }
    }
    ws[OFF_FLAG] = ok;
  }
}

// ---------------- K1: LN1 + in_proj(loc->dout[0..31], glob) + qkv + pooled/gate ----------------
__global__ __launch_bounds__(256) void k1_proj(
    const float* __restrict__ x, const float* __restrict__ ln1_w, const float* __restrict__ ln1_b,
    const float* __restrict__ in_proj_w, const float* __restrict__ qkv_w,
    const float* __restrict__ pre_w, const float* __restrict__ pre_b,
    const float* __restrict__ g1w, const float* __restrict__ g1b,
    const float* __restrict__ g2w, const float* __restrict__ g2b,
    float* __restrict__ dout, float* __restrict__ qkvl,
    float* __restrict__ pooled, float* __restrict__ gsum)
{
  __shared__ float sPool[4][32];
  __shared__ float sRed[4];
  const int tid = threadIdx.x;
  const int p = blockIdx.x * 256 + tid;
  const int b = p >> 16;
  const int hw = p & (HW - 1);
  const int wave = tid >> 6, lane = tid & 63;
  const float* xb = x + (size_t)(b * 64) * HW + hw;
  float xv[64];
  float mu = 0.f;
#pragma unroll
  for (int c = 0; c < 64; ++c) { xv[c] = xb[(size_t)c * HW]; mu += xv[c]; }
  mu *= (1.f / 64.f);
  float var = 0.f;
#pragma unroll
  for (int c = 0; c < 64; ++c) { float d = xv[c] - mu; var += d * d; }
  var *= (1.f / 64.f);
  const float rs = rsqrtf(var + 1e-5f);
#pragma unroll
  for (int c = 0; c < 64; ++c) xv[c] = (xv[c] - mu) * rs * ln1_w[c] + ln1_b[c];

  // local = in_proj rows 0..31 -> store into dout channels 0..31
  float loc[32];
  for (int o = 0; o < 32; ++o) {
    float s = 0.f;
#pragma unroll
    for (int c = 0; c < 64; ++c) s += in_proj_w[o * 64 + c] * xv[c];
    loc[o] = s;
    dout[(size_t)(b * 64 + o) * HW + hw] = s;
  }
  // pre = pre_w @ loc + pre_b  (only pooled reduction; not stored)
  for (int o = 0; o < 32; ++o) {
    float s = pre_b[o];
#pragma unroll
    for (int j = 0; j < 32; ++j) s += pre_w[o * 32 + j] * loc[j];
    float r = wredsum(s);
    if (lane == 0) sPool[wave][o] = r;
  }
  // glob = in_proj rows 32..63
  float gl[32];
  for (int o = 0; o < 32; ++o) {
    float s = 0.f;
#pragma unroll
    for (int c = 0; c < 64; ++c) s += in_proj_w[(32 + o) * 64 + c] * xv[c];
    gl[o] = s;
  }
  // qkv linear (96 x 32)
  for (int o = 0; o < 96; ++o) {
    float s = 0.f;
#pragma unroll
    for (int j = 0; j < 32; ++j) s += qkv_w[o * 32 + j] * gl[j];
    qkvl[(size_t)(b * 96 + o) * HW + hw] = s;
  }
  // gate scalar
  float gacc = g2b[0];
  for (int o = 0; o < 16; ++o) {
    float h = g1b[o];
#pragma unroll
    for (int j = 0; j < 32; ++j) h += g1w[o * 32 + j] * gl[j];
    gacc += g2w[o] * fmaxf(h, 0.f);
  }
  float gv = wredsum(sigm(gacc));
  if (lane == 0) sRed[wave] = gv;
  __syncthreads();
  if (tid == 0) atomicAdd(gsum, sRed[0] + sRed[1] + sRed[2] + sRed[3]);
  if (tid < 32) {
    float s = sPool[0][tid] + sPool[1][tid] + sPool[2][tid] + sPool[3][tid];
    atomicAdd(&pooled[b * 32 + tid], s);
  }
}

// ---------------- K2: dwconv(q,k) + Gram/norm reductions (no q/k stores) ----------------
__global__ __launch_bounds__(256) void k2_gram(
    const float* __restrict__ qkvl, const float* __restrict__ qkv_dw, float* __restrict__ gram)
{
  __shared__ float sg[320];
  const int tid = threadIdx.x;
  const int p = blockIdx.x * 256 + tid;
  const int b = p >> 16, hw = p & (HW - 1);
  const int y = hw >> 8, xx = hw & 255;
  for (int i = tid; i < 320; i += 256) sg[i] = 0.f;
  __syncthreads();
  int offs[9]; bool ok[9];
#pragma unroll
  for (int dy = -1; dy <= 1; ++dy)
#pragma unroll
    for (int dx = -1; dx <= 1; ++dx) {
      int i = (dy + 1) * 3 + (dx + 1);
      int yy = y + dy, x2 = xx + dx;
      ok[i] = ((unsigned)yy < 256u) && ((unsigned)x2 < 256u);
      offs[i] = yy * 256 + x2;
    }
  const float* base = qkvl + (size_t)b * 96 * HW;
  float qv[32], kv[32];
  for (int ch = 0; ch < 32; ++ch) {
    const float* plane = base + (size_t)ch * HW;
    float acc = 0.f;
#pragma unroll
    for (int i = 0; i < 9; ++i) if (ok[i]) acc += plane[offs[i]] * qkv_dw[ch * 9 + i];
    qv[ch] = acc;
  }
  for (int ch = 0; ch < 32; ++ch) {
    const float* plane = base + (size_t)(32 + ch) * HW;
    float acc = 0.f;
#pragma unroll
    for (int i = 0; i < 9; ++i) if (ok[i]) acc += plane[offs[i]] * qkv_dw[(32 + ch) * 9 + i];
    kv[ch] = acc;
  }
  const int lane = tid & 63;
  for (int h = 0; h < 4; ++h) {
#pragma unroll
    for (int c = 0; c < 8; ++c) {
#pragma unroll
      for (int d = 0; d < 8; ++d) {
        float v = wredsum(qv[h * 8 + c] * kv[h * 8 + d]);
        if (lane == 0) atomicAdd(&sg[h * 80 + c * 8 + d], v);
      }
    }
#pragma unroll
    for (int c = 0; c < 8; ++c) {
      float v = wredsum(qv[h * 8 + c] * qv[h * 8 + c]);
      if (lane == 0) atomicAdd(&sg[h * 80 + 64 + c], v);
      float w = wredsum(kv[h * 8 + c] * kv[h * 8 + c]);
      if (lane == 0) atomicAdd(&sg[h * 80 + 72 + c], w);
    }
  }
  __syncthreads();
  for (int i = tid; i < 320; i += 256) atomicAdd(&gram[b * 320 + i], sg[i]);
}

// ---------------- K3: dk, CBAM channel weights, attention matrices ----------------
__global__ __launch_bounds__(256) void k3_final(
    const float* __restrict__ m1w, const float* __restrict__ m1b,
    const float* __restrict__ m2w, const float* __restrict__ m2b,
    const float* __restrict__ temperature, const float* __restrict__ attn_scales,
    const float* __restrict__ gsum, const float* __restrict__ pooled,
    const float* __restrict__ gram, float* __restrict__ Abuf, float* __restrict__ cwbuf)
{
  __shared__ int s_dk;
  __shared__ float s_scale;
  const int tid = threadIdx.x;
  if (tid == 0) {
    float gmean = gsum[0] / (float)NPIX;
    int dk = (int)floorf(8.f * gmean);
    if (dk < 1) dk = 1;
    if (dk > 8) dk = 8;
    s_dk = dk;
    s_scale = attn_scales[0] + attn_scales[1] + attn_scales[2] + attn_scales[3];
  }
  __syncthreads();
  if (tid < 128) {
    int b = tid >> 5, ch = tid & 31, g = ch >> 2, c = ch & 3;
    float h1 = m1b[g];
#pragma unroll
    for (int cc = 0; cc < 4; ++cc)
      h1 += (pooled[b * 32 + g * 4 + cc] * (1.f / 65536.f)) * m1w[g * 4 + cc];
    h1 = fmaxf(h1, 0.f);
    cwbuf[tid] = sigm(h1 * m2w[g * 4 + c] + m2b[g * 4 + c]);

    int r = tid, h = (r >> 3) & 3, c8 = r & 7;
    const float* gm = gram + (b * 4 + h) * 80;
    float qn = fmaxf(sqrtf(gm[64 + c8]), 1e-12f);
    float temp = temperature[h];
    float a[8];
#pragma unroll
    for (int d = 0; d < 8; ++d) {
      float kn = fmaxf(sqrtf(gm[72 + d]), 1e-12f);
      a[d] = gm[c8 * 8 + d] / (qn * kn) * temp;
    }
    float t[8];
#pragma unroll
    for (int d = 0; d < 8; ++d) t[d] = a[d];
#pragma unroll
    for (int i = 0; i < 8; ++i)
#pragma unroll
      for (int j = 0; j < 8; ++j)
        if (j > i && t[j] > t[i]) { float tmp = t[i]; t[i] = t[j]; t[j] = tmp; }
    float kth = t[s_dk - 1];
    float mx = t[0];
    float e[8]; float sum = 0.f;
#pragma unroll
    for (int d = 0; d < 8; ++d) {
      e[d] = (a[d] >= kth) ? expf(a[d] - mx) : 0.f;
      sum += e[d];
    }
    float inv = s_scale / sum;
#pragma unroll
    for (int d = 0; d < 8; ++d) Abuf[r * 8 + d] = e[d] * inv;
  }
}

// ---------------- K4a: resp-mean (threshold) reduction; PRE recomputed from LOC ----------------
__global__ __launch_bounds__(256) void k4a_thr(
    const float* __restrict__ pre_w, const float* __restrict__ pre_b,
    const float* __restrict__ spw, const float* __restrict__ spb,
    const float* __restrict__ cwbuf, const float* __restrict__ dout, float* __restrict__ thrbuf)
{
  const int tid = threadIdx.x;
  const int p = blockIdx.x * 256 + tid;
  const int b = p >> 16, hw = p & (HW - 1);
  const float* LOCp = dout + (size_t)b * 64 * HW + hw;
  const float* cw = cwbuf + b * 32;
  float loc[32];
#pragma unroll
  for (int c = 0; c < 32; ++c) loc[c] = LOCp[(size_t)c * HW];
  float pre[32];
  for (int o = 0; o < 32; ++o) {
    float s = pre_b[o];
#pragma unroll
    for (int j = 0; j < 32; ++j) s += pre_w[o * 32 + j] * loc[j];
    pre[o] = s;
  }
  const int lane = tid & 63;
#pragma unroll
  for (int g = 0; g < 8; ++g) {
    float xa[4];
    float sdot = spb[g];
#pragma unroll
    for (int c = 0; c < 4; ++c) {
      xa[c] = pre[g * 4 + c] * cw[g * 4 + c];
      sdot += xa[c] * spw[g * 4 + c];
    }
    float sgv = sigm(sdot);
    float r = 0.f;
#pragma unroll
    for (int c = 0; c < 4; ++c) r += sigm(xa[c] * sgv);
    float v = wredsum(r);
    if (lane == 0) atomicAdd(&thrbuf[b * 8 + g], v);
  }
}

// ---------------- K4b: LGCE finish + V-dwconv + attn + out_proj + residual -> dout ----------------
__global__ __launch_bounds__(256) void k4b_fuse(
    const float* __restrict__ x, const float* __restrict__ pre_w, const float* __restrict__ pre_b,
    const float* __restrict__ post_w, const float* __restrict__ post_b,
    const float* __restrict__ out_proj_w, const float* __restrict__ spw, const float* __restrict__ spb,
    const float* __restrict__ qkv_dw, const float* __restrict__ qkvl,
    const float* __restrict__ Abuf, const float* __restrict__ cwbuf, const float* __restrict__ thrbuf,
    float* dout)
{
  const int tid = threadIdx.x;
  const int p = blockIdx.x * 256 + tid;
  const int b = p >> 16, hw = p & (HW - 1);
  const int y = hw >> 8, xx = hw & 255;
  const float* cw = cwbuf + b * 32;
  const float* A = Abuf + b * 256;
  float* doutb = dout + (size_t)b * 64 * HW + hw;
  float loc[32];
#pragma unroll
  for (int c = 0; c < 32; ++c) loc[c] = doutb[(size_t)c * HW];
  float pre[32];
  for (int o = 0; o < 32; ++o) {
    float s = pre_b[o];
#pragma unroll
    for (int j = 0; j < 32; ++j) s += pre_w[o * 32 + j] * loc[j];
    pre[o] = s;
  }
  float mx[32];
#pragma unroll
  for (int g = 0; g < 8; ++g) {
    float xa[4];
    float sdot = spb[g];
#pragma unroll
    for (int c = 0; c < 4; ++c) {
      xa[c] = pre[g * 4 + c] * cw[g * 4 + c];
      sdot += xa[c] * spw[g * 4 + c];
    }
    float sgv = sigm(sdot);
    float thr = thrbuf[b * 8 + g] * (1.f / (4.f * 65536.f));
#pragma unroll
    for (int c = 0; c < 4; ++c) {
      float resp = sigm(xa[c] * sgv);
      float m = (resp > thr) ? 1.f : resp;
      mx[g * 4 + c] = pre[g * 4 + c] * m;
    }
  }
  // V via dwconv on qkvl channels 64..95
  int offs[9]; bool okn[9];
#pragma unroll
  for (int dy = -1; dy <= 1; ++dy)
#pragma unroll
    for (int dx = -1; dx <= 1; ++dx) {
      int i = (dy + 1) * 3 + (dx + 1);
      int yy = y + dy, x2 = xx + dx;
      okn[i] = ((unsigned)yy < 256u) && ((unsigned)x2 < 256u);
      offs[i] = yy * 256 + x2;
    }
  const float* vbase = qkvl + (size_t)(b * 96 + 64) * HW;
  float vv[32];
  for (int ch = 0; ch < 32; ++ch) {
    const float* plane = vbase + (size_t)ch * HW;
    float acc = 0.f;
#pragma unroll
    for (int i = 0; i < 9; ++i) if (okn[i]) acc += plane[offs[i]] * qkv_dw[(64 + ch) * 9 + i];
    vv[ch] = acc;
  }
  float fused[64];
#pragma unroll
  for (int j = 0; j < 32; ++j) {
    int h = j >> 3, c = j & 7;
    float s = 0.f;
#pragma unroll
    for (int d = 0; d < 8; ++d) s += A[(h * 8 + c) * 8 + d] * vv[h * 8 + d];
    fused[j] = s;
  }
  for (int o = 0; o < 32; ++o) {
    float s = post_b[o];
#pragma unroll
    for (int j = 0; j < 32; ++j) s += post_w[o * 32 + j] * mx[j];
    fused[32 + o] = s + loc[o];
  }
  const float* xb = x + (size_t)b * 64 * HW + hw;
  for (int o = 0; o < 64; ++o) {
    float s = 0.f;
#pragma unroll
    for (int j = 0; j < 64; ++j) s += out_proj_w[o * 64 + j] * fused[j];
    doutb[(size_t)o * HW] = s + xb[(size_t)o * HW];
  }
}

// ---------------- K5: LN2 + ffn_in (64->256) for one strip (+halo 2) ----------------
__global__ __launch_bounds__(256) void k5_ffnin(
    const float* __restrict__ ln2_w, const float* __restrict__ ln2_b,
    const float* __restrict__ ffn_in_w, const float* __restrict__ dout,
    float* __restrict__ T, int rs)
{
  const int tid = threadIdx.x;
  const int p = blockIdx.x * 256 + tid;   // 144 blocks * 256 = 36864 = 4b * 36rows * 256
  const int b = p / 9216;
  const int rem = p - b * 9216;
  const int rl = rem >> 8, col = rem & 255;
  const int row = rs - 2 + rl;
  if ((unsigned)row > 255u) return;
  const float* yb = dout + (size_t)b * 64 * HW + row * 256 + col;
  float xv[64];
  float mu = 0.f;
#pragma unroll
  for (int c = 0; c < 64; ++c) { xv[c] = yb[(size_t)c * HW]; mu += xv[c]; }
  mu *= (1.f / 64.f);
  float var = 0.f;
#pragma unroll
  for (int c = 0; c < 64; ++c) { float d = xv[c] - mu; var += d * d; }
  var *= (1.f / 64.f);
  float rsv = rsqrtf(var + 1e-5f);
#pragma unroll
  for (int c = 0; c < 64; ++c) xv[c] = (xv[c] - mu) * rsv * ln2_w[c] + ln2_b[c];
  float* Tp = T + (size_t)(b * 256) * T_PLANE + rl * 256 + col;
  for (int o = 0; o < 256; ++o) {
    float s = 0.f;
#pragma unroll
    for (int c = 0; c < 64; ++c) s += ffn_in_w[o * 64 + c] * xv[c];
    Tp[(size_t)o * T_PLANE] = s;
  }
}

// ---------------- K6: dwconv3/dwconv5 + gelu*mul + ffn_out for one strip ----------------
__global__ __launch_bounds__(256) void k6_dwffn(
    const float* __restrict__ dw3_w, const float* __restrict__ dw5_w,
    const float* __restrict__ ffn_out_w, const float* __restrict__ T,
    const float* __restrict__ flag, float* __restrict__ dout, float* __restrict__ Zs, int rs)
{
  const int tid = threadIdx.x;
  const int p = blockIdx.x * 256 + tid;   // 128 blocks * 256 = 32768 = 4b * 32rows * 256
  const int b = p >> 13;
  const int rem = p & 8191;
  const int r = rem >> 8, col = rem & 255;
  const int row = rs + r;
  const int hw = row * 256 + col;
  const int rl = r + 2;
  const float flg = flag[0];
  const float* Tb = T + (size_t)b * 256 * T_PLANE;
  bool oky[5], okx[5];
#pragma unroll
  for (int d = 0; d < 5; ++d) {
    oky[d] = ((unsigned)(row + d - 2) < 256u);
    okx[d] = ((unsigned)(col + d - 2) < 256u);
  }
  float z[64];
#pragma unroll
  for (int o = 0; o < 64; ++o) z[o] = 0.f;
  for (int j = 0; j < 128; ++j) {
    const float* pl = Tb + (size_t)j * T_PLANE;
    float a = 0.f;
#pragma unroll
    for (int dy = -1; dy <= 1; ++dy) {
      if (!oky[dy + 2]) continue;
#pragma unroll
      for (int dx = -1; dx <= 1; ++dx) {
        if (!okx[dx + 2]) continue;
        a += pl[(rl + dy) * 256 + col + dx] * dw3_w[j * 9 + (dy + 1) * 3 + (dx + 1)];
      }
    }
    const float* pm = Tb + (size_t)(128 + j) * T_PLANE;
    float m = 0.f;
    if (j < 64) {
#pragma unroll
      for (int dy = -1; dy <= 1; ++dy) {
        if (!oky[dy + 2]) continue;
#pragma unroll
        for (int dx = -1; dx <= 1; ++dx) {
          if (!okx[dx + 2]) continue;
          m += pm[(rl + dy) * 256 + col + dx] * dw3_w[(128 + j) * 9 + (dy + 1) * 3 + (dx + 1)];
        }
      }
    } else {
#pragma unroll
      for (int dy = -2; dy <= 2; ++dy) {
        if (!oky[dy + 2]) continue;
#pragma unroll
        for (int dx = -2; dx <= 2; ++dx) {
          if (!okx[dx + 2]) continue;
          m += pm[(rl + dy) * 256 + col + dx] * dw5_w[(j - 64) * 25 + (dy + 2) * 5 + (dx + 2)];
        }
      }
    }
    float gl = 0.5f * a * (1.f + erff(a * 0.70710678118654752f));
    float yv = gl * m;
#pragma unroll
    for (int o = 0; o < 64; ++o) z[o] += ffn_out_w[o * 128 + j] * yv;
  }
  if (flg > 0.5f) {
    float* ob = dout + (size_t)b * 64 * HW + hw;
#pragma unroll
    for (int o = 0; o < 64; ++o) ob[(size_t)o * HW] += z[o];
  } else {
    float* zb = Zs + ((size_t)(b * 64) * 32 + r) * 256 + col;
#pragma unroll
    for (int o = 0; o < 64; ++o) zb[(size_t)o * 8192] = z[o];
  }
}

// ---------------- K7: general fft path — per-patch 8x8 circular conv (early-exit if identity) ----------------
__global__ __launch_bounds__(256) void k7_fft(
    const float* __restrict__ fftw, const float* __restrict__ flag,
    const float* __restrict__ Zs, float* __restrict__ dout, int rs)
{
  if (flag[0] > 0.5f) return;
  __shared__ float swv[64];
  __shared__ float spatch[4][64];
  const int tid = threadIdx.x;
  const int bc = blockIdx.x >> 5;       // b*64+ch  (0..255)
  const int pblk = blockIdx.x & 31;     // 32 blocks per plane-strip, 4 patches each
  const int c = bc & 63;
  if (tid < 64) swv[tid] = fftw[c * 64 + tid];
  const int lp = tid >> 6, e = tid & 63;
  const int patch = pblk * 4 + lp;      // 0..127 within strip
  const int prow = patch >> 5, pcol = patch & 31;
  const int i = e >> 3, jj = e & 7;
  const int zr = prow * 8 + i;          // row within strip (0..31)
  const float zv = Zs[((size_t)bc * 32 + zr) * 256 + pcol * 8 + jj];
  spatch[lp][e] = zv;
  __syncthreads();
  float s = 0.f;
#pragma unroll
  for (int a = 0; a < 8; ++a)
#pragma unroll
    for (int b2 = 0; b2 < 8; ++b2)
      s += swv[a * 8 + b2] * spatch[lp][((i - a) & 7) * 8 + ((jj - b2) & 7)];
  dout[(size_t)bc * HW + (rs + zr) * 256 + pcol * 8 + jj] += s;
}

extern "C" void kernel_launch(void* const* d_in, const int* in_sizes, int n_in,
                              void* d_out, int out_size, void* d_ws, size_t ws_size,
                              hipStream_t stream) {
  const float* x          = (const float*)d_in[0];
  const float* ln1_w      = (const float*)d_in[1];
  const float* ln1_b      = (const float*)d_in[2];
  const float* in_proj_w  = (const float*)d_in[3];
  const float* qkv_w      = (const float*)d_in[4];
  const float* qkv_dw     = (const float*)d_in[5];
  const float* out_proj_w = (const float*)d_in[6];
  const float* temperature= (const float*)d_in[7];
  const float* attn_scales= (const float*)d_in[8];
  const float* gate_w1    = (const float*)d_in[9];
  const float* gate_b1    = (const float*)d_in[10];
  const float* gate_w2    = (const float*)d_in[11];
  const float* gate_b2    = (const float*)d_in[12];
  const float* lgce_pre_w = (const float*)d_in[13];
  const float* lgce_pre_b = (const float*)d_in[14];
  const float* lgce_post_w= (const float*)d_in[15];
  const float* lgce_post_b= (const float*)d_in[16];
  const float* cbam_m1w   = (const float*)d_in[17];
  const float* cbam_m1b   = (const float*)d_in[18];
  const float* cbam_m2w   = (const float*)d_in[19];
  const float* cbam_m2b   = (const float*)d_in[20];
  const float* cbam_spw   = (const float*)d_in[21];
  const float* cbam_spb   = (const float*)d_in[22];
  const float* ln2_w      = (const float*)d_in[23];
  const float* ln2_b      = (const float*)d_in[24];
  const float* ffn_in_w   = (const float*)d_in[25];
  const float* dw3_w      = (const float*)d_in[26];
  const float* dw5_w      = (const float*)d_in[27];
  const float* ffn_out_w  = (const float*)d_in[28];
  const float* fft_W      = (const float*)d_in[29];
  float* ws = (float*)d_ws;
  float* out = (float*)d_out;

  hipLaunchKernelGGL(k0_setup, dim3(1), dim3(256), 0, stream, fft_W, ws);
  hipLaunchKernelGGL(k1_proj, dim3(1024), dim3(256), 0, stream,
                     x, ln1_w, ln1_b, in_proj_w, qkv_w, lgce_pre_w, lgce_pre_b,
                     gate_w1, gate_b1, gate_w2, gate_b2,
                     out, ws + OFF_QKVL, ws + OFF_POOL, ws + OFF_GSUM);
  hipLaunchKernelGGL(k2_gram, dim3(1024), dim3(256), 0, stream,
                     ws + OFF_QKVL, qkv_dw, ws + OFF_GRAM);
  hipLaunchKernelGGL(k3_final, dim3(1), dim3(256), 0, stream,
                     cbam_m1w, cbam_m1b, cbam_m2w, cbam_m2b, temperature, attn_scales,
                     ws + OFF_GSUM, ws + OFF_POOL, ws + OFF_GRAM, ws + OFF_A, ws + OFF_CW);
  hipLaunchKernelGGL(k4a_thr, dim3(1024), dim3(256), 0, stream,
                     lgce_pre_w, lgce_pre_b, cbam_spw, cbam_spb, ws + OFF_CW, out, ws + OFF_THR);
  hipLaunchKernelGGL(k4b_fuse, dim3(1024), dim3(256), 0, stream,
                     x, lgce_pre_w, lgce_pre_b, lgce_post_w, lgce_post_b, out_proj_w,
                     cbam_spw, cbam_spb, qkv_dw, ws + OFF_QKVL,
                     ws + OFF_A, ws + OFF_CW, ws + OFF_THR, out);

  // MFFN: 8 strips of 32 rows, double-buffered T; k5(s+1) must precede k6(s)
  const int NS = 8;
  float* Tb[2] = { ws + OFF_T0, ws + OFF_T1 };
  hipLaunchKernelGGL(k5_ffnin, dim3(144), dim3(256), 0, stream,
                     ln2_w, ln2_b, ffn_in_w, out, Tb[0], 0);
  for (int s = 0; s < NS; ++s) {
    if (s + 1 < NS)
      hipLaunchKernelGGL(k5_ffnin, dim3(144), dim3(256), 0, stream,
                         ln2_w, ln2_b, ffn_in_w, out, Tb[(s + 1) & 1], (s + 1) * 32);
    hipLaunchKernelGGL(k6_dwffn, dim3(128), dim3(256), 0, stream,
                       dw3_w, dw5_w, ffn_out_w, Tb[s & 1], ws + OFF_FLAG, out, ws + OFF_Z, s * 32);
    hipLaunchKernelGGL(k7_fft, dim3(8192), dim3(256), 0, stream,
                       ws + OFF_FFTW, ws + OFF_FLAG, ws + OFF_Z, out, s * 32);
  }
}

// Round 3
// 2029.646 us; speedup vs baseline: 3.1506x; 3.1506x over previous
//
#include <hip/hip_runtime.h>
#include <hip/hip_bf16.h>
#include <math.h>

#define HW 65536
#define NPIX 262144

// ---- workspace layout (float offsets) ----
#define OFF_FFTW 0            // 64x64 spatial fft kernel
#define OFF_FLAG 4096         // 1
#define OFF_GSUM 4097         // 1   (zeroed in k0)
#define OFF_POOL 4098         // 128 (zeroed in k0)
#define OFF_GRAM 4226         // 1280 (zeroed in k0)
#define OFF_THR  5506         // 32  (zeroed in k0)
#define OFF_A    5538         // 1024
#define OFF_CW   6562         // 128
#define OFF_QKVL 8192         // 96ch * 65536 floats (end 100.7 MB) — SGSA phase
// MFFN phase (per-batch buffers, overlap QKVL which is dead by then):
#define OFF_T    8192                      // 256ch * 65536 fp32 = 16777216 floats
#define OFF_Y    (OFF_T + 16777216)        // 128ch * 65536 bf16 = 4194304 float-slots
#define OFF_Z    (OFF_Y + 4194304)         // 64ch * 65536 fp32 = 4194304 floats
// peak ws usage = 25174016 floats = 100.7 MB (same as round-1 proven footprint)

__device__ __forceinline__ float sigm(float v) { return 1.f / (1.f + expf(-v)); }
__device__ __forceinline__ float wredsum(float v) {
#pragma unroll
  for (int off = 32; off >= 1; off >>= 1) v += __shfl_xor(v, off);
  return v;
}

// ---------------- K0: zero accumulators + fft spatial kernel + identity flag ----------------
__global__ __launch_bounds__(256) void k0_setup(
    const float* __restrict__ fft_W, float* __restrict__ ws)
{
  __shared__ float ct8[8];
  const int tid = threadIdx.x;
  if (tid < 8) ct8[tid] = cosf((float)tid * 0.78539816339744831f); // cos(k*pi/4)
  for (int i = tid; i < 1441; i += 256) ws[OFF_GSUM + i] = 0.f;    // gsum,pool,gram,thr
  __syncthreads();
  for (int i = tid; i < 64 * 64; i += 256) {
    int ch = i >> 6, ab = i & 63;
    int a = ab >> 3, b2 = ab & 7;
    float s = 0.f;
    for (int u = 0; u < 8; ++u)
      for (int v = 0; v < 8; ++v) {
        float Wf;
        if (v == 0 || v == 4)
          Wf = 0.5f * (fft_W[ch * 40 + u * 5 + v] + fft_W[ch * 40 + ((8 - u) & 7) * 5 + v]);
        else if (v < 5)
          Wf = fft_W[ch * 40 + u * 5 + v];
        else
          Wf = fft_W[ch * 40 + ((8 - u) & 7) * 5 + (8 - v)];
        s += Wf * ct8[(u * a + v * b2) & 7];
      }
    ws[OFF_FFTW + i] = s * (1.f / 64.f);
  }
  __syncthreads();
  if (tid == 0) {
    float ok = 1.f;
    for (int i2 = 0; i2 < 4096; ++i2) {
      float expect = ((i2 & 63) == 0) ? 1.f : 0.f;
      if (fabsf(ws[OFF_FFTW + i2] - expect) > 1e-4f) { ok = 0.f; break; }
    }
    ws[OFF_FLAG] = ok;
  }
}

// ---------------- K1: LN1 + in_proj(loc->dout[0..31], glob) + qkv + pooled/gate ----------------
__global__ __launch_bounds__(256) void k1_proj(
    const float* __restrict__ x, const float* __restrict__ ln1_w, const float* __restrict__ ln1_b,
    const float* __restrict__ in_proj_w, const float* __restrict__ qkv_w,
    const float* __restrict__ pre_w, const float* __restrict__ pre_b,
    const float* __restrict__ g1w, const float* __restrict__ g1b,
    const float* __restrict__ g2w, const float* __restrict__ g2b,
    float* __restrict__ dout, float* __restrict__ qkvl,
    float* __restrict__ pooled, float* __restrict__ gsum)
{
  __shared__ float sPool[4][32];
  __shared__ float sRed[4];
  const int tid = threadIdx.x;
  const int p = blockIdx.x * 256 + tid;
  const int b = p >> 16;
  const int hw = p & (HW - 1);
  const int wave = tid >> 6, lane = tid & 63;
  const float* xb = x + (size_t)(b * 64) * HW + hw;
  float xv[64];
  float mu = 0.f;
#pragma unroll
  for (int c = 0; c < 64; ++c) { xv[c] = xb[(size_t)c * HW]; mu += xv[c]; }
  mu *= (1.f / 64.f);
  float var = 0.f;
#pragma unroll
  for (int c = 0; c < 64; ++c) { float d = xv[c] - mu; var += d * d; }
  var *= (1.f / 64.f);
  const float rs = rsqrtf(var + 1e-5f);
#pragma unroll
  for (int c = 0; c < 64; ++c) xv[c] = (xv[c] - mu) * rs * ln1_w[c] + ln1_b[c];

  float loc[32];
  for (int o = 0; o < 32; ++o) {
    float s = 0.f;
#pragma unroll
    for (int c = 0; c < 64; ++c) s += in_proj_w[o * 64 + c] * xv[c];
    loc[o] = s;
    dout[(size_t)(b * 64 + o) * HW + hw] = s;
  }
  for (int o = 0; o < 32; ++o) {
    float s = pre_b[o];
#pragma unroll
    for (int j = 0; j < 32; ++j) s += pre_w[o * 32 + j] * loc[j];
    float r = wredsum(s);
    if (lane == 0) sPool[wave][o] = r;
  }
  float gl[32];
  for (int o = 0; o < 32; ++o) {
    float s = 0.f;
#pragma unroll
    for (int c = 0; c < 64; ++c) s += in_proj_w[(32 + o) * 64 + c] * xv[c];
    gl[o] = s;
  }
  for (int o = 0; o < 96; ++o) {
    float s = 0.f;
#pragma unroll
    for (int j = 0; j < 32; ++j) s += qkv_w[o * 32 + j] * gl[j];
    qkvl[(size_t)(b * 96 + o) * HW + hw] = s;
  }
  float gacc = g2b[0];
  for (int o = 0; o < 16; ++o) {
    float h = g1b[o];
#pragma unroll
    for (int j = 0; j < 32; ++j) h += g1w[o * 32 + j] * gl[j];
    gacc += g2w[o] * fmaxf(h, 0.f);
  }
  float gv = wredsum(sigm(gacc));
  if (lane == 0) sRed[wave] = gv;
  __syncthreads();
  if (tid == 0) atomicAdd(gsum, sRed[0] + sRed[1] + sRed[2] + sRed[3]);
  if (tid < 32) {
    float s = sPool[0][tid] + sPool[1][tid] + sPool[2][tid] + sPool[3][tid];
    atomicAdd(&pooled[b * 32 + tid], s);
  }
}

// ---------------- K2: dwconv(q,k) + Gram/norm reductions (no q/k stores) ----------------
__global__ __launch_bounds__(256) void k2_gram(
    const float* __restrict__ qkvl, const float* __restrict__ qkv_dw, float* __restrict__ gram)
{
  __shared__ float sg[320];
  const int tid = threadIdx.x;
  const int p = blockIdx.x * 256 + tid;
  const int b = p >> 16, hw = p & (HW - 1);
  const int y = hw >> 8, xx = hw & 255;
  for (int i = tid; i < 320; i += 256) sg[i] = 0.f;
  __syncthreads();
  int offs[9]; bool ok[9];
#pragma unroll
  for (int dy = -1; dy <= 1; ++dy)
#pragma unroll
    for (int dx = -1; dx <= 1; ++dx) {
      int i = (dy + 1) * 3 + (dx + 1);
      int yy = y + dy, x2 = xx + dx;
      ok[i] = ((unsigned)yy < 256u) && ((unsigned)x2 < 256u);
      offs[i] = yy * 256 + x2;
    }
  const float* base = qkvl + (size_t)b * 96 * HW;
  float qv[32], kv[32];
  for (int ch = 0; ch < 32; ++ch) {
    const float* plane = base + (size_t)ch * HW;
    float acc = 0.f;
#pragma unroll
    for (int i = 0; i < 9; ++i) if (ok[i]) acc += plane[offs[i]] * qkv_dw[ch * 9 + i];
    qv[ch] = acc;
  }
  for (int ch = 0; ch < 32; ++ch) {
    const float* plane = base + (size_t)(32 + ch) * HW;
    float acc = 0.f;
#pragma unroll
    for (int i = 0; i < 9; ++i) if (ok[i]) acc += plane[offs[i]] * qkv_dw[(32 + ch) * 9 + i];
    kv[ch] = acc;
  }
  const int lane = tid & 63;
  for (int h = 0; h < 4; ++h) {
#pragma unroll
    for (int c = 0; c < 8; ++c) {
#pragma unroll
      for (int d = 0; d < 8; ++d) {
        float v = wredsum(qv[h * 8 + c] * kv[h * 8 + d]);
        if (lane == 0) atomicAdd(&sg[h * 80 + c * 8 + d], v);
      }
    }
#pragma unroll
    for (int c = 0; c < 8; ++c) {
      float v = wredsum(qv[h * 8 + c] * qv[h * 8 + c]);
      if (lane == 0) atomicAdd(&sg[h * 80 + 64 + c], v);
      float w = wredsum(kv[h * 8 + c] * kv[h * 8 + c]);
      if (lane == 0) atomicAdd(&sg[h * 80 + 72 + c], w);
    }
  }
  __syncthreads();
  for (int i = tid; i < 320; i += 256) atomicAdd(&gram[b * 320 + i], sg[i]);
}

// ---------------- K3: dk, CBAM channel weights, attention matrices ----------------
__global__ __launch_bounds__(256) void k3_final(
    const float* __restrict__ m1w, const float* __restrict__ m1b,
    const float* __restrict__ m2w, const float* __restrict__ m2b,
    const float* __restrict__ temperature, const float* __restrict__ attn_scales,
    const float* __restrict__ gsum, const float* __restrict__ pooled,
    const float* __restrict__ gram, float* __restrict__ Abuf, float* __restrict__ cwbuf)
{
  __shared__ int s_dk;
  __shared__ float s_scale;
  const int tid = threadIdx.x;
  if (tid == 0) {
    float gmean = gsum[0] / (float)NPIX;
    int dk = (int)floorf(8.f * gmean);
    if (dk < 1) dk = 1;
    if (dk > 8) dk = 8;
    s_dk = dk;
    s_scale = attn_scales[0] + attn_scales[1] + attn_scales[2] + attn_scales[3];
  }
  __syncthreads();
  if (tid < 128) {
    int b = tid >> 5, ch = tid & 31, g = ch >> 2, c = ch & 3;
    float h1 = m1b[g];
#pragma unroll
    for (int cc = 0; cc < 4; ++cc)
      h1 += (pooled[b * 32 + g * 4 + cc] * (1.f / 65536.f)) * m1w[g * 4 + cc];
    h1 = fmaxf(h1, 0.f);
    cwbuf[tid] = sigm(h1 * m2w[g * 4 + c] + m2b[g * 4 + c]);

    int r = tid, h = (r >> 3) & 3, c8 = r & 7;
    const float* gm = gram + (b * 4 + h) * 80;
    float qn = fmaxf(sqrtf(gm[64 + c8]), 1e-12f);
    float temp = temperature[h];
    float a[8];
#pragma unroll
    for (int d = 0; d < 8; ++d) {
      float kn = fmaxf(sqrtf(gm[72 + d]), 1e-12f);
      a[d] = gm[c8 * 8 + d] / (qn * kn) * temp;
    }
    float t[8];
#pragma unroll
    for (int d = 0; d < 8; ++d) t[d] = a[d];
#pragma unroll
    for (int i = 0; i < 8; ++i)
#pragma unroll
      for (int j = 0; j < 8; ++j)
        if (j > i && t[j] > t[i]) { float tmp = t[i]; t[i] = t[j]; t[j] = tmp; }
    float kth = t[s_dk - 1];
    float mx = t[0];
    float e[8]; float sum = 0.f;
#pragma unroll
    for (int d = 0; d < 8; ++d) {
      e[d] = (a[d] >= kth) ? expf(a[d] - mx) : 0.f;
      sum += e[d];
    }
    float inv = s_scale / sum;
#pragma unroll
    for (int d = 0; d < 8; ++d) Abuf[r * 8 + d] = e[d] * inv;
  }
}

// ---------------- K4a: resp-mean (threshold) reduction; PRE recomputed from LOC ----------------
__global__ __launch_bounds__(256) void k4a_thr(
    const float* __restrict__ pre_w, const float* __restrict__ pre_b,
    const float* __restrict__ spw, const float* __restrict__ spb,
    const float* __restrict__ cwbuf, const float* __restrict__ dout, float* __restrict__ thrbuf)
{
  const int tid = threadIdx.x;
  const int p = blockIdx.x * 256 + tid;
  const int b = p >> 16, hw = p & (HW - 1);
  const float* LOCp = dout + (size_t)b * 64 * HW + hw;
  const float* cw = cwbuf + b * 32;
  float loc[32];
#pragma unroll
  for (int c = 0; c < 32; ++c) loc[c] = LOCp[(size_t)c * HW];
  float pre[32];
  for (int o = 0; o < 32; ++o) {
    float s = pre_b[o];
#pragma unroll
    for (int j = 0; j < 32; ++j) s += pre_w[o * 32 + j] * loc[j];
    pre[o] = s;
  }
  const int lane = tid & 63;
#pragma unroll
  for (int g = 0; g < 8; ++g) {
    float xa[4];
    float sdot = spb[g];
#pragma unroll
    for (int c = 0; c < 4; ++c) {
      xa[c] = pre[g * 4 + c] * cw[g * 4 + c];
      sdot += xa[c] * spw[g * 4 + c];
    }
    float sgv = sigm(sdot);
    float r = 0.f;
#pragma unroll
    for (int c = 0; c < 4; ++c) r += sigm(xa[c] * sgv);
    float v = wredsum(r);
    if (lane == 0) atomicAdd(&thrbuf[b * 8 + g], v);
  }
}

// ---------------- K4b: LGCE finish + V-dwconv + attn + out_proj + residual -> dout ----------------
__global__ __launch_bounds__(256) void k4b_fuse(
    const float* __restrict__ x, const float* __restrict__ pre_w, const float* __restrict__ pre_b,
    const float* __restrict__ post_w, const float* __restrict__ post_b,
    const float* __restrict__ out_proj_w, const float* __restrict__ spw, const float* __restrict__ spb,
    const float* __restrict__ qkv_dw, const float* __restrict__ qkvl,
    const float* __restrict__ Abuf, const float* __restrict__ cwbuf, const float* __restrict__ thrbuf,
    float* dout)
{
  const int tid = threadIdx.x;
  const int p = blockIdx.x * 256 + tid;
  const int b = p >> 16, hw = p & (HW - 1);
  const int y = hw >> 8, xx = hw & 255;
  const float* cw = cwbuf + b * 32;
  const float* A = Abuf + b * 256;
  float* doutb = dout + (size_t)b * 64 * HW + hw;
  float loc[32];
#pragma unroll
  for (int c = 0; c < 32; ++c) loc[c] = doutb[(size_t)c * HW];
  float pre[32];
  for (int o = 0; o < 32; ++o) {
    float s = pre_b[o];
#pragma unroll
    for (int j = 0; j < 32; ++j) s += pre_w[o * 32 + j] * loc[j];
    pre[o] = s;
  }
  float mx[32];
#pragma unroll
  for (int g = 0; g < 8; ++g) {
    float xa[4];
    float sdot = spb[g];
#pragma unroll
    for (int c = 0; c < 4; ++c) {
      xa[c] = pre[g * 4 + c] * cw[g * 4 + c];
      sdot += xa[c] * spw[g * 4 + c];
    }
    float sgv = sigm(sdot);
    float thr = thrbuf[b * 8 + g] * (1.f / (4.f * 65536.f));
#pragma unroll
    for (int c = 0; c < 4; ++c) {
      float resp = sigm(xa[c] * sgv);
      float m = (resp > thr) ? 1.f : resp;
      mx[g * 4 + c] = pre[g * 4 + c] * m;
    }
  }
  int offs[9]; bool okn[9];
#pragma unroll
  for (int dy = -1; dy <= 1; ++dy)
#pragma unroll
    for (int dx = -1; dx <= 1; ++dx) {
      int i = (dy + 1) * 3 + (dx + 1);
      int yy = y + dy, x2 = xx + dx;
      okn[i] = ((unsigned)yy < 256u) && ((unsigned)x2 < 256u);
      offs[i] = yy * 256 + x2;
    }
  const float* vbase = qkvl + (size_t)(b * 96 + 64) * HW;
  float vv[32];
  for (int ch = 0; ch < 32; ++ch) {
    const float* plane = vbase + (size_t)ch * HW;
    float acc = 0.f;
#pragma unroll
    for (int i = 0; i < 9; ++i) if (okn[i]) acc += plane[offs[i]] * qkv_dw[(64 + ch) * 9 + i];
    vv[ch] = acc;
  }
  float fused[64];
#pragma unroll
  for (int j = 0; j < 32; ++j) {
    int h = j >> 3, c = j & 7;
    float s = 0.f;
#pragma unroll
    for (int d = 0; d < 8; ++d) s += A[(h * 8 + c) * 8 + d] * vv[h * 8 + d];
    fused[j] = s;
  }
  for (int o = 0; o < 32; ++o) {
    float s = post_b[o];
#pragma unroll
    for (int j = 0; j < 32; ++j) s += post_w[o * 32 + j] * mx[j];
    fused[32 + o] = s + loc[o];
  }
  const float* xb = x + (size_t)b * 64 * HW + hw;
  for (int o = 0; o < 64; ++o) {
    float s = 0.f;
#pragma unroll
    for (int j = 0; j < 64; ++j) s += out_proj_w[o * 64 + j] * fused[j];
    doutb[(size_t)o * HW] = s + xb[(size_t)o * HW];
  }
}

// ---------------- K5: LN2 + ffn_in (64->256), one batch, o-chunked ----------------
__global__ __launch_bounds__(256) void k5_ffnin(
    const float* __restrict__ ln2_w, const float* __restrict__ ln2_b,
    const float* __restrict__ ffn_in_w, const float* __restrict__ dout,
    float* __restrict__ T, int b)
{
  __shared__ float sW[4096];   // 64 out rows x 64
  const int tid = threadIdx.x;
  const int obase = blockIdx.y * 64;
  for (int i = tid; i < 4096; i += 256) sW[i] = ffn_in_w[obase * 64 + i];
  const int px = blockIdx.x * 256 + tid;
  const float* yb = dout + (size_t)b * 64 * HW + px;
  float xv[64];
  float mu = 0.f;
#pragma unroll
  for (int c = 0; c < 64; ++c) { xv[c] = yb[(size_t)c * HW]; mu += xv[c]; }
  mu *= (1.f / 64.f);
  float var = 0.f;
#pragma unroll
  for (int c = 0; c < 64; ++c) { float d = xv[c] - mu; var += d * d; }
  var *= (1.f / 64.f);
  float rsv = rsqrtf(var + 1e-5f);
#pragma unroll
  for (int c = 0; c < 64; ++c) xv[c] = (xv[c] - mu) * rsv * ln2_w[c] + ln2_b[c];
  __syncthreads();
  float* Tp = T + (size_t)obase * HW + px;
  for (int o = 0; o < 64; ++o) {
    float s = 0.f;
#pragma unroll
    for (int c = 0; c < 64; ++c) s += sW[o * 64 + c] * xv[c];
    Tp[(size_t)o * HW] = s;
  }
}

// ---------------- K6a: dwconv3/dwconv5 + gelu*mul -> Y (bf16), one batch, j-chunked ----------------
__global__ __launch_bounds__(256) void k6a_dw(
    const float* __restrict__ dw3_w, const float* __restrict__ dw5_w,
    const float* __restrict__ T, __hip_bfloat16* __restrict__ Y)
{
  const int tid = threadIdx.x;
  const int px = blockIdx.x * 256 + tid;
  const int j0 = blockIdx.y * 8;
  const int row = px >> 8, col = px & 255;
  bool oky[5], okx[5];
#pragma unroll
  for (int d = 0; d < 5; ++d) {
    oky[d] = ((unsigned)(row + d - 2) < 256u);
    okx[d] = ((unsigned)(col + d - 2) < 256u);
  }
#pragma unroll
  for (int jj = 0; jj < 8; ++jj) {
    const int j = j0 + jj;
    const float* pl = T + (size_t)j * HW;
    float a = 0.f;
#pragma unroll
    for (int dy = -1; dy <= 1; ++dy) {
      if (!oky[dy + 2]) continue;
#pragma unroll
      for (int dx = -1; dx <= 1; ++dx) {
        if (!okx[dx + 2]) continue;
        a += pl[px + dy * 256 + dx] * dw3_w[j * 9 + (dy + 1) * 3 + (dx + 1)];
      }
    }
    float m = 0.f;
    if (j < 64) {
      const float* pm = T + (size_t)(128 + j) * HW;
#pragma unroll
      for (int dy = -1; dy <= 1; ++dy) {
        if (!oky[dy + 2]) continue;
#pragma unroll
        for (int dx = -1; dx <= 1; ++dx) {
          if (!okx[dx + 2]) continue;
          m += pm[px + dy * 256 + dx] * dw3_w[(128 + j) * 9 + (dy + 1) * 3 + (dx + 1)];
        }
      }
    } else {
      const float* pm = T + (size_t)(128 + j) * HW;   // 128+j in [192,255]
#pragma unroll
      for (int dy = -2; dy <= 2; ++dy) {
        if (!oky[dy + 2]) continue;
#pragma unroll
        for (int dx = -2; dx <= 2; ++dx) {
          if (!okx[dx + 2]) continue;
          m += pm[px + dy * 256 + dx] * dw5_w[(j - 64) * 25 + (dy + 2) * 5 + (dx + 2)];
        }
      }
    }
    float gl = 0.5f * a * (1.f + erff(a * 0.70710678118654752f));
    Y[(size_t)j * HW + px] = __float2bfloat16(gl * m);
  }
}

// ---------------- K6b: ffn_out (128->64) from Y, one batch, o-chunked ----------------
__global__ __launch_bounds__(256) void k6b_out(
    const float* __restrict__ ffn_out_w, const __hip_bfloat16* __restrict__ Y,
    const float* __restrict__ flag, float* __restrict__ dout, float* __restrict__ Z, int b)
{
  __shared__ float sW[2048];   // 16 out rows x 128
  const int tid = threadIdx.x;
  const int o0 = blockIdx.y * 16;
  for (int i = tid; i < 2048; i += 256) sW[i] = ffn_out_w[o0 * 128 + i];
  __syncthreads();
  const int px = blockIdx.x * 256 + tid;
  float z[16];
#pragma unroll
  for (int o = 0; o < 16; ++o) z[o] = 0.f;
  for (int j = 0; j < 128; ++j) {
    float yv = __bfloat162float(Y[(size_t)j * HW + px]);
#pragma unroll
    for (int o = 0; o < 16; ++o) z[o] += sW[o * 128 + j] * yv;
  }
  if (flag[0] > 0.5f) {
    float* ob = dout + (size_t)(b * 64 + o0) * HW + px;
#pragma unroll
    for (int o = 0; o < 16; ++o) ob[(size_t)o * HW] += z[o];
  } else {
    float* zb = Z + (size_t)o0 * HW + px;
#pragma unroll
    for (int o = 0; o < 16; ++o) zb[(size_t)o * HW] = z[o];
  }
}

// ---------------- K7: general fft path — per-patch 8x8 circular conv (early-exit if identity) ----------------
__global__ __launch_bounds__(256) void k7_fft(
    const float* __restrict__ fftw, const float* __restrict__ flag,
    const float* __restrict__ Z, float* __restrict__ dout, int b)
{
  if (flag[0] > 0.5f) return;
  __shared__ float swv[64];
  __shared__ float spatch[4][64];
  const int tid = threadIdx.x;
  const int c = blockIdx.x >> 8;        // channel 0..63
  const int pblk = blockIdx.x & 255;    // 256 patch-groups per plane, 4 patches each
  if (tid < 64) swv[tid] = fftw[c * 64 + tid];
  const int lp = tid >> 6, e = tid & 63;
  const int patch = pblk * 4 + lp;      // 0..1023
  const int pi = patch >> 5, pj = patch & 31;
  const int i = e >> 3, jj = e & 7;
  const int gidx = (pi * 8 + i) * 256 + pj * 8 + jj;
  const float zv = Z[(size_t)c * HW + gidx];
  spatch[lp][e] = zv;
  __syncthreads();
  float s = 0.f;
#pragma unroll
  for (int a = 0; a < 8; ++a)
#pragma unroll
    for (int b2 = 0; b2 < 8; ++b2)
      s += swv[a * 8 + b2] * spatch[lp][((i - a) & 7) * 8 + ((jj - b2) & 7)];
  dout[(size_t)(b * 64 + c) * HW + gidx] += s;
}

extern "C" void kernel_launch(void* const* d_in, const int* in_sizes, int n_in,
                              void* d_out, int out_size, void* d_ws, size_t ws_size,
                              hipStream_t stream) {
  const float* x          = (const float*)d_in[0];
  const float* ln1_w      = (const float*)d_in[1];
  const float* ln1_b      = (const float*)d_in[2];
  const float* in_proj_w  = (const float*)d_in[3];
  const float* qkv_w      = (const float*)d_in[4];
  const float* qkv_dw     = (const float*)d_in[5];
  const float* out_proj_w = (const float*)d_in[6];
  const float* temperature= (const float*)d_in[7];
  const float* attn_scales= (const float*)d_in[8];
  const float* gate_w1    = (const float*)d_in[9];
  const float* gate_b1    = (const float*)d_in[10];
  const float* gate_w2    = (const float*)d_in[11];
  const float* gate_b2    = (const float*)d_in[12];
  const float* lgce_pre_w = (const float*)d_in[13];
  const float* lgce_pre_b = (const float*)d_in[14];
  const float* lgce_post_w= (const float*)d_in[15];
  const float* lgce_post_b= (const float*)d_in[16];
  const float* cbam_m1w   = (const float*)d_in[17];
  const float* cbam_m1b   = (const float*)d_in[18];
  const float* cbam_m2w   = (const float*)d_in[19];
  const float* cbam_m2b   = (const float*)d_in[20];
  const float* cbam_spw   = (const float*)d_in[21];
  const float* cbam_spb   = (const float*)d_in[22];
  const float* ln2_w      = (const float*)d_in[23];
  const float* ln2_b      = (const float*)d_in[24];
  const float* ffn_in_w   = (const float*)d_in[25];
  const float* dw3_w      = (const float*)d_in[26];
  const float* dw5_w      = (const float*)d_in[27];
  const float* ffn_out_w  = (const float*)d_in[28];
  const float* fft_W      = (const float*)d_in[29];
  float* ws = (float*)d_ws;
  float* out = (float*)d_out;

  hipLaunchKernelGGL(k0_setup, dim3(1), dim3(256), 0, stream, fft_W, ws);
  hipLaunchKernelGGL(k1_proj, dim3(1024), dim3(256), 0, stream,
                     x, ln1_w, ln1_b, in_proj_w, qkv_w, lgce_pre_w, lgce_pre_b,
                     gate_w1, gate_b1, gate_w2, gate_b2,
                     out, ws + OFF_QKVL, ws + OFF_POOL, ws + OFF_GSUM);
  hipLaunchKernelGGL(k2_gram, dim3(1024), dim3(256), 0, stream,
                     ws + OFF_QKVL, qkv_dw, ws + OFF_GRAM);
  hipLaunchKernelGGL(k3_final, dim3(1), dim3(256), 0, stream,
                     cbam_m1w, cbam_m1b, cbam_m2w, cbam_m2b, temperature, attn_scales,
                     ws + OFF_GSUM, ws + OFF_POOL, ws + OFF_GRAM, ws + OFF_A, ws + OFF_CW);
  hipLaunchKernelGGL(k4a_thr, dim3(1024), dim3(256), 0, stream,
                     lgce_pre_w, lgce_pre_b, cbam_spw, cbam_spb, ws + OFF_CW, out, ws + OFF_THR);
  hipLaunchKernelGGL(k4b_fuse, dim3(1024), dim3(256), 0, stream,
                     x, lgce_pre_w, lgce_pre_b, lgce_post_w, lgce_post_b, out_proj_w,
                     cbam_spw, cbam_spb, qkv_dw, ws + OFF_QKVL,
                     ws + OFF_A, ws + OFF_CW, ws + OFF_THR, out);

  // MFFN: batch-split, 4 stages per batch (T/Y/Z per-batch buffers)
  __hip_bfloat16* Ybuf = (__hip_bfloat16*)(ws + OFF_Y);
  for (int b = 0; b < 4; ++b) {
    hipLaunchKernelGGL(k5_ffnin, dim3(256, 4), dim3(256), 0, stream,
                       ln2_w, ln2_b, ffn_in_w, out, ws + OFF_T, b);
    hipLaunchKernelGGL(k6a_dw, dim3(256, 16), dim3(256), 0, stream,
                       dw3_w, dw5_w, ws + OFF_T, Ybuf);
    hipLaunchKernelGGL(k6b_out, dim3(256, 4), dim3(256), 0, stream,
                       ffn_out_w, Ybuf, ws + OFF_FLAG, out, ws + OFF_Z, b);
    hipLaunchKernelGGL(k7_fft, dim3(16384), dim3(256), 0, stream,
                       ws + OFF_FFTW, ws + OFF_FLAG, ws + OFF_Z, out, b);
  }
}

// Round 4
// 1904.800 us; speedup vs baseline: 3.3571x; 1.0655x over previous
//
#include <hip/hip_runtime.h>
#include <hip/hip_bf16.h>
#include <math.h>

#define HW 65536
#define NPIX 262144

// ---- workspace layout (float offsets) ----
#define OFF_FFTW 0            // 64x64 spatial fft kernel
#define OFF_FLAG 4096         // 1
#define OFF_GSUM 4097         // 1    (zeroed in k0)
#define OFF_POOL 4098         // 128  (zeroed in k0)
#define OFF_GRAM 4226         // 1280 (zeroed in k0)
#define OFF_THR  5506         // 32   (zeroed in k0)
#define OFF_BAD  5538         // 1    (zeroed in k0)  -- mfma checker flag
#define OFF_A    5539         // 1024
#define OFF_CW   6563         // 128
#define OFF_QKVL 8192         // 96ch * 65536 floats — SGSA phase
// MFFN phase (per-batch buffers, overlap QKVL which is dead by then):
#define OFF_T    8192                      // 256ch * 65536 bf16 (uses half of reserved fp32 extent)
#define OFF_Y    (OFF_T + 16777216)        // 128ch * 65536 bf16
#define OFF_Z    (OFF_Y + 4194304)         // 64ch * 65536 fp32
// peak ws usage = 25174016 floats = 100.7 MB (same proven footprint)

typedef __attribute__((ext_vector_type(8))) short short8v;
typedef __attribute__((ext_vector_type(4))) float f32x4;

__device__ __forceinline__ float sigm(float v) { return 1.f / (1.f + expf(-v)); }
__device__ __forceinline__ float wredsum(float v) {
#pragma unroll
  for (int off = 32; off >= 1; off >>= 1) v += __shfl_xor(v, off);
  return v;
}
__device__ __forceinline__ unsigned short f2bf(float f) {
  union { float f; unsigned u; } x; x.f = f;
  unsigned r = x.u + 0x7fffu + ((x.u >> 16) & 1u);
  return (unsigned short)(r >> 16);
}
__device__ __forceinline__ float bf2f(unsigned short u) {
  union { unsigned u; float f; } x; x.u = ((unsigned)u) << 16;
  return x.f;
}

// ---------------- K0: zero accumulators + fft spatial kernel + identity flag ----------------
__global__ __launch_bounds__(256) void k0_setup(
    const float* __restrict__ fft_W, float* __restrict__ ws)
{
  __shared__ float ct8[8];
  __shared__ int sbad;
  const int tid = threadIdx.x;
  if (tid < 8) ct8[tid] = cosf((float)tid * 0.78539816339744831f); // cos(k*pi/4)
  if (tid == 0) sbad = 0;
  for (int i = tid; i < 1442; i += 256) ws[OFF_GSUM + i] = 0.f;    // gsum,pool,gram,thr,bad
  __syncthreads();
  bool ok = true;
  for (int i = tid; i < 64 * 64; i += 256) {
    int ch = i >> 6, ab = i & 63;
    int a = ab >> 3, b2 = ab & 7;
    float s = 0.f;
    for (int u = 0; u < 8; ++u)
      for (int v = 0; v < 8; ++v) {
        float Wf;
        if (v == 0 || v == 4)
          Wf = 0.5f * (fft_W[ch * 40 + u * 5 + v] + fft_W[ch * 40 + ((8 - u) & 7) * 5 + v]);
        else if (v < 5)
          Wf = fft_W[ch * 40 + u * 5 + v];
        else
          Wf = fft_W[ch * 40 + ((8 - u) & 7) * 5 + (8 - v)];
        s += Wf * ct8[(u * a + v * b2) & 7];
      }
    s *= (1.f / 64.f);
    ws[OFF_FFTW + i] = s;
    float expect = ((i & 63) == 0) ? 1.f : 0.f;
    if (fabsf(s - expect) > 1e-4f) ok = false;
  }
  if (!ok) atomicOr(&sbad, 1);
  __syncthreads();
  if (tid == 0) ws[OFF_FLAG] = sbad ? 0.f : 1.f;
}

// ---------------- K1: LN1 + in_proj(loc->dout[0..31], glob) + qkv + pooled/gate ----------------
__global__ __launch_bounds__(256) void k1_proj(
    const float* __restrict__ x, const float* __restrict__ ln1_w, const float* __restrict__ ln1_b,
    const float* __restrict__ in_proj_w, const float* __restrict__ qkv_w,
    const float* __restrict__ pre_w, const float* __restrict__ pre_b,
    const float* __restrict__ g1w, const float* __restrict__ g1b,
    const float* __restrict__ g2w, const float* __restrict__ g2b,
    float* __restrict__ dout, float* __restrict__ qkvl,
    float* __restrict__ pooled, float* __restrict__ gsum)
{
  __shared__ float sPool[4][32];
  __shared__ float sRed[4];
  const int tid = threadIdx.x;
  const int p = blockIdx.x * 256 + tid;
  const int b = p >> 16;
  const int hw = p & (HW - 1);
  const int wave = tid >> 6, lane = tid & 63;
  const float* xb = x + (size_t)(b * 64) * HW + hw;
  float xv[64];
  float mu = 0.f;
#pragma unroll
  for (int c = 0; c < 64; ++c) { xv[c] = xb[(size_t)c * HW]; mu += xv[c]; }
  mu *= (1.f / 64.f);
  float var = 0.f;
#pragma unroll
  for (int c = 0; c < 64; ++c) { float d = xv[c] - mu; var += d * d; }
  var *= (1.f / 64.f);
  const float rs = rsqrtf(var + 1e-5f);
#pragma unroll
  for (int c = 0; c < 64; ++c) xv[c] = (xv[c] - mu) * rs * ln1_w[c] + ln1_b[c];

  float loc[32];
  for (int o = 0; o < 32; ++o) {
    float s = 0.f;
#pragma unroll
    for (int c = 0; c < 64; ++c) s += in_proj_w[o * 64 + c] * xv[c];
    loc[o] = s;
    dout[(size_t)(b * 64 + o) * HW + hw] = s;
  }
  for (int o = 0; o < 32; ++o) {
    float s = pre_b[o];
#pragma unroll
    for (int j = 0; j < 32; ++j) s += pre_w[o * 32 + j] * loc[j];
    float r = wredsum(s);
    if (lane == 0) sPool[wave][o] = r;
  }
  float gl[32];
  for (int o = 0; o < 32; ++o) {
    float s = 0.f;
#pragma unroll
    for (int c = 0; c < 64; ++c) s += in_proj_w[(32 + o) * 64 + c] * xv[c];
    gl[o] = s;
  }
  for (int o = 0; o < 96; ++o) {
    float s = 0.f;
#pragma unroll
    for (int j = 0; j < 32; ++j) s += qkv_w[o * 32 + j] * gl[j];
    qkvl[(size_t)(b * 96 + o) * HW + hw] = s;
  }
  float gacc = g2b[0];
  for (int o = 0; o < 16; ++o) {
    float h = g1b[o];
#pragma unroll
    for (int j = 0; j < 32; ++j) h += g1w[o * 32 + j] * gl[j];
    gacc += g2w[o] * fmaxf(h, 0.f);
  }
  float gv = wredsum(sigm(gacc));
  if (lane == 0) sRed[wave] = gv;
  __syncthreads();
  if (tid == 0) atomicAdd(gsum, sRed[0] + sRed[1] + sRed[2] + sRed[3]);
  if (tid < 32) {
    float s = sPool[0][tid] + sPool[1][tid] + sPool[2][tid] + sPool[3][tid];
    atomicAdd(&pooled[b * 32 + tid], s);
  }
}

// ---------------- K2: dwconv(q,k) + Gram/norm reductions — one (h,b) per block, 8px/thread ----------------
__global__ __launch_bounds__(256) void k2_gram(
    const float* __restrict__ qkvl, const float* __restrict__ qkv_dw, float* __restrict__ gram)
{
  const int tid = threadIdx.x;
  const int slab = blockIdx.x;        // 0..31  (2048 px each)
  const int h = blockIdx.y;           // 0..3
  const int b = blockIdx.z;           // 0..3
  const float* qbase = qkvl + (size_t)(b * 96 + h * 8) * HW;
  const float* kbase = qkvl + (size_t)(b * 96 + 32 + h * 8) * HW;
  const float* qw = qkv_dw + (h * 8) * 9;
  const float* kw = qkv_dw + (32 + h * 8) * 9;
  float acc[80];
#pragma unroll
  for (int i = 0; i < 80; ++i) acc[i] = 0.f;
  for (int i = 0; i < 8; ++i) {
    const int hw = slab * 2048 + i * 256 + tid;
    const int y = hw >> 8, xx = hw & 255;
    int offs[9]; bool ok[9];
#pragma unroll
    for (int dy = -1; dy <= 1; ++dy)
#pragma unroll
      for (int dx = -1; dx <= 1; ++dx) {
        int t = (dy + 1) * 3 + (dx + 1);
        int yy = y + dy, x2 = xx + dx;
        ok[t] = ((unsigned)yy < 256u) && ((unsigned)x2 < 256u);
        offs[t] = yy * 256 + x2;
      }
    float qv[8], kv[8];
#pragma unroll
    for (int c = 0; c < 8; ++c) {
      const float* plane = qbase + (size_t)c * HW;
      float a = 0.f;
#pragma unroll
      for (int t = 0; t < 9; ++t) if (ok[t]) a += plane[offs[t]] * qw[c * 9 + t];
      qv[c] = a;
    }
#pragma unroll
    for (int c = 0; c < 8; ++c) {
      const float* plane = kbase + (size_t)c * HW;
      float a = 0.f;
#pragma unroll
      for (int t = 0; t < 9; ++t) if (ok[t]) a += plane[offs[t]] * kw[c * 9 + t];
      kv[c] = a;
    }
#pragma unroll
    for (int c = 0; c < 8; ++c) {
#pragma unroll
      for (int d = 0; d < 8; ++d) acc[c * 8 + d] += qv[c] * kv[d];
      acc[64 + c] += qv[c] * qv[c];
      acc[72 + c] += kv[c] * kv[c];
    }
  }
  const int lane = tid & 63;
  float* gm = gram + (b * 4 + h) * 80;
#pragma unroll
  for (int j = 0; j < 80; ++j) {
    float v = wredsum(acc[j]);
    if (lane == 0) atomicAdd(&gm[j], v);
  }
}

// ---------------- K3: dk, CBAM channel weights, attention matrices ----------------
__global__ __launch_bounds__(256) void k3_final(
    const float* __restrict__ m1w, const float* __restrict__ m1b,
    const float* __restrict__ m2w, const float* __restrict__ m2b,
    const float* __restrict__ temperature, const float* __restrict__ attn_scales,
    const float* __restrict__ gsum, const float* __restrict__ pooled,
    const float* __restrict__ gram, float* __restrict__ Abuf, float* __restrict__ cwbuf)
{
  __shared__ int s_dk;
  __shared__ float s_scale;
  const int tid = threadIdx.x;
  if (tid == 0) {
    float gmean = gsum[0] / (float)NPIX;
    int dk = (int)floorf(8.f * gmean);
    if (dk < 1) dk = 1;
    if (dk > 8) dk = 8;
    s_dk = dk;
    s_scale = attn_scales[0] + attn_scales[1] + attn_scales[2] + attn_scales[3];
  }
  __syncthreads();
  if (tid < 128) {
    int b = tid >> 5, ch = tid & 31, g = ch >> 2, c = ch & 3;
    float h1 = m1b[g];
#pragma unroll
    for (int cc = 0; cc < 4; ++cc)
      h1 += (pooled[b * 32 + g * 4 + cc] * (1.f / 65536.f)) * m1w[g * 4 + cc];
    h1 = fmaxf(h1, 0.f);
    cwbuf[tid] = sigm(h1 * m2w[g * 4 + c] + m2b[g * 4 + c]);

    int r = tid, h = (r >> 3) & 3, c8 = r & 7;
    const float* gm = gram + (b * 4 + h) * 80;
    float qn = fmaxf(sqrtf(gm[64 + c8]), 1e-12f);
    float temp = temperature[h];
    float a[8];
#pragma unroll
    for (int d = 0; d < 8; ++d) {
      float kn = fmaxf(sqrtf(gm[72 + d]), 1e-12f);
      a[d] = gm[c8 * 8 + d] / (qn * kn) * temp;
    }
    float t[8];
#pragma unroll
    for (int d = 0; d < 8; ++d) t[d] = a[d];
#pragma unroll
    for (int i = 0; i < 8; ++i)
#pragma unroll
      for (int j = 0; j < 8; ++j)
        if (j > i && t[j] > t[i]) { float tmp = t[i]; t[i] = t[j]; t[j] = tmp; }
    float kth = t[s_dk - 1];
    float mx = t[0];
    float e[8]; float sum = 0.f;
#pragma unroll
    for (int d = 0; d < 8; ++d) {
      e[d] = (a[d] >= kth) ? expf(a[d] - mx) : 0.f;
      sum += e[d];
    }
    float inv = s_scale / sum;
#pragma unroll
    for (int d = 0; d < 8; ++d) Abuf[r * 8 + d] = e[d] * inv;
  }
}

// ---------------- K4a: resp-mean (threshold) reduction; PRE recomputed from LOC ----------------
__global__ __launch_bounds__(256) void k4a_thr(
    const float* __restrict__ pre_w, const float* __restrict__ pre_b,
    const float* __restrict__ spw, const float* __restrict__ spb,
    const float* __restrict__ cwbuf, const float* __restrict__ dout, float* __restrict__ thrbuf)
{
  const int tid = threadIdx.x;
  const int p = blockIdx.x * 256 + tid;
  const int b = p >> 16, hw = p & (HW - 1);
  const float* LOCp = dout + (size_t)b * 64 * HW + hw;
  const float* cw = cwbuf + b * 32;
  float loc[32];
#pragma unroll
  for (int c = 0; c < 32; ++c) loc[c] = LOCp[(size_t)c * HW];
  float pre[32];
  for (int o = 0; o < 32; ++o) {
    float s = pre_b[o];
#pragma unroll
    for (int j = 0; j < 32; ++j) s += pre_w[o * 32 + j] * loc[j];
    pre[o] = s;
  }
  const int lane = tid & 63;
#pragma unroll
  for (int g = 0; g < 8; ++g) {
    float xa[4];
    float sdot = spb[g];
#pragma unroll
    for (int c = 0; c < 4; ++c) {
      xa[c] = pre[g * 4 + c] * cw[g * 4 + c];
      sdot += xa[c] * spw[g * 4 + c];
    }
    float sgv = sigm(sdot);
    float r = 0.f;
#pragma unroll
    for (int c = 0; c < 4; ++c) r += sigm(xa[c] * sgv);
    float v = wredsum(r);
    if (lane == 0) atomicAdd(&thrbuf[b * 8 + g], v);
  }
}

// ---------------- K4b: LGCE finish + V-dwconv + attn + out_proj + residual -> dout ----------------
__global__ __launch_bounds__(256) void k4b_fuse(
    const float* __restrict__ x, const float* __restrict__ pre_w, const float* __restrict__ pre_b,
    const float* __restrict__ post_w, const float* __restrict__ post_b,
    const float* __restrict__ out_proj_w, const float* __restrict__ spw, const float* __restrict__ spb,
    const float* __restrict__ qkv_dw, const float* __restrict__ qkvl,
    const float* __restrict__ Abuf, const float* __restrict__ cwbuf, const float* __restrict__ thrbuf,
    float* dout)
{
  const int tid = threadIdx.x;
  const int p = blockIdx.x * 256 + tid;
  const int b = p >> 16, hw = p & (HW - 1);
  const int y = hw >> 8, xx = hw & 255;
  const float* cw = cwbuf + b * 32;
  const float* A = Abuf + b * 256;
  float* doutb = dout + (size_t)b * 64 * HW + hw;
  float loc[32];
#pragma unroll
  for (int c = 0; c < 32; ++c) loc[c] = doutb[(size_t)c * HW];
  float pre[32];
  for (int o = 0; o < 32; ++o) {
    float s = pre_b[o];
#pragma unroll
    for (int j = 0; j < 32; ++j) s += pre_w[o * 32 + j] * loc[j];
    pre[o] = s;
  }
  float mx[32];
#pragma unroll
  for (int g = 0; g < 8; ++g) {
    float xa[4];
    float sdot = spb[g];
#pragma unroll
    for (int c = 0; c < 4; ++c) {
      xa[c] = pre[g * 4 + c] * cw[g * 4 + c];
      sdot += xa[c] * spw[g * 4 + c];
    }
    float sgv = sigm(sdot);
    float thr = thrbuf[b * 8 + g] * (1.f / (4.f * 65536.f));
#pragma unroll
    for (int c = 0; c < 4; ++c) {
      float resp = sigm(xa[c] * sgv);
      float m = (resp > thr) ? 1.f : resp;
      mx[g * 4 + c] = pre[g * 4 + c] * m;
    }
  }
  int offs[9]; bool okn[9];
#pragma unroll
  for (int dy = -1; dy <= 1; ++dy)
#pragma unroll
    for (int dx = -1; dx <= 1; ++dx) {
      int i = (dy + 1) * 3 + (dx + 1);
      int yy = y + dy, x2 = xx + dx;
      okn[i] = ((unsigned)yy < 256u) && ((unsigned)x2 < 256u);
      offs[i] = yy * 256 + x2;
    }
  const float* vbase = qkvl + (size_t)(b * 96 + 64) * HW;
  float vv[32];
  for (int ch = 0; ch < 32; ++ch) {
    const float* plane = vbase + (size_t)ch * HW;
    float acc = 0.f;
#pragma unroll
    for (int i = 0; i < 9; ++i) if (okn[i]) acc += plane[offs[i]] * qkv_dw[(64 + ch) * 9 + i];
    vv[ch] = acc;
  }
  float fused[64];
#pragma unroll
  for (int j = 0; j < 32; ++j) {
    int h = j >> 3, c = j & 7;
    float s = 0.f;
#pragma unroll
    for (int d = 0; d < 8; ++d) s += A[(h * 8 + c) * 8 + d] * vv[h * 8 + d];
    fused[j] = s;
  }
  for (int o = 0; o < 32; ++o) {
    float s = post_b[o];
#pragma unroll
    for (int j = 0; j < 32; ++j) s += post_w[o * 32 + j] * mx[j];
    fused[32 + o] = s + loc[o];
  }
  const float* xb = x + (size_t)b * 64 * HW + hw;
  for (int o = 0; o < 64; ++o) {
    float s = 0.f;
#pragma unroll
    for (int j = 0; j < 64; ++j) s += out_proj_w[o * 64 + j] * fused[j];
    doutb[(size_t)o * HW] = s + xb[(size_t)o * HW];
  }
}

// ---------------- K5 (MFMA): LN2 + ffn_in (64->256) bf16 MFMA, T stored bf16 ----------------
// block: 64 px (blockIdx.x), 64 outs (blockIdx.y*64), 4 waves (one 16-out strip each)
__global__ __launch_bounds__(256) void k5_mfma(
    const float* __restrict__ ln2_w, const float* __restrict__ ln2_b,
    const float* __restrict__ ffn_in_w, const float* __restrict__ dout,
    unsigned short* __restrict__ Tb, int b)
{
  __shared__ float sStage[64][65];
  __shared__ unsigned short sXnb[64][72];
  __shared__ float sMu[64], sRs[64];
  const int tid = threadIdx.x;
  const int px0 = blockIdx.x * 64;
  const int o0base = blockIdx.y * 64;
  // stage dout[64c][64px] -> sStage[px][c]
  const float* db = dout + (size_t)(b * 64) * HW + px0;
#pragma unroll
  for (int i = 0; i < 16; ++i) {
    int idx = tid + i * 256;
    int c = idx >> 6, px = idx & 63;
    sStage[px][c] = db[(size_t)c * HW + px];
  }
  __syncthreads();
  if (tid < 64) {
    float mu = 0.f;
#pragma unroll
    for (int c = 0; c < 64; ++c) mu += sStage[tid][c];
    mu *= (1.f / 64.f);
    float var = 0.f;
#pragma unroll
    for (int c = 0; c < 64; ++c) { float d = sStage[tid][c] - mu; var += d * d; }
    var *= (1.f / 64.f);
    sMu[tid] = mu;
    sRs[tid] = rsqrtf(var + 1e-5f);
  }
  __syncthreads();
#pragma unroll
  for (int i = 0; i < 16; ++i) {
    int idx = tid + i * 256;
    int px = idx >> 6, c = idx & 63;
    float xn = (sStage[px][c] - sMu[px]) * sRs[px] * ln2_w[c] + ln2_b[c];
    sXnb[px][c] = f2bf(xn);
  }
  __syncthreads();
  // MFMA: each wave computes 64px x 16o
  const int w = tid >> 6, lane = tid & 63;
  const int col = lane & 15, kgrp = lane >> 4;
  const int og = o0base + w * 16 + col;
  f32x4 acc[4];
#pragma unroll
  for (int s = 0; s < 4; ++s) acc[s] = (f32x4){0.f, 0.f, 0.f, 0.f};
#pragma unroll
  for (int kk = 0; kk < 2; ++kk) {
    const int c0 = kk * 32 + kgrp * 8;
    union { short8v v; unsigned short s[8]; } bw;
    const float* wp = ffn_in_w + (size_t)og * 64 + c0;
#pragma unroll
    for (int j = 0; j < 8; ++j) bw.s[j] = f2bf(wp[j]);
#pragma unroll
    for (int s = 0; s < 4; ++s) {
      short8v av = *reinterpret_cast<const short8v*>(&sXnb[s * 16 + col][c0]);
      acc[s] = __builtin_amdgcn_mfma_f32_16x16x32_bf16(av, bw.v, acc[s], 0, 0, 0);
    }
  }
  // write D into LDS tile [o_local][px] (reuse sStage as bf16)
  unsigned short* outb = reinterpret_cast<unsigned short*>(&sStage[0][0]);
  const int o_l = w * 16 + col;
#pragma unroll
  for (int s = 0; s < 4; ++s) {
#pragma unroll
    for (int r = 0; r < 4; ++r) {
      int px_l = s * 16 + kgrp * 4 + r;
      outb[o_l * 72 + px_l] = f2bf(acc[s][r]);
    }
  }
  __syncthreads();
  // cooperative coalesced store: thread t -> (o = t>>2, 16-px segment t&3)
  {
    const int ol = tid >> 2, seg = tid & 3;
    const unsigned short* src = outb + ol * 72 + seg * 16;
    unsigned short* dst = Tb + (size_t)(o0base + ol) * HW + px0 + seg * 16;
    *reinterpret_cast<short8v*>(dst) = *reinterpret_cast<const short8v*>(src);
    *(reinterpret_cast<short8v*>(dst) + 1) = *(reinterpret_cast<const short8v*>(src) + 1);
  }
}

// ---------------- K5 checker: sample-verify MFMA T vs fp32 reference (b=0) ----------------
__global__ __launch_bounds__(256) void k5_check(
    const float* __restrict__ ln2_w, const float* __restrict__ ln2_b,
    const float* __restrict__ ffn_in_w, const float* __restrict__ dout,
    const unsigned short* __restrict__ Tb, float* __restrict__ bad)
{
  const int i = blockIdx.x * 256 + threadIdx.x;   // 4096 samples
  const int px = (i * 16) & (HW - 1);
  const float* yb = dout + px;
  float xv[64];
  float mu = 0.f;
#pragma unroll
  for (int c = 0; c < 64; ++c) { xv[c] = yb[(size_t)c * HW]; mu += xv[c]; }
  mu *= (1.f / 64.f);
  float var = 0.f;
#pragma unroll
  for (int c = 0; c < 64; ++c) { float d = xv[c] - mu; var += d * d; }
  var *= (1.f / 64.f);
  float rs = rsqrtf(var + 1e-5f);
#pragma unroll
  for (int c = 0; c < 64; ++c) xv[c] = (xv[c] - mu) * rs * ln2_w[c] + ln2_b[c];
  bool fail = false;
  for (int o = 0; o < 256; ++o) {
    float s = 0.f;
#pragma unroll
    for (int c = 0; c < 64; ++c) s += ffn_in_w[o * 64 + c] * xv[c];
    float got = bf2f(Tb[(size_t)o * HW + px]);
    if (fabsf(got - s) > 0.03f + 0.03f * fabsf(s)) fail = true;
  }
  if (fail) atomicExch(bad, 1.f);
}

// ---------------- K5 fallback: scalar LN2+ffn_in (only if checker failed) ----------------
__global__ __launch_bounds__(256) void k5_fb(
    const float* __restrict__ ln2_w, const float* __restrict__ ln2_b,
    const float* __restrict__ ffn_in_w, const float* __restrict__ dout,
    const float* __restrict__ bad, unsigned short* __restrict__ Tb, int b)
{
  if (bad[0] < 0.5f) return;
  __shared__ float sW[4096];
  const int tid = threadIdx.x;
  const int obase = blockIdx.y * 64;
  for (int i = tid; i < 4096; i += 256) sW[i] = ffn_in_w[obase * 64 + i];
  const int px = blockIdx.x * 256 + tid;
  const float* yb = dout + (size_t)b * 64 * HW + px;
  float xv[64];
  float mu = 0.f;
#pragma unroll
  for (int c = 0; c < 64; ++c) { xv[c] = yb[(size_t)c * HW]; mu += xv[c]; }
  mu *= (1.f / 64.f);
  float var = 0.f;
#pragma unroll
  for (int c = 0; c < 64; ++c) { float d = xv[c] - mu; var += d * d; }
  var *= (1.f / 64.f);
  float rsv = rsqrtf(var + 1e-5f);
#pragma unroll
  for (int c = 0; c < 64; ++c) xv[c] = (xv[c] - mu) * rsv * ln2_w[c] + ln2_b[c];
  __syncthreads();
  unsigned short* Tp = Tb + (size_t)obase * HW + px;
  for (int o = 0; o < 64; ++o) {
    float s = 0.f;
#pragma unroll
    for (int c = 0; c < 64; ++c) s += sW[o * 64 + c] * xv[c];
    Tp[(size_t)o * HW] = f2bf(s);
  }
}

// ---------------- K6a: dwconv3/dwconv5 + gelu*mul -> Y (bf16), one batch, j-chunked ----------------
__global__ __launch_bounds__(256) void k6a_dw(
    const float* __restrict__ dw3_w, const float* __restrict__ dw5_w,
    const unsigned short* __restrict__ T, __hip_bfloat16* __restrict__ Y)
{
  const int tid = threadIdx.x;
  const int px = blockIdx.x * 256 + tid;
  const int j0 = blockIdx.y * 8;
  const int row = px >> 8, col = px & 255;
  bool oky[5], okx[5];
#pragma unroll
  for (int d = 0; d < 5; ++d) {
    oky[d] = ((unsigned)(row + d - 2) < 256u);
    okx[d] = ((unsigned)(col + d - 2) < 256u);
  }
#pragma unroll
  for (int jj = 0; jj < 8; ++jj) {
    const int j = j0 + jj;
    const unsigned short* pl = T + (size_t)j * HW;
    float a = 0.f;
#pragma unroll
    for (int dy = -1; dy <= 1; ++dy) {
      if (!oky[dy + 2]) continue;
#pragma unroll
      for (int dx = -1; dx <= 1; ++dx) {
        if (!okx[dx + 2]) continue;
        a += bf2f(pl[px + dy * 256 + dx]) * dw3_w[j * 9 + (dy + 1) * 3 + (dx + 1)];
      }
    }
    float m = 0.f;
    const unsigned short* pm = T + (size_t)(128 + j) * HW;
    if (j < 64) {
#pragma unroll
      for (int dy = -1; dy <= 1; ++dy) {
        if (!oky[dy + 2]) continue;
#pragma unroll
        for (int dx = -1; dx <= 1; ++dx) {
          if (!okx[dx + 2]) continue;
          m += bf2f(pm[px + dy * 256 + dx]) * dw3_w[(128 + j) * 9 + (dy + 1) * 3 + (dx + 1)];
        }
      }
    } else {
#pragma unroll
      for (int dy = -2; dy <= 2; ++dy) {
        if (!oky[dy + 2]) continue;
#pragma unroll
        for (int dx = -2; dx <= 2; ++dx) {
          if (!okx[dx + 2]) continue;
          m += bf2f(pm[px + dy * 256 + dx]) * dw5_w[(j - 64) * 25 + (dy + 2) * 5 + (dx + 2)];
        }
      }
    }
    float gl = 0.5f * a * (1.f + erff(a * 0.70710678118654752f));
    Y[(size_t)j * HW + px] = __float2bfloat16(gl * m);
  }
}

// ---------------- K6b: ffn_out (128->64) from Y, one batch, o-chunked ----------------
__global__ __launch_bounds__(256) void k6b_out(
    const float* __restrict__ ffn_out_w, const __hip_bfloat16* __restrict__ Y,
    const float* __restrict__ flag, float* __restrict__ dout, float* __restrict__ Z, int b)
{
  __shared__ float sW[2048];   // 16 out rows x 128
  const int tid = threadIdx.x;
  const int o0 = blockIdx.y * 16;
  for (int i = tid; i < 2048; i += 256) sW[i] = ffn_out_w[o0 * 128 + i];
  __syncthreads();
  const int px = blockIdx.x * 256 + tid;
  float z[16];
#pragma unroll
  for (int o = 0; o < 16; ++o) z[o] = 0.f;
  for (int j = 0; j < 128; ++j) {
    float yv = __bfloat162float(Y[(size_t)j * HW + px]);
#pragma unroll
    for (int o = 0; o < 16; ++o) z[o] += sW[o * 128 + j] * yv;
  }
  if (flag[0] > 0.5f) {
    float* ob = dout + (size_t)(b * 64 + o0) * HW + px;
#pragma unroll
    for (int o = 0; o < 16; ++o) ob[(size_t)o * HW] += z[o];
  } else {
    float* zb = Z + (size_t)o0 * HW + px;
#pragma unroll
    for (int o = 0; o < 16; ++o) zb[(size_t)o * HW] = z[o];
  }
}

// ---------------- K7: general fft path — per-patch 8x8 circular conv (early-exit if identity) ----------------
__global__ __launch_bounds__(256) void k7_fft(
    const float* __restrict__ fftw, const float* __restrict__ flag,
    const float* __restrict__ Z, float* __restrict__ dout, int b)
{
  if (flag[0] > 0.5f) return;
  __shared__ float swv[64];
  __shared__ float spatch[4][64];
  const int tid = threadIdx.x;
  const int c = blockIdx.x >> 8;
  const int pblk = blockIdx.x & 255;
  if (tid < 64) swv[tid] = fftw[c * 64 + tid];
  const int lp = tid >> 6, e = tid & 63;
  const int patch = pblk * 4 + lp;
  const int pi = patch >> 5, pj = patch & 31;
  const int i = e >> 3, jj = e & 7;
  const int gidx = (pi * 8 + i) * 256 + pj * 8 + jj;
  const float zv = Z[(size_t)c * HW + gidx];
  spatch[lp][e] = zv;
  __syncthreads();
  float s = 0.f;
#pragma unroll
  for (int a = 0; a < 8; ++a)
#pragma unroll
    for (int b2 = 0; b2 < 8; ++b2)
      s += swv[a * 8 + b2] * spatch[lp][((i - a) & 7) * 8 + ((jj - b2) & 7)];
  dout[(size_t)(b * 64 + c) * HW + gidx] += s;
}

extern "C" void kernel_launch(void* const* d_in, const int* in_sizes, int n_in,
                              void* d_out, int out_size, void* d_ws, size_t ws_size,
                              hipStream_t stream) {
  const float* x          = (const float*)d_in[0];
  const float* ln1_w      = (const float*)d_in[1];
  const float* ln1_b      = (const float*)d_in[2];
  const float* in_proj_w  = (const float*)d_in[3];
  const float* qkv_w      = (const float*)d_in[4];
  const float* qkv_dw     = (const float*)d_in[5];
  const float* out_proj_w = (const float*)d_in[6];
  const float* temperature= (const float*)d_in[7];
  const float* attn_scales= (const float*)d_in[8];
  const float* gate_w1    = (const float*)d_in[9];
  const float* gate_b1    = (const float*)d_in[10];
  const float* gate_w2    = (const float*)d_in[11];
  const float* gate_b2    = (const float*)d_in[12];
  const float* lgce_pre_w = (const float*)d_in[13];
  const float* lgce_pre_b = (const float*)d_in[14];
  const float* lgce_post_w= (const float*)d_in[15];
  const float* lgce_post_b= (const float*)d_in[16];
  const float* cbam_m1w   = (const float*)d_in[17];
  const float* cbam_m1b   = (const float*)d_in[18];
  const float* cbam_m2w   = (const float*)d_in[19];
  const float* cbam_m2b   = (const float*)d_in[20];
  const float* cbam_spw   = (const float*)d_in[21];
  const float* cbam_spb   = (const float*)d_in[22];
  const float* ln2_w      = (const float*)d_in[23];
  const float* ln2_b      = (const float*)d_in[24];
  const float* ffn_in_w   = (const float*)d_in[25];
  const float* dw3_w      = (const float*)d_in[26];
  const float* dw5_w      = (const float*)d_in[27];
  const float* ffn_out_w  = (const float*)d_in[28];
  const float* fft_W      = (const float*)d_in[29];
  float* ws = (float*)d_ws;
  float* out = (float*)d_out;
  unsigned short* Tb = (unsigned short*)(ws + OFF_T);
  __hip_bfloat16* Ybuf = (__hip_bfloat16*)(ws + OFF_Y);

  hipLaunchKernelGGL(k0_setup, dim3(1), dim3(256), 0, stream, fft_W, ws);
  hipLaunchKernelGGL(k1_proj, dim3(1024), dim3(256), 0, stream,
                     x, ln1_w, ln1_b, in_proj_w, qkv_w, lgce_pre_w, lgce_pre_b,
                     gate_w1, gate_b1, gate_w2, gate_b2,
                     out, ws + OFF_QKVL, ws + OFF_POOL, ws + OFF_GSUM);
  hipLaunchKernelGGL(k2_gram, dim3(32, 4, 4), dim3(256), 0, stream,
                     ws + OFF_QKVL, qkv_dw, ws + OFF_GRAM);
  hipLaunchKernelGGL(k3_final, dim3(1), dim3(256), 0, stream,
                     cbam_m1w, cbam_m1b, cbam_m2w, cbam_m2b, temperature, attn_scales,
                     ws + OFF_GSUM, ws + OFF_POOL, ws + OFF_GRAM, ws + OFF_A, ws + OFF_CW);
  hipLaunchKernelGGL(k4a_thr, dim3(1024), dim3(256), 0, stream,
                     lgce_pre_w, lgce_pre_b, cbam_spw, cbam_spb, ws + OFF_CW, out, ws + OFF_THR);
  hipLaunchKernelGGL(k4b_fuse, dim3(1024), dim3(256), 0, stream,
                     x, lgce_pre_w, lgce_pre_b, lgce_post_w, lgce_post_b, out_proj_w,
                     cbam_spw, cbam_spb, qkv_dw, ws + OFF_QKVL,
                     ws + OFF_A, ws + OFF_CW, ws + OFF_THR, out);

  for (int b = 0; b < 4; ++b) {
    hipLaunchKernelGGL(k5_mfma, dim3(1024, 4), dim3(256), 0, stream,
                       ln2_w, ln2_b, ffn_in_w, out, Tb, b);
    if (b == 0)
      hipLaunchKernelGGL(k5_check, dim3(16), dim3(256), 0, stream,
                         ln2_w, ln2_b, ffn_in_w, out, Tb, ws + OFF_BAD);
    hipLaunchKernelGGL(k5_fb, dim3(256, 4), dim3(256), 0, stream,
                       ln2_w, ln2_b, ffn_in_w, out, ws + OFF_BAD, Tb, b);
    hipLaunchKernelGGL(k6a_dw, dim3(256, 16), dim3(256), 0, stream,
                       dw3_w, dw5_w, Tb, Ybuf);
    hipLaunchKernelGGL(k6b_out, dim3(256, 4), dim3(256), 0, stream,
                       ffn_out_w, Ybuf, ws + OFF_FLAG, out, ws + OFF_Z, b);
    hipLaunchKernelGGL(k7_fft, dim3(16384), dim3(256), 0, stream,
                       ws + OFF_FFTW, ws + OFF_FLAG, ws + OFF_Z, out, b);
  }
}

// Round 5
// 1779.091 us; speedup vs baseline: 3.5944x; 1.0707x over previous
//
#include <hip/hip_runtime.h>
#include <hip/hip_bf16.h>
#include <math.h>

#define HW 65536
#define NPIX 262144

// ---- workspace layout (float offsets) ----
#define OFF_FFTW 0            // 64x64 spatial fft kernel
#define OFF_FLAG 4096         // 1
#define OFF_GSUM 4097         // 1    (zeroed in k0)
#define OFF_POOL 4098         // 128  (zeroed in k0)
#define OFF_GRAM 4226         // 1280 (zeroed in k0)
#define OFF_THR  5506         // 32   (zeroed in k0)
#define OFF_BAD  5538         // 1    (zeroed in k0)  -- mfma checker flag
#define OFF_A    5539         // 1024
#define OFF_CW   6563         // 128
#define OFF_QKVL 8192         // 96ch * 65536 floats — SGSA phase
// MFFN phase (per-batch buffers, overlap QKVL which is dead by then):
#define OFF_T    8192                      // 256ch * 65536 bf16
#define OFF_Y    (OFF_T + 16777216)        // 128ch * 65536 bf16
#define OFF_Z    (OFF_Y + 4194304)         // 64ch * 65536 fp32
// peak ws usage = 25174016 floats = 100.7 MB (same proven footprint)

typedef __attribute__((ext_vector_type(8))) short short8v;
typedef __attribute__((ext_vector_type(4))) float f32x4;

__device__ __forceinline__ float sigm(float v) { return 1.f / (1.f + expf(-v)); }
__device__ __forceinline__ float wredsum(float v) {
#pragma unroll
  for (int off = 32; off >= 1; off >>= 1) v += __shfl_xor(v, off);
  return v;
}
__device__ __forceinline__ unsigned short f2bf(float f) {
  union { float f; unsigned u; } x; x.f = f;
  unsigned r = x.u + 0x7fffu + ((x.u >> 16) & 1u);
  return (unsigned short)(r >> 16);
}
__device__ __forceinline__ float bf2f(unsigned short u) {
  union { unsigned u; float f; } x; x.u = ((unsigned)u) << 16;
  return x.f;
}

// ---------------- K0: zero accumulators + fft spatial kernel + identity flag ----------------
__global__ __launch_bounds__(256) void k0_setup(
    const float* __restrict__ fft_W, float* __restrict__ ws)
{
  __shared__ float ct8[8];
  __shared__ int sbad;
  const int tid = threadIdx.x;
  if (tid < 8) ct8[tid] = cosf((float)tid * 0.78539816339744831f); // cos(k*pi/4)
  if (tid == 0) sbad = 0;
  for (int i = tid; i < 1442; i += 256) ws[OFF_GSUM + i] = 0.f;    // gsum,pool,gram,thr,bad
  __syncthreads();
  bool ok = true;
  for (int i = tid; i < 64 * 64; i += 256) {
    int ch = i >> 6, ab = i & 63;
    int a = ab >> 3, b2 = ab & 7;
    float s = 0.f;
    for (int u = 0; u < 8; ++u)
      for (int v = 0; v < 8; ++v) {
        float Wf;
        if (v == 0 || v == 4)
          Wf = 0.5f * (fft_W[ch * 40 + u * 5 + v] + fft_W[ch * 40 + ((8 - u) & 7) * 5 + v]);
        else if (v < 5)
          Wf = fft_W[ch * 40 + u * 5 + v];
        else
          Wf = fft_W[ch * 40 + ((8 - u) & 7) * 5 + (8 - v)];
        s += Wf * ct8[(u * a + v * b2) & 7];
      }
    s *= (1.f / 64.f);
    ws[OFF_FFTW + i] = s;
    float expect = ((i & 63) == 0) ? 1.f : 0.f;
    if (fabsf(s - expect) > 1e-4f) ok = false;
  }
  if (!ok) atomicOr(&sbad, 1);
  __syncthreads();
  if (tid == 0) ws[OFF_FLAG] = sbad ? 0.f : 1.f;
}

// ---------------- K1: LN1 + in_proj(loc->dout[0..31], glob) + qkv + pooled/gate ----------------
__global__ __launch_bounds__(256) void k1_proj(
    const float* __restrict__ x, const float* __restrict__ ln1_w, const float* __restrict__ ln1_b,
    const float* __restrict__ in_proj_w, const float* __restrict__ qkv_w,
    const float* __restrict__ pre_w, const float* __restrict__ pre_b,
    const float* __restrict__ g1w, const float* __restrict__ g1b,
    const float* __restrict__ g2w, const float* __restrict__ g2b,
    float* __restrict__ dout, float* __restrict__ qkvl,
    float* __restrict__ pooled, float* __restrict__ gsum)
{
  __shared__ float sPool[4][32];
  __shared__ float sRed[4];
  const int tid = threadIdx.x;
  const int p = blockIdx.x * 256 + tid;
  const int b = p >> 16;
  const int hw = p & (HW - 1);
  const int wave = tid >> 6, lane = tid & 63;
  const float* xb = x + (size_t)(b * 64) * HW + hw;
  float xv[64];
  float mu = 0.f;
#pragma unroll
  for (int c = 0; c < 64; ++c) { xv[c] = xb[(size_t)c * HW]; mu += xv[c]; }
  mu *= (1.f / 64.f);
  float var = 0.f;
#pragma unroll
  for (int c = 0; c < 64; ++c) { float d = xv[c] - mu; var += d * d; }
  var *= (1.f / 64.f);
  const float rs = rsqrtf(var + 1e-5f);
#pragma unroll
  for (int c = 0; c < 64; ++c) xv[c] = (xv[c] - mu) * rs * ln1_w[c] + ln1_b[c];

  float loc[32];
  for (int o = 0; o < 32; ++o) {
    float s = 0.f;
#pragma unroll
    for (int c = 0; c < 64; ++c) s += in_proj_w[o * 64 + c] * xv[c];
    loc[o] = s;
    dout[(size_t)(b * 64 + o) * HW + hw] = s;
  }
  for (int o = 0; o < 32; ++o) {
    float s = pre_b[o];
#pragma unroll
    for (int j = 0; j < 32; ++j) s += pre_w[o * 32 + j] * loc[j];
    float r = wredsum(s);
    if (lane == 0) sPool[wave][o] = r;
  }
  float gl[32];
  for (int o = 0; o < 32; ++o) {
    float s = 0.f;
#pragma unroll
    for (int c = 0; c < 64; ++c) s += in_proj_w[(32 + o) * 64 + c] * xv[c];
    gl[o] = s;
  }
  for (int o = 0; o < 96; ++o) {
    float s = 0.f;
#pragma unroll
    for (int j = 0; j < 32; ++j) s += qkv_w[o * 32 + j] * gl[j];
    qkvl[(size_t)(b * 96 + o) * HW + hw] = s;
  }
  float gacc = g2b[0];
  for (int o = 0; o < 16; ++o) {
    float h = g1b[o];
#pragma unroll
    for (int j = 0; j < 32; ++j) h += g1w[o * 32 + j] * gl[j];
    gacc += g2w[o] * fmaxf(h, 0.f);
  }
  float gv = wredsum(sigm(gacc));
  if (lane == 0) sRed[wave] = gv;
  __syncthreads();
  if (tid == 0) atomicAdd(gsum, sRed[0] + sRed[1] + sRed[2] + sRed[3]);
  if (tid < 32) {
    float s = sPool[0][tid] + sPool[1][tid] + sPool[2][tid] + sPool[3][tid];
    atomicAdd(&pooled[b * 32 + tid], s);
  }
}

// ---------------- K2 (MFMA): dwconv(q,k) + Gram via V·V^T, V = [q0..q7,k0..k7] ----------------
// grid (128 slabs, 4 heads, 4 batches); block 256 = 4 waves; wave: 128 px via 4 MFMAs.
// Layout robustness: A and B are the same fragment, so any k-permutation cancels;
// Gram is symmetric, so a row/col C-swap is also harmless.
__global__ __launch_bounds__(256) void k2_mfma(
    const float* __restrict__ qkvl, const float* __restrict__ qkv_dw, float* __restrict__ gram)
{
  __shared__ float sred[4][256];
  const int tid = threadIdx.x;
  const int slab = blockIdx.x;        // 512 px each
  const int h = blockIdx.y, b = blockIdx.z;
  const int w = tid >> 6, lane = tid & 63;
  const int ch = lane & 15, grp = lane >> 4;
  const int gch = (ch < 8) ? (h * 8 + ch) : (32 + h * 8 + (ch - 8));
  const float* plane = qkvl + (size_t)(b * 96 + gch) * HW;
  const float* wt = qkv_dw + gch * 9;
  float w9[9];
#pragma unroll
  for (int t = 0; t < 9; ++t) w9[t] = wt[t];
  f32x4 acc = (f32x4){0.f, 0.f, 0.f, 0.f};
#pragma unroll
  for (int iter = 0; iter < 4; ++iter) {
    const int pxbase = slab * 512 + w * 128 + iter * 32 + grp * 8;
    const int y = pxbase >> 8;
    const int x0 = pxbase & 255;
    union { short8v v; unsigned short s[8]; } frag;
#pragma unroll
    for (int j = 0; j < 8; ++j) {
      const int x = x0 + j;           // stays within the row (32-aligned chunks)
      float a = 0.f;
#pragma unroll
      for (int dy = -1; dy <= 1; ++dy) {
        const int yy = y + dy;
        if ((unsigned)yy >= 256u) continue;
#pragma unroll
        for (int dx = -1; dx <= 1; ++dx) {
          const int x2 = x + dx;
          if ((unsigned)x2 >= 256u) continue;
          a += plane[yy * 256 + x2] * w9[(dy + 1) * 3 + (dx + 1)];
        }
      }
      frag.s[j] = f2bf(a);
    }
    acc = __builtin_amdgcn_mfma_f32_16x16x32_bf16(frag.v, frag.v, acc, 0, 0, 0);
  }
  // C/D: col = lane&15, row = grp*4 + r  (m89-verified mapping)
#pragma unroll
  for (int r = 0; r < 4; ++r) sred[w][(grp * 4 + r) * 16 + ch] = acc[r];
  __syncthreads();
  if (tid < 256) {
    float g = sred[0][tid] + sred[1][tid] + sred[2][tid] + sred[3][tid];
    const int row = tid >> 4, col = tid & 15;
    int idx = -1;
    if (row < 8 && col >= 8) idx = row * 8 + (col - 8);      // q·k
    else if (row == col && row < 8) idx = 64 + row;          // |q|^2
    else if (row == col) idx = 72 + (row - 8);               // |k|^2
    if (idx >= 0) atomicAdd(&gram[(b * 4 + h) * 80 + idx], g);
  }
}

// ---------------- K3: dk, CBAM channel weights, attention matrices ----------------
__global__ __launch_bounds__(256) void k3_final(
    const float* __restrict__ m1w, const float* __restrict__ m1b,
    const float* __restrict__ m2w, const float* __restrict__ m2b,
    const float* __restrict__ temperature, const float* __restrict__ attn_scales,
    const float* __restrict__ gsum, const float* __restrict__ pooled,
    const float* __restrict__ gram, float* __restrict__ Abuf, float* __restrict__ cwbuf)
{
  __shared__ int s_dk;
  __shared__ float s_scale;
  const int tid = threadIdx.x;
  if (tid == 0) {
    float gmean = gsum[0] / (float)NPIX;
    int dk = (int)floorf(8.f * gmean);
    if (dk < 1) dk = 1;
    if (dk > 8) dk = 8;
    s_dk = dk;
    s_scale = attn_scales[0] + attn_scales[1] + attn_scales[2] + attn_scales[3];
  }
  __syncthreads();
  if (tid < 128) {
    int b = tid >> 5, ch = tid & 31, g = ch >> 2, c = ch & 3;
    float h1 = m1b[g];
#pragma unroll
    for (int cc = 0; cc < 4; ++cc)
      h1 += (pooled[b * 32 + g * 4 + cc] * (1.f / 65536.f)) * m1w[g * 4 + cc];
    h1 = fmaxf(h1, 0.f);
    cwbuf[tid] = sigm(h1 * m2w[g * 4 + c] + m2b[g * 4 + c]);

    int r = tid, h = (r >> 3) & 3, c8 = r & 7;
    const float* gm = gram + (b * 4 + h) * 80;
    float qn = fmaxf(sqrtf(gm[64 + c8]), 1e-12f);
    float temp = temperature[h];
    float a[8];
#pragma unroll
    for (int d = 0; d < 8; ++d) {
      float kn = fmaxf(sqrtf(gm[72 + d]), 1e-12f);
      a[d] = gm[c8 * 8 + d] / (qn * kn) * temp;
    }
    float t[8];
#pragma unroll
    for (int d = 0; d < 8; ++d) t[d] = a[d];
#pragma unroll
    for (int i = 0; i < 8; ++i)
#pragma unroll
      for (int j = 0; j < 8; ++j)
        if (j > i && t[j] > t[i]) { float tmp = t[i]; t[i] = t[j]; t[j] = tmp; }
    float kth = t[s_dk - 1];
    float mx = t[0];
    float e[8]; float sum = 0.f;
#pragma unroll
    for (int d = 0; d < 8; ++d) {
      e[d] = (a[d] >= kth) ? expf(a[d] - mx) : 0.f;
      sum += e[d];
    }
    float inv = s_scale / sum;
#pragma unroll
    for (int d = 0; d < 8; ++d) Abuf[r * 8 + d] = e[d] * inv;
  }
}

// ---------------- K4a: resp-mean (threshold) reduction; PRE recomputed from LOC ----------------
__global__ __launch_bounds__(256) void k4a_thr(
    const float* __restrict__ pre_w, const float* __restrict__ pre_b,
    const float* __restrict__ spw, const float* __restrict__ spb,
    const float* __restrict__ cwbuf, const float* __restrict__ dout, float* __restrict__ thrbuf)
{
  const int tid = threadIdx.x;
  const int p = blockIdx.x * 256 + tid;
  const int b = p >> 16, hw = p & (HW - 1);
  const float* LOCp = dout + (size_t)b * 64 * HW + hw;
  const float* cw = cwbuf + b * 32;
  float loc[32];
#pragma unroll
  for (int c = 0; c < 32; ++c) loc[c] = LOCp[(size_t)c * HW];
  float pre[32];
  for (int o = 0; o < 32; ++o) {
    float s = pre_b[o];
#pragma unroll
    for (int j = 0; j < 32; ++j) s += pre_w[o * 32 + j] * loc[j];
    pre[o] = s;
  }
  const int lane = tid & 63;
#pragma unroll
  for (int g = 0; g < 8; ++g) {
    float xa[4];
    float sdot = spb[g];
#pragma unroll
    for (int c = 0; c < 4; ++c) {
      xa[c] = pre[g * 4 + c] * cw[g * 4 + c];
      sdot += xa[c] * spw[g * 4 + c];
    }
    float sgv = sigm(sdot);
    float r = 0.f;
#pragma unroll
    for (int c = 0; c < 4; ++c) r += sigm(xa[c] * sgv);
    float v = wredsum(r);
    if (lane == 0) atomicAdd(&thrbuf[b * 8 + g], v);
  }
}

// ---------------- K4b: LGCE finish + V-dwconv + attn + out_proj + residual -> dout ----------------
__global__ __launch_bounds__(256) void k4b_fuse(
    const float* __restrict__ x, const float* __restrict__ pre_w, const float* __restrict__ pre_b,
    const float* __restrict__ post_w, const float* __restrict__ post_b,
    const float* __restrict__ out_proj_w, const float* __restrict__ spw, const float* __restrict__ spb,
    const float* __restrict__ qkv_dw, const float* __restrict__ qkvl,
    const float* __restrict__ Abuf, const float* __restrict__ cwbuf, const float* __restrict__ thrbuf,
    float* dout)
{
  const int tid = threadIdx.x;
  const int p = blockIdx.x * 256 + tid;
  const int b = p >> 16, hw = p & (HW - 1);
  const int y = hw >> 8, xx = hw & 255;
  const float* cw = cwbuf + b * 32;
  const float* A = Abuf + b * 256;
  float* doutb = dout + (size_t)b * 64 * HW + hw;
  float loc[32];
#pragma unroll
  for (int c = 0; c < 32; ++c) loc[c] = doutb[(size_t)c * HW];
  float pre[32];
  for (int o = 0; o < 32; ++o) {
    float s = pre_b[o];
#pragma unroll
    for (int j = 0; j < 32; ++j) s += pre_w[o * 32 + j] * loc[j];
    pre[o] = s;
  }
  float mx[32];
#pragma unroll
  for (int g = 0; g < 8; ++g) {
    float xa[4];
    float sdot = spb[g];
#pragma unroll
    for (int c = 0; c < 4; ++c) {
      xa[c] = pre[g * 4 + c] * cw[g * 4 + c];
      sdot += xa[c] * spw[g * 4 + c];
    }
    float sgv = sigm(sdot);
    float thr = thrbuf[b * 8 + g] * (1.f / (4.f * 65536.f));
#pragma unroll
    for (int c = 0; c < 4; ++c) {
      float resp = sigm(xa[c] * sgv);
      float m = (resp > thr) ? 1.f : resp;
      mx[g * 4 + c] = pre[g * 4 + c] * m;
    }
  }
  int offs[9]; bool okn[9];
#pragma unroll
  for (int dy = -1; dy <= 1; ++dy)
#pragma unroll
    for (int dx = -1; dx <= 1; ++dx) {
      int i = (dy + 1) * 3 + (dx + 1);
      int yy = y + dy, x2 = xx + dx;
      okn[i] = ((unsigned)yy < 256u) && ((unsigned)x2 < 256u);
      offs[i] = yy * 256 + x2;
    }
  const float* vbase = qkvl + (size_t)(b * 96 + 64) * HW;
  float vv[32];
  for (int ch = 0; ch < 32; ++ch) {
    const float* plane = vbase + (size_t)ch * HW;
    float acc = 0.f;
#pragma unroll
    for (int i = 0; i < 9; ++i) if (okn[i]) acc += plane[offs[i]] * qkv_dw[(64 + ch) * 9 + i];
    vv[ch] = acc;
  }
  float fused[64];
#pragma unroll
  for (int j = 0; j < 32; ++j) {
    int h = j >> 3, c = j & 7;
    float s = 0.f;
#pragma unroll
    for (int d = 0; d < 8; ++d) s += A[(h * 8 + c) * 8 + d] * vv[h * 8 + d];
    fused[j] = s;
  }
  for (int o = 0; o < 32; ++o) {
    float s = post_b[o];
#pragma unroll
    for (int j = 0; j < 32; ++j) s += post_w[o * 32 + j] * mx[j];
    fused[32 + o] = s + loc[o];
  }
  const float* xb = x + (size_t)b * 64 * HW + hw;
  for (int o = 0; o < 64; ++o) {
    float s = 0.f;
#pragma unroll
    for (int j = 0; j < 64; ++j) s += out_proj_w[o * 64 + j] * fused[j];
    doutb[(size_t)o * HW] = s + xb[(size_t)o * HW];
  }
}

// ---------------- K5 (MFMA): LN2 + ffn_in (64->256) bf16 MFMA, T stored bf16 ----------------
__global__ __launch_bounds__(256) void k5_mfma(
    const float* __restrict__ ln2_w, const float* __restrict__ ln2_b,
    const float* __restrict__ ffn_in_w, const float* __restrict__ dout,
    unsigned short* __restrict__ Tb, int b)
{
  __shared__ float sStage[64][65];
  __shared__ unsigned short sXnb[64][72];
  __shared__ float sMu[64], sRs[64];
  const int tid = threadIdx.x;
  const int px0 = blockIdx.x * 64;
  const int o0base = blockIdx.y * 64;
  const float* db = dout + (size_t)(b * 64) * HW + px0;
#pragma unroll
  for (int i = 0; i < 16; ++i) {
    int idx = tid + i * 256;
    int c = idx >> 6, px = idx & 63;
    sStage[px][c] = db[(size_t)c * HW + px];
  }
  __syncthreads();
  if (tid < 64) {
    float mu = 0.f;
#pragma unroll
    for (int c = 0; c < 64; ++c) mu += sStage[tid][c];
    mu *= (1.f / 64.f);
    float var = 0.f;
#pragma unroll
    for (int c = 0; c < 64; ++c) { float d = sStage[tid][c] - mu; var += d * d; }
    var *= (1.f / 64.f);
    sMu[tid] = mu;
    sRs[tid] = rsqrtf(var + 1e-5f);
  }
  __syncthreads();
#pragma unroll
  for (int i = 0; i < 16; ++i) {
    int idx = tid + i * 256;
    int px = idx >> 6, c = idx & 63;
    float xn = (sStage[px][c] - sMu[px]) * sRs[px] * ln2_w[c] + ln2_b[c];
    sXnb[px][c] = f2bf(xn);
  }
  __syncthreads();
  const int w = tid >> 6, lane = tid & 63;
  const int col = lane & 15, kgrp = lane >> 4;
  const int og = o0base + w * 16 + col;
  f32x4 acc[4];
#pragma unroll
  for (int s = 0; s < 4; ++s) acc[s] = (f32x4){0.f, 0.f, 0.f, 0.f};
#pragma unroll
  for (int kk = 0; kk < 2; ++kk) {
    const int c0 = kk * 32 + kgrp * 8;
    union { short8v v; unsigned short s[8]; } bw;
    const float* wp = ffn_in_w + (size_t)og * 64 + c0;
#pragma unroll
    for (int j = 0; j < 8; ++j) bw.s[j] = f2bf(wp[j]);
#pragma unroll
    for (int s = 0; s < 4; ++s) {
      short8v av = *reinterpret_cast<const short8v*>(&sXnb[s * 16 + col][c0]);
      acc[s] = __builtin_amdgcn_mfma_f32_16x16x32_bf16(av, bw.v, acc[s], 0, 0, 0);
    }
  }
  unsigned short* outb = reinterpret_cast<unsigned short*>(&sStage[0][0]);
  const int o_l = w * 16 + col;
#pragma unroll
  for (int s = 0; s < 4; ++s) {
#pragma unroll
    for (int r = 0; r < 4; ++r) {
      int px_l = s * 16 + kgrp * 4 + r;
      outb[o_l * 72 + px_l] = f2bf(acc[s][r]);
    }
  }
  __syncthreads();
  {
    const int ol = tid >> 2, seg = tid & 3;
    const unsigned short* src = outb + ol * 72 + seg * 16;
    unsigned short* dst = Tb + (size_t)(o0base + ol) * HW + px0 + seg * 16;
    *reinterpret_cast<short8v*>(dst) = *reinterpret_cast<const short8v*>(src);
    *(reinterpret_cast<short8v*>(dst) + 1) = *(reinterpret_cast<const short8v*>(src) + 1);
  }
}

// ---------------- K5 checker: sample-verify MFMA T vs fp32 reference (b=0) ----------------
__global__ __launch_bounds__(256) void k5_check(
    const float* __restrict__ ln2_w, const float* __restrict__ ln2_b,
    const float* __restrict__ ffn_in_w, const float* __restrict__ dout,
    const unsigned short* __restrict__ Tb, float* __restrict__ bad)
{
  const int i = blockIdx.x * 256 + threadIdx.x;
  const int px = (i * 16) & (HW - 1);
  const float* yb = dout + px;
  float xv[64];
  float mu = 0.f;
#pragma unroll
  for (int c = 0; c < 64; ++c) { xv[c] = yb[(size_t)c * HW]; mu += xv[c]; }
  mu *= (1.f / 64.f);
  float var = 0.f;
#pragma unroll
  for (int c = 0; c < 64; ++c) { float d = xv[c] - mu; var += d * d; }
  var *= (1.f / 64.f);
  float rs = rsqrtf(var + 1e-5f);
#pragma unroll
  for (int c = 0; c < 64; ++c) xv[c] = (xv[c] - mu) * rs * ln2_w[c] + ln2_b[c];
  bool fail = false;
  for (int o = 0; o < 256; ++o) {
    float s = 0.f;
#pragma unroll
    for (int c = 0; c < 64; ++c) s += ffn_in_w[o * 64 + c] * xv[c];
    float got = bf2f(Tb[(size_t)o * HW + px]);
    if (fabsf(got - s) > 0.03f + 0.03f * fabsf(s)) fail = true;
  }
  if (fail) atomicExch(bad, 1.f);
}

// ---------------- K5 fallback: scalar LN2+ffn_in (only if checker failed) ----------------
__global__ __launch_bounds__(256) void k5_fb(
    const float* __restrict__ ln2_w, const float* __restrict__ ln2_b,
    const float* __restrict__ ffn_in_w, const float* __restrict__ dout,
    const float* __restrict__ bad, unsigned short* __restrict__ Tb, int b)
{
  if (bad[0] < 0.5f) return;
  __shared__ float sW[4096];
  const int tid = threadIdx.x;
  const int obase = blockIdx.y * 64;
  for (int i = tid; i < 4096; i += 256) sW[i] = ffn_in_w[obase * 64 + i];
  const int px = blockIdx.x * 256 + tid;
  const float* yb = dout + (size_t)b * 64 * HW + px;
  float xv[64];
  float mu = 0.f;
#pragma unroll
  for (int c = 0; c < 64; ++c) { xv[c] = yb[(size_t)c * HW]; mu += xv[c]; }
  mu *= (1.f / 64.f);
  float var = 0.f;
#pragma unroll
  for (int c = 0; c < 64; ++c) { float d = xv[c] - mu; var += d * d; }
  var *= (1.f / 64.f);
  float rsv = rsqrtf(var + 1e-5f);
#pragma unroll
  for (int c = 0; c < 64; ++c) xv[c] = (xv[c] - mu) * rsv * ln2_w[c] + ln2_b[c];
  __syncthreads();
  unsigned short* Tp = Tb + (size_t)obase * HW + px;
  for (int o = 0; o < 64; ++o) {
    float s = 0.f;
#pragma unroll
    for (int c = 0; c < 64; ++c) s += sW[o * 64 + c] * xv[c];
    Tp[(size_t)o * HW] = f2bf(s);
  }
}

// ---------------- K6a: dwconv3/dwconv5 + gelu*mul -> Y (bf16), one batch, j-chunked ----------------
__global__ __launch_bounds__(256) void k6a_dw(
    const float* __restrict__ dw3_w, const float* __restrict__ dw5_w,
    const unsigned short* __restrict__ T, __hip_bfloat16* __restrict__ Y)
{
  const int tid = threadIdx.x;
  const int px = blockIdx.x * 256 + tid;
  const int j0 = blockIdx.y * 8;
  const int row = px >> 8, col = px & 255;
  bool oky[5], okx[5];
#pragma unroll
  for (int d = 0; d < 5; ++d) {
    oky[d] = ((unsigned)(row + d - 2) < 256u);
    okx[d] = ((unsigned)(col + d - 2) < 256u);
  }
#pragma unroll
  for (int jj = 0; jj < 8; ++jj) {
    const int j = j0 + jj;
    const unsigned short* pl = T + (size_t)j * HW;
    float a = 0.f;
#pragma unroll
    for (int dy = -1; dy <= 1; ++dy) {
      if (!oky[dy + 2]) continue;
#pragma unroll
      for (int dx = -1; dx <= 1; ++dx) {
        if (!okx[dx + 2]) continue;
        a += bf2f(pl[px + dy * 256 + dx]) * dw3_w[j * 9 + (dy + 1) * 3 + (dx + 1)];
      }
    }
    float m = 0.f;
    const unsigned short* pm = T + (size_t)(128 + j) * HW;
    if (j < 64) {
#pragma unroll
      for (int dy = -1; dy <= 1; ++dy) {
        if (!oky[dy + 2]) continue;
#pragma unroll
        for (int dx = -1; dx <= 1; ++dx) {
          if (!okx[dx + 2]) continue;
          m += bf2f(pm[px + dy * 256 + dx]) * dw3_w[(128 + j) * 9 + (dy + 1) * 3 + (dx + 1)];
        }
      }
    } else {
#pragma unroll
      for (int dy = -2; dy <= 2; ++dy) {
        if (!oky[dy + 2]) continue;
#pragma unroll
        for (int dx = -2; dx <= 2; ++dx) {
          if (!okx[dx + 2]) continue;
          m += bf2f(pm[px + dy * 256 + dx]) * dw5_w[(j - 64) * 25 + (dy + 2) * 5 + (dx + 2)];
        }
      }
    }
    float gl = 0.5f * a * (1.f + erff(a * 0.70710678118654752f));
    Y[(size_t)j * HW + px] = __float2bfloat16(gl * m);
  }
}

// ---------------- K6b: ffn_out (128->64) from Y, one batch, o-chunked ----------------
__global__ __launch_bounds__(256) void k6b_out(
    const float* __restrict__ ffn_out_w, const __hip_bfloat16* __restrict__ Y,
    const float* __restrict__ flag, float* __restrict__ dout, float* __restrict__ Z, int b)
{
  __shared__ float sW[2048];
  const int tid = threadIdx.x;
  const int o0 = blockIdx.y * 16;
  for (int i = tid; i < 2048; i += 256) sW[i] = ffn_out_w[o0 * 128 + i];
  __syncthreads();
  const int px = blockIdx.x * 256 + tid;
  float z[16];
#pragma unroll
  for (int o = 0; o < 16; ++o) z[o] = 0.f;
  for (int j = 0; j < 128; ++j) {
    float yv = __bfloat162float(Y[(size_t)j * HW + px]);
#pragma unroll
    for (int o = 0; o < 16; ++o) z[o] += sW[o * 128 + j] * yv;
  }
  if (flag[0] > 0.5f) {
    float* ob = dout + (size_t)(b * 64 + o0) * HW + px;
#pragma unroll
    for (int o = 0; o < 16; ++o) ob[(size_t)o * HW] += z[o];
  } else {
    float* zb = Z + (size_t)o0 * HW + px;
#pragma unroll
    for (int o = 0; o < 16; ++o) zb[(size_t)o * HW] = z[o];
  }
}

// ---------------- K7: general fft path (early-exit if identity) ----------------
__global__ __launch_bounds__(256) void k7_fft(
    const float* __restrict__ fftw, const float* __restrict__ flag,
    const float* __restrict__ Z, float* __restrict__ dout, int b)
{
  if (flag[0] > 0.5f) return;
  __shared__ float swv[64];
  __shared__ float spatch[4][64];
  const int tid = threadIdx.x;
  const int c = blockIdx.x >> 8;
  const int pblk = blockIdx.x & 255;
  if (tid < 64) swv[tid] = fftw[c * 64 + tid];
  const int lp = tid >> 6, e = tid & 63;
  const int patch = pblk * 4 + lp;
  const int pi = patch >> 5, pj = patch & 31;
  const int i = e >> 3, jj = e & 7;
  const int gidx = (pi * 8 + i) * 256 + pj * 8 + jj;
  const float zv = Z[(size_t)c * HW + gidx];
  spatch[lp][e] = zv;
  __syncthreads();
  float s = 0.f;
#pragma unroll
  for (int a = 0; a < 8; ++a)
#pragma unroll
    for (int b2 = 0; b2 < 8; ++b2)
      s += swv[a * 8 + b2] * spatch[lp][((i - a) & 7) * 8 + ((jj - b2) & 7)];
  dout[(size_t)(b * 64 + c) * HW + gidx] += s;
}

extern "C" void kernel_launch(void* const* d_in, const int* in_sizes, int n_in,
                              void* d_out, int out_size, void* d_ws, size_t ws_size,
                              hipStream_t stream) {
  const float* x          = (const float*)d_in[0];
  const float* ln1_w      = (const float*)d_in[1];
  const float* ln1_b      = (const float*)d_in[2];
  const float* in_proj_w  = (const float*)d_in[3];
  const float* qkv_w      = (const float*)d_in[4];
  const float* qkv_dw     = (const float*)d_in[5];
  const float* out_proj_w = (const float*)d_in[6];
  const float* temperature= (const float*)d_in[7];
  const float* attn_scales= (const float*)d_in[8];
  const float* gate_w1    = (const float*)d_in[9];
  const float* gate_b1    = (const float*)d_in[10];
  const float* gate_w2    = (const float*)d_in[11];
  const float* gate_b2    = (const float*)d_in[12];
  const float* lgce_pre_w = (const float*)d_in[13];
  const float* lgce_pre_b = (const float*)d_in[14];
  const float* lgce_post_w= (const float*)d_in[15];
  const float* lgce_post_b= (const float*)d_in[16];
  const float* cbam_m1w   = (const float*)d_in[17];
  const float* cbam_m1b   = (const float*)d_in[18];
  const float* cbam_m2w   = (const float*)d_in[19];
  const float* cbam_m2b   = (const float*)d_in[20];
  const float* cbam_spw   = (const float*)d_in[21];
  const float* cbam_spb   = (const float*)d_in[22];
  const float* ln2_w      = (const float*)d_in[23];
  const float* ln2_b      = (const float*)d_in[24];
  const float* ffn_in_w   = (const float*)d_in[25];
  const float* dw3_w      = (const float*)d_in[26];
  const float* dw5_w      = (const float*)d_in[27];
  const float* ffn_out_w  = (const float*)d_in[28];
  const float* fft_W      = (const float*)d_in[29];
  float* ws = (float*)d_ws;
  float* out = (float*)d_out;
  unsigned short* Tb = (unsigned short*)(ws + OFF_T);
  __hip_bfloat16* Ybuf = (__hip_bfloat16*)(ws + OFF_Y);

  hipLaunchKernelGGL(k0_setup, dim3(1), dim3(256), 0, stream, fft_W, ws);
  hipLaunchKernelGGL(k1_proj, dim3(1024), dim3(256), 0, stream,
                     x, ln1_w, ln1_b, in_proj_w, qkv_w, lgce_pre_w, lgce_pre_b,
                     gate_w1, gate_b1, gate_w2, gate_b2,
                     out, ws + OFF_QKVL, ws + OFF_POOL, ws + OFF_GSUM);
  hipLaunchKernelGGL(k2_mfma, dim3(128, 4, 4), dim3(256), 0, stream,
                     ws + OFF_QKVL, qkv_dw, ws + OFF_GRAM);
  hipLaunchKernelGGL(k3_final, dim3(1), dim3(256), 0, stream,
                     cbam_m1w, cbam_m1b, cbam_m2w, cbam_m2b, temperature, attn_scales,
                     ws + OFF_GSUM, ws + OFF_POOL, ws + OFF_GRAM, ws + OFF_A, ws + OFF_CW);
  hipLaunchKernelGGL(k4a_thr, dim3(1024), dim3(256), 0, stream,
                     lgce_pre_w, lgce_pre_b, cbam_spw, cbam_spb, ws + OFF_CW, out, ws + OFF_THR);
  hipLaunchKernelGGL(k4b_fuse, dim3(1024), dim3(256), 0, stream,
                     x, lgce_pre_w, lgce_pre_b, lgce_post_w, lgce_post_b, out_proj_w,
                     cbam_spw, cbam_spb, qkv_dw, ws + OFF_QKVL,
                     ws + OFF_A, ws + OFF_CW, ws + OFF_THR, out);

  for (int b = 0; b < 4; ++b) {
    hipLaunchKernelGGL(k5_mfma, dim3(1024, 4), dim3(256), 0, stream,
                       ln2_w, ln2_b, ffn_in_w, out, Tb, b);
    if (b == 0)
      hipLaunchKernelGGL(k5_check, dim3(16), dim3(256), 0, stream,
                         ln2_w, ln2_b, ffn_in_w, out, Tb, ws + OFF_BAD);
    hipLaunchKernelGGL(k5_fb, dim3(256, 4), dim3(256), 0, stream,
                       ln2_w, ln2_b, ffn_in_w, out, ws + OFF_BAD, Tb, b);
    hipLaunchKernelGGL(k6a_dw, dim3(256, 16), dim3(256), 0, stream,
                       dw3_w, dw5_w, Tb, Ybuf);
    hipLaunchKernelGGL(k6b_out, dim3(256, 4), dim3(256), 0, stream,
                       ffn_out_w, Ybuf, ws + OFF_FLAG, out, ws + OFF_Z, b);
    hipLaunchKernelGGL(k7_fft, dim3(16384), dim3(256), 0, stream,
                       ws + OFF_FFTW, ws + OFF_FLAG, ws + OFF_Z, out, b);
  }
}

// Round 6
// 1668.286 us; speedup vs baseline: 3.8331x; 1.0664x over previous
//
#include <hip/hip_runtime.h>
#include <hip/hip_bf16.h>
#include <math.h>

#define HW 65536
#define NPIX 262144

// ---- workspace layout (float offsets) ----
#define OFF_FFTW 0            // 64x64 spatial fft kernel
#define OFF_FLAG 4096         // 1
#define OFF_GSUM 4097         // 1    (zeroed in k0)
#define OFF_POOL 4098         // 128  (zeroed in k0)  -- pooled(loc) sums
#define OFF_GRAM 4226         // 1280 (zeroed in k0)
#define OFF_THR  5506         // 32   (zeroed in k0)
#define OFF_BAD  5538         // 1    (zeroed in k0)  -- k1 checker flag
#define OFF_A    5539         // 1024
#define OFF_CW   6563         // 128
#define OFF_QKVL 8192         // 96ch * 262144 px bf16 = 12582912 float-slots (SGSA phase)
#define OFF_MQKV 12591104     // 96*64 fp32 composed qkv matrix
#define OFF_MG1  (OFF_MQKV + 6144)   // 16*64 fp32 composed gate matrix (ends 12598272)
// MFFN phase (per-batch, overlap QKVL which is dead by then; T actually ends 8396800 < OFF_MQKV):
#define OFF_T    8192                      // 256ch * 65536 bf16
#define OFF_Y    (OFF_T + 16777216)        // 128ch * 65536 bf16
#define OFF_Z    (OFF_Y + 4194304)         // 64ch * 65536 fp32
// peak ws usage = 25174016 floats = 100.7 MB (unchanged proven footprint)

typedef __attribute__((ext_vector_type(8))) short short8v;
typedef __attribute__((ext_vector_type(4))) float f32x4;

__device__ __forceinline__ float sigm(float v) { return 1.f / (1.f + expf(-v)); }
__device__ __forceinline__ float wredsum(float v) {
#pragma unroll
  for (int off = 32; off >= 1; off >>= 1) v += __shfl_xor(v, off);
  return v;
}
__device__ __forceinline__ unsigned short f2bf(float f) {
  union { float f; unsigned u; } x; x.f = f;
  unsigned r = x.u + 0x7fffu + ((x.u >> 16) & 1u);
  return (unsigned short)(r >> 16);
}
__device__ __forceinline__ float bf2f(unsigned short u) {
  union { unsigned u; float f; } x; x.u = ((unsigned)u) << 16;
  return x.f;
}

// ---------------- K0: zero accumulators + fft spatial kernel + composed matrices ----------------
__global__ __launch_bounds__(256) void k0_setup(
    const float* __restrict__ fft_W, const float* __restrict__ in_proj_w,
    const float* __restrict__ qkv_w, const float* __restrict__ g1w,
    float* __restrict__ ws)
{
  __shared__ float ct8[8];
  __shared__ int sbad;
  const int tid = threadIdx.x;
  if (tid < 8) ct8[tid] = cosf((float)tid * 0.78539816339744831f); // cos(k*pi/4)
  if (tid == 0) sbad = 0;
  for (int i = tid; i < 1442; i += 256) ws[OFF_GSUM + i] = 0.f;    // gsum,pool,gram,thr,bad
  // composed matrices: mqkv = qkv_w @ in_proj[32:64], mg1 = g1w @ in_proj[32:64]
  for (int i = tid; i < 96 * 64; i += 256) {
    int o = i >> 6, c = i & 63;
    float s = 0.f;
    for (int j = 0; j < 32; ++j) s += qkv_w[o * 32 + j] * in_proj_w[(32 + j) * 64 + c];
    ws[OFF_MQKV + i] = s;
  }
  for (int i = tid; i < 16 * 64; i += 256) {
    int o = i >> 6, c = i & 63;
    float s = 0.f;
    for (int j = 0; j < 32; ++j) s += g1w[o * 32 + j] * in_proj_w[(32 + j) * 64 + c];
    ws[OFF_MG1 + i] = s;
  }
  __syncthreads();
  bool ok = true;
  for (int i = tid; i < 64 * 64; i += 256) {
    int ch = i >> 6, ab = i & 63;
    int a = ab >> 3, b2 = ab & 7;
    float s = 0.f;
    for (int u = 0; u < 8; ++u)
      for (int v = 0; v < 8; ++v) {
        float Wf;
        if (v == 0 || v == 4)
          Wf = 0.5f * (fft_W[ch * 40 + u * 5 + v] + fft_W[ch * 40 + ((8 - u) & 7) * 5 + v]);
        else if (v < 5)
          Wf = fft_W[ch * 40 + u * 5 + v];
        else
          Wf = fft_W[ch * 40 + ((8 - u) & 7) * 5 + (8 - v)];
        s += Wf * ct8[(u * a + v * b2) & 7];
      }
    s *= (1.f / 64.f);
    ws[OFF_FFTW + i] = s;
    float expect = ((i & 63) == 0) ? 1.f : 0.f;
    if (fabsf(s - expect) > 1e-4f) ok = false;
  }
  if (!ok) atomicOr(&sbad, 1);
  __syncthreads();
  if (tid == 0) ws[OFF_FLAG] = sbad ? 0.f : 1.f;
}

// ---------------- K1 (MFMA): LN1 + [loc(32) | qkv(96)] via composed matrices + gate + pooled-loc ----------------
// block: 64 px; 4 waves x 2 passes = 8 MFMA tiles of 16 outs.
__global__ __launch_bounds__(256) void k1_mfma(
    const float* __restrict__ x, const float* __restrict__ ln1_w, const float* __restrict__ ln1_b,
    const float* __restrict__ in_proj_w, const float* __restrict__ mqkv, const float* __restrict__ mg1,
    const float* __restrict__ g1b, const float* __restrict__ g2w, const float* __restrict__ g2b,
    float* __restrict__ dout, unsigned short* __restrict__ qkvl,
    float* __restrict__ pooled, float* __restrict__ gsum)
{
  __shared__ float sStage[64][65];          // raw x; reused as fp32 loc tile [32][65] after LN
  __shared__ unsigned short sXnb[64][72];   // LN'd bf16 activations
  __shared__ unsigned short sQkv[96][72];   // qkv outs bf16
  __shared__ float sMu[64], sRs[64];
  __shared__ float sPoolL[32];
  __shared__ float sRed[4];
  const int tid = threadIdx.x;
  const int p0 = blockIdx.x * 64;
  const int b = p0 >> 16;
  const int hw0 = p0 & (HW - 1);
  const float* xb = x + (size_t)(b * 64) * HW + hw0;
#pragma unroll
  for (int i = 0; i < 16; ++i) {
    int idx = tid + i * 256;
    int c = idx >> 6, px = idx & 63;
    sStage[px][c] = xb[(size_t)c * HW + px];
  }
  __syncthreads();
  if (tid < 64) {
    float mu = 0.f;
#pragma unroll
    for (int c = 0; c < 64; ++c) mu += sStage[tid][c];
    mu *= (1.f / 64.f);
    float var = 0.f;
#pragma unroll
    for (int c = 0; c < 64; ++c) { float d = sStage[tid][c] - mu; var += d * d; }
    var *= (1.f / 64.f);
    sMu[tid] = mu;
    sRs[tid] = rsqrtf(var + 1e-5f);
  }
  __syncthreads();
#pragma unroll
  for (int i = 0; i < 16; ++i) {
    int idx = tid + i * 256;
    int px = idx >> 6, c = idx & 63;
    float xn = (sStage[px][c] - sMu[px]) * sRs[px] * ln1_w[c] + ln1_b[c];
    sXnb[px][c] = f2bf(xn);
  }
  __syncthreads();
  const int w = tid >> 6, lane = tid & 63;
  const int col = lane & 15, kgrp = lane >> 4;
  float* sLoc = &sStage[0][0];              // [o][px] stride 65, o<32 (sStage now free)
#pragma unroll
  for (int pass = 0; pass < 2; ++pass) {
    const int tile = pass * 4 + w;
    const int og = tile * 16 + col;         // 0..127
    f32x4 acc[4];
#pragma unroll
    for (int s = 0; s < 4; ++s) acc[s] = (f32x4){0.f, 0.f, 0.f, 0.f};
#pragma unroll
    for (int kk = 0; kk < 2; ++kk) {
      const int c0 = kk * 32 + kgrp * 8;
      const float* wrow = (og < 32) ? (in_proj_w + og * 64) : (mqkv + (og - 32) * 64);
      union { short8v v; unsigned short s[8]; } bw;
#pragma unroll
      for (int j = 0; j < 8; ++j) bw.s[j] = f2bf(wrow[c0 + j]);
#pragma unroll
      for (int s = 0; s < 4; ++s) {
        short8v av = *reinterpret_cast<const short8v*>(&sXnb[s * 16 + col][c0]);
        acc[s] = __builtin_amdgcn_mfma_f32_16x16x32_bf16(av, bw.v, acc[s], 0, 0, 0);
      }
    }
    if (og < 32) {
      float ps = 0.f;
#pragma unroll
      for (int s = 0; s < 4; ++s) {
#pragma unroll
        for (int r = 0; r < 4; ++r) {
          int px_l = s * 16 + kgrp * 4 + r;
          sLoc[og * 65 + px_l] = acc[s][r];
          ps += acc[s][r];
        }
      }
      ps += __shfl_xor(ps, 16);
      ps += __shfl_xor(ps, 32);
      if (kgrp == 0) sPoolL[og] = ps;
    } else {
      const int oq = og - 32;
#pragma unroll
      for (int s = 0; s < 4; ++s) {
#pragma unroll
        for (int r = 0; r < 4; ++r) {
          int px_l = s * 16 + kgrp * 4 + r;
          sQkv[oq][px_l] = f2bf(acc[s][r]);
        }
      }
    }
  }
  // gate (scalar fp32 weights, bf16 activations): thread -> (px = tid>>2, 4 h-rows)
  {
    const int gpx = tid >> 2, gq = tid & 3;
    float h[4];
#pragma unroll
    for (int i = 0; i < 4; ++i) h[i] = g1b[gq * 4 + i];
#pragma unroll
    for (int cc = 0; cc < 64; cc += 8) {
      union { short8v v; unsigned short s[8]; } xu;
      xu.v = *reinterpret_cast<const short8v*>(&sXnb[gpx][cc]);
#pragma unroll
      for (int j = 0; j < 8; ++j) {
        float xf = bf2f(xu.s[j]);
#pragma unroll
        for (int i = 0; i < 4; ++i) h[i] += mg1[(gq * 4 + i) * 64 + cc + j] * xf;
      }
    }
    float gpart = 0.f;
#pragma unroll
    for (int i = 0; i < 4; ++i) gpart += g2w[gq * 4 + i] * fmaxf(h[i], 0.f);
    gpart += __shfl_xor(gpart, 1);
    gpart += __shfl_xor(gpart, 2);
    float gv = (gq == 0) ? sigm(gpart + g2b[0]) : 0.f;
    gv = wredsum(gv);
    if (lane == 0) sRed[w] = gv;
  }
  __syncthreads();
  // cooperative stores
  for (int i = tid; i < 2048; i += 256) {
    int o = i >> 6, px = i & 63;
    dout[(size_t)(b * 64 + o) * HW + hw0 + px] = sLoc[o * 65 + px];
  }
  for (int i = tid; i < 768; i += 256) {
    int o = i >> 3, seg = i & 7;
    *reinterpret_cast<short8v*>(qkvl + (size_t)(b * 96 + o) * HW + hw0 + seg * 8) =
        *reinterpret_cast<const short8v*>(&sQkv[o][seg * 8]);
  }
  if (tid < 32) atomicAdd(&pooled[b * 32 + tid], sPoolL[tid]);
  if (tid == 0) atomicAdd(gsum, sRed[0] + sRed[1] + sRed[2] + sRed[3]);
}

// ---------------- K1 checker: 256 sampled px vs independent glob-chain fp32 reference ----------------
__global__ __launch_bounds__(256) void k1_check(
    const float* __restrict__ x, const float* __restrict__ ln1_w, const float* __restrict__ ln1_b,
    const float* __restrict__ in_proj_w, const float* __restrict__ qkv_w,
    const float* __restrict__ dout, const unsigned short* __restrict__ qkvl,
    float* __restrict__ bad)
{
  const int t = threadIdx.x;
  const int b = t & 3;
  const int px = (t * 1031) & (HW - 1);
  const float* xb = x + (size_t)(b * 64) * HW + px;
  float xv[64];
  float mu = 0.f;
#pragma unroll
  for (int c = 0; c < 64; ++c) { xv[c] = xb[(size_t)c * HW]; mu += xv[c]; }
  mu *= (1.f / 64.f);
  float var = 0.f;
#pragma unroll
  for (int c = 0; c < 64; ++c) { float d = xv[c] - mu; var += d * d; }
  var *= (1.f / 64.f);
  float rs = rsqrtf(var + 1e-5f);
#pragma unroll
  for (int c = 0; c < 64; ++c) xv[c] = (xv[c] - mu) * rs * ln1_w[c] + ln1_b[c];
  bool fail = false;
  float gl[32];
  for (int o = 0; o < 32; ++o) {
    float s = 0.f;
#pragma unroll
    for (int c = 0; c < 64; ++c) s += in_proj_w[o * 64 + c] * xv[c];
    float got = dout[(size_t)(b * 64 + o) * HW + px];
    if (fabsf(got - s) > 0.05f + 0.05f * fabsf(s)) fail = true;
    float s2 = 0.f;
#pragma unroll
    for (int c = 0; c < 64; ++c) s2 += in_proj_w[(32 + o) * 64 + c] * xv[c];
    gl[o] = s2;
  }
  for (int o = 0; o < 96; ++o) {
    float s = 0.f;
#pragma unroll
    for (int j = 0; j < 32; ++j) s += qkv_w[o * 32 + j] * gl[j];
    float got = bf2f(qkvl[(size_t)(b * 96 + o) * HW + px]);
    if (fabsf(got - s) > 0.05f + 0.05f * fabsf(s)) fail = true;
  }
  if (fail) atomicExch(bad, 1.f);
}

// ---------------- K1 reset (only if checker failed): zero gsum+pooled ----------------
__global__ __launch_bounds__(256) void k1r_reset(const float* __restrict__ bad, float* __restrict__ gsum)
{
  if (bad[0] < 0.5f) return;
  const int tid = threadIdx.x;
  if (tid < 129) gsum[tid] = 0.f;   // gsum(1) + pooled(128), contiguous
}

// ---------------- K1 fallback: full scalar path (only if checker failed) ----------------
__global__ __launch_bounds__(256) void k1_fb(
    const float* __restrict__ x, const float* __restrict__ ln1_w, const float* __restrict__ ln1_b,
    const float* __restrict__ in_proj_w, const float* __restrict__ qkv_w,
    const float* __restrict__ g1w, const float* __restrict__ g1b,
    const float* __restrict__ g2w, const float* __restrict__ g2b,
    const float* __restrict__ bad,
    float* __restrict__ dout, unsigned short* __restrict__ qkvl,
    float* __restrict__ pooled, float* __restrict__ gsum)
{
  if (bad[0] < 0.5f) return;
  __shared__ float sPool[4][32];
  __shared__ float sRed[4];
  const int tid = threadIdx.x;
  const int p = blockIdx.x * 256 + tid;
  const int b = p >> 16;
  const int hw = p & (HW - 1);
  const int wave = tid >> 6, lane = tid & 63;
  const float* xb = x + (size_t)(b * 64) * HW + hw;
  float xv[64];
  float mu = 0.f;
#pragma unroll
  for (int c = 0; c < 64; ++c) { xv[c] = xb[(size_t)c * HW]; mu += xv[c]; }
  mu *= (1.f / 64.f);
  float var = 0.f;
#pragma unroll
  for (int c = 0; c < 64; ++c) { float d = xv[c] - mu; var += d * d; }
  var *= (1.f / 64.f);
  const float rs = rsqrtf(var + 1e-5f);
#pragma unroll
  for (int c = 0; c < 64; ++c) xv[c] = (xv[c] - mu) * rs * ln1_w[c] + ln1_b[c];
  float loc[32];
  for (int o = 0; o < 32; ++o) {
    float s = 0.f;
#pragma unroll
    for (int c = 0; c < 64; ++c) s += in_proj_w[o * 64 + c] * xv[c];
    loc[o] = s;
    dout[(size_t)(b * 64 + o) * HW + hw] = s;
    float r = wredsum(s);
    if (lane == 0) sPool[wave][o] = r;
  }
  float gl[32];
  for (int o = 0; o < 32; ++o) {
    float s = 0.f;
#pragma unroll
    for (int c = 0; c < 64; ++c) s += in_proj_w[(32 + o) * 64 + c] * xv[c];
    gl[o] = s;
  }
  for (int o = 0; o < 96; ++o) {
    float s = 0.f;
#pragma unroll
    for (int j = 0; j < 32; ++j) s += qkv_w[o * 32 + j] * gl[j];
    qkvl[(size_t)(b * 96 + o) * HW + hw] = f2bf(s);
  }
  float gacc = g2b[0];
  for (int o = 0; o < 16; ++o) {
    float h = g1b[o];
#pragma unroll
    for (int j = 0; j < 32; ++j) h += g1w[o * 32 + j] * gl[j];
    gacc += g2w[o] * fmaxf(h, 0.f);
  }
  float gv = wredsum(sigm(gacc));
  if (lane == 0) sRed[wave] = gv;
  __syncthreads();
  if (tid == 0) atomicAdd(gsum, sRed[0] + sRed[1] + sRed[2] + sRed[3]);
  if (tid < 32) {
    float s = sPool[0][tid] + sPool[1][tid] + sPool[2][tid] + sPool[3][tid];
    atomicAdd(&pooled[b * 32 + tid], s);
  }
}

// ---------------- K2 (MFMA): dwconv(q,k) + Gram via V·V^T (qkvl now bf16) ----------------
__global__ __launch_bounds__(256) void k2_mfma(
    const unsigned short* __restrict__ qkvl, const float* __restrict__ qkv_dw, float* __restrict__ gram)
{
  __shared__ float sred[4][256];
  const int tid = threadIdx.x;
  const int slab = blockIdx.x;
  const int h = blockIdx.y, b = blockIdx.z;
  const int w = tid >> 6, lane = tid & 63;
  const int ch = lane & 15, grp = lane >> 4;
  const int gch = (ch < 8) ? (h * 8 + ch) : (32 + h * 8 + (ch - 8));
  const unsigned short* plane = qkvl + (size_t)(b * 96 + gch) * HW;
  const float* wt = qkv_dw + gch * 9;
  float w9[9];
#pragma unroll
  for (int t = 0; t < 9; ++t) w9[t] = wt[t];
  f32x4 acc = (f32x4){0.f, 0.f, 0.f, 0.f};
#pragma unroll
  for (int iter = 0; iter < 4; ++iter) {
    const int pxbase = slab * 512 + w * 128 + iter * 32 + grp * 8;
    const int y = pxbase >> 8;
    const int x0 = pxbase & 255;
    union { short8v v; unsigned short s[8]; } frag;
#pragma unroll
    for (int j = 0; j < 8; ++j) {
      const int x = x0 + j;
      float a = 0.f;
#pragma unroll
      for (int dy = -1; dy <= 1; ++dy) {
        const int yy = y + dy;
        if ((unsigned)yy >= 256u) continue;
#pragma unroll
        for (int dx = -1; dx <= 1; ++dx) {
          const int x2 = x + dx;
          if ((unsigned)x2 >= 256u) continue;
          a += bf2f(plane[yy * 256 + x2]) * w9[(dy + 1) * 3 + (dx + 1)];
        }
      }
      frag.s[j] = f2bf(a);
    }
    acc = __builtin_amdgcn_mfma_f32_16x16x32_bf16(frag.v, frag.v, acc, 0, 0, 0);
  }
#pragma unroll
  for (int r = 0; r < 4; ++r) sred[w][(grp * 4 + r) * 16 + ch] = acc[r];
  __syncthreads();
  if (tid < 256) {
    float g = sred[0][tid] + sred[1][tid] + sred[2][tid] + sred[3][tid];
    const int row = tid >> 4, col = tid & 15;
    int idx = -1;
    if (row < 8 && col >= 8) idx = row * 8 + (col - 8);
    else if (row == col && row < 8) idx = 64 + row;
    else if (row == col) idx = 72 + (row - 8);
    if (idx >= 0) atomicAdd(&gram[(b * 4 + h) * 80 + idx], g);
  }
}

// ---------------- K3: dk, CBAM weights (pooled = pooled-loc now), attention matrices ----------------
__global__ __launch_bounds__(256) void k3_final(
    const float* __restrict__ m1w, const float* __restrict__ m1b,
    const float* __restrict__ m2w, const float* __restrict__ m2b,
    const float* __restrict__ temperature, const float* __restrict__ attn_scales,
    const float* __restrict__ pre_w, const float* __restrict__ pre_b,
    const float* __restrict__ gsum, const float* __restrict__ pooled,
    const float* __restrict__ gram, float* __restrict__ Abuf, float* __restrict__ cwbuf)
{
  __shared__ int s_dk;
  __shared__ float s_scale;
  const int tid = threadIdx.x;
  if (tid == 0) {
    float gmean = gsum[0] / (float)NPIX;
    int dk = (int)floorf(8.f * gmean);
    if (dk < 1) dk = 1;
    if (dk > 8) dk = 8;
    s_dk = dk;
    s_scale = attn_scales[0] + attn_scales[1] + attn_scales[2] + attn_scales[3];
  }
  __syncthreads();
  if (tid < 128) {
    int b = tid >> 5, ch = tid & 31, g = ch >> 2, c = ch & 3;
    // pre-pooled from pooled-loc: mean(pre) = pre_w @ mean(loc) + pre_b
    float h1 = m1b[g];
#pragma unroll
    for (int cc = 0; cc < 4; ++cc) {
      int row = g * 4 + cc;
      float pp = pre_b[row];
#pragma unroll
      for (int j = 0; j < 32; ++j)
        pp += pre_w[row * 32 + j] * (pooled[b * 32 + j] * (1.f / 65536.f));
      h1 += pp * m1w[g * 4 + cc];
    }
    h1 = fmaxf(h1, 0.f);
    cwbuf[tid] = sigm(h1 * m2w[g * 4 + c] + m2b[g * 4 + c]);

    int r = tid, h = (r >> 3) & 3, c8 = r & 7;
    const float* gm = gram + (b * 4 + h) * 80;
    float qn = fmaxf(sqrtf(gm[64 + c8]), 1e-12f);
    float temp = temperature[h];
    float a[8];
#pragma unroll
    for (int d = 0; d < 8; ++d) {
      float kn = fmaxf(sqrtf(gm[72 + d]), 1e-12f);
      a[d] = gm[c8 * 8 + d] / (qn * kn) * temp;
    }
    float t[8];
#pragma unroll
    for (int d = 0; d < 8; ++d) t[d] = a[d];
#pragma unroll
    for (int i = 0; i < 8; ++i)
#pragma unroll
      for (int j = 0; j < 8; ++j)
        if (j > i && t[j] > t[i]) { float tmp = t[i]; t[i] = t[j]; t[j] = tmp; }
    float kth = t[s_dk - 1];
    float mx = t[0];
    float e[8]; float sum = 0.f;
#pragma unroll
    for (int d = 0; d < 8; ++d) {
      e[d] = (a[d] >= kth) ? expf(a[d] - mx) : 0.f;
      sum += e[d];
    }
    float inv = s_scale / sum;
#pragma unroll
    for (int d = 0; d < 8; ++d) Abuf[r * 8 + d] = e[d] * inv;
  }
}

// ---------------- K4a: resp-mean (threshold) reduction; PRE recomputed from LOC ----------------
__global__ __launch_bounds__(256) void k4a_thr(
    const float* __restrict__ pre_w, const float* __restrict__ pre_b,
    const float* __restrict__ spw, const float* __restrict__ spb,
    const float* __restrict__ cwbuf, const float* __restrict__ dout, float* __restrict__ thrbuf)
{
  const int tid = threadIdx.x;
  const int p = blockIdx.x * 256 + tid;
  const int b = p >> 16, hw = p & (HW - 1);
  const float* LOCp = dout + (size_t)b * 64 * HW + hw;
  const float* cw = cwbuf + b * 32;
  float loc[32];
#pragma unroll
  for (int c = 0; c < 32; ++c) loc[c] = LOCp[(size_t)c * HW];
  float pre[32];
  for (int o = 0; o < 32; ++o) {
    float s = pre_b[o];
#pragma unroll
    for (int j = 0; j < 32; ++j) s += pre_w[o * 32 + j] * loc[j];
    pre[o] = s;
  }
  const int lane = tid & 63;
#pragma unroll
  for (int g = 0; g < 8; ++g) {
    float xa[4];
    float sdot = spb[g];
#pragma unroll
    for (int c = 0; c < 4; ++c) {
      xa[c] = pre[g * 4 + c] * cw[g * 4 + c];
      sdot += xa[c] * spw[g * 4 + c];
    }
    float sgv = sigm(sdot);
    float r = 0.f;
#pragma unroll
    for (int c = 0; c < 4; ++c) r += sigm(xa[c] * sgv);
    float v = wredsum(r);
    if (lane == 0) atomicAdd(&thrbuf[b * 8 + g], v);
  }
}

// ---------------- K4b: LGCE finish + V-dwconv(bf16) + attn + out_proj + residual -> dout ----------------
__global__ __launch_bounds__(256) void k4b_fuse(
    const float* __restrict__ x, const float* __restrict__ pre_w, const float* __restrict__ pre_b,
    const float* __restrict__ post_w, const float* __restrict__ post_b,
    const float* __restrict__ out_proj_w, const float* __restrict__ spw, const float* __restrict__ spb,
    const float* __restrict__ qkv_dw, const unsigned short* __restrict__ qkvl,
    const float* __restrict__ Abuf, const float* __restrict__ cwbuf, const float* __restrict__ thrbuf,
    float* dout)
{
  const int tid = threadIdx.x;
  const int p = blockIdx.x * 256 + tid;
  const int b = p >> 16, hw = p & (HW - 1);
  const int y = hw >> 8, xx = hw & 255;
  const float* cw = cwbuf + b * 32;
  const float* A = Abuf + b * 256;
  float* doutb = dout + (size_t)b * 64 * HW + hw;
  float loc[32];
#pragma unroll
  for (int c = 0; c < 32; ++c) loc[c] = doutb[(size_t)c * HW];
  float pre[32];
  for (int o = 0; o < 32; ++o) {
    float s = pre_b[o];
#pragma unroll
    for (int j = 0; j < 32; ++j) s += pre_w[o * 32 + j] * loc[j];
    pre[o] = s;
  }
  float mx[32];
#pragma unroll
  for (int g = 0; g < 8; ++g) {
    float xa[4];
    float sdot = spb[g];
#pragma unroll
    for (int c = 0; c < 4; ++c) {
      xa[c] = pre[g * 4 + c] * cw[g * 4 + c];
      sdot += xa[c] * spw[g * 4 + c];
    }
    float sgv = sigm(sdot);
    float thr = thrbuf[b * 8 + g] * (1.f / (4.f * 65536.f));
#pragma unroll
    for (int c = 0; c < 4; ++c) {
      float resp = sigm(xa[c] * sgv);
      float m = (resp > thr) ? 1.f : resp;
      mx[g * 4 + c] = pre[g * 4 + c] * m;
    }
  }
  int offs[9]; bool okn[9];
#pragma unroll
  for (int dy = -1; dy <= 1; ++dy)
#pragma unroll
    for (int dx = -1; dx <= 1; ++dx) {
      int i = (dy + 1) * 3 + (dx + 1);
      int yy = y + dy, x2 = xx + dx;
      okn[i] = ((unsigned)yy < 256u) && ((unsigned)x2 < 256u);
      offs[i] = yy * 256 + x2;
    }
  const unsigned short* vbase = qkvl + (size_t)(b * 96 + 64) * HW;
  float vv[32];
  for (int ch = 0; ch < 32; ++ch) {
    const unsigned short* plane = vbase + (size_t)ch * HW;
    float acc = 0.f;
#pragma unroll
    for (int i = 0; i < 9; ++i) if (okn[i]) acc += bf2f(plane[offs[i]]) * qkv_dw[(64 + ch) * 9 + i];
    vv[ch] = acc;
  }
  float fused[64];
#pragma unroll
  for (int j = 0; j < 32; ++j) {
    int h = j >> 3, c = j & 7;
    float s = 0.f;
#pragma unroll
    for (int d = 0; d < 8; ++d) s += A[(h * 8 + c) * 8 + d] * vv[h * 8 + d];
    fused[j] = s;
  }
  for (int o = 0; o < 32; ++o) {
    float s = post_b[o];
#pragma unroll
    for (int j = 0; j < 32; ++j) s += post_w[o * 32 + j] * mx[j];
    fused[32 + o] = s + loc[o];
  }
  const float* xb = x + (size_t)b * 64 * HW + hw;
  for (int o = 0; o < 64; ++o) {
    float s = 0.f;
#pragma unroll
    for (int j = 0; j < 64; ++j) s += out_proj_w[o * 64 + j] * fused[j];
    doutb[(size_t)o * HW] = s + xb[(size_t)o * HW];
  }
}

// ---------------- K5 (MFMA): LN2 + ffn_in (64->256), 128 outs/block ----------------
__global__ __launch_bounds__(256) void k5_mfma(
    const float* __restrict__ ln2_w, const float* __restrict__ ln2_b,
    const float* __restrict__ ffn_in_w, const float* __restrict__ dout,
    unsigned short* __restrict__ Tb, int b)
{
  __shared__ float sStage[64][65];
  __shared__ unsigned short sXnb[64][72];
  __shared__ unsigned short sOutB[128][72];
  __shared__ float sMu[64], sRs[64];
  const int tid = threadIdx.x;
  const int px0 = blockIdx.x * 64;
  const int o0base = blockIdx.y * 128;
  const float* db = dout + (size_t)(b * 64) * HW + px0;
#pragma unroll
  for (int i = 0; i < 16; ++i) {
    int idx = tid + i * 256;
    int c = idx >> 6, px = idx & 63;
    sStage[px][c] = db[(size_t)c * HW + px];
  }
  __syncthreads();
  if (tid < 64) {
    float mu = 0.f;
#pragma unroll
    for (int c = 0; c < 64; ++c) mu += sStage[tid][c];
    mu *= (1.f / 64.f);
    float var = 0.f;
#pragma unroll
    for (int c = 0; c < 64; ++c) { float d = sStage[tid][c] - mu; var += d * d; }
    var *= (1.f / 64.f);
    sMu[tid] = mu;
    sRs[tid] = rsqrtf(var + 1e-5f);
  }
  __syncthreads();
#pragma unroll
  for (int i = 0; i < 16; ++i) {
    int idx = tid + i * 256;
    int px = idx >> 6, c = idx & 63;
    float xn = (sStage[px][c] - sMu[px]) * sRs[px] * ln2_w[c] + ln2_b[c];
    sXnb[px][c] = f2bf(xn);
  }
  __syncthreads();
  const int w = tid >> 6, lane = tid & 63;
  const int col = lane & 15, kgrp = lane >> 4;
#pragma unroll
  for (int pass = 0; pass < 2; ++pass) {
    const int o_l = pass * 64 + w * 16 + col;
    const int og = o0base + o_l;
    f32x4 acc[4];
#pragma unroll
    for (int s = 0; s < 4; ++s) acc[s] = (f32x4){0.f, 0.f, 0.f, 0.f};
#pragma unroll
    for (int kk = 0; kk < 2; ++kk) {
      const int c0 = kk * 32 + kgrp * 8;
      union { short8v v; unsigned short s[8]; } bw;
      const float* wp = ffn_in_w + (size_t)og * 64 + c0;
#pragma unroll
      for (int j = 0; j < 8; ++j) bw.s[j] = f2bf(wp[j]);
#pragma unroll
      for (int s = 0; s < 4; ++s) {
        short8v av = *reinterpret_cast<const short8v*>(&sXnb[s * 16 + col][c0]);
        acc[s] = __builtin_amdgcn_mfma_f32_16x16x32_bf16(av, bw.v, acc[s], 0, 0, 0);
      }
    }
#pragma unroll
    for (int s = 0; s < 4; ++s) {
#pragma unroll
      for (int r = 0; r < 4; ++r) {
        int px_l = s * 16 + kgrp * 4 + r;
        sOutB[o_l][px_l] = f2bf(acc[s][r]);
      }
    }
  }
  __syncthreads();
  for (int i = tid; i < 1024; i += 256) {
    int o = i >> 3, seg = i & 7;
    *reinterpret_cast<short8v*>(Tb + (size_t)(o0base + o) * HW + px0 + seg * 8) =
        *reinterpret_cast<const short8v*>(&sOutB[o][seg * 8]);
  }
}

// ---------------- K6a: dwconv3/dwconv5 + gelu*mul -> Y (bf16), one batch, j-chunked ----------------
__global__ __launch_bounds__(256) void k6a_dw(
    const float* __restrict__ dw3_w, const float* __restrict__ dw5_w,
    const unsigned short* __restrict__ T, __hip_bfloat16* __restrict__ Y)
{
  const int tid = threadIdx.x;
  const int px = blockIdx.x * 256 + tid;
  const int j0 = blockIdx.y * 8;
  const int row = px >> 8, col = px & 255;
  bool oky[5], okx[5];
#pragma unroll
  for (int d = 0; d < 5; ++d) {
    oky[d] = ((unsigned)(row + d - 2) < 256u);
    okx[d] = ((unsigned)(col + d - 2) < 256u);
  }
#pragma unroll
  for (int jj = 0; jj < 8; ++jj) {
    const int j = j0 + jj;
    const unsigned short* pl = T + (size_t)j * HW;
    float a = 0.f;
#pragma unroll
    for (int dy = -1; dy <= 1; ++dy) {
      if (!oky[dy + 2]) continue;
#pragma unroll
      for (int dx = -1; dx <= 1; ++dx) {
        if (!okx[dx + 2]) continue;
        a += bf2f(pl[px + dy * 256 + dx]) * dw3_w[j * 9 + (dy + 1) * 3 + (dx + 1)];
      }
    }
    float m = 0.f;
    const unsigned short* pm = T + (size_t)(128 + j) * HW;
    if (j < 64) {
#pragma unroll
      for (int dy = -1; dy <= 1; ++dy) {
        if (!oky[dy + 2]) continue;
#pragma unroll
        for (int dx = -1; dx <= 1; ++dx) {
          if (!okx[dx + 2]) continue;
          m += bf2f(pm[px + dy * 256 + dx]) * dw3_w[(128 + j) * 9 + (dy + 1) * 3 + (dx + 1)];
        }
      }
    } else {
#pragma unroll
      for (int dy = -2; dy <= 2; ++dy) {
        if (!oky[dy + 2]) continue;
#pragma unroll
        for (int dx = -2; dx <= 2; ++dx) {
          if (!okx[dx + 2]) continue;
          m += bf2f(pm[px + dy * 256 + dx]) * dw5_w[(j - 64) * 25 + (dy + 2) * 5 + (dx + 2)];
        }
      }
    }
    float gl = 0.5f * a * (1.f + erff(a * 0.70710678118654752f));
    Y[(size_t)j * HW + px] = __float2bfloat16(gl * m);
  }
}

// ---------------- K6b: ffn_out (128->64) from Y, one batch, o-chunked ----------------
__global__ __launch_bounds__(256) void k6b_out(
    const float* __restrict__ ffn_out_w, const __hip_bfloat16* __restrict__ Y,
    const float* __restrict__ flag, float* __restrict__ dout, float* __restrict__ Z, int b)
{
  __shared__ float sW[2048];
  const int tid = threadIdx.x;
  const int o0 = blockIdx.y * 16;
  for (int i = tid; i < 2048; i += 256) sW[i] = ffn_out_w[o0 * 128 + i];
  __syncthreads();
  const int px = blockIdx.x * 256 + tid;
  float z[16];
#pragma unroll
  for (int o = 0; o < 16; ++o) z[o] = 0.f;
  for (int j = 0; j < 128; ++j) {
    float yv = __bfloat162float(Y[(size_t)j * HW + px]);
#pragma unroll
    for (int o = 0; o < 16; ++o) z[o] += sW[o * 128 + j] * yv;
  }
  if (flag[0] > 0.5f) {
    float* ob = dout + (size_t)(b * 64 + o0) * HW + px;
#pragma unroll
    for (int o = 0; o < 16; ++o) ob[(size_t)o * HW] += z[o];
  } else {
    float* zb = Z + (size_t)o0 * HW + px;
#pragma unroll
    for (int o = 0; o < 16; ++o) zb[(size_t)o * HW] = z[o];
  }
}

// ---------------- K7: general fft path (early-exit if identity) ----------------
__global__ __launch_bounds__(256) void k7_fft(
    const float* __restrict__ fftw, const float* __restrict__ flag,
    const float* __restrict__ Z, float* __restrict__ dout, int b)
{
  if (flag[0] > 0.5f) return;
  __shared__ float swv[64];
  __shared__ float spatch[4][64];
  const int tid = threadIdx.x;
  const int c = blockIdx.x >> 8;
  const int pblk = blockIdx.x & 255;
  if (tid < 64) swv[tid] = fftw[c * 64 + tid];
  const int lp = tid >> 6, e = tid & 63;
  const int patch = pblk * 4 + lp;
  const int pi = patch >> 5, pj = patch & 31;
  const int i = e >> 3, jj = e & 7;
  const int gidx = (pi * 8 + i) * 256 + pj * 8 + jj;
  const float zv = Z[(size_t)c * HW + gidx];
  spatch[lp][e] = zv;
  __syncthreads();
  float s = 0.f;
#pragma unroll
  for (int a = 0; a < 8; ++a)
#pragma unroll
    for (int b2 = 0; b2 < 8; ++b2)
      s += swv[a * 8 + b2] * spatch[lp][((i - a) & 7) * 8 + ((jj - b2) & 7)];
  dout[(size_t)(b * 64 + c) * HW + gidx] += s;
}

extern "C" void kernel_launch(void* const* d_in, const int* in_sizes, int n_in,
                              void* d_out, int out_size, void* d_ws, size_t ws_size,
                              hipStream_t stream) {
  const float* x          = (const float*)d_in[0];
  const float* ln1_w      = (const float*)d_in[1];
  const float* ln1_b      = (const float*)d_in[2];
  const float* in_proj_w  = (const float*)d_in[3];
  const float* qkv_w      = (const float*)d_in[4];
  const float* qkv_dw     = (const float*)d_in[5];
  const float* out_proj_w = (const float*)d_in[6];
  const float* temperature= (const float*)d_in[7];
  const float* attn_scales= (const float*)d_in[8];
  const float* gate_w1    = (const float*)d_in[9];
  const float* gate_b1    = (const float*)d_in[10];
  const float* gate_w2    = (const float*)d_in[11];
  const float* gate_b2    = (const float*)d_in[12];
  const float* lgce_pre_w = (const float*)d_in[13];
  const float* lgce_pre_b = (const float*)d_in[14];
  const float* lgce_post_w= (const float*)d_in[15];
  const float* lgce_post_b= (const float*)d_in[16];
  const float* cbam_m1w   = (const float*)d_in[17];
  const float* cbam_m1b   = (const float*)d_in[18];
  const float* cbam_m2w   = (const float*)d_in[19];
  const float* cbam_m2b   = (const float*)d_in[20];
  const float* cbam_spw   = (const float*)d_in[21];
  const float* cbam_spb   = (const float*)d_in[22];
  const float* ln2_w      = (const float*)d_in[23];
  const float* ln2_b      = (const float*)d_in[24];
  const float* ffn_in_w   = (const float*)d_in[25];
  const float* dw3_w      = (const float*)d_in[26];
  const float* dw5_w      = (const float*)d_in[27];
  const float* ffn_out_w  = (const float*)d_in[28];
  const float* fft_W      = (const float*)d_in[29];
  float* ws = (float*)d_ws;
  float* out = (float*)d_out;
  unsigned short* qkvlp = (unsigned short*)(ws + OFF_QKVL);
  unsigned short* Tb = (unsigned short*)(ws + OFF_T);
  __hip_bfloat16* Ybuf = (__hip_bfloat16*)(ws + OFF_Y);

  hipLaunchKernelGGL(k0_setup, dim3(1), dim3(256), 0, stream,
                     fft_W, in_proj_w, qkv_w, gate_w1, ws);
  hipLaunchKernelGGL(k1_mfma, dim3(4096), dim3(256), 0, stream,
                     x, ln1_w, ln1_b, in_proj_w, ws + OFF_MQKV, ws + OFF_MG1,
                     gate_b1, gate_w2, gate_b2,
                     out, qkvlp, ws + OFF_POOL, ws + OFF_GSUM);
  hipLaunchKernelGGL(k1_check, dim3(1), dim3(256), 0, stream,
                     x, ln1_w, ln1_b, in_proj_w, qkv_w, out, qkvlp, ws + OFF_BAD);
  hipLaunchKernelGGL(k1r_reset, dim3(1), dim3(256), 0, stream,
                     ws + OFF_BAD, ws + OFF_GSUM);
  hipLaunchKernelGGL(k1_fb, dim3(1024), dim3(256), 0, stream,
                     x, ln1_w, ln1_b, in_proj_w, qkv_w, gate_w1, gate_b1, gate_w2, gate_b2,
                     ws + OFF_BAD, out, qkvlp, ws + OFF_POOL, ws + OFF_GSUM);
  hipLaunchKernelGGL(k2_mfma, dim3(128, 4, 4), dim3(256), 0, stream,
                     qkvlp, qkv_dw, ws + OFF_GRAM);
  hipLaunchKernelGGL(k3_final, dim3(1), dim3(256), 0, stream,
                     cbam_m1w, cbam_m1b, cbam_m2w, cbam_m2b, temperature, attn_scales,
                     lgce_pre_w, lgce_pre_b,
                     ws + OFF_GSUM, ws + OFF_POOL, ws + OFF_GRAM, ws + OFF_A, ws + OFF_CW);
  hipLaunchKernelGGL(k4a_thr, dim3(1024), dim3(256), 0, stream,
                     lgce_pre_w, lgce_pre_b, cbam_spw, cbam_spb, ws + OFF_CW, out, ws + OFF_THR);
  hipLaunchKernelGGL(k4b_fuse, dim3(1024), dim3(256), 0, stream,
                     x, lgce_pre_w, lgce_pre_b, lgce_post_w, lgce_post_b, out_proj_w,
                     cbam_spw, cbam_spb, qkv_dw, qkvlp,
                     ws + OFF_A, ws + OFF_CW, ws + OFF_THR, out);

  for (int b = 0; b < 4; ++b) {
    hipLaunchKernelGGL(k5_mfma, dim3(1024, 2), dim3(256), 0, stream,
                       ln2_w, ln2_b, ffn_in_w, out, Tb, b);
    hipLaunchKernelGGL(k6a_dw, dim3(256, 16), dim3(256), 0, stream,
                       dw3_w, dw5_w, Tb, Ybuf);
    hipLaunchKernelGGL(k6b_out, dim3(256, 4), dim3(256), 0, stream,
                       ffn_out_w, Ybuf, ws + OFF_FLAG, out, ws + OFF_Z, b);
    hipLaunchKernelGGL(k7_fft, dim3(16384), dim3(256), 0, stream,
                       ws + OFF_FFTW, ws + OFF_FLAG, ws + OFF_Z, out, b);
  }
}

// Round 7
// 1437.938 us; speedup vs baseline: 4.4471x; 1.1602x over previous
//
#include <hip/hip_runtime.h>
#include <hip/hip_bf16.h>
#include <math.h>

#define HW 65536
#define NPIX 262144

// ---- workspace layout (float offsets) ----
#define OFF_FFTW 0            // 64x64 spatial fft kernel
#define OFF_FLAG 4096         // 1
#define OFF_GSUM 4097         // 1    (zeroed in k0)
#define OFF_POOL 4098         // 128  (zeroed in k0)  -- pooled(loc) sums
#define OFF_GRAM 4226         // 1280 (zeroed in k0)
#define OFF_THR  5506         // 32   (written by k4a_red)
#define OFF_BAD  5538         // 1    (zeroed in k0)  -- k1 checker flag
#define OFF_A    5539         // 1024
#define OFF_CW   6563         // 128
#define OFF_QKVL 8192         // 96ch * 262144 px bf16 = 12582912 float-slots (SGSA phase)
#define OFF_MQKV 12591104     // 96*64 fp32 composed qkv matrix
#define OFF_MG1  (OFF_MQKV + 6144)     // 16*64 fp32  (ends 12598272)
#define OFF_MPRE 12598272     // 32*64 fp32 composed pre matrix (ends 12600320)
#define OFF_PRE  12600320     // [4][65536][32] fp32 px-major = 8388608 (ends 20988928)
#define OFF_PART 20988928     // 2048 blk * 4 waves * 4 g = 32768 (ends 21021696)
// MFFN phase (per-batch, overlaps QKVL/PRE which are dead by then):
#define OFF_T    8192                      // 256ch * 65536 bf16
#define OFF_Y    (OFF_T + 16777216)        // 128ch * 65536 bf16
#define OFF_Z    (OFF_Y + 4194304)         // 64ch * 65536 fp32
// peak ws usage = 25174016 floats = 100.7 MB (unchanged proven footprint)

typedef __attribute__((ext_vector_type(8))) short short8v;
typedef __attribute__((ext_vector_type(4))) float f32x4;

__device__ __forceinline__ float sigm(float v) { return 1.f / (1.f + expf(-v)); }
__device__ __forceinline__ float wredsum(float v) {
#pragma unroll
  for (int off = 32; off >= 1; off >>= 1) v += __shfl_xor(v, off);
  return v;
}
__device__ __forceinline__ unsigned short f2bf(float f) {
  union { float f; unsigned u; } x; x.f = f;
  unsigned r = x.u + 0x7fffu + ((x.u >> 16) & 1u);
  return (unsigned short)(r >> 16);
}
__device__ __forceinline__ float bf2f(unsigned short u) {
  union { unsigned u; float f; } x; x.u = ((unsigned)u) << 16;
  return x.f;
}

// ---------------- K0: zero accumulators + fft spatial kernel + composed matrices ----------------
__global__ __launch_bounds__(256) void k0_setup(
    const float* __restrict__ fft_W, const float* __restrict__ in_proj_w,
    const float* __restrict__ qkv_w, const float* __restrict__ g1w,
    const float* __restrict__ pre_w, float* __restrict__ ws)
{
  __shared__ float ct8[8];
  __shared__ int sbad;
  const int tid = threadIdx.x;
  if (tid < 8) ct8[tid] = cosf((float)tid * 0.78539816339744831f); // cos(k*pi/4)
  if (tid == 0) sbad = 0;
  for (int i = tid; i < 1442; i += 256) ws[OFF_GSUM + i] = 0.f;    // gsum,pool,gram,thr,bad
  // composed matrices
  for (int i = tid; i < 96 * 64; i += 256) {
    int o = i >> 6, c = i & 63;
    float s = 0.f;
    for (int j = 0; j < 32; ++j) s += qkv_w[o * 32 + j] * in_proj_w[(32 + j) * 64 + c];
    ws[OFF_MQKV + i] = s;
  }
  for (int i = tid; i < 16 * 64; i += 256) {
    int o = i >> 6, c = i & 63;
    float s = 0.f;
    for (int j = 0; j < 32; ++j) s += g1w[o * 32 + j] * in_proj_w[(32 + j) * 64 + c];
    ws[OFF_MG1 + i] = s;
  }
  for (int i = tid; i < 32 * 64; i += 256) {
    int o = i >> 6, c = i & 63;
    float s = 0.f;
    for (int j = 0; j < 32; ++j) s += pre_w[o * 32 + j] * in_proj_w[j * 64 + c];
    ws[OFF_MPRE + i] = s;
  }
  __syncthreads();
  bool ok = true;
  for (int i = tid; i < 64 * 64; i += 256) {
    int ch = i >> 6, ab = i & 63;
    int a = ab >> 3, b2 = ab & 7;
    float s = 0.f;
    for (int u = 0; u < 8; ++u)
      for (int v = 0; v < 8; ++v) {
        float Wf;
        if (v == 0 || v == 4)
          Wf = 0.5f * (fft_W[ch * 40 + u * 5 + v] + fft_W[ch * 40 + ((8 - u) & 7) * 5 + v]);
        else if (v < 5)
          Wf = fft_W[ch * 40 + u * 5 + v];
        else
          Wf = fft_W[ch * 40 + ((8 - u) & 7) * 5 + (8 - v)];
        s += Wf * ct8[(u * a + v * b2) & 7];
      }
    s *= (1.f / 64.f);
    ws[OFF_FFTW + i] = s;
    float expect = ((i & 63) == 0) ? 1.f : 0.f;
    if (fabsf(s - expect) > 1e-4f) ok = false;
  }
  if (!ok) atomicOr(&sbad, 1);
  __syncthreads();
  if (tid == 0) ws[OFF_FLAG] = sbad ? 0.f : 1.f;
}

// ---------------- K1 (MFMA): LN1 + [loc(32)|qkv(96)|pre(32)] + gate + pooled-loc ----------------
// block: 64 px; 4 waves; 10 MFMA tiles of 16 outs over 3 passes.
__global__ __launch_bounds__(256) void k1_mfma(
    const float* __restrict__ x, const float* __restrict__ ln1_w, const float* __restrict__ ln1_b,
    const float* __restrict__ in_proj_w, const float* __restrict__ mqkv, const float* __restrict__ mg1,
    const float* __restrict__ mpre, const float* __restrict__ pre_b,
    const float* __restrict__ g1b, const float* __restrict__ g2w, const float* __restrict__ g2b,
    float* __restrict__ dout, unsigned short* __restrict__ qkvl, float* __restrict__ PREi,
    float* __restrict__ pooled, float* __restrict__ gsum)
{
  __shared__ float sStage[64][65];          // raw x; rows 0..31 reused as loc [32][65], rows 32..63 as pre [64px][32]
  __shared__ unsigned short sXnb[64][72];   // LN'd bf16 activations
  __shared__ unsigned short sQkv[96][72];   // qkv outs bf16
  __shared__ float sMu[64], sRs[64];
  __shared__ float sPoolL[32];
  __shared__ float sRed[4];
  const int tid = threadIdx.x;
  const int p0 = blockIdx.x * 64;
  const int b = p0 >> 16;
  const int hw0 = p0 & (HW - 1);
  const float* xb = x + (size_t)(b * 64) * HW + hw0;
#pragma unroll
  for (int i = 0; i < 16; ++i) {
    int idx = tid + i * 256;
    int c = idx >> 6, px = idx & 63;
    sStage[px][c] = xb[(size_t)c * HW + px];
  }
  __syncthreads();
  if (tid < 64) {
    float mu = 0.f;
#pragma unroll
    for (int c = 0; c < 64; ++c) mu += sStage[tid][c];
    mu *= (1.f / 64.f);
    float var = 0.f;
#pragma unroll
    for (int c = 0; c < 64; ++c) { float d = sStage[tid][c] - mu; var += d * d; }
    var *= (1.f / 64.f);
    sMu[tid] = mu;
    sRs[tid] = rsqrtf(var + 1e-5f);
  }
  __syncthreads();
#pragma unroll
  for (int i = 0; i < 16; ++i) {
    int idx = tid + i * 256;
    int px = idx >> 6, c = idx & 63;
    float xn = (sStage[px][c] - sMu[px]) * sRs[px] * ln1_w[c] + ln1_b[c];
    sXnb[px][c] = f2bf(xn);
  }
  __syncthreads();
  const int w = tid >> 6, lane = tid & 63;
  const int col = lane & 15, kgrp = lane >> 4;
  float* sLoc = &sStage[0][0];              // [o][px] stride 65, o<32
  float* sPreB = &sStage[32][0];            // [px][32] flat, 2048 floats
#pragma unroll
  for (int pass = 0; pass < 3; ++pass) {
    const int tile = pass * 4 + w;
    if (tile >= 10) continue;               // wave-uniform
    const int og = tile * 16 + col;         // 0..159
    f32x4 acc[4];
#pragma unroll
    for (int s = 0; s < 4; ++s) acc[s] = (f32x4){0.f, 0.f, 0.f, 0.f};
#pragma unroll
    for (int kk = 0; kk < 2; ++kk) {
      const int c0 = kk * 32 + kgrp * 8;
      const float* wrow = (og < 32) ? (in_proj_w + og * 64)
                        : (og < 128) ? (mqkv + (og - 32) * 64)
                                     : (mpre + (og - 128) * 64);
      union { short8v v; unsigned short s[8]; } bw;
#pragma unroll
      for (int j = 0; j < 8; ++j) bw.s[j] = f2bf(wrow[c0 + j]);
#pragma unroll
      for (int s = 0; s < 4; ++s) {
        short8v av = *reinterpret_cast<const short8v*>(&sXnb[s * 16 + col][c0]);
        acc[s] = __builtin_amdgcn_mfma_f32_16x16x32_bf16(av, bw.v, acc[s], 0, 0, 0);
      }
    }
    if (og < 32) {
      float ps = 0.f;
#pragma unroll
      for (int s = 0; s < 4; ++s) {
#pragma unroll
        for (int r = 0; r < 4; ++r) {
          int px_l = s * 16 + kgrp * 4 + r;
          sLoc[og * 65 + px_l] = acc[s][r];
          ps += acc[s][r];
        }
      }
      ps += __shfl_xor(ps, 16);
      ps += __shfl_xor(ps, 32);
      if (kgrp == 0) sPoolL[og] = ps;
    } else if (og < 128) {
      const int oq = og - 32;
#pragma unroll
      for (int s = 0; s < 4; ++s) {
#pragma unroll
        for (int r = 0; r < 4; ++r) {
          int px_l = s * 16 + kgrp * 4 + r;
          sQkv[oq][px_l] = f2bf(acc[s][r]);
        }
      }
    } else {
      const int op = og - 128;
      const float bias = pre_b[op];
#pragma unroll
      for (int s = 0; s < 4; ++s) {
#pragma unroll
        for (int r = 0; r < 4; ++r) {
          int px_l = s * 16 + kgrp * 4 + r;
          sPreB[px_l * 32 + op] = acc[s][r] + bias;
        }
      }
    }
  }
  // gate (scalar fp32 weights, bf16 activations)
  {
    const int gpx = tid >> 2, gq = tid & 3;
    float h[4];
#pragma unroll
    for (int i = 0; i < 4; ++i) h[i] = g1b[gq * 4 + i];
#pragma unroll
    for (int cc = 0; cc < 64; cc += 8) {
      union { short8v v; unsigned short s[8]; } xu;
      xu.v = *reinterpret_cast<const short8v*>(&sXnb[gpx][cc]);
#pragma unroll
      for (int j = 0; j < 8; ++j) {
        float xf = bf2f(xu.s[j]);
#pragma unroll
        for (int i = 0; i < 4; ++i) h[i] += mg1[(gq * 4 + i) * 64 + cc + j] * xf;
      }
    }
    float gpart = 0.f;
#pragma unroll
    for (int i = 0; i < 4; ++i) gpart += g2w[gq * 4 + i] * fmaxf(h[i], 0.f);
    gpart += __shfl_xor(gpart, 1);
    gpart += __shfl_xor(gpart, 2);
    float gv = (gq == 0) ? sigm(gpart + g2b[0]) : 0.f;
    gv = wredsum(gv);
    if (lane == 0) sRed[w] = gv;
  }
  __syncthreads();
  // cooperative stores
  for (int i = tid; i < 2048; i += 256) {
    int o = i >> 6, px = i & 63;
    dout[(size_t)(b * 64 + o) * HW + hw0 + px] = sLoc[o * 65 + px];
  }
  for (int i = tid; i < 768; i += 256) {
    int o = i >> 3, seg = i & 7;
    *reinterpret_cast<short8v*>(qkvl + (size_t)(b * 96 + o) * HW + hw0 + seg * 8) =
        *reinterpret_cast<const short8v*>(&sQkv[o][seg * 8]);
  }
  {
    float* Pg = PREi + ((size_t)b * HW + hw0) * 32;
#pragma unroll
    for (int i = 0; i < 8; ++i) {
      int idx = tid + i * 256;             // 2048 = 64px*32ch, px-major contiguous
      Pg[idx] = sPreB[idx];
    }
  }
  if (tid < 32) atomicAdd(&pooled[b * 32 + tid], sPoolL[tid]);
  if (tid == 0) atomicAdd(gsum, sRed[0] + sRed[1] + sRed[2] + sRed[3]);
}

// ---------------- K1 checker: 256 sampled px vs independent fp32 reference ----------------
__global__ __launch_bounds__(256) void k1_check(
    const float* __restrict__ x, const float* __restrict__ ln1_w, const float* __restrict__ ln1_b,
    const float* __restrict__ in_proj_w, const float* __restrict__ qkv_w,
    const float* __restrict__ pre_w, const float* __restrict__ pre_b,
    const float* __restrict__ dout, const unsigned short* __restrict__ qkvl,
    const float* __restrict__ PREi, float* __restrict__ bad)
{
  const int t = threadIdx.x;
  const int b = t & 3;
  const int px = (t * 1031) & (HW - 1);
  const float* xb = x + (size_t)(b * 64) * HW + px;
  float xv[64];
  float mu = 0.f;
#pragma unroll
  for (int c = 0; c < 64; ++c) { xv[c] = xb[(size_t)c * HW]; mu += xv[c]; }
  mu *= (1.f / 64.f);
  float var = 0.f;
#pragma unroll
  for (int c = 0; c < 64; ++c) { float d = xv[c] - mu; var += d * d; }
  var *= (1.f / 64.f);
  float rs = rsqrtf(var + 1e-5f);
#pragma unroll
  for (int c = 0; c < 64; ++c) xv[c] = (xv[c] - mu) * rs * ln1_w[c] + ln1_b[c];
  bool fail = false;
  float lc[32], gl[32];
  for (int o = 0; o < 32; ++o) {
    float s = 0.f;
#pragma unroll
    for (int c = 0; c < 64; ++c) s += in_proj_w[o * 64 + c] * xv[c];
    lc[o] = s;
    float got = dout[(size_t)(b * 64 + o) * HW + px];
    if (fabsf(got - s) > 0.05f + 0.05f * fabsf(s)) fail = true;
    float s2 = 0.f;
#pragma unroll
    for (int c = 0; c < 64; ++c) s2 += in_proj_w[(32 + o) * 64 + c] * xv[c];
    gl[o] = s2;
  }
  for (int o = 0; o < 96; ++o) {
    float s = 0.f;
#pragma unroll
    for (int j = 0; j < 32; ++j) s += qkv_w[o * 32 + j] * gl[j];
    float got = bf2f(qkvl[(size_t)(b * 96 + o) * HW + px]);
    if (fabsf(got - s) > 0.05f + 0.05f * fabsf(s)) fail = true;
  }
  for (int o = 0; o < 32; ++o) {
    float s = pre_b[o];
#pragma unroll
    for (int j = 0; j < 32; ++j) s += pre_w[o * 32 + j] * lc[j];
    float got = PREi[((size_t)b * HW + px) * 32 + o];
    if (fabsf(got - s) > 0.05f + 0.05f * fabsf(s)) fail = true;
  }
  if (fail) atomicExch(bad, 1.f);
}

// ---------------- K1 reset (only if checker failed): zero gsum+pooled ----------------
__global__ __launch_bounds__(256) void k1r_reset(const float* __restrict__ bad, float* __restrict__ gsum)
{
  if (bad[0] < 0.5f) return;
  const int tid = threadIdx.x;
  if (tid < 129) gsum[tid] = 0.f;   // gsum(1) + pooled(128), contiguous
}

// ---------------- K1 fallback: full scalar path (only if checker failed) ----------------
__global__ __launch_bounds__(256) void k1_fb(
    const float* __restrict__ x, const float* __restrict__ ln1_w, const float* __restrict__ ln1_b,
    const float* __restrict__ in_proj_w, const float* __restrict__ qkv_w,
    const float* __restrict__ pre_w, const float* __restrict__ pre_b,
    const float* __restrict__ g1w, const float* __restrict__ g1b,
    const float* __restrict__ g2w, const float* __restrict__ g2b,
    const float* __restrict__ bad,
    float* __restrict__ dout, unsigned short* __restrict__ qkvl, float* __restrict__ PREi,
    float* __restrict__ pooled, float* __restrict__ gsum)
{
  if (bad[0] < 0.5f) return;
  __shared__ float sPool[4][32];
  __shared__ float sRed[4];
  const int tid = threadIdx.x;
  const int p = blockIdx.x * 256 + tid;
  const int b = p >> 16;
  const int hw = p & (HW - 1);
  const int wave = tid >> 6, lane = tid & 63;
  const float* xb = x + (size_t)(b * 64) * HW + hw;
  float xv[64];
  float mu = 0.f;
#pragma unroll
  for (int c = 0; c < 64; ++c) { xv[c] = xb[(size_t)c * HW]; mu += xv[c]; }
  mu *= (1.f / 64.f);
  float var = 0.f;
#pragma unroll
  for (int c = 0; c < 64; ++c) { float d = xv[c] - mu; var += d * d; }
  var *= (1.f / 64.f);
  const float rs = rsqrtf(var + 1e-5f);
#pragma unroll
  for (int c = 0; c < 64; ++c) xv[c] = (xv[c] - mu) * rs * ln1_w[c] + ln1_b[c];
  float loc[32];
  for (int o = 0; o < 32; ++o) {
    float s = 0.f;
#pragma unroll
    for (int c = 0; c < 64; ++c) s += in_proj_w[o * 64 + c] * xv[c];
    loc[o] = s;
    dout[(size_t)(b * 64 + o) * HW + hw] = s;
    float r = wredsum(s);
    if (lane == 0) sPool[wave][o] = r;
  }
  for (int o = 0; o < 32; ++o) {
    float s = pre_b[o];
#pragma unroll
    for (int j = 0; j < 32; ++j) s += pre_w[o * 32 + j] * loc[j];
    PREi[((size_t)b * HW + hw) * 32 + o] = s;
  }
  float gl[32];
  for (int o = 0; o < 32; ++o) {
    float s = 0.f;
#pragma unroll
    for (int c = 0; c < 64; ++c) s += in_proj_w[(32 + o) * 64 + c] * xv[c];
    gl[o] = s;
  }
  for (int o = 0; o < 96; ++o) {
    float s = 0.f;
#pragma unroll
    for (int j = 0; j < 32; ++j) s += qkv_w[o * 32 + j] * gl[j];
    qkvl[(size_t)(b * 96 + o) * HW + hw] = f2bf(s);
  }
  float gacc = g2b[0];
  for (int o = 0; o < 16; ++o) {
    float h = g1b[o];
#pragma unroll
    for (int j = 0; j < 32; ++j) h += g1w[o * 32 + j] * gl[j];
    gacc += g2w[o] * fmaxf(h, 0.f);
  }
  float gv = wredsum(sigm(gacc));
  if (lane == 0) sRed[wave] = gv;
  __syncthreads();
  if (tid == 0) atomicAdd(gsum, sRed[0] + sRed[1] + sRed[2] + sRed[3]);
  if (tid < 32) {
    float s = sPool[0][tid] + sPool[1][tid] + sPool[2][tid] + sPool[3][tid];
    atomicAdd(&pooled[b * 32 + tid], s);
  }
}

// ---------------- K2 (MFMA): dwconv(q,k) + Gram via V·V^T (qkvl bf16) ----------------
__global__ __launch_bounds__(256) void k2_mfma(
    const unsigned short* __restrict__ qkvl, const float* __restrict__ qkv_dw, float* __restrict__ gram)
{
  __shared__ float sred[4][256];
  const int tid = threadIdx.x;
  const int slab = blockIdx.x;
  const int h = blockIdx.y, b = blockIdx.z;
  const int w = tid >> 6, lane = tid & 63;
  const int ch = lane & 15, grp = lane >> 4;
  const int gch = (ch < 8) ? (h * 8 + ch) : (32 + h * 8 + (ch - 8));
  const unsigned short* plane = qkvl + (size_t)(b * 96 + gch) * HW;
  const float* wt = qkv_dw + gch * 9;
  float w9[9];
#pragma unroll
  for (int t = 0; t < 9; ++t) w9[t] = wt[t];
  f32x4 acc = (f32x4){0.f, 0.f, 0.f, 0.f};
#pragma unroll
  for (int iter = 0; iter < 4; ++iter) {
    const int pxbase = slab * 512 + w * 128 + iter * 32 + grp * 8;
    const int y = pxbase >> 8;
    const int x0 = pxbase & 255;
    union { short8v v; unsigned short s[8]; } frag;
#pragma unroll
    for (int j = 0; j < 8; ++j) {
      const int x = x0 + j;
      float a = 0.f;
#pragma unroll
      for (int dy = -1; dy <= 1; ++dy) {
        const int yy = y + dy;
        if ((unsigned)yy >= 256u) continue;
#pragma unroll
        for (int dx = -1; dx <= 1; ++dx) {
          const int x2 = x + dx;
          if ((unsigned)x2 >= 256u) continue;
          a += bf2f(plane[yy * 256 + x2]) * w9[(dy + 1) * 3 + (dx + 1)];
        }
      }
      frag.s[j] = f2bf(a);
    }
    acc = __builtin_amdgcn_mfma_f32_16x16x32_bf16(frag.v, frag.v, acc, 0, 0, 0);
  }
#pragma unroll
  for (int r = 0; r < 4; ++r) sred[w][(grp * 4 + r) * 16 + ch] = acc[r];
  __syncthreads();
  if (tid < 256) {
    float g = sred[0][tid] + sred[1][tid] + sred[2][tid] + sred[3][tid];
    const int row = tid >> 4, col = tid & 15;
    int idx = -1;
    if (row < 8 && col >= 8) idx = row * 8 + (col - 8);
    else if (row == col && row < 8) idx = 64 + row;
    else if (row == col) idx = 72 + (row - 8);
    if (idx >= 0) atomicAdd(&gram[(b * 4 + h) * 80 + idx], g);
  }
}

// ---------------- K3: dk, CBAM weights, attention matrices ----------------
__global__ __launch_bounds__(256) void k3_final(
    const float* __restrict__ m1w, const float* __restrict__ m1b,
    const float* __restrict__ m2w, const float* __restrict__ m2b,
    const float* __restrict__ temperature, const float* __restrict__ attn_scales,
    const float* __restrict__ pre_w, const float* __restrict__ pre_b,
    const float* __restrict__ gsum, const float* __restrict__ pooled,
    const float* __restrict__ gram, float* __restrict__ Abuf, float* __restrict__ cwbuf)
{
  __shared__ int s_dk;
  __shared__ float s_scale;
  const int tid = threadIdx.x;
  if (tid == 0) {
    float gmean = gsum[0] / (float)NPIX;
    int dk = (int)floorf(8.f * gmean);
    if (dk < 1) dk = 1;
    if (dk > 8) dk = 8;
    s_dk = dk;
    s_scale = attn_scales[0] + attn_scales[1] + attn_scales[2] + attn_scales[3];
  }
  __syncthreads();
  if (tid < 128) {
    int b = tid >> 5, ch = tid & 31, g = ch >> 2, c = ch & 3;
    float h1 = m1b[g];
#pragma unroll
    for (int cc = 0; cc < 4; ++cc) {
      int row = g * 4 + cc;
      float pp = pre_b[row];
#pragma unroll
      for (int j = 0; j < 32; ++j)
        pp += pre_w[row * 32 + j] * (pooled[b * 32 + j] * (1.f / 65536.f));
      h1 += pp * m1w[g * 4 + cc];
    }
    h1 = fmaxf(h1, 0.f);
    cwbuf[tid] = sigm(h1 * m2w[g * 4 + c] + m2b[g * 4 + c]);

    int r = tid, h = (r >> 3) & 3, c8 = r & 7;
    const float* gm = gram + (b * 4 + h) * 80;
    float qn = fmaxf(sqrtf(gm[64 + c8]), 1e-12f);
    float temp = temperature[h];
    float a[8];
#pragma unroll
    for (int d = 0; d < 8; ++d) {
      float kn = fmaxf(sqrtf(gm[72 + d]), 1e-12f);
      a[d] = gm[c8 * 8 + d] / (qn * kn) * temp;
    }
    float t[8];
#pragma unroll
    for (int d = 0; d < 8; ++d) t[d] = a[d];
#pragma unroll
    for (int i = 0; i < 8; ++i)
#pragma unroll
      for (int j = 0; j < 8; ++j)
        if (j > i && t[j] > t[i]) { float tmp = t[i]; t[i] = t[j]; t[j] = tmp; }
    float kth = t[s_dk - 1];
    float mx = t[0];
    float e[8]; float sum = 0.f;
#pragma unroll
    for (int d = 0; d < 8; ++d) {
      e[d] = (a[d] >= kth) ? expf(a[d] - mx) : 0.f;
      sum += e[d];
    }
    float inv = s_scale / sum;
#pragma unroll
    for (int d = 0; d < 8; ++d) Abuf[r * 8 + d] = e[d] * inv;
  }
}

// ---------------- K4a: resp partial sums (atomic-free), 2048 blocks x 4 groups ----------------
__global__ __launch_bounds__(256) void k4a_thr(
    const float* __restrict__ spw, const float* __restrict__ spb,
    const float* __restrict__ cwbuf, const float* __restrict__ PREi, float* __restrict__ wpart)
{
  const int tid = threadIdx.x;
  const int pxb = blockIdx.x >> 1;     // 0..1023 (256 px each)
  const int gh = blockIdx.x & 1;       // group half: groups gh*4..gh*4+3
  const int px = pxb * 256 + tid;
  const int b = px >> 16, hw = px & (HW - 1);
  const int w = tid >> 6, lane = tid & 63;
  const float* cw = cwbuf + b * 32;
  const float4* pp = reinterpret_cast<const float4*>(PREi + ((size_t)b * HW + hw) * 32 + gh * 16);
  float4 pv[4];
#pragma unroll
  for (int k = 0; k < 4; ++k) pv[k] = pp[k];
  float racc[4];
#pragma unroll
  for (int g4 = 0; g4 < 4; ++g4) {
    const int g = gh * 4 + g4;
    float xa[4];
    float sdot = spb[g];
#pragma unroll
    for (int c = 0; c < 4; ++c) {
      float pr = (&pv[g4].x)[c];
      xa[c] = pr * cw[g * 4 + c];
      sdot += xa[c] * spw[g * 4 + c];
    }
    float sgv = sigm(sdot);
    float r = 0.f;
#pragma unroll
    for (int c = 0; c < 4; ++c) r += sigm(xa[c] * sgv);
    racc[g4] = r;
  }
#pragma unroll
  for (int g4 = 0; g4 < 4; ++g4) {
    float v = wredsum(racc[g4]);
    if (lane == 0) wpart[(blockIdx.x * 4 + w) * 4 + g4] = v;
  }
}

// ---------------- K4a_red: reduce wpart -> thrbuf, 32 blocks (b,g) ----------------
__global__ __launch_bounds__(256) void k4a_red(
    const float* __restrict__ wpart, float* __restrict__ thrbuf)
{
  __shared__ float sr[256];
  const int tid = threadIdx.x;
  const int b = blockIdx.x >> 3, g = blockIdx.x & 7;
  const int gh = g >> 2, gl = g & 3;
  float s = 0.f;
#pragma unroll
  for (int w = 0; w < 4; ++w)
    s += wpart[((((size_t)(b * 256 + tid) * 2 + gh) * 4) + w) * 4 + gl];
  sr[tid] = s;
  __syncthreads();
  for (int st = 128; st >= 1; st >>= 1) {
    if (tid < st) sr[tid] += sr[tid + st];
    __syncthreads();
  }
  if (tid == 0) thrbuf[b * 8 + g] = sr[0];
}

// ---------------- K4b: LGCE finish + V-dwconv(bf16) + attn + out_proj + residual -> dout ----------------
__global__ __launch_bounds__(256) void k4b_fuse(
    const float* __restrict__ x,
    const float* __restrict__ post_w, const float* __restrict__ post_b,
    const float* __restrict__ out_proj_w, const float* __restrict__ spw, const float* __restrict__ spb,
    const float* __restrict__ qkv_dw, const unsigned short* __restrict__ qkvl,
    const float* __restrict__ PREi,
    const float* __restrict__ Abuf, const float* __restrict__ cwbuf, const float* __restrict__ thrbuf,
    float* dout)
{
  const int tid = threadIdx.x;
  const int p = blockIdx.x * 256 + tid;
  const int b = p >> 16, hw = p & (HW - 1);
  const int y = hw >> 8, xx = hw & 255;
  const float* cw = cwbuf + b * 32;
  const float* A = Abuf + b * 256;
  float* doutb = dout + (size_t)b * 64 * HW + hw;
  float loc[32];
#pragma unroll
  for (int c = 0; c < 32; ++c) loc[c] = doutb[(size_t)c * HW];
  float pre[32];
  {
    const float4* pp = reinterpret_cast<const float4*>(PREi + ((size_t)b * HW + hw) * 32);
#pragma unroll
    for (int k = 0; k < 8; ++k) {
      float4 v = pp[k];
      pre[k * 4 + 0] = v.x; pre[k * 4 + 1] = v.y; pre[k * 4 + 2] = v.z; pre[k * 4 + 3] = v.w;
    }
  }
  float mx[32];
#pragma unroll
  for (int g = 0; g < 8; ++g) {
    float xa[4];
    float sdot = spb[g];
#pragma unroll
    for (int c = 0; c < 4; ++c) {
      xa[c] = pre[g * 4 + c] * cw[g * 4 + c];
      sdot += xa[c] * spw[g * 4 + c];
    }
    float sgv = sigm(sdot);
    float thr = thrbuf[b * 8 + g] * (1.f / (4.f * 65536.f));
#pragma unroll
    for (int c = 0; c < 4; ++c) {
      float resp = sigm(xa[c] * sgv);
      float m = (resp > thr) ? 1.f : resp;
      mx[g * 4 + c] = pre[g * 4 + c] * m;
    }
  }
  int offs[9]; bool okn[9];
#pragma unroll
  for (int dy = -1; dy <= 1; ++dy)
#pragma unroll
    for (int dx = -1; dx <= 1; ++dx) {
      int i = (dy + 1) * 3 + (dx + 1);
      int yy = y + dy, x2 = xx + dx;
      okn[i] = ((unsigned)yy < 256u) && ((unsigned)x2 < 256u);
      offs[i] = yy * 256 + x2;
    }
  const unsigned short* vbase = qkvl + (size_t)(b * 96 + 64) * HW;
  float vv[32];
  for (int ch = 0; ch < 32; ++ch) {
    const unsigned short* plane = vbase + (size_t)ch * HW;
    float acc = 0.f;
#pragma unroll
    for (int i = 0; i < 9; ++i) if (okn[i]) acc += bf2f(plane[offs[i]]) * qkv_dw[(64 + ch) * 9 + i];
    vv[ch] = acc;
  }
  float fused[64];
#pragma unroll
  for (int j = 0; j < 32; ++j) {
    int h = j >> 3, c = j & 7;
    float s = 0.f;
#pragma unroll
    for (int d = 0; d < 8; ++d) s += A[(h * 8 + c) * 8 + d] * vv[h * 8 + d];
    fused[j] = s;
  }
  for (int o = 0; o < 32; ++o) {
    float s = post_b[o];
#pragma unroll
    for (int j = 0; j < 32; ++j) s += post_w[o * 32 + j] * mx[j];
    fused[32 + o] = s + loc[o];
  }
  const float* xb = x + (size_t)b * 64 * HW + hw;
  for (int o = 0; o < 64; ++o) {
    float s = 0.f;
#pragma unroll
    for (int j = 0; j < 64; ++j) s += out_proj_w[o * 64 + j] * fused[j];
    doutb[(size_t)o * HW] = s + xb[(size_t)o * HW];
  }
}

// ---------------- K5 (MFMA): LN2 + ffn_in (64->256), 128 outs/block ----------------
__global__ __launch_bounds__(256) void k5_mfma(
    const float* __restrict__ ln2_w, const float* __restrict__ ln2_b,
    const float* __restrict__ ffn_in_w, const float* __restrict__ dout,
    unsigned short* __restrict__ Tb, int b)
{
  __shared__ float sStage[64][65];
  __shared__ unsigned short sXnb[64][72];
  __shared__ unsigned short sOutB[128][72];
  __shared__ float sMu[64], sRs[64];
  const int tid = threadIdx.x;
  const int px0 = blockIdx.x * 64;
  const int o0base = blockIdx.y * 128;
  const float* db = dout + (size_t)(b * 64) * HW + px0;
#pragma unroll
  for (int i = 0; i < 16; ++i) {
    int idx = tid + i * 256;
    int c = idx >> 6, px = idx & 63;
    sStage[px][c] = db[(size_t)c * HW + px];
  }
  __syncthreads();
  if (tid < 64) {
    float mu = 0.f;
#pragma unroll
    for (int c = 0; c < 64; ++c) mu += sStage[tid][c];
    mu *= (1.f / 64.f);
    float var = 0.f;
#pragma unroll
    for (int c = 0; c < 64; ++c) { float d = sStage[tid][c] - mu; var += d * d; }
    var *= (1.f / 64.f);
    sMu[tid] = mu;
    sRs[tid] = rsqrtf(var + 1e-5f);
  }
  __syncthreads();
#pragma unroll
  for (int i = 0; i < 16; ++i) {
    int idx = tid + i * 256;
    int px = idx >> 6, c = idx & 63;
    float xn = (sStage[px][c] - sMu[px]) * sRs[px] * ln2_w[c] + ln2_b[c];
    sXnb[px][c] = f2bf(xn);
  }
  __syncthreads();
  const int w = tid >> 6, lane = tid & 63;
  const int col = lane & 15, kgrp = lane >> 4;
#pragma unroll
  for (int pass = 0; pass < 2; ++pass) {
    const int o_l = pass * 64 + w * 16 + col;
    const int og = o0base + o_l;
    f32x4 acc[4];
#pragma unroll
    for (int s = 0; s < 4; ++s) acc[s] = (f32x4){0.f, 0.f, 0.f, 0.f};
#pragma unroll
    for (int kk = 0; kk < 2; ++kk) {
      const int c0 = kk * 32 + kgrp * 8;
      union { short8v v; unsigned short s[8]; } bw;
      const float* wp = ffn_in_w + (size_t)og * 64 + c0;
#pragma unroll
      for (int j = 0; j < 8; ++j) bw.s[j] = f2bf(wp[j]);
#pragma unroll
      for (int s = 0; s < 4; ++s) {
        short8v av = *reinterpret_cast<const short8v*>(&sXnb[s * 16 + col][c0]);
        acc[s] = __builtin_amdgcn_mfma_f32_16x16x32_bf16(av, bw.v, acc[s], 0, 0, 0);
      }
    }
#pragma unroll
    for (int s = 0; s < 4; ++s) {
#pragma unroll
      for (int r = 0; r < 4; ++r) {
        int px_l = s * 16 + kgrp * 4 + r;
        sOutB[o_l][px_l] = f2bf(acc[s][r]);
      }
    }
  }
  __syncthreads();
  for (int i = tid; i < 1024; i += 256) {
    int o = i >> 3, seg = i & 7;
    *reinterpret_cast<short8v*>(Tb + (size_t)(o0base + o) * HW + px0 + seg * 8) =
        *reinterpret_cast<const short8v*>(&sOutB[o][seg * 8]);
  }
}

// ---------------- K6a: dwconv3/dwconv5 + gelu*mul -> Y (bf16) ----------------
__global__ __launch_bounds__(256) void k6a_dw(
    const float* __restrict__ dw3_w, const float* __restrict__ dw5_w,
    const unsigned short* __restrict__ T, __hip_bfloat16* __restrict__ Y)
{
  const int tid = threadIdx.x;
  const int px = blockIdx.x * 256 + tid;
  const int j0 = blockIdx.y * 8;
  const int row = px >> 8, col = px & 255;
  bool oky[5], okx[5];
#pragma unroll
  for (int d = 0; d < 5; ++d) {
    oky[d] = ((unsigned)(row + d - 2) < 256u);
    okx[d] = ((unsigned)(col + d - 2) < 256u);
  }
#pragma unroll
  for (int jj = 0; jj < 8; ++jj) {
    const int j = j0 + jj;
    const unsigned short* pl = T + (size_t)j * HW;
    float a = 0.f;
#pragma unroll
    for (int dy = -1; dy <= 1; ++dy) {
      if (!oky[dy + 2]) continue;
#pragma unroll
      for (int dx = -1; dx <= 1; ++dx) {
        if (!okx[dx + 2]) continue;
        a += bf2f(pl[px + dy * 256 + dx]) * dw3_w[j * 9 + (dy + 1) * 3 + (dx + 1)];
      }
    }
    float m = 0.f;
    const unsigned short* pm = T + (size_t)(128 + j) * HW;
    if (j < 64) {
#pragma unroll
      for (int dy = -1; dy <= 1; ++dy) {
        if (!oky[dy + 2]) continue;
#pragma unroll
        for (int dx = -1; dx <= 1; ++dx) {
          if (!okx[dx + 2]) continue;
          m += bf2f(pm[px + dy * 256 + dx]) * dw3_w[(128 + j) * 9 + (dy + 1) * 3 + (dx + 1)];
        }
      }
    } else {
#pragma unroll
      for (int dy = -2; dy <= 2; ++dy) {
        if (!oky[dy + 2]) continue;
#pragma unroll
        for (int dx = -2; dx <= 2; ++dx) {
          if (!okx[dx + 2]) continue;
          m += bf2f(pm[px + dy * 256 + dx]) * dw5_w[(j - 64) * 25 + (dy + 2) * 5 + (dx + 2)];
        }
      }
    }
    float gl = 0.5f * a * (1.f + erff(a * 0.70710678118654752f));
    Y[(size_t)j * HW + px] = __float2bfloat16(gl * m);
  }
}

// ---------------- K6b: ffn_out (128->64) from Y ----------------
__global__ __launch_bounds__(256) void k6b_out(
    const float* __restrict__ ffn_out_w, const __hip_bfloat16* __restrict__ Y,
    const float* __restrict__ flag, float* __restrict__ dout, float* __restrict__ Z, int b)
{
  __shared__ float sW[2048];
  const int tid = threadIdx.x;
  const int o0 = blockIdx.y * 16;
  for (int i = tid; i < 2048; i += 256) sW[i] = ffn_out_w[o0 * 128 + i];
  __syncthreads();
  const int px = blockIdx.x * 256 + tid;
  float z[16];
#pragma unroll
  for (int o = 0; o < 16; ++o) z[o] = 0.f;
  for (int j = 0; j < 128; ++j) {
    float yv = __bfloat162float(Y[(size_t)j * HW + px]);
#pragma unroll
    for (int o = 0; o < 16; ++o) z[o] += sW[o * 128 + j] * yv;
  }
  if (flag[0] > 0.5f) {
    float* ob = dout + (size_t)(b * 64 + o0) * HW + px;
#pragma unroll
    for (int o = 0; o < 16; ++o) ob[(size_t)o * HW] += z[o];
  } else {
    float* zb = Z + (size_t)o0 * HW + px;
#pragma unroll
    for (int o = 0; o < 16; ++o) zb[(size_t)o * HW] = z[o];
  }
}

// ---------------- K7: general fft path (early-exit if identity) ----------------
__global__ __launch_bounds__(256) void k7_fft(
    const float* __restrict__ fftw, const float* __restrict__ flag,
    const float* __restrict__ Z, float* __restrict__ dout, int b)
{
  if (flag[0] > 0.5f) return;
  __shared__ float swv[64];
  __shared__ float spatch[4][64];
  const int tid = threadIdx.x;
  const int c = blockIdx.x >> 8;
  const int pblk = blockIdx.x & 255;
  if (tid < 64) swv[tid] = fftw[c * 64 + tid];
  const int lp = tid >> 6, e = tid & 63;
  const int patch = pblk * 4 + lp;
  const int pi = patch >> 5, pj = patch & 31;
  const int i = e >> 3, jj = e & 7;
  const int gidx = (pi * 8 + i) * 256 + pj * 8 + jj;
  const float zv = Z[(size_t)c * HW + gidx];
  spatch[lp][e] = zv;
  __syncthreads();
  float s = 0.f;
#pragma unroll
  for (int a = 0; a < 8; ++a)
#pragma unroll
    for (int b2 = 0; b2 < 8; ++b2)
      s += swv[a * 8 + b2] * spatch[lp][((i - a) & 7) * 8 + ((jj - b2) & 7)];
  dout[(size_t)(b * 64 + c) * HW + gidx] += s;
}

extern "C" void kernel_launch(void* const* d_in, const int* in_sizes, int n_in,
                              void* d_out, int out_size, void* d_ws, size_t ws_size,
                              hipStream_t stream) {
  const float* x          = (const float*)d_in[0];
  const float* ln1_w      = (const float*)d_in[1];
  const float* ln1_b      = (const float*)d_in[2];
  const float* in_proj_w  = (const float*)d_in[3];
  const float* qkv_w      = (const float*)d_in[4];
  const float* qkv_dw     = (const float*)d_in[5];
  const float* out_proj_w = (const float*)d_in[6];
  const float* temperature= (const float*)d_in[7];
  const float* attn_scales= (const float*)d_in[8];
  const float* gate_w1    = (const float*)d_in[9];
  const float* gate_b1    = (const float*)d_in[10];
  const float* gate_w2    = (const float*)d_in[11];
  const float* gate_b2    = (const float*)d_in[12];
  const float* lgce_pre_w = (const float*)d_in[13];
  const float* lgce_pre_b = (const float*)d_in[14];
  const float* lgce_post_w= (const float*)d_in[15];
  const float* lgce_post_b= (const float*)d_in[16];
  const float* cbam_m1w   = (const float*)d_in[17];
  const float* cbam_m1b   = (const float*)d_in[18];
  const float* cbam_m2w   = (const float*)d_in[19];
  const float* cbam_m2b   = (const float*)d_in[20];
  const float* cbam_spw   = (const float*)d_in[21];
  const float* cbam_spb   = (const float*)d_in[22];
  const float* ln2_w      = (const float*)d_in[23];
  const float* ln2_b      = (const float*)d_in[24];
  const float* ffn_in_w   = (const float*)d_in[25];
  const float* dw3_w      = (const float*)d_in[26];
  const float* dw5_w      = (const float*)d_in[27];
  const float* ffn_out_w  = (const float*)d_in[28];
  const float* fft_W      = (const float*)d_in[29];
  float* ws = (float*)d_ws;
  float* out = (float*)d_out;
  unsigned short* qkvlp = (unsigned short*)(ws + OFF_QKVL);
  unsigned short* Tb = (unsigned short*)(ws + OFF_T);
  __hip_bfloat16* Ybuf = (__hip_bfloat16*)(ws + OFF_Y);

  hipLaunchKernelGGL(k0_setup, dim3(1), dim3(256), 0, stream,
                     fft_W, in_proj_w, qkv_w, gate_w1, lgce_pre_w, ws);
  hipLaunchKernelGGL(k1_mfma, dim3(4096), dim3(256), 0, stream,
                     x, ln1_w, ln1_b, in_proj_w, ws + OFF_MQKV, ws + OFF_MG1,
                     ws + OFF_MPRE, lgce_pre_b,
                     gate_b1, gate_w2, gate_b2,
                     out, qkvlp, ws + OFF_PRE, ws + OFF_POOL, ws + OFF_GSUM);
  hipLaunchKernelGGL(k1_check, dim3(1), dim3(256), 0, stream,
                     x, ln1_w, ln1_b, in_proj_w, qkv_w, lgce_pre_w, lgce_pre_b,
                     out, qkvlp, ws + OFF_PRE, ws + OFF_BAD);
  hipLaunchKernelGGL(k1r_reset, dim3(1), dim3(256), 0, stream,
                     ws + OFF_BAD, ws + OFF_GSUM);
  hipLaunchKernelGGL(k1_fb, dim3(1024), dim3(256), 0, stream,
                     x, ln1_w, ln1_b, in_proj_w, qkv_w, lgce_pre_w, lgce_pre_b,
                     gate_w1, gate_b1, gate_w2, gate_b2,
                     ws + OFF_BAD, out, qkvlp, ws + OFF_PRE, ws + OFF_POOL, ws + OFF_GSUM);
  hipLaunchKernelGGL(k2_mfma, dim3(128, 4, 4), dim3(256), 0, stream,
                     qkvlp, qkv_dw, ws + OFF_GRAM);
  hipLaunchKernelGGL(k3_final, dim3(1), dim3(256), 0, stream,
                     cbam_m1w, cbam_m1b, cbam_m2w, cbam_m2b, temperature, attn_scales,
                     lgce_pre_w, lgce_pre_b,
                     ws + OFF_GSUM, ws + OFF_POOL, ws + OFF_GRAM, ws + OFF_A, ws + OFF_CW);
  hipLaunchKernelGGL(k4a_thr, dim3(2048), dim3(256), 0, stream,
                     cbam_spw, cbam_spb, ws + OFF_CW, ws + OFF_PRE, ws + OFF_PART);
  hipLaunchKernelGGL(k4a_red, dim3(32), dim3(256), 0, stream,
                     ws + OFF_PART, ws + OFF_THR);
  hipLaunchKernelGGL(k4b_fuse, dim3(1024), dim3(256), 0, stream,
                     x, lgce_post_w, lgce_post_b, out_proj_w,
                     cbam_spw, cbam_spb, qkv_dw, qkvlp, ws + OFF_PRE,
                     ws + OFF_A, ws + OFF_CW, ws + OFF_THR, out);

  for (int b = 0; b < 4; ++b) {
    hipLaunchKernelGGL(k5_mfma, dim3(1024, 2), dim3(256), 0, stream,
                       ln2_w, ln2_b, ffn_in_w, out, Tb, b);
    hipLaunchKernelGGL(k6a_dw, dim3(256, 16), dim3(256), 0, stream,
                       dw3_w, dw5_w, Tb, Ybuf);
    hipLaunchKernelGGL(k6b_out, dim3(256, 4), dim3(256), 0, stream,
                       ffn_out_w, Ybuf, ws + OFF_FLAG, out, ws + OFF_Z, b);
    hipLaunchKernelGGL(k7_fft, dim3(16384), dim3(256), 0, stream,
                       ws + OFF_FFTW, ws + OFF_FLAG, ws + OFF_Z, out, b);
  }
}

// Round 8
// 1349.390 us; speedup vs baseline: 4.7389x; 1.0656x over previous
//
#include <hip/hip_runtime.h>
#include <hip/hip_bf16.h>
#include <math.h>

#define HW 65536
#define NPIX 262144

// ---- workspace layout (float offsets) ----
#define OFF_FFTW 0            // 64x64 spatial fft kernel
#define OFF_FLAG 4096         // 1
#define OFF_GSUM 4097         // 1    (zeroed in k0)
#define OFF_POOL 4098         // 128  (zeroed in k0)  -- pooled(loc) sums
#define OFF_GRAM 4226         // 1280 (zeroed in k0)
#define OFF_THR  5506         // 32   (written by k4a_red)
#define OFF_BAD  5538         // 1    (zeroed in k0)  -- k1 checker flag
#define OFF_A    5539         // 1024
#define OFF_CW   6563         // 128
#define OFF_QKVL 8192         // 96ch * 262144 px bf16 = 12582912 float-slots (SGSA phase)
#define OFF_MQKV 12591104     // 96*64 fp32 composed qkv matrix
#define OFF_MG1  (OFF_MQKV + 6144)     // 16*64 fp32  (ends 12598272)
#define OFF_MPRE 12598272     // 32*64 fp32 composed pre matrix (ends 12600320)
#define OFF_PRE  12600320     // [4][65536][32] fp32 px-major = 8388608 (ends 20988928)
#define OFF_PART 20988928     // 2048 blk * 4 waves * 4 g = 32768 (ends 21021696)
#define OFF_W96  21021696     // 64*96 fp32 composed out_proj|post matrix (SGSA phase only)
#define OFF_CB   (OFF_W96 + 6144)      // 64 fp32 (ends 21027904 < 25174016)
// MFFN phase (per-batch, overlaps QKVL/PRE/W96 which are dead by then):
#define OFF_T    8192                      // 256ch * 65536 bf16
#define OFF_Y    (OFF_T + 16777216)        // 128ch * 65536 bf16
#define OFF_Z    (OFF_Y + 4194304)         // 64ch * 65536 fp32
// peak ws usage = 25174016 floats = 100.7 MB (unchanged proven footprint)

typedef __attribute__((ext_vector_type(8))) short short8v;
typedef __attribute__((ext_vector_type(4))) float f32x4;

__device__ __forceinline__ float sigm(float v) { return 1.f / (1.f + expf(-v)); }
__device__ __forceinline__ float wredsum(float v) {
#pragma unroll
  for (int off = 32; off >= 1; off >>= 1) v += __shfl_xor(v, off);
  return v;
}
__device__ __forceinline__ unsigned short f2bf(float f) {
  union { float f; unsigned u; } x; x.f = f;
  unsigned r = x.u + 0x7fffu + ((x.u >> 16) & 1u);
  return (unsigned short)(r >> 16);
}
__device__ __forceinline__ float bf2f(unsigned short u) {
  union { unsigned u; float f; } x; x.u = ((unsigned)u) << 16;
  return x.f;
}

// ---------------- K0: zero accumulators + fft kernel + composed matrices ----------------
__global__ __launch_bounds__(256) void k0_setup(
    const float* __restrict__ fft_W, const float* __restrict__ in_proj_w,
    const float* __restrict__ qkv_w, const float* __restrict__ g1w,
    const float* __restrict__ pre_w, const float* __restrict__ out_proj_w,
    const float* __restrict__ post_w, const float* __restrict__ post_b,
    float* __restrict__ ws)
{
  __shared__ float ct8[8];
  __shared__ int sbad;
  const int tid = threadIdx.x;
  if (tid < 8) ct8[tid] = cosf((float)tid * 0.78539816339744831f); // cos(k*pi/4)
  if (tid == 0) sbad = 0;
  for (int i = tid; i < 1442; i += 256) ws[OFF_GSUM + i] = 0.f;    // gsum,pool,gram,thr,bad
  // composed matrices
  for (int i = tid; i < 96 * 64; i += 256) {
    int o = i >> 6, c = i & 63;
    float s = 0.f;
    for (int j = 0; j < 32; ++j) s += qkv_w[o * 32 + j] * in_proj_w[(32 + j) * 64 + c];
    ws[OFF_MQKV + i] = s;
  }
  for (int i = tid; i < 16 * 64; i += 256) {
    int o = i >> 6, c = i & 63;
    float s = 0.f;
    for (int j = 0; j < 32; ++j) s += g1w[o * 32 + j] * in_proj_w[(32 + j) * 64 + c];
    ws[OFF_MG1 + i] = s;
  }
  for (int i = tid; i < 32 * 64; i += 256) {
    int o = i >> 6, c = i & 63;
    float s = 0.f;
    for (int j = 0; j < 32; ++j) s += pre_w[o * 32 + j] * in_proj_w[j * 64 + c];
    ws[OFF_MPRE + i] = s;
  }
  // W96 = [ op[:, :32] | op[:,32:]@post_w | op[:,32:] ],  cb = op[:,32:]@post_b
  for (int i = tid; i < 64 * 96; i += 256) {
    int o = i / 96, c = i - o * 96;
    float s;
    if (c < 32) s = out_proj_w[o * 64 + c];
    else if (c < 64) {
      s = 0.f;
      for (int k = 0; k < 32; ++k) s += out_proj_w[o * 64 + 32 + k] * post_w[k * 32 + (c - 32)];
    } else s = out_proj_w[o * 64 + (c - 32)];
    ws[OFF_W96 + i] = s;
  }
  for (int i = tid; i < 64; i += 256) {
    float s = 0.f;
    for (int k = 0; k < 32; ++k) s += out_proj_w[i * 64 + 32 + k] * post_b[k];
    ws[OFF_CB + i] = s;
  }
  __syncthreads();
  bool ok = true;
  for (int i = tid; i < 64 * 64; i += 256) {
    int ch = i >> 6, ab = i & 63;
    int a = ab >> 3, b2 = ab & 7;
    float s = 0.f;
    for (int u = 0; u < 8; ++u)
      for (int v = 0; v < 8; ++v) {
        float Wf;
        if (v == 0 || v == 4)
          Wf = 0.5f * (fft_W[ch * 40 + u * 5 + v] + fft_W[ch * 40 + ((8 - u) & 7) * 5 + v]);
        else if (v < 5)
          Wf = fft_W[ch * 40 + u * 5 + v];
        else
          Wf = fft_W[ch * 40 + ((8 - u) & 7) * 5 + (8 - v)];
        s += Wf * ct8[(u * a + v * b2) & 7];
      }
    s *= (1.f / 64.f);
    ws[OFF_FFTW + i] = s;
    float expect = ((i & 63) == 0) ? 1.f : 0.f;
    if (fabsf(s - expect) > 1e-4f) ok = false;
  }
  if (!ok) atomicOr(&sbad, 1);
  __syncthreads();
  if (tid == 0) ws[OFF_FLAG] = sbad ? 0.f : 1.f;
}

// ---------------- K1 (MFMA): LN1 + [loc(32)|qkv(96)|pre(32)] + gate + pooled-loc ----------------
__global__ __launch_bounds__(256) void k1_mfma(
    const float* __restrict__ x, const float* __restrict__ ln1_w, const float* __restrict__ ln1_b,
    const float* __restrict__ in_proj_w, const float* __restrict__ mqkv, const float* __restrict__ mg1,
    const float* __restrict__ mpre, const float* __restrict__ pre_b,
    const float* __restrict__ g1b, const float* __restrict__ g2w, const float* __restrict__ g2b,
    float* __restrict__ dout, unsigned short* __restrict__ qkvl, float* __restrict__ PREi,
    float* __restrict__ pooled, float* __restrict__ gsum)
{
  __shared__ float sStage[64][65];
  __shared__ unsigned short sXnb[64][72];
  __shared__ unsigned short sQkv[96][72];
  __shared__ float sMu[64], sRs[64];
  __shared__ float sPoolL[32];
  __shared__ float sRed[4];
  const int tid = threadIdx.x;
  const int p0 = blockIdx.x * 64;
  const int b = p0 >> 16;
  const int hw0 = p0 & (HW - 1);
  const float* xb = x + (size_t)(b * 64) * HW + hw0;
#pragma unroll
  for (int i = 0; i < 16; ++i) {
    int idx = tid + i * 256;
    int c = idx >> 6, px = idx & 63;
    sStage[px][c] = xb[(size_t)c * HW + px];
  }
  __syncthreads();
  if (tid < 64) {
    float mu = 0.f;
#pragma unroll
    for (int c = 0; c < 64; ++c) mu += sStage[tid][c];
    mu *= (1.f / 64.f);
    float var = 0.f;
#pragma unroll
    for (int c = 0; c < 64; ++c) { float d = sStage[tid][c] - mu; var += d * d; }
    var *= (1.f / 64.f);
    sMu[tid] = mu;
    sRs[tid] = rsqrtf(var + 1e-5f);
  }
  __syncthreads();
#pragma unroll
  for (int i = 0; i < 16; ++i) {
    int idx = tid + i * 256;
    int px = idx >> 6, c = idx & 63;
    float xn = (sStage[px][c] - sMu[px]) * sRs[px] * ln1_w[c] + ln1_b[c];
    sXnb[px][c] = f2bf(xn);
  }
  __syncthreads();
  const int w = tid >> 6, lane = tid & 63;
  const int col = lane & 15, kgrp = lane >> 4;
  float* sLoc = &sStage[0][0];
  float* sPreB = &sStage[32][0];
#pragma unroll
  for (int pass = 0; pass < 3; ++pass) {
    const int tile = pass * 4 + w;
    if (tile >= 10) continue;
    const int og = tile * 16 + col;
    f32x4 acc[4];
#pragma unroll
    for (int s = 0; s < 4; ++s) acc[s] = (f32x4){0.f, 0.f, 0.f, 0.f};
#pragma unroll
    for (int kk = 0; kk < 2; ++kk) {
      const int c0 = kk * 32 + kgrp * 8;
      const float* wrow = (og < 32) ? (in_proj_w + og * 64)
                        : (og < 128) ? (mqkv + (og - 32) * 64)
                                     : (mpre + (og - 128) * 64);
      union { short8v v; unsigned short s[8]; } bw;
#pragma unroll
      for (int j = 0; j < 8; ++j) bw.s[j] = f2bf(wrow[c0 + j]);
#pragma unroll
      for (int s = 0; s < 4; ++s) {
        short8v av = *reinterpret_cast<const short8v*>(&sXnb[s * 16 + col][c0]);
        acc[s] = __builtin_amdgcn_mfma_f32_16x16x32_bf16(av, bw.v, acc[s], 0, 0, 0);
      }
    }
    if (og < 32) {
      float ps = 0.f;
#pragma unroll
      for (int s = 0; s < 4; ++s) {
#pragma unroll
        for (int r = 0; r < 4; ++r) {
          int px_l = s * 16 + kgrp * 4 + r;
          sLoc[og * 65 + px_l] = acc[s][r];
          ps += acc[s][r];
        }
      }
      ps += __shfl_xor(ps, 16);
      ps += __shfl_xor(ps, 32);
      if (kgrp == 0) sPoolL[og] = ps;
    } else if (og < 128) {
      const int oq = og - 32;
#pragma unroll
      for (int s = 0; s < 4; ++s) {
#pragma unroll
        for (int r = 0; r < 4; ++r) {
          int px_l = s * 16 + kgrp * 4 + r;
          sQkv[oq][px_l] = f2bf(acc[s][r]);
        }
      }
    } else {
      const int op = og - 128;
      const float bias = pre_b[op];
#pragma unroll
      for (int s = 0; s < 4; ++s) {
#pragma unroll
        for (int r = 0; r < 4; ++r) {
          int px_l = s * 16 + kgrp * 4 + r;
          sPreB[px_l * 32 + op] = acc[s][r] + bias;
        }
      }
    }
  }
  {
    const int gpx = tid >> 2, gq = tid & 3;
    float h[4];
#pragma unroll
    for (int i = 0; i < 4; ++i) h[i] = g1b[gq * 4 + i];
#pragma unroll
    for (int cc = 0; cc < 64; cc += 8) {
      union { short8v v; unsigned short s[8]; } xu;
      xu.v = *reinterpret_cast<const short8v*>(&sXnb[gpx][cc]);
#pragma unroll
      for (int j = 0; j < 8; ++j) {
        float xf = bf2f(xu.s[j]);
#pragma unroll
        for (int i = 0; i < 4; ++i) h[i] += mg1[(gq * 4 + i) * 64 + cc + j] * xf;
      }
    }
    float gpart = 0.f;
#pragma unroll
    for (int i = 0; i < 4; ++i) gpart += g2w[gq * 4 + i] * fmaxf(h[i], 0.f);
    gpart += __shfl_xor(gpart, 1);
    gpart += __shfl_xor(gpart, 2);
    float gv = (gq == 0) ? sigm(gpart + g2b[0]) : 0.f;
    gv = wredsum(gv);
    if (lane == 0) sRed[w] = gv;
  }
  __syncthreads();
  for (int i = tid; i < 2048; i += 256) {
    int o = i >> 6, px = i & 63;
    dout[(size_t)(b * 64 + o) * HW + hw0 + px] = sLoc[o * 65 + px];
  }
  for (int i = tid; i < 768; i += 256) {
    int o = i >> 3, seg = i & 7;
    *reinterpret_cast<short8v*>(qkvl + (size_t)(b * 96 + o) * HW + hw0 + seg * 8) =
        *reinterpret_cast<const short8v*>(&sQkv[o][seg * 8]);
  }
  {
    float* Pg = PREi + ((size_t)b * HW + hw0) * 32;
#pragma unroll
    for (int i = 0; i < 8; ++i) {
      int idx = tid + i * 256;
      Pg[idx] = sPreB[idx];
    }
  }
  if (tid < 32) atomicAdd(&pooled[b * 32 + tid], sPoolL[tid]);
  if (tid == 0) atomicAdd(gsum, sRed[0] + sRed[1] + sRed[2] + sRed[3]);
}

// ---------------- K1 checker ----------------
__global__ __launch_bounds__(256) void k1_check(
    const float* __restrict__ x, const float* __restrict__ ln1_w, const float* __restrict__ ln1_b,
    const float* __restrict__ in_proj_w, const float* __restrict__ qkv_w,
    const float* __restrict__ pre_w, const float* __restrict__ pre_b,
    const float* __restrict__ dout, const unsigned short* __restrict__ qkvl,
    const float* __restrict__ PREi, float* __restrict__ bad)
{
  const int t = threadIdx.x;
  const int b = t & 3;
  const int px = (t * 1031) & (HW - 1);
  const float* xb = x + (size_t)(b * 64) * HW + px;
  float xv[64];
  float mu = 0.f;
#pragma unroll
  for (int c = 0; c < 64; ++c) { xv[c] = xb[(size_t)c * HW]; mu += xv[c]; }
  mu *= (1.f / 64.f);
  float var = 0.f;
#pragma unroll
  for (int c = 0; c < 64; ++c) { float d = xv[c] - mu; var += d * d; }
  var *= (1.f / 64.f);
  float rs = rsqrtf(var + 1e-5f);
#pragma unroll
  for (int c = 0; c < 64; ++c) xv[c] = (xv[c] - mu) * rs * ln1_w[c] + ln1_b[c];
  bool fail = false;
  float lc[32], gl[32];
  for (int o = 0; o < 32; ++o) {
    float s = 0.f;
#pragma unroll
    for (int c = 0; c < 64; ++c) s += in_proj_w[o * 64 + c] * xv[c];
    lc[o] = s;
    float got = dout[(size_t)(b * 64 + o) * HW + px];
    if (fabsf(got - s) > 0.05f + 0.05f * fabsf(s)) fail = true;
    float s2 = 0.f;
#pragma unroll
    for (int c = 0; c < 64; ++c) s2 += in_proj_w[(32 + o) * 64 + c] * xv[c];
    gl[o] = s2;
  }
  for (int o = 0; o < 96; ++o) {
    float s = 0.f;
#pragma unroll
    for (int j = 0; j < 32; ++j) s += qkv_w[o * 32 + j] * gl[j];
    float got = bf2f(qkvl[(size_t)(b * 96 + o) * HW + px]);
    if (fabsf(got - s) > 0.05f + 0.05f * fabsf(s)) fail = true;
  }
  for (int o = 0; o < 32; ++o) {
    float s = pre_b[o];
#pragma unroll
    for (int j = 0; j < 32; ++j) s += pre_w[o * 32 + j] * lc[j];
    float got = PREi[((size_t)b * HW + px) * 32 + o];
    if (fabsf(got - s) > 0.05f + 0.05f * fabsf(s)) fail = true;
  }
  if (fail) atomicExch(bad, 1.f);
}

// ---------------- K1 reset (only if checker failed) ----------------
__global__ __launch_bounds__(256) void k1r_reset(const float* __restrict__ bad, float* __restrict__ gsum)
{
  if (bad[0] < 0.5f) return;
  const int tid = threadIdx.x;
  if (tid < 129) gsum[tid] = 0.f;
}

// ---------------- K1 fallback (only if checker failed) ----------------
__global__ __launch_bounds__(256) void k1_fb(
    const float* __restrict__ x, const float* __restrict__ ln1_w, const float* __restrict__ ln1_b,
    const float* __restrict__ in_proj_w, const float* __restrict__ qkv_w,
    const float* __restrict__ pre_w, const float* __restrict__ pre_b,
    const float* __restrict__ g1w, const float* __restrict__ g1b,
    const float* __restrict__ g2w, const float* __restrict__ g2b,
    const float* __restrict__ bad,
    float* __restrict__ dout, unsigned short* __restrict__ qkvl, float* __restrict__ PREi,
    float* __restrict__ pooled, float* __restrict__ gsum)
{
  if (bad[0] < 0.5f) return;
  __shared__ float sPool[4][32];
  __shared__ float sRed[4];
  const int tid = threadIdx.x;
  const int p = blockIdx.x * 256 + tid;
  const int b = p >> 16;
  const int hw = p & (HW - 1);
  const int wave = tid >> 6, lane = tid & 63;
  const float* xb = x + (size_t)(b * 64) * HW + hw;
  float xv[64];
  float mu = 0.f;
#pragma unroll
  for (int c = 0; c < 64; ++c) { xv[c] = xb[(size_t)c * HW]; mu += xv[c]; }
  mu *= (1.f / 64.f);
  float var = 0.f;
#pragma unroll
  for (int c = 0; c < 64; ++c) { float d = xv[c] - mu; var += d * d; }
  var *= (1.f / 64.f);
  const float rs = rsqrtf(var + 1e-5f);
#pragma unroll
  for (int c = 0; c < 64; ++c) xv[c] = (xv[c] - mu) * rs * ln1_w[c] + ln1_b[c];
  float loc[32];
  for (int o = 0; o < 32; ++o) {
    float s = 0.f;
#pragma unroll
    for (int c = 0; c < 64; ++c) s += in_proj_w[o * 64 + c] * xv[c];
    loc[o] = s;
    dout[(size_t)(b * 64 + o) * HW + hw] = s;
    float r = wredsum(s);
    if (lane == 0) sPool[wave][o] = r;
  }
  for (int o = 0; o < 32; ++o) {
    float s = pre_b[o];
#pragma unroll
    for (int j = 0; j < 32; ++j) s += pre_w[o * 32 + j] * loc[j];
    PREi[((size_t)b * HW + hw) * 32 + o] = s;
  }
  float gl[32];
  for (int o = 0; o < 32; ++o) {
    float s = 0.f;
#pragma unroll
    for (int c = 0; c < 64; ++c) s += in_proj_w[(32 + o) * 64 + c] * xv[c];
    gl[o] = s;
  }
  for (int o = 0; o < 96; ++o) {
    float s = 0.f;
#pragma unroll
    for (int j = 0; j < 32; ++j) s += qkv_w[o * 32 + j] * gl[j];
    qkvl[(size_t)(b * 96 + o) * HW + hw] = f2bf(s);
  }
  float gacc = g2b[0];
  for (int o = 0; o < 16; ++o) {
    float h = g1b[o];
#pragma unroll
    for (int j = 0; j < 32; ++j) h += g1w[o * 32 + j] * gl[j];
    gacc += g2w[o] * fmaxf(h, 0.f);
  }
  float gv = wredsum(sigm(gacc));
  if (lane == 0) sRed[wave] = gv;
  __syncthreads();
  if (tid == 0) atomicAdd(gsum, sRed[0] + sRed[1] + sRed[2] + sRed[3]);
  if (tid < 32) {
    float s = sPool[0][tid] + sPool[1][tid] + sPool[2][tid] + sPool[3][tid];
    atomicAdd(&pooled[b * 32 + tid], s);
  }
}

// ---------------- K2 (MFMA): dwconv(q,k) + Gram via V·V^T ----------------
__global__ __launch_bounds__(256) void k2_mfma(
    const unsigned short* __restrict__ qkvl, const float* __restrict__ qkv_dw, float* __restrict__ gram)
{
  __shared__ float sred[4][256];
  const int tid = threadIdx.x;
  const int slab = blockIdx.x;
  const int h = blockIdx.y, b = blockIdx.z;
  const int w = tid >> 6, lane = tid & 63;
  const int ch = lane & 15, grp = lane >> 4;
  const int gch = (ch < 8) ? (h * 8 + ch) : (32 + h * 8 + (ch - 8));
  const unsigned short* plane = qkvl + (size_t)(b * 96 + gch) * HW;
  const float* wt = qkv_dw + gch * 9;
  float w9[9];
#pragma unroll
  for (int t = 0; t < 9; ++t) w9[t] = wt[t];
  f32x4 acc = (f32x4){0.f, 0.f, 0.f, 0.f};
#pragma unroll
  for (int iter = 0; iter < 4; ++iter) {
    const int pxbase = slab * 512 + w * 128 + iter * 32 + grp * 8;
    const int y = pxbase >> 8;
    const int x0 = pxbase & 255;
    union { short8v v; unsigned short s[8]; } frag;
#pragma unroll
    for (int j = 0; j < 8; ++j) {
      const int x = x0 + j;
      float a = 0.f;
#pragma unroll
      for (int dy = -1; dy <= 1; ++dy) {
        const int yy = y + dy;
        if ((unsigned)yy >= 256u) continue;
#pragma unroll
        for (int dx = -1; dx <= 1; ++dx) {
          const int x2 = x + dx;
          if ((unsigned)x2 >= 256u) continue;
          a += bf2f(plane[yy * 256 + x2]) * w9[(dy + 1) * 3 + (dx + 1)];
        }
      }
      frag.s[j] = f2bf(a);
    }
    acc = __builtin_amdgcn_mfma_f32_16x16x32_bf16(frag.v, frag.v, acc, 0, 0, 0);
  }
#pragma unroll
  for (int r = 0; r < 4; ++r) sred[w][(grp * 4 + r) * 16 + ch] = acc[r];
  __syncthreads();
  if (tid < 256) {
    float g = sred[0][tid] + sred[1][tid] + sred[2][tid] + sred[3][tid];
    const int row = tid >> 4, col = tid & 15;
    int idx = -1;
    if (row < 8 && col >= 8) idx = row * 8 + (col - 8);
    else if (row == col && row < 8) idx = 64 + row;
    else if (row == col) idx = 72 + (row - 8);
    if (idx >= 0) atomicAdd(&gram[(b * 4 + h) * 80 + idx], g);
  }
}

// ---------------- K3: dk, CBAM weights, attention matrices ----------------
__global__ __launch_bounds__(256) void k3_final(
    const float* __restrict__ m1w, const float* __restrict__ m1b,
    const float* __restrict__ m2w, const float* __restrict__ m2b,
    const float* __restrict__ temperature, const float* __restrict__ attn_scales,
    const float* __restrict__ pre_w, const float* __restrict__ pre_b,
    const float* __restrict__ gsum, const float* __restrict__ pooled,
    const float* __restrict__ gram, float* __restrict__ Abuf, float* __restrict__ cwbuf)
{
  __shared__ int s_dk;
  __shared__ float s_scale;
  const int tid = threadIdx.x;
  if (tid == 0) {
    float gmean = gsum[0] / (float)NPIX;
    int dk = (int)floorf(8.f * gmean);
    if (dk < 1) dk = 1;
    if (dk > 8) dk = 8;
    s_dk = dk;
    s_scale = attn_scales[0] + attn_scales[1] + attn_scales[2] + attn_scales[3];
  }
  __syncthreads();
  if (tid < 128) {
    int b = tid >> 5, ch = tid & 31, g = ch >> 2, c = ch & 3;
    float h1 = m1b[g];
#pragma unroll
    for (int cc = 0; cc < 4; ++cc) {
      int row = g * 4 + cc;
      float pp = pre_b[row];
#pragma unroll
      for (int j = 0; j < 32; ++j)
        pp += pre_w[row * 32 + j] * (pooled[b * 32 + j] * (1.f / 65536.f));
      h1 += pp * m1w[g * 4 + cc];
    }
    h1 = fmaxf(h1, 0.f);
    cwbuf[tid] = sigm(h1 * m2w[g * 4 + c] + m2b[g * 4 + c]);

    int r = tid, h = (r >> 3) & 3, c8 = r & 7;
    const float* gm = gram + (b * 4 + h) * 80;
    float qn = fmaxf(sqrtf(gm[64 + c8]), 1e-12f);
    float temp = temperature[h];
    float a[8];
#pragma unroll
    for (int d = 0; d < 8; ++d) {
      float kn = fmaxf(sqrtf(gm[72 + d]), 1e-12f);
      a[d] = gm[c8 * 8 + d] / (qn * kn) * temp;
    }
    float t[8];
#pragma unroll
    for (int d = 0; d < 8; ++d) t[d] = a[d];
#pragma unroll
    for (int i = 0; i < 8; ++i)
#pragma unroll
      for (int j = 0; j < 8; ++j)
        if (j > i && t[j] > t[i]) { float tmp = t[i]; t[i] = t[j]; t[j] = tmp; }
    float kth = t[s_dk - 1];
    float mx = t[0];
    float e[8]; float sum = 0.f;
#pragma unroll
    for (int d = 0; d < 8; ++d) {
      e[d] = (a[d] >= kth) ? expf(a[d] - mx) : 0.f;
      sum += e[d];
    }
    float inv = s_scale / sum;
#pragma unroll
    for (int d = 0; d < 8; ++d) Abuf[r * 8 + d] = e[d] * inv;
  }
}

// ---------------- K4a: resp partial sums (atomic-free) ----------------
__global__ __launch_bounds__(256) void k4a_thr(
    const float* __restrict__ spw, const float* __restrict__ spb,
    const float* __restrict__ cwbuf, const float* __restrict__ PREi, float* __restrict__ wpart)
{
  const int tid = threadIdx.x;
  const int pxb = blockIdx.x >> 1;
  const int gh = blockIdx.x & 1;
  const int px = pxb * 256 + tid;
  const int b = px >> 16, hw = px & (HW - 1);
  const int w = tid >> 6, lane = tid & 63;
  const float* cw = cwbuf + b * 32;
  const float4* pp = reinterpret_cast<const float4*>(PREi + ((size_t)b * HW + hw) * 32 + gh * 16);
  float4 pv[4];
#pragma unroll
  for (int k = 0; k < 4; ++k) pv[k] = pp[k];
  float racc[4];
#pragma unroll
  for (int g4 = 0; g4 < 4; ++g4) {
    const int g = gh * 4 + g4;
    float xa[4];
    float sdot = spb[g];
#pragma unroll
    for (int c = 0; c < 4; ++c) {
      float pr = (&pv[g4].x)[c];
      xa[c] = pr * cw[g * 4 + c];
      sdot += xa[c] * spw[g * 4 + c];
    }
    float sgv = sigm(sdot);
    float r = 0.f;
#pragma unroll
    for (int c = 0; c < 4; ++c) r += sigm(xa[c] * sgv);
    racc[g4] = r;
  }
#pragma unroll
  for (int g4 = 0; g4 < 4; ++g4) {
    float v = wredsum(racc[g4]);
    if (lane == 0) wpart[(blockIdx.x * 4 + w) * 4 + g4] = v;
  }
}

// ---------------- K4a_red: reduce wpart -> thrbuf ----------------
__global__ __launch_bounds__(256) void k4a_red(
    const float* __restrict__ wpart, float* __restrict__ thrbuf)
{
  __shared__ float sr[256];
  const int tid = threadIdx.x;
  const int b = blockIdx.x >> 3, g = blockIdx.x & 7;
  const int gh = g >> 2, gl = g & 3;
  float s = 0.f;
#pragma unroll
  for (int w = 0; w < 4; ++w)
    s += wpart[((((size_t)(b * 256 + tid) * 2 + gh) * 4) + w) * 4 + gl];
  sr[tid] = s;
  __syncthreads();
  for (int st = 128; st >= 1; st >>= 1) {
    if (tid < st) sr[tid] += sr[tid + st];
    __syncthreads();
  }
  if (tid == 0) thrbuf[b * 8 + g] = sr[0];
}

// ---------------- K4b (MFMA): LGCE finish + V-dwconv + attn -> A96, W96 MFMA + cb + x -> dout ----------------
// block: 64 px, 4 threads/px (quarter q owns 8 channels); 4 waves x 3 K-steps MFMA.
__global__ __launch_bounds__(256) void k4b_fuse(
    const float* __restrict__ x, const float* __restrict__ spw, const float* __restrict__ spb,
    const float* __restrict__ qkv_dw, const unsigned short* __restrict__ qkvl,
    const float* __restrict__ PREi,
    const float* __restrict__ Abuf, const float* __restrict__ cwbuf, const float* __restrict__ thrbuf,
    const float* __restrict__ W96, const float* __restrict__ cb,
    float* dout)
{
  __shared__ unsigned short sA[64][104];    // [px][96ch]: attnout | mx | loc  (pad 104; row=208B, 16B-aligned)
  __shared__ float sOut[64][65];            // [o][px]
  const int tid = threadIdx.x;
  const int px_l = tid & 63, q = tid >> 6;
  const int p0 = blockIdx.x * 64;
  const int b = p0 >> 16;
  const int hw0 = p0 & (HW - 1);
  const int hw = hw0 + px_l;
  const int y = hw >> 8, xx = hw & 255;
  const float* cw = cwbuf + b * 32;
  const float* A = Abuf + b * 256;
  // loc: dout channels q*8..q*8+8
  float loc8[8];
#pragma unroll
  for (int j = 0; j < 8; ++j)
    loc8[j] = dout[(size_t)(b * 64 + q * 8 + j) * HW + hw];
  // pre: 8 channels q*8..
  float pre8[8];
  {
    const float4* pp = reinterpret_cast<const float4*>(PREi + ((size_t)b * HW + hw) * 32 + q * 8);
    float4 v0 = pp[0], v1 = pp[1];
    pre8[0] = v0.x; pre8[1] = v0.y; pre8[2] = v0.z; pre8[3] = v0.w;
    pre8[4] = v1.x; pre8[5] = v1.y; pre8[6] = v1.z; pre8[7] = v1.w;
  }
  // mx for groups 2q, 2q+1
  float mx8[8];
#pragma unroll
  for (int g2 = 0; g2 < 2; ++g2) {
    const int g = 2 * q + g2;
    float xa[4];
    float sdot = spb[g];
#pragma unroll
    for (int c = 0; c < 4; ++c) {
      xa[c] = pre8[g2 * 4 + c] * cw[g * 4 + c];
      sdot += xa[c] * spw[g * 4 + c];
    }
    float sgv = sigm(sdot);
    float thr = thrbuf[b * 8 + g] * (1.f / (4.f * 65536.f));
#pragma unroll
    for (int c = 0; c < 4; ++c) {
      float resp = sigm(xa[c] * sgv);
      float m = (resp > thr) ? 1.f : resp;
      mx8[g2 * 4 + c] = pre8[g2 * 4 + c] * m;
    }
  }
  // V dwconv for head q (channels q*8..q*8+8)
  int offs[9]; bool okn[9];
#pragma unroll
  for (int dy = -1; dy <= 1; ++dy)
#pragma unroll
    for (int dx = -1; dx <= 1; ++dx) {
      int i = (dy + 1) * 3 + (dx + 1);
      int yy = y + dy, x2 = xx + dx;
      okn[i] = ((unsigned)yy < 256u) && ((unsigned)x2 < 256u);
      offs[i] = yy * 256 + x2;
    }
  float v8[8];
#pragma unroll
  for (int j = 0; j < 8; ++j) {
    const unsigned short* plane = qkvl + (size_t)(b * 96 + 64 + q * 8 + j) * HW;
    float acc = 0.f;
#pragma unroll
    for (int i = 0; i < 9; ++i)
      if (okn[i]) acc += bf2f(plane[offs[i]]) * qkv_dw[(64 + q * 8 + j) * 9 + i];
    v8[j] = acc;
  }
  // attnout for head q
#pragma unroll
  for (int j = 0; j < 8; ++j) {
    float s = 0.f;
#pragma unroll
    for (int d = 0; d < 8; ++d) s += A[(q * 8 + j) * 8 + d] * v8[d];
    sA[px_l][q * 8 + j] = f2bf(s);
    sA[px_l][32 + q * 8 + j] = f2bf(mx8[j]);
    sA[px_l][64 + q * 8 + j] = f2bf(loc8[j]);
  }
  __syncthreads();
  // MFMA: wave w computes outs w*16+col over 64 px, K=96
  const int w = q, lane = tid & 63;
  const int col = lane & 15, kgrp = lane >> 4;
  const int og = w * 16 + col;
  f32x4 acc[4];
#pragma unroll
  for (int s = 0; s < 4; ++s) acc[s] = (f32x4){0.f, 0.f, 0.f, 0.f};
#pragma unroll
  for (int kk = 0; kk < 3; ++kk) {
    const int c0 = kk * 32 + kgrp * 8;
    union { short8v v; unsigned short s[8]; } bw;
    const float* wp = W96 + og * 96 + c0;
#pragma unroll
    for (int j = 0; j < 8; ++j) bw.s[j] = f2bf(wp[j]);
#pragma unroll
    for (int s = 0; s < 4; ++s) {
      short8v av = *reinterpret_cast<const short8v*>(&sA[s * 16 + col][c0]);
      acc[s] = __builtin_amdgcn_mfma_f32_16x16x32_bf16(av, bw.v, acc[s], 0, 0, 0);
    }
  }
#pragma unroll
  for (int s = 0; s < 4; ++s) {
#pragma unroll
    for (int r = 0; r < 4; ++r) {
      int pxl = s * 16 + kgrp * 4 + r;
      sOut[og][pxl] = acc[s][r];
    }
  }
  __syncthreads();
  // epilogue: dout = sOut + cb + x (coalesced, 16 elems/thread)
  const float* xb = x + (size_t)(b * 64) * HW + hw0;
  float* db = dout + (size_t)(b * 64) * HW + hw0;
#pragma unroll
  for (int i = 0; i < 16; ++i) {
    int idx = tid + i * 256;
    int o = idx >> 6, px = idx & 63;
    db[(size_t)o * HW + px] = sOut[o][px] + cb[o] + xb[(size_t)o * HW + px];
  }
}

// ---------------- K5 (MFMA): LN2 + ffn_in (64->256), 128 outs/block ----------------
__global__ __launch_bounds__(256) void k5_mfma(
    const float* __restrict__ ln2_w, const float* __restrict__ ln2_b,
    const float* __restrict__ ffn_in_w, const float* __restrict__ dout,
    unsigned short* __restrict__ Tb, int b)
{
  __shared__ float sStage[64][65];
  __shared__ unsigned short sXnb[64][72];
  __shared__ unsigned short sOutB[128][72];
  __shared__ float sMu[64], sRs[64];
  const int tid = threadIdx.x;
  const int px0 = blockIdx.x * 64;
  const int o0base = blockIdx.y * 128;
  const float* db = dout + (size_t)(b * 64) * HW + px0;
#pragma unroll
  for (int i = 0; i < 16; ++i) {
    int idx = tid + i * 256;
    int c = idx >> 6, px = idx & 63;
    sStage[px][c] = db[(size_t)c * HW + px];
  }
  __syncthreads();
  if (tid < 64) {
    float mu = 0.f;
#pragma unroll
    for (int c = 0; c < 64; ++c) mu += sStage[tid][c];
    mu *= (1.f / 64.f);
    float var = 0.f;
#pragma unroll
    for (int c = 0; c < 64; ++c) { float d = sStage[tid][c] - mu; var += d * d; }
    var *= (1.f / 64.f);
    sMu[tid] = mu;
    sRs[tid] = rsqrtf(var + 1e-5f);
  }
  __syncthreads();
#pragma unroll
  for (int i = 0; i < 16; ++i) {
    int idx = tid + i * 256;
    int px = idx >> 6, c = idx & 63;
    float xn = (sStage[px][c] - sMu[px]) * sRs[px] * ln2_w[c] + ln2_b[c];
    sXnb[px][c] = f2bf(xn);
  }
  __syncthreads();
  const int w = tid >> 6, lane = tid & 63;
  const int col = lane & 15, kgrp = lane >> 4;
#pragma unroll
  for (int pass = 0; pass < 2; ++pass) {
    const int o_l = pass * 64 + w * 16 + col;
    const int og = o0base + o_l;
    f32x4 acc[4];
#pragma unroll
    for (int s = 0; s < 4; ++s) acc[s] = (f32x4){0.f, 0.f, 0.f, 0.f};
#pragma unroll
    for (int kk = 0; kk < 2; ++kk) {
      const int c0 = kk * 32 + kgrp * 8;
      union { short8v v; unsigned short s[8]; } bw;
      const float* wp = ffn_in_w + (size_t)og * 64 + c0;
#pragma unroll
      for (int j = 0; j < 8; ++j) bw.s[j] = f2bf(wp[j]);
#pragma unroll
      for (int s = 0; s < 4; ++s) {
        short8v av = *reinterpret_cast<const short8v*>(&sXnb[s * 16 + col][c0]);
        acc[s] = __builtin_amdgcn_mfma_f32_16x16x32_bf16(av, bw.v, acc[s], 0, 0, 0);
      }
    }
#pragma unroll
    for (int s = 0; s < 4; ++s) {
#pragma unroll
      for (int r = 0; r < 4; ++r) {
        int px_l = s * 16 + kgrp * 4 + r;
        sOutB[o_l][px_l] = f2bf(acc[s][r]);
      }
    }
  }
  __syncthreads();
  for (int i = tid; i < 1024; i += 256) {
    int o = i >> 3, seg = i & 7;
    *reinterpret_cast<short8v*>(Tb + (size_t)(o0base + o) * HW + px0 + seg * 8) =
        *reinterpret_cast<const short8v*>(&sOutB[o][seg * 8]);
  }
}

// ---------------- K6a: dwconv3/dwconv5 + gelu*mul -> Y (bf16) ----------------
__global__ __launch_bounds__(256) void k6a_dw(
    const float* __restrict__ dw3_w, const float* __restrict__ dw5_w,
    const unsigned short* __restrict__ T, __hip_bfloat16* __restrict__ Y)
{
  const int tid = threadIdx.x;
  const int px = blockIdx.x * 256 + tid;
  const int j0 = blockIdx.y * 8;
  const int row = px >> 8, col = px & 255;
  bool oky[5], okx[5];
#pragma unroll
  for (int d = 0; d < 5; ++d) {
    oky[d] = ((unsigned)(row + d - 2) < 256u);
    okx[d] = ((unsigned)(col + d - 2) < 256u);
  }
#pragma unroll
  for (int jj = 0; jj < 8; ++jj) {
    const int j = j0 + jj;
    const unsigned short* pl = T + (size_t)j * HW;
    float a = 0.f;
#pragma unroll
    for (int dy = -1; dy <= 1; ++dy) {
      if (!oky[dy + 2]) continue;
#pragma unroll
      for (int dx = -1; dx <= 1; ++dx) {
        if (!okx[dx + 2]) continue;
        a += bf2f(pl[px + dy * 256 + dx]) * dw3_w[j * 9 + (dy + 1) * 3 + (dx + 1)];
      }
    }
    float m = 0.f;
    const unsigned short* pm = T + (size_t)(128 + j) * HW;
    if (j < 64) {
#pragma unroll
      for (int dy = -1; dy <= 1; ++dy) {
        if (!oky[dy + 2]) continue;
#pragma unroll
        for (int dx = -1; dx <= 1; ++dx) {
          if (!okx[dx + 2]) continue;
          m += bf2f(pm[px + dy * 256 + dx]) * dw3_w[(128 + j) * 9 + (dy + 1) * 3 + (dx + 1)];
        }
      }
    } else {
#pragma unroll
      for (int dy = -2; dy <= 2; ++dy) {
        if (!oky[dy + 2]) continue;
#pragma unroll
        for (int dx = -2; dx <= 2; ++dx) {
          if (!okx[dx + 2]) continue;
          m += bf2f(pm[px + dy * 256 + dx]) * dw5_w[(j - 64) * 25 + (dy + 2) * 5 + (dx + 2)];
        }
      }
    }
    float gl = 0.5f * a * (1.f + erff(a * 0.70710678118654752f));
    Y[(size_t)j * HW + px] = __float2bfloat16(gl * m);
  }
}

// ---------------- K6b: ffn_out (128->64) from Y ----------------
__global__ __launch_bounds__(256) void k6b_out(
    const float* __restrict__ ffn_out_w, const __hip_bfloat16* __restrict__ Y,
    const float* __restrict__ flag, float* __restrict__ dout, float* __restrict__ Z, int b)
{
  __shared__ float sW[2048];
  const int tid = threadIdx.x;
  const int o0 = blockIdx.y * 16;
  for (int i = tid; i < 2048; i += 256) sW[i] = ffn_out_w[o0 * 128 + i];
  __syncthreads();
  const int px = blockIdx.x * 256 + tid;
  float z[16];
#pragma unroll
  for (int o = 0; o < 16; ++o) z[o] = 0.f;
  for (int j = 0; j < 128; ++j) {
    float yv = __bfloat162float(Y[(size_t)j * HW + px]);
#pragma unroll
    for (int o = 0; o < 16; ++o) z[o] += sW[o * 128 + j] * yv;
  }
  if (flag[0] > 0.5f) {
    float* ob = dout + (size_t)(b * 64 + o0) * HW + px;
#pragma unroll
    for (int o = 0; o < 16; ++o) ob[(size_t)o * HW] += z[o];
  } else {
    float* zb = Z + (size_t)o0 * HW + px;
#pragma unroll
    for (int o = 0; o < 16; ++o) zb[(size_t)o * HW] = z[o];
  }
}

// ---------------- K7: general fft path (early-exit if identity) ----------------
__global__ __launch_bounds__(256) void k7_fft(
    const float* __restrict__ fftw, const float* __restrict__ flag,
    const float* __restrict__ Z, float* __restrict__ dout, int b)
{
  if (flag[0] > 0.5f) return;
  __shared__ float swv[64];
  __shared__ float spatch[4][64];
  const int tid = threadIdx.x;
  const int c = blockIdx.x >> 8;
  const int pblk = blockIdx.x & 255;
  if (tid < 64) swv[tid] = fftw[c * 64 + tid];
  const int lp = tid >> 6, e = tid & 63;
  const int patch = pblk * 4 + lp;
  const int pi = patch >> 5, pj = patch & 31;
  const int i = e >> 3, jj = e & 7;
  const int gidx = (pi * 8 + i) * 256 + pj * 8 + jj;
  const float zv = Z[(size_t)c * HW + gidx];
  spatch[lp][e] = zv;
  __syncthreads();
  float s = 0.f;
#pragma unroll
  for (int a = 0; a < 8; ++a)
#pragma unroll
    for (int b2 = 0; b2 < 8; ++b2)
      s += swv[a * 8 + b2] * spatch[lp][((i - a) & 7) * 8 + ((jj - b2) & 7)];
  dout[(size_t)(b * 64 + c) * HW + gidx] += s;
}

extern "C" void kernel_launch(void* const* d_in, const int* in_sizes, int n_in,
                              void* d_out, int out_size, void* d_ws, size_t ws_size,
                              hipStream_t stream) {
  const float* x          = (const float*)d_in[0];
  const float* ln1_w      = (const float*)d_in[1];
  const float* ln1_b      = (const float*)d_in[2];
  const float* in_proj_w  = (const float*)d_in[3];
  const float* qkv_w      = (const float*)d_in[4];
  const float* qkv_dw     = (const float*)d_in[5];
  const float* out_proj_w = (const float*)d_in[6];
  const float* temperature= (const float*)d_in[7];
  const float* attn_scales= (const float*)d_in[8];
  const float* gate_w1    = (const float*)d_in[9];
  const float* gate_b1    = (const float*)d_in[10];
  const float* gate_w2    = (const float*)d_in[11];
  const float* gate_b2    = (const float*)d_in[12];
  const float* lgce_pre_w = (const float*)d_in[13];
  const float* lgce_pre_b = (const float*)d_in[14];
  const float* lgce_post_w= (const float*)d_in[15];
  const float* lgce_post_b= (const float*)d_in[16];
  const float* cbam_m1w   = (const float*)d_in[17];
  const float* cbam_m1b   = (const float*)d_in[18];
  const float* cbam_m2w   = (const float*)d_in[19];
  const float* cbam_m2b   = (const float*)d_in[20];
  const float* cbam_spw   = (const float*)d_in[21];
  const float* cbam_spb   = (const float*)d_in[22];
  const float* ln2_w      = (const float*)d_in[23];
  const float* ln2_b      = (const float*)d_in[24];
  const float* ffn_in_w   = (const float*)d_in[25];
  const float* dw3_w      = (const float*)d_in[26];
  const float* dw5_w      = (const float*)d_in[27];
  const float* ffn_out_w  = (const float*)d_in[28];
  const float* fft_W      = (const float*)d_in[29];
  float* ws = (float*)d_ws;
  float* out = (float*)d_out;
  unsigned short* qkvlp = (unsigned short*)(ws + OFF_QKVL);
  unsigned short* Tb = (unsigned short*)(ws + OFF_T);
  __hip_bfloat16* Ybuf = (__hip_bfloat16*)(ws + OFF_Y);

  hipLaunchKernelGGL(k0_setup, dim3(1), dim3(256), 0, stream,
                     fft_W, in_proj_w, qkv_w, gate_w1, lgce_pre_w,
                     out_proj_w, lgce_post_w, lgce_post_b, ws);
  hipLaunchKernelGGL(k1_mfma, dim3(4096), dim3(256), 0, stream,
                     x, ln1_w, ln1_b, in_proj_w, ws + OFF_MQKV, ws + OFF_MG1,
                     ws + OFF_MPRE, lgce_pre_b,
                     gate_b1, gate_w2, gate_b2,
                     out, qkvlp, ws + OFF_PRE, ws + OFF_POOL, ws + OFF_GSUM);
  hipLaunchKernelGGL(k1_check, dim3(1), dim3(256), 0, stream,
                     x, ln1_w, ln1_b, in_proj_w, qkv_w, lgce_pre_w, lgce_pre_b,
                     out, qkvlp, ws + OFF_PRE, ws + OFF_BAD);
  hipLaunchKernelGGL(k1r_reset, dim3(1), dim3(256), 0, stream,
                     ws + OFF_BAD, ws + OFF_GSUM);
  hipLaunchKernelGGL(k1_fb, dim3(1024), dim3(256), 0, stream,
                     x, ln1_w, ln1_b, in_proj_w, qkv_w, lgce_pre_w, lgce_pre_b,
                     gate_w1, gate_b1, gate_w2, gate_b2,
                     ws + OFF_BAD, out, qkvlp, ws + OFF_PRE, ws + OFF_POOL, ws + OFF_GSUM);
  hipLaunchKernelGGL(k2_mfma, dim3(128, 4, 4), dim3(256), 0, stream,
                     qkvlp, qkv_dw, ws + OFF_GRAM);
  hipLaunchKernelGGL(k3_final, dim3(1), dim3(256), 0, stream,
                     cbam_m1w, cbam_m1b, cbam_m2w, cbam_m2b, temperature, attn_scales,
                     lgce_pre_w, lgce_pre_b,
                     ws + OFF_GSUM, ws + OFF_POOL, ws + OFF_GRAM, ws + OFF_A, ws + OFF_CW);
  hipLaunchKernelGGL(k4a_thr, dim3(2048), dim3(256), 0, stream,
                     cbam_spw, cbam_spb, ws + OFF_CW, ws + OFF_PRE, ws + OFF_PART);
  hipLaunchKernelGGL(k4a_red, dim3(32), dim3(256), 0, stream,
                     ws + OFF_PART, ws + OFF_THR);
  hipLaunchKernelGGL(k4b_fuse, dim3(4096), dim3(256), 0, stream,
                     x, cbam_spw, cbam_spb, qkv_dw, qkvlp, ws + OFF_PRE,
                     ws + OFF_A, ws + OFF_CW, ws + OFF_THR,
                     ws + OFF_W96, ws + OFF_CB, out);

  for (int b = 0; b < 4; ++b) {
    hipLaunchKernelGGL(k5_mfma, dim3(1024, 2), dim3(256), 0, stream,
                       ln2_w, ln2_b, ffn_in_w, out, Tb, b);
    hipLaunchKernelGGL(k6a_dw, dim3(256, 16), dim3(256), 0, stream,
                       dw3_w, dw5_w, Tb, Ybuf);
    hipLaunchKernelGGL(k6b_out, dim3(256, 4), dim3(256), 0, stream,
                       ffn_out_w, Ybuf, ws + OFF_FLAG, out, ws + OFF_Z, b);
    hipLaunchKernelGGL(k7_fft, dim3(16384), dim3(256), 0, stream,
                       ws + OFF_FFTW, ws + OFF_FLAG, ws + OFF_Z, out, b);
  }
}

// Round 9
// 1184.577 us; speedup vs baseline: 5.3983x; 1.1391x over previous
//
#include <hip/hip_runtime.h>
#include <hip/hip_bf16.h>
#include <math.h>

#define HW 65536
#define NPIX 262144

// ---- workspace layout (float offsets) ----
#define OFF_FFTW 0            // 64x64 spatial fft kernel
#define OFF_FLAG 4096         // 1
#define OFF_GSUM 4097         // 1    (zeroed in k0)
#define OFF_POOL 4098         // 128  (zeroed in k0)  -- pooled(loc) sums
#define OFF_GRAM 4226         // 1280 (zeroed in k0)
#define OFF_THR  5506         // 32   (written by k4a_red)
#define OFF_BAD  5538         // 1    (zeroed in k0)  -- k1 checker flag
#define OFF_A    5539         // 1024
#define OFF_CW   6563         // 128
#define OFF_QKVL 8192         // 96ch * 262144 px bf16 = 12582912 float-slots (SGSA phase)
#define OFF_MQKV 12591104     // 96*64 fp32 composed qkv matrix
#define OFF_MG1  (OFF_MQKV + 6144)     // 16*64 fp32  (ends 12598272)
#define OFF_MPRE 12598272     // 32*64 fp32 composed pre matrix (ends 12600320)
#define OFF_PRE  12600320     // [4][65536][32] fp32 px-major = 8388608 (ends 20988928)
#define OFF_PART 20988928     // 2048 blk * 4 waves * 4 g = 32768 (ends 21021696)
#define OFF_W96  21021696     // 64*96 fp32 composed out_proj|post matrix (SGSA phase only)
#define OFF_CB   (OFF_W96 + 6144)      // 64 fp32 (ends 21027904 < 25174016)
// MFFN phase (per-batch, overlaps QKVL/PRE/W96 which are dead by then):
#define OFF_T    8192                      // 256ch * 65536 bf16
#define OFF_Y    (OFF_T + 16777216)        // 128ch * 65536 bf16
#define OFF_Z    (OFF_Y + 4194304)         // 64ch * 65536 fp32
// peak ws usage = 25174016 floats = 100.7 MB (unchanged proven footprint)

typedef __attribute__((ext_vector_type(8))) short short8v;
typedef __attribute__((ext_vector_type(4))) float f32x4;

__device__ __forceinline__ float sigm(float v) { return 1.f / (1.f + expf(-v)); }
__device__ __forceinline__ float wredsum(float v) {
#pragma unroll
  for (int off = 32; off >= 1; off >>= 1) v += __shfl_xor(v, off);
  return v;
}
__device__ __forceinline__ unsigned short f2bf(float f) {
  union { float f; unsigned u; } x; x.f = f;
  unsigned r = x.u + 0x7fffu + ((x.u >> 16) & 1u);
  return (unsigned short)(r >> 16);
}
__device__ __forceinline__ float bf2f(unsigned short u) {
  union { unsigned u; float f; } x; x.u = ((unsigned)u) << 16;
  return x.f;
}

// ---------------- K0: zero accumulators + fft kernel + composed matrices ----------------
__global__ __launch_bounds__(256) void k0_setup(
    const float* __restrict__ fft_W, const float* __restrict__ in_proj_w,
    const float* __restrict__ qkv_w, const float* __restrict__ g1w,
    const float* __restrict__ pre_w, const float* __restrict__ out_proj_w,
    const float* __restrict__ post_w, const float* __restrict__ post_b,
    float* __restrict__ ws)
{
  __shared__ float ct8[8];
  __shared__ int sbad;
  const int tid = threadIdx.x;
  if (tid < 8) ct8[tid] = cosf((float)tid * 0.78539816339744831f); // cos(k*pi/4)
  if (tid == 0) sbad = 0;
  for (int i = tid; i < 1442; i += 256) ws[OFF_GSUM + i] = 0.f;    // gsum,pool,gram,thr,bad
  // composed matrices
  for (int i = tid; i < 96 * 64; i += 256) {
    int o = i >> 6, c = i & 63;
    float s = 0.f;
    for (int j = 0; j < 32; ++j) s += qkv_w[o * 32 + j] * in_proj_w[(32 + j) * 64 + c];
    ws[OFF_MQKV + i] = s;
  }
  for (int i = tid; i < 16 * 64; i += 256) {
    int o = i >> 6, c = i & 63;
    float s = 0.f;
    for (int j = 0; j < 32; ++j) s += g1w[o * 32 + j] * in_proj_w[(32 + j) * 64 + c];
    ws[OFF_MG1 + i] = s;
  }
  for (int i = tid; i < 32 * 64; i += 256) {
    int o = i >> 6, c = i & 63;
    float s = 0.f;
    for (int j = 0; j < 32; ++j) s += pre_w[o * 32 + j] * in_proj_w[j * 64 + c];
    ws[OFF_MPRE + i] = s;
  }
  // W96 = [ op[:, :32] | op[:,32:]@post_w | op[:,32:] ],  cb = op[:,32:]@post_b
  for (int i = tid; i < 64 * 96; i += 256) {
    int o = i / 96, c = i - o * 96;
    float s;
    if (c < 32) s = out_proj_w[o * 64 + c];
    else if (c < 64) {
      s = 0.f;
      for (int k = 0; k < 32; ++k) s += out_proj_w[o * 64 + 32 + k] * post_w[k * 32 + (c - 32)];
    } else s = out_proj_w[o * 64 + (c - 32)];
    ws[OFF_W96 + i] = s;
  }
  for (int i = tid; i < 64; i += 256) {
    float s = 0.f;
    for (int k = 0; k < 32; ++k) s += out_proj_w[i * 64 + 32 + k] * post_b[k];
    ws[OFF_CB + i] = s;
  }
  __syncthreads();
  bool ok = true;
  for (int i = tid; i < 64 * 64; i += 256) {
    int ch = i >> 6, ab = i & 63;
    int a = ab >> 3, b2 = ab & 7;
    float s = 0.f;
    for (int u = 0; u < 8; ++u)
      for (int v = 0; v < 8; ++v) {
        float Wf;
        if (v == 0 || v == 4)
          Wf = 0.5f * (fft_W[ch * 40 + u * 5 + v] + fft_W[ch * 40 + ((8 - u) & 7) * 5 + v]);
        else if (v < 5)
          Wf = fft_W[ch * 40 + u * 5 + v];
        else
          Wf = fft_W[ch * 40 + ((8 - u) & 7) * 5 + (8 - v)];
        s += Wf * ct8[(u * a + v * b2) & 7];
      }
    s *= (1.f / 64.f);
    ws[OFF_FFTW + i] = s;
    float expect = ((i & 63) == 0) ? 1.f : 0.f;
    if (fabsf(s - expect) > 1e-4f) ok = false;
  }
  if (!ok) atomicOr(&sbad, 1);
  __syncthreads();
  if (tid == 0) ws[OFF_FLAG] = sbad ? 0.f : 1.f;
}

// ---------------- K1 (MFMA): LN1 + [loc(32)|qkv(96)|pre(32)] + gate + pooled-loc ----------------
__global__ __launch_bounds__(256) void k1_mfma(
    const float* __restrict__ x, const float* __restrict__ ln1_w, const float* __restrict__ ln1_b,
    const float* __restrict__ in_proj_w, const float* __restrict__ mqkv, const float* __restrict__ mg1,
    const float* __restrict__ mpre, const float* __restrict__ pre_b,
    const float* __restrict__ g1b, const float* __restrict__ g2w, const float* __restrict__ g2b,
    float* __restrict__ dout, unsigned short* __restrict__ qkvl, float* __restrict__ PREi,
    float* __restrict__ pooled, float* __restrict__ gsum)
{
  __shared__ float sStage[64][65];
  __shared__ unsigned short sXnb[64][72];
  __shared__ unsigned short sQkv[96][72];
  __shared__ float sMu[64], sRs[64];
  __shared__ float sPoolL[32];
  __shared__ float sRed[4];
  const int tid = threadIdx.x;
  const int p0 = blockIdx.x * 64;
  const int b = p0 >> 16;
  const int hw0 = p0 & (HW - 1);
  const float* xb = x + (size_t)(b * 64) * HW + hw0;
#pragma unroll
  for (int i = 0; i < 16; ++i) {
    int idx = tid + i * 256;
    int c = idx >> 6, px = idx & 63;
    sStage[px][c] = xb[(size_t)c * HW + px];
  }
  __syncthreads();
  if (tid < 64) {
    float mu = 0.f;
#pragma unroll
    for (int c = 0; c < 64; ++c) mu += sStage[tid][c];
    mu *= (1.f / 64.f);
    float var = 0.f;
#pragma unroll
    for (int c = 0; c < 64; ++c) { float d = sStage[tid][c] - mu; var += d * d; }
    var *= (1.f / 64.f);
    sMu[tid] = mu;
    sRs[tid] = rsqrtf(var + 1e-5f);
  }
  __syncthreads();
#pragma unroll
  for (int i = 0; i < 16; ++i) {
    int idx = tid + i * 256;
    int px = idx >> 6, c = idx & 63;
    float xn = (sStage[px][c] - sMu[px]) * sRs[px] * ln1_w[c] + ln1_b[c];
    sXnb[px][c] = f2bf(xn);
  }
  __syncthreads();
  const int w = tid >> 6, lane = tid & 63;
  const int col = lane & 15, kgrp = lane >> 4;
  float* sLoc = &sStage[0][0];
  float* sPreB = &sStage[32][0];
#pragma unroll
  for (int pass = 0; pass < 3; ++pass) {
    const int tile = pass * 4 + w;
    if (tile >= 10) continue;
    const int og = tile * 16 + col;
    f32x4 acc[4];
#pragma unroll
    for (int s = 0; s < 4; ++s) acc[s] = (f32x4){0.f, 0.f, 0.f, 0.f};
#pragma unroll
    for (int kk = 0; kk < 2; ++kk) {
      const int c0 = kk * 32 + kgrp * 8;
      const float* wrow = (og < 32) ? (in_proj_w + og * 64)
                        : (og < 128) ? (mqkv + (og - 32) * 64)
                                     : (mpre + (og - 128) * 64);
      union { short8v v; unsigned short s[8]; } bw;
#pragma unroll
      for (int j = 0; j < 8; ++j) bw.s[j] = f2bf(wrow[c0 + j]);
#pragma unroll
      for (int s = 0; s < 4; ++s) {
        short8v av = *reinterpret_cast<const short8v*>(&sXnb[s * 16 + col][c0]);
        acc[s] = __builtin_amdgcn_mfma_f32_16x16x32_bf16(av, bw.v, acc[s], 0, 0, 0);
      }
    }
    if (og < 32) {
      float ps = 0.f;
#pragma unroll
      for (int s = 0; s < 4; ++s) {
#pragma unroll
        for (int r = 0; r < 4; ++r) {
          int px_l = s * 16 + kgrp * 4 + r;
          sLoc[og * 65 + px_l] = acc[s][r];
          ps += acc[s][r];
        }
      }
      ps += __shfl_xor(ps, 16);
      ps += __shfl_xor(ps, 32);
      if (kgrp == 0) sPoolL[og] = ps;
    } else if (og < 128) {
      const int oq = og - 32;
#pragma unroll
      for (int s = 0; s < 4; ++s) {
#pragma unroll
        for (int r = 0; r < 4; ++r) {
          int px_l = s * 16 + kgrp * 4 + r;
          sQkv[oq][px_l] = f2bf(acc[s][r]);
        }
      }
    } else {
      const int op = og - 128;
      const float bias = pre_b[op];
#pragma unroll
      for (int s = 0; s < 4; ++s) {
#pragma unroll
        for (int r = 0; r < 4; ++r) {
          int px_l = s * 16 + kgrp * 4 + r;
          sPreB[px_l * 32 + op] = acc[s][r] + bias;
        }
      }
    }
  }
  {
    const int gpx = tid >> 2, gq = tid & 3;
    float h[4];
#pragma unroll
    for (int i = 0; i < 4; ++i) h[i] = g1b[gq * 4 + i];
#pragma unroll
    for (int cc = 0; cc < 64; cc += 8) {
      union { short8v v; unsigned short s[8]; } xu;
      xu.v = *reinterpret_cast<const short8v*>(&sXnb[gpx][cc]);
#pragma unroll
      for (int j = 0; j < 8; ++j) {
        float xf = bf2f(xu.s[j]);
#pragma unroll
        for (int i = 0; i < 4; ++i) h[i] += mg1[(gq * 4 + i) * 64 + cc + j] * xf;
      }
    }
    float gpart = 0.f;
#pragma unroll
    for (int i = 0; i < 4; ++i) gpart += g2w[gq * 4 + i] * fmaxf(h[i], 0.f);
    gpart += __shfl_xor(gpart, 1);
    gpart += __shfl_xor(gpart, 2);
    float gv = (gq == 0) ? sigm(gpart + g2b[0]) : 0.f;
    gv = wredsum(gv);
    if (lane == 0) sRed[w] = gv;
  }
  __syncthreads();
  for (int i = tid; i < 2048; i += 256) {
    int o = i >> 6, px = i & 63;
    dout[(size_t)(b * 64 + o) * HW + hw0 + px] = sLoc[o * 65 + px];
  }
  for (int i = tid; i < 768; i += 256) {
    int o = i >> 3, seg = i & 7;
    *reinterpret_cast<short8v*>(qkvl + (size_t)(b * 96 + o) * HW + hw0 + seg * 8) =
        *reinterpret_cast<const short8v*>(&sQkv[o][seg * 8]);
  }
  {
    float* Pg = PREi + ((size_t)b * HW + hw0) * 32;
#pragma unroll
    for (int i = 0; i < 8; ++i) {
      int idx = tid + i * 256;
      Pg[idx] = sPreB[idx];
    }
  }
  if (tid < 32) atomicAdd(&pooled[b * 32 + tid], sPoolL[tid]);
  if (tid == 0) atomicAdd(gsum, sRed[0] + sRed[1] + sRed[2] + sRed[3]);
}

// ---------------- K1 checker ----------------
__global__ __launch_bounds__(256) void k1_check(
    const float* __restrict__ x, const float* __restrict__ ln1_w, const float* __restrict__ ln1_b,
    const float* __restrict__ in_proj_w, const float* __restrict__ qkv_w,
    const float* __restrict__ pre_w, const float* __restrict__ pre_b,
    const float* __restrict__ dout, const unsigned short* __restrict__ qkvl,
    const float* __restrict__ PREi, float* __restrict__ bad)
{
  const int t = threadIdx.x;
  const int b = t & 3;
  const int px = (t * 1031) & (HW - 1);
  const float* xb = x + (size_t)(b * 64) * HW + px;
  float xv[64];
  float mu = 0.f;
#pragma unroll
  for (int c = 0; c < 64; ++c) { xv[c] = xb[(size_t)c * HW]; mu += xv[c]; }
  mu *= (1.f / 64.f);
  float var = 0.f;
#pragma unroll
  for (int c = 0; c < 64; ++c) { float d = xv[c] - mu; var += d * d; }
  var *= (1.f / 64.f);
  float rs = rsqrtf(var + 1e-5f);
#pragma unroll
  for (int c = 0; c < 64; ++c) xv[c] = (xv[c] - mu) * rs * ln1_w[c] + ln1_b[c];
  bool fail = false;
  float lc[32], gl[32];
  for (int o = 0; o < 32; ++o) {
    float s = 0.f;
#pragma unroll
    for (int c = 0; c < 64; ++c) s += in_proj_w[o * 64 + c] * xv[c];
    lc[o] = s;
    float got = dout[(size_t)(b * 64 + o) * HW + px];
    if (fabsf(got - s) > 0.05f + 0.05f * fabsf(s)) fail = true;
    float s2 = 0.f;
#pragma unroll
    for (int c = 0; c < 64; ++c) s2 += in_proj_w[(32 + o) * 64 + c] * xv[c];
    gl[o] = s2;
  }
  for (int o = 0; o < 96; ++o) {
    float s = 0.f;
#pragma unroll
    for (int j = 0; j < 32; ++j) s += qkv_w[o * 32 + j] * gl[j];
    float got = bf2f(qkvl[(size_t)(b * 96 + o) * HW + px]);
    if (fabsf(got - s) > 0.05f + 0.05f * fabsf(s)) fail = true;
  }
  for (int o = 0; o < 32; ++o) {
    float s = pre_b[o];
#pragma unroll
    for (int j = 0; j < 32; ++j) s += pre_w[o * 32 + j] * lc[j];
    float got = PREi[((size_t)b * HW + px) * 32 + o];
    if (fabsf(got - s) > 0.05f + 0.05f * fabsf(s)) fail = true;
  }
  if (fail) atomicExch(bad, 1.f);
}

// ---------------- K1 reset (only if checker failed) ----------------
__global__ __launch_bounds__(256) void k1r_reset(const float* __restrict__ bad, float* __restrict__ gsum)
{
  if (bad[0] < 0.5f) return;
  const int tid = threadIdx.x;
  if (tid < 129) gsum[tid] = 0.f;
}

// ---------------- K1 fallback (only if checker failed) ----------------
__global__ __launch_bounds__(256) void k1_fb(
    const float* __restrict__ x, const float* __restrict__ ln1_w, const float* __restrict__ ln1_b,
    const float* __restrict__ in_proj_w, const float* __restrict__ qkv_w,
    const float* __restrict__ pre_w, const float* __restrict__ pre_b,
    const float* __restrict__ g1w, const float* __restrict__ g1b,
    const float* __restrict__ g2w, const float* __restrict__ g2b,
    const float* __restrict__ bad,
    float* __restrict__ dout, unsigned short* __restrict__ qkvl, float* __restrict__ PREi,
    float* __restrict__ pooled, float* __restrict__ gsum)
{
  if (bad[0] < 0.5f) return;
  __shared__ float sPool[4][32];
  __shared__ float sRed[4];
  const int tid = threadIdx.x;
  const int p = blockIdx.x * 256 + tid;
  const int b = p >> 16;
  const int hw = p & (HW - 1);
  const int wave = tid >> 6, lane = tid & 63;
  const float* xb = x + (size_t)(b * 64) * HW + hw;
  float xv[64];
  float mu = 0.f;
#pragma unroll
  for (int c = 0; c < 64; ++c) { xv[c] = xb[(size_t)c * HW]; mu += xv[c]; }
  mu *= (1.f / 64.f);
  float var = 0.f;
#pragma unroll
  for (int c = 0; c < 64; ++c) { float d = xv[c] - mu; var += d * d; }
  var *= (1.f / 64.f);
  const float rs = rsqrtf(var + 1e-5f);
#pragma unroll
  for (int c = 0; c < 64; ++c) xv[c] = (xv[c] - mu) * rs * ln1_w[c] + ln1_b[c];
  float loc[32];
  for (int o = 0; o < 32; ++o) {
    float s = 0.f;
#pragma unroll
    for (int c = 0; c < 64; ++c) s += in_proj_w[o * 64 + c] * xv[c];
    loc[o] = s;
    dout[(size_t)(b * 64 + o) * HW + hw] = s;
    float r = wredsum(s);
    if (lane == 0) sPool[wave][o] = r;
  }
  for (int o = 0; o < 32; ++o) {
    float s = pre_b[o];
#pragma unroll
    for (int j = 0; j < 32; ++j) s += pre_w[o * 32 + j] * loc[j];
    PREi[((size_t)b * HW + hw) * 32 + o] = s;
  }
  float gl[32];
  for (int o = 0; o < 32; ++o) {
    float s = 0.f;
#pragma unroll
    for (int c = 0; c < 64; ++c) s += in_proj_w[(32 + o) * 64 + c] * xv[c];
    gl[o] = s;
  }
  for (int o = 0; o < 96; ++o) {
    float s = 0.f;
#pragma unroll
    for (int j = 0; j < 32; ++j) s += qkv_w[o * 32 + j] * gl[j];
    qkvl[(size_t)(b * 96 + o) * HW + hw] = f2bf(s);
  }
  float gacc = g2b[0];
  for (int o = 0; o < 16; ++o) {
    float h = g1b[o];
#pragma unroll
    for (int j = 0; j < 32; ++j) h += g1w[o * 32 + j] * gl[j];
    gacc += g2w[o] * fmaxf(h, 0.f);
  }
  float gv = wredsum(sigm(gacc));
  if (lane == 0) sRed[wave] = gv;
  __syncthreads();
  if (tid == 0) atomicAdd(gsum, sRed[0] + sRed[1] + sRed[2] + sRed[3]);
  if (tid < 32) {
    float s = sPool[0][tid] + sPool[1][tid] + sPool[2][tid] + sPool[3][tid];
    atomicAdd(&pooled[b * 32 + tid], s);
  }
}

// ---------------- K2 (MFMA): dwconv(q,k) + Gram via V·V^T — vectorized row loads ----------------
// Per lane: 3x short8v row loads + 6 scalar edges per iter (was 72 scalar loads).
__global__ __launch_bounds__(256) void k2_mfma(
    const unsigned short* __restrict__ qkvl, const float* __restrict__ qkv_dw, float* __restrict__ gram)
{
  __shared__ float sred[4][256];
  const int tid = threadIdx.x;
  const int slab = blockIdx.x;
  const int h = blockIdx.y, b = blockIdx.z;
  const int w = tid >> 6, lane = tid & 63;
  const int ch = lane & 15, grp = lane >> 4;
  const int gch = (ch < 8) ? (h * 8 + ch) : (32 + h * 8 + (ch - 8));
  const unsigned short* plane = qkvl + (size_t)(b * 96 + gch) * HW;
  const float* wt = qkv_dw + gch * 9;
  float w9[9];
#pragma unroll
  for (int t = 0; t < 9; ++t) w9[t] = wt[t];
  f32x4 acc = (f32x4){0.f, 0.f, 0.f, 0.f};
#pragma unroll
  for (int iter = 0; iter < 4; ++iter) {
    const int pxbase = slab * 512 + w * 128 + iter * 32 + grp * 8;
    const int y = pxbase >> 8;
    const int x0 = pxbase & 255;        // multiple of 8
    float row[3][10];
#pragma unroll
    for (int dy = 0; dy < 3; ++dy) {
      const int yy = y + dy - 1;
      if ((unsigned)yy >= 256u) {
#pragma unroll
        for (int j = 0; j < 10; ++j) row[dy][j] = 0.f;
        continue;
      }
      const unsigned short* rp = plane + yy * 256;
      union { short8v v; unsigned short s[8]; } cu;
      cu.v = *reinterpret_cast<const short8v*>(rp + x0);   // aligned 16B
#pragma unroll
      for (int j = 0; j < 8; ++j) row[dy][j + 1] = bf2f(cu.s[j]);
      row[dy][0] = (x0 > 0) ? bf2f(rp[x0 - 1]) : 0.f;
      row[dy][9] = (x0 < 248) ? bf2f(rp[x0 + 8]) : 0.f;
    }
    union { short8v v; unsigned short s[8]; } frag;
#pragma unroll
    for (int j = 0; j < 8; ++j) {
      float a = 0.f;
#pragma unroll
      for (int dy = 0; dy < 3; ++dy)
#pragma unroll
        for (int dx = 0; dx < 3; ++dx)
          a += row[dy][j + dx] * w9[dy * 3 + dx];
      frag.s[j] = f2bf(a);
    }
    acc = __builtin_amdgcn_mfma_f32_16x16x32_bf16(frag.v, frag.v, acc, 0, 0, 0);
  }
#pragma unroll
  for (int r = 0; r < 4; ++r) sred[w][(grp * 4 + r) * 16 + ch] = acc[r];
  __syncthreads();
  if (tid < 256) {
    float g = sred[0][tid] + sred[1][tid] + sred[2][tid] + sred[3][tid];
    const int row_ = tid >> 4, col_ = tid & 15;
    int idx = -1;
    if (row_ < 8 && col_ >= 8) idx = row_ * 8 + (col_ - 8);
    else if (row_ == col_ && row_ < 8) idx = 64 + row_;
    else if (row_ == col_) idx = 72 + (row_ - 8);
    if (idx >= 0) atomicAdd(&gram[(b * 4 + h) * 80 + idx], g);
  }
}

// ---------------- K3: dk, CBAM weights, attention matrices ----------------
__global__ __launch_bounds__(256) void k3_final(
    const float* __restrict__ m1w, const float* __restrict__ m1b,
    const float* __restrict__ m2w, const float* __restrict__ m2b,
    const float* __restrict__ temperature, const float* __restrict__ attn_scales,
    const float* __restrict__ pre_w, const float* __restrict__ pre_b,
    const float* __restrict__ gsum, const float* __restrict__ pooled,
    const float* __restrict__ gram, float* __restrict__ Abuf, float* __restrict__ cwbuf)
{
  __shared__ int s_dk;
  __shared__ float s_scale;
  const int tid = threadIdx.x;
  if (tid == 0) {
    float gmean = gsum[0] / (float)NPIX;
    int dk = (int)floorf(8.f * gmean);
    if (dk < 1) dk = 1;
    if (dk > 8) dk = 8;
    s_dk = dk;
    s_scale = attn_scales[0] + attn_scales[1] + attn_scales[2] + attn_scales[3];
  }
  __syncthreads();
  if (tid < 128) {
    int b = tid >> 5, ch = tid & 31, g = ch >> 2, c = ch & 3;
    float h1 = m1b[g];
#pragma unroll
    for (int cc = 0; cc < 4; ++cc) {
      int row = g * 4 + cc;
      float pp = pre_b[row];
#pragma unroll
      for (int j = 0; j < 32; ++j)
        pp += pre_w[row * 32 + j] * (pooled[b * 32 + j] * (1.f / 65536.f));
      h1 += pp * m1w[g * 4 + cc];
    }
    h1 = fmaxf(h1, 0.f);
    cwbuf[tid] = sigm(h1 * m2w[g * 4 + c] + m2b[g * 4 + c]);

    int r = tid, h = (r >> 3) & 3, c8 = r & 7;
    const float* gm = gram + (b * 4 + h) * 80;
    float qn = fmaxf(sqrtf(gm[64 + c8]), 1e-12f);
    float temp = temperature[h];
    float a[8];
#pragma unroll
    for (int d = 0; d < 8; ++d) {
      float kn = fmaxf(sqrtf(gm[72 + d]), 1e-12f);
      a[d] = gm[c8 * 8 + d] / (qn * kn) * temp;
    }
    float t[8];
#pragma unroll
    for (int d = 0; d < 8; ++d) t[d] = a[d];
#pragma unroll
    for (int i = 0; i < 8; ++i)
#pragma unroll
      for (int j = 0; j < 8; ++j)
        if (j > i && t[j] > t[i]) { float tmp = t[i]; t[i] = t[j]; t[j] = tmp; }
    float kth = t[s_dk - 1];
    float mx = t[0];
    float e[8]; float sum = 0.f;
#pragma unroll
    for (int d = 0; d < 8; ++d) {
      e[d] = (a[d] >= kth) ? expf(a[d] - mx) : 0.f;
      sum += e[d];
    }
    float inv = s_scale / sum;
#pragma unroll
    for (int d = 0; d < 8; ++d) Abuf[r * 8 + d] = e[d] * inv;
  }
}

// ---------------- K4a: resp partial sums (atomic-free) ----------------
__global__ __launch_bounds__(256) void k4a_thr(
    const float* __restrict__ spw, const float* __restrict__ spb,
    const float* __restrict__ cwbuf, const float* __restrict__ PREi, float* __restrict__ wpart)
{
  const int tid = threadIdx.x;
  const int pxb = blockIdx.x >> 1;
  const int gh = blockIdx.x & 1;
  const int px = pxb * 256 + tid;
  const int b = px >> 16, hw = px & (HW - 1);
  const int w = tid >> 6, lane = tid & 63;
  const float* cw = cwbuf + b * 32;
  const float4* pp = reinterpret_cast<const float4*>(PREi + ((size_t)b * HW + hw) * 32 + gh * 16);
  float4 pv[4];
#pragma unroll
  for (int k = 0; k < 4; ++k) pv[k] = pp[k];
  float racc[4];
#pragma unroll
  for (int g4 = 0; g4 < 4; ++g4) {
    const int g = gh * 4 + g4;
    float xa[4];
    float sdot = spb[g];
#pragma unroll
    for (int c = 0; c < 4; ++c) {
      float pr = (&pv[g4].x)[c];
      xa[c] = pr * cw[g * 4 + c];
      sdot += xa[c] * spw[g * 4 + c];
    }
    float sgv = sigm(sdot);
    float r = 0.f;
#pragma unroll
    for (int c = 0; c < 4; ++c) r += sigm(xa[c] * sgv);
    racc[g4] = r;
  }
#pragma unroll
  for (int g4 = 0; g4 < 4; ++g4) {
    float v = wredsum(racc[g4]);
    if (lane == 0) wpart[(blockIdx.x * 4 + w) * 4 + g4] = v;
  }
}

// ---------------- K4a_red: reduce wpart -> thrbuf ----------------
__global__ __launch_bounds__(256) void k4a_red(
    const float* __restrict__ wpart, float* __restrict__ thrbuf)
{
  __shared__ float sr[256];
  const int tid = threadIdx.x;
  const int b = blockIdx.x >> 3, g = blockIdx.x & 7;
  const int gh = g >> 2, gl = g & 3;
  float s = 0.f;
#pragma unroll
  for (int w = 0; w < 4; ++w)
    s += wpart[((((size_t)(b * 256 + tid) * 2 + gh) * 4) + w) * 4 + gl];
  sr[tid] = s;
  __syncthreads();
  for (int st = 128; st >= 1; st >>= 1) {
    if (tid < st) sr[tid] += sr[tid + st];
    __syncthreads();
  }
  if (tid == 0) thrbuf[b * 8 + g] = sr[0];
}

// ---------------- K4b (MFMA): LGCE finish + V-dwconv + attn -> A96, W96 MFMA + cb + x -> dout ----------------
__global__ __launch_bounds__(256) void k4b_fuse(
    const float* __restrict__ x, const float* __restrict__ spw, const float* __restrict__ spb,
    const float* __restrict__ qkv_dw, const unsigned short* __restrict__ qkvl,
    const float* __restrict__ PREi,
    const float* __restrict__ Abuf, const float* __restrict__ cwbuf, const float* __restrict__ thrbuf,
    const float* __restrict__ W96, const float* __restrict__ cb,
    float* dout)
{
  __shared__ unsigned short sA[64][104];
  __shared__ float sOut[64][65];
  const int tid = threadIdx.x;
  const int px_l = tid & 63, q = tid >> 6;
  const int p0 = blockIdx.x * 64;
  const int b = p0 >> 16;
  const int hw0 = p0 & (HW - 1);
  const int hw = hw0 + px_l;
  const int y = hw >> 8, xx = hw & 255;
  const float* cw = cwbuf + b * 32;
  const float* A = Abuf + b * 256;
  float loc8[8];
#pragma unroll
  for (int j = 0; j < 8; ++j)
    loc8[j] = dout[(size_t)(b * 64 + q * 8 + j) * HW + hw];
  float pre8[8];
  {
    const float4* pp = reinterpret_cast<const float4*>(PREi + ((size_t)b * HW + hw) * 32 + q * 8);
    float4 v0 = pp[0], v1 = pp[1];
    pre8[0] = v0.x; pre8[1] = v0.y; pre8[2] = v0.z; pre8[3] = v0.w;
    pre8[4] = v1.x; pre8[5] = v1.y; pre8[6] = v1.z; pre8[7] = v1.w;
  }
  float mx8[8];
#pragma unroll
  for (int g2 = 0; g2 < 2; ++g2) {
    const int g = 2 * q + g2;
    float xa[4];
    float sdot = spb[g];
#pragma unroll
    for (int c = 0; c < 4; ++c) {
      xa[c] = pre8[g2 * 4 + c] * cw[g * 4 + c];
      sdot += xa[c] * spw[g * 4 + c];
    }
    float sgv = sigm(sdot);
    float thr = thrbuf[b * 8 + g] * (1.f / (4.f * 65536.f));
#pragma unroll
    for (int c = 0; c < 4; ++c) {
      float resp = sigm(xa[c] * sgv);
      float m = (resp > thr) ? 1.f : resp;
      mx8[g2 * 4 + c] = pre8[g2 * 4 + c] * m;
    }
  }
  int offs[9]; bool okn[9];
#pragma unroll
  for (int dy = -1; dy <= 1; ++dy)
#pragma unroll
    for (int dx = -1; dx <= 1; ++dx) {
      int i = (dy + 1) * 3 + (dx + 1);
      int yy = y + dy, x2 = xx + dx;
      okn[i] = ((unsigned)yy < 256u) && ((unsigned)x2 < 256u);
      offs[i] = yy * 256 + x2;
    }
  float v8[8];
#pragma unroll
  for (int j = 0; j < 8; ++j) {
    const unsigned short* plane = qkvl + (size_t)(b * 96 + 64 + q * 8 + j) * HW;
    float acc = 0.f;
#pragma unroll
    for (int i = 0; i < 9; ++i)
      if (okn[i]) acc += bf2f(plane[offs[i]]) * qkv_dw[(64 + q * 8 + j) * 9 + i];
    v8[j] = acc;
  }
#pragma unroll
  for (int j = 0; j < 8; ++j) {
    float s = 0.f;
#pragma unroll
    for (int d = 0; d < 8; ++d) s += A[(q * 8 + j) * 8 + d] * v8[d];
    sA[px_l][q * 8 + j] = f2bf(s);
    sA[px_l][32 + q * 8 + j] = f2bf(mx8[j]);
    sA[px_l][64 + q * 8 + j] = f2bf(loc8[j]);
  }
  __syncthreads();
  const int w = q, lane = tid & 63;
  const int col = lane & 15, kgrp = lane >> 4;
  const int og = w * 16 + col;
  f32x4 acc[4];
#pragma unroll
  for (int s = 0; s < 4; ++s) acc[s] = (f32x4){0.f, 0.f, 0.f, 0.f};
#pragma unroll
  for (int kk = 0; kk < 3; ++kk) {
    const int c0 = kk * 32 + kgrp * 8;
    union { short8v v; unsigned short s[8]; } bw;
    const float* wp = W96 + og * 96 + c0;
#pragma unroll
    for (int j = 0; j < 8; ++j) bw.s[j] = f2bf(wp[j]);
#pragma unroll
    for (int s = 0; s < 4; ++s) {
      short8v av = *reinterpret_cast<const short8v*>(&sA[s * 16 + col][c0]);
      acc[s] = __builtin_amdgcn_mfma_f32_16x16x32_bf16(av, bw.v, acc[s], 0, 0, 0);
    }
  }
#pragma unroll
  for (int s = 0; s < 4; ++s) {
#pragma unroll
    for (int r = 0; r < 4; ++r) {
      int pxl = s * 16 + kgrp * 4 + r;
      sOut[og][pxl] = acc[s][r];
    }
  }
  __syncthreads();
  const float* xb = x + (size_t)(b * 64) * HW + hw0;
  float* db = dout + (size_t)(b * 64) * HW + hw0;
#pragma unroll
  for (int i = 0; i < 16; ++i) {
    int idx = tid + i * 256;
    int o = idx >> 6, px = idx & 63;
    db[(size_t)o * HW + px] = sOut[o][px] + cb[o] + xb[(size_t)o * HW + px];
  }
}

// ---------------- K5 (MFMA): LN2 + ffn_in (64->256), 128 outs/block ----------------
__global__ __launch_bounds__(256) void k5_mfma(
    const float* __restrict__ ln2_w, const float* __restrict__ ln2_b,
    const float* __restrict__ ffn_in_w, const float* __restrict__ dout,
    unsigned short* __restrict__ Tb, int b)
{
  __shared__ float sStage[64][65];
  __shared__ unsigned short sXnb[64][72];
  __shared__ unsigned short sOutB[128][72];
  __shared__ float sMu[64], sRs[64];
  const int tid = threadIdx.x;
  const int px0 = blockIdx.x * 64;
  const int o0base = blockIdx.y * 128;
  const float* db = dout + (size_t)(b * 64) * HW + px0;
#pragma unroll
  for (int i = 0; i < 16; ++i) {
    int idx = tid + i * 256;
    int c = idx >> 6, px = idx & 63;
    sStage[px][c] = db[(size_t)c * HW + px];
  }
  __syncthreads();
  if (tid < 64) {
    float mu = 0.f;
#pragma unroll
    for (int c = 0; c < 64; ++c) mu += sStage[tid][c];
    mu *= (1.f / 64.f);
    float var = 0.f;
#pragma unroll
    for (int c = 0; c < 64; ++c) { float d = sStage[tid][c] - mu; var += d * d; }
    var *= (1.f / 64.f);
    sMu[tid] = mu;
    sRs[tid] = rsqrtf(var + 1e-5f);
  }
  __syncthreads();
#pragma unroll
  for (int i = 0; i < 16; ++i) {
    int idx = tid + i * 256;
    int px = idx >> 6, c = idx & 63;
    float xn = (sStage[px][c] - sMu[px]) * sRs[px] * ln2_w[c] + ln2_b[c];
    sXnb[px][c] = f2bf(xn);
  }
  __syncthreads();
  const int w = tid >> 6, lane = tid & 63;
  const int col = lane & 15, kgrp = lane >> 4;
#pragma unroll
  for (int pass = 0; pass < 2; ++pass) {
    const int o_l = pass * 64 + w * 16 + col;
    const int og = o0base + o_l;
    f32x4 acc[4];
#pragma unroll
    for (int s = 0; s < 4; ++s) acc[s] = (f32x4){0.f, 0.f, 0.f, 0.f};
#pragma unroll
    for (int kk = 0; kk < 2; ++kk) {
      const int c0 = kk * 32 + kgrp * 8;
      union { short8v v; unsigned short s[8]; } bw;
      const float* wp = ffn_in_w + (size_t)og * 64 + c0;
#pragma unroll
      for (int j = 0; j < 8; ++j) bw.s[j] = f2bf(wp[j]);
#pragma unroll
      for (int s = 0; s < 4; ++s) {
        short8v av = *reinterpret_cast<const short8v*>(&sXnb[s * 16 + col][c0]);
        acc[s] = __builtin_amdgcn_mfma_f32_16x16x32_bf16(av, bw.v, acc[s], 0, 0, 0);
      }
    }
#pragma unroll
    for (int s = 0; s < 4; ++s) {
#pragma unroll
      for (int r = 0; r < 4; ++r) {
        int px_l = s * 16 + kgrp * 4 + r;
        sOutB[o_l][px_l] = f2bf(acc[s][r]);
      }
    }
  }
  __syncthreads();
  for (int i = tid; i < 1024; i += 256) {
    int o = i >> 3, seg = i & 7;
    *reinterpret_cast<short8v*>(Tb + (size_t)(o0base + o) * HW + px0 + seg * 8) =
        *reinterpret_cast<const short8v*>(&sOutB[o][seg * 8]);
  }
}

// ---------------- K6a: dwconv3/dwconv5 + gelu*mul -> Y (bf16) ----------------
__global__ __launch_bounds__(256) void k6a_dw(
    const float* __restrict__ dw3_w, const float* __restrict__ dw5_w,
    const unsigned short* __restrict__ T, __hip_bfloat16* __restrict__ Y)
{
  const int tid = threadIdx.x;
  const int px = blockIdx.x * 256 + tid;
  const int j0 = blockIdx.y * 8;
  const int row = px >> 8, col = px & 255;
  bool oky[5], okx[5];
#pragma unroll
  for (int d = 0; d < 5; ++d) {
    oky[d] = ((unsigned)(row + d - 2) < 256u);
    okx[d] = ((unsigned)(col + d - 2) < 256u);
  }
#pragma unroll
  for (int jj = 0; jj < 8; ++jj) {
    const int j = j0 + jj;
    const unsigned short* pl = T + (size_t)j * HW;
    float a = 0.f;
#pragma unroll
    for (int dy = -1; dy <= 1; ++dy) {
      if (!oky[dy + 2]) continue;
#pragma unroll
      for (int dx = -1; dx <= 1; ++dx) {
        if (!okx[dx + 2]) continue;
        a += bf2f(pl[px + dy * 256 + dx]) * dw3_w[j * 9 + (dy + 1) * 3 + (dx + 1)];
      }
    }
    float m = 0.f;
    const unsigned short* pm = T + (size_t)(128 + j) * HW;
    if (j < 64) {
#pragma unroll
      for (int dy = -1; dy <= 1; ++dy) {
        if (!oky[dy + 2]) continue;
#pragma unroll
        for (int dx = -1; dx <= 1; ++dx) {
          if (!okx[dx + 2]) continue;
          m += bf2f(pm[px + dy * 256 + dx]) * dw3_w[(128 + j) * 9 + (dy + 1) * 3 + (dx + 1)];
        }
      }
    } else {
#pragma unroll
      for (int dy = -2; dy <= 2; ++dy) {
        if (!oky[dy + 2]) continue;
#pragma unroll
        for (int dx = -2; dx <= 2; ++dx) {
          if (!okx[dx + 2]) continue;
          m += bf2f(pm[px + dy * 256 + dx]) * dw5_w[(j - 64) * 25 + (dy + 2) * 5 + (dx + 2)];
        }
      }
    }
    float gl = 0.5f * a * (1.f + erff(a * 0.70710678118654752f));
    Y[(size_t)j * HW + px] = __float2bfloat16(gl * m);
  }
}

// ---------------- K6b: ffn_out (128->64) from Y ----------------
__global__ __launch_bounds__(256) void k6b_out(
    const float* __restrict__ ffn_out_w, const __hip_bfloat16* __restrict__ Y,
    const float* __restrict__ flag, float* __restrict__ dout, float* __restrict__ Z, int b)
{
  __shared__ float sW[2048];
  const int tid = threadIdx.x;
  const int o0 = blockIdx.y * 16;
  for (int i = tid; i < 2048; i += 256) sW[i] = ffn_out_w[o0 * 128 + i];
  __syncthreads();
  const int px = blockIdx.x * 256 + tid;
  float z[16];
#pragma unroll
  for (int o = 0; o < 16; ++o) z[o] = 0.f;
  for (int j = 0; j < 128; ++j) {
    float yv = __bfloat162float(Y[(size_t)j * HW + px]);
#pragma unroll
    for (int o = 0; o < 16; ++o) z[o] += sW[o * 128 + j] * yv;
  }
  if (flag[0] > 0.5f) {
    float* ob = dout + (size_t)(b * 64 + o0) * HW + px;
#pragma unroll
    for (int o = 0; o < 16; ++o) ob[(size_t)o * HW] += z[o];
  } else {
    float* zb = Z + (size_t)o0 * HW + px;
#pragma unroll
    for (int o = 0; o < 16; ++o) zb[(size_t)o * HW] = z[o];
  }
}

// ---------------- K7: general fft path (early-exit if identity) ----------------
__global__ __launch_bounds__(256) void k7_fft(
    const float* __restrict__ fftw, const float* __restrict__ flag,
    const float* __restrict__ Z, float* __restrict__ dout, int b)
{
  if (flag[0] > 0.5f) return;
  __shared__ float swv[64];
  __shared__ float spatch[4][64];
  const int tid = threadIdx.x;
  const int c = blockIdx.x >> 8;
  const int pblk = blockIdx.x & 255;
  if (tid < 64) swv[tid] = fftw[c * 64 + tid];
  const int lp = tid >> 6, e = tid & 63;
  const int patch = pblk * 4 + lp;
  const int pi = patch >> 5, pj = patch & 31;
  const int i = e >> 3, jj = e & 7;
  const int gidx = (pi * 8 + i) * 256 + pj * 8 + jj;
  const float zv = Z[(size_t)c * HW + gidx];
  spatch[lp][e] = zv;
  __syncthreads();
  float s = 0.f;
#pragma unroll
  for (int a = 0; a < 8; ++a)
#pragma unroll
    for (int b2 = 0; b2 < 8; ++b2)
      s += swv[a * 8 + b2] * spatch[lp][((i - a) & 7) * 8 + ((jj - b2) & 7)];
  dout[(size_t)(b * 64 + c) * HW + gidx] += s;
}

extern "C" void kernel_launch(void* const* d_in, const int* in_sizes, int n_in,
                              void* d_out, int out_size, void* d_ws, size_t ws_size,
                              hipStream_t stream) {
  const float* x          = (const float*)d_in[0];
  const float* ln1_w      = (const float*)d_in[1];
  const float* ln1_b      = (const float*)d_in[2];
  const float* in_proj_w  = (const float*)d_in[3];
  const float* qkv_w      = (const float*)d_in[4];
  const float* qkv_dw     = (const float*)d_in[5];
  const float* out_proj_w = (const float*)d_in[6];
  const float* temperature= (const float*)d_in[7];
  const float* attn_scales= (const float*)d_in[8];
  const float* gate_w1    = (const float*)d_in[9];
  const float* gate_b1    = (const float*)d_in[10];
  const float* gate_w2    = (const float*)d_in[11];
  const float* gate_b2    = (const float*)d_in[12];
  const float* lgce_pre_w = (const float*)d_in[13];
  const float* lgce_pre_b = (const float*)d_in[14];
  const float* lgce_post_w= (const float*)d_in[15];
  const float* lgce_post_b= (const float*)d_in[16];
  const float* cbam_m1w   = (const float*)d_in[17];
  const float* cbam_m1b   = (const float*)d_in[18];
  const float* cbam_m2w   = (const float*)d_in[19];
  const float* cbam_m2b   = (const float*)d_in[20];
  const float* cbam_spw   = (const float*)d_in[21];
  const float* cbam_spb   = (const float*)d_in[22];
  const float* ln2_w      = (const float*)d_in[23];
  const float* ln2_b      = (const float*)d_in[24];
  const float* ffn_in_w   = (const float*)d_in[25];
  const float* dw3_w      = (const float*)d_in[26];
  const float* dw5_w      = (const float*)d_in[27];
  const float* ffn_out_w  = (const float*)d_in[28];
  const float* fft_W      = (const float*)d_in[29];
  float* ws = (float*)d_ws;
  float* out = (float*)d_out;
  unsigned short* qkvlp = (unsigned short*)(ws + OFF_QKVL);
  unsigned short* Tb = (unsigned short*)(ws + OFF_T);
  __hip_bfloat16* Ybuf = (__hip_bfloat16*)(ws + OFF_Y);

  hipLaunchKernelGGL(k0_setup, dim3(1), dim3(256), 0, stream,
                     fft_W, in_proj_w, qkv_w, gate_w1, lgce_pre_w,
                     out_proj_w, lgce_post_w, lgce_post_b, ws);
  hipLaunchKernelGGL(k1_mfma, dim3(4096), dim3(256), 0, stream,
                     x, ln1_w, ln1_b, in_proj_w, ws + OFF_MQKV, ws + OFF_MG1,
                     ws + OFF_MPRE, lgce_pre_b,
                     gate_b1, gate_w2, gate_b2,
                     out, qkvlp, ws + OFF_PRE, ws + OFF_POOL, ws + OFF_GSUM);
  hipLaunchKernelGGL(k1_check, dim3(1), dim3(256), 0, stream,
                     x, ln1_w, ln1_b, in_proj_w, qkv_w, lgce_pre_w, lgce_pre_b,
                     out, qkvlp, ws + OFF_PRE, ws + OFF_BAD);
  hipLaunchKernelGGL(k1r_reset, dim3(1), dim3(256), 0, stream,
                     ws + OFF_BAD, ws + OFF_GSUM);
  hipLaunchKernelGGL(k1_fb, dim3(1024), dim3(256), 0, stream,
                     x, ln1_w, ln1_b, in_proj_w, qkv_w, lgce_pre_w, lgce_pre_b,
                     gate_w1, gate_b1, gate_w2, gate_b2,
                     ws + OFF_BAD, out, qkvlp, ws + OFF_PRE, ws + OFF_POOL, ws + OFF_GSUM);
  hipLaunchKernelGGL(k2_mfma, dim3(128, 4, 4), dim3(256), 0, stream,
                     qkvlp, qkv_dw, ws + OFF_GRAM);
  hipLaunchKernelGGL(k3_final, dim3(1), dim3(256), 0, stream,
                     cbam_m1w, cbam_m1b, cbam_m2w, cbam_m2b, temperature, attn_scales,
                     lgce_pre_w, lgce_pre_b,
                     ws + OFF_GSUM, ws + OFF_POOL, ws + OFF_GRAM, ws + OFF_A, ws + OFF_CW);
  hipLaunchKernelGGL(k4a_thr, dim3(2048), dim3(256), 0, stream,
                     cbam_spw, cbam_spb, ws + OFF_CW, ws + OFF_PRE, ws + OFF_PART);
  hipLaunchKernelGGL(k4a_red, dim3(32), dim3(256), 0, stream,
                     ws + OFF_PART, ws + OFF_THR);
  hipLaunchKernelGGL(k4b_fuse, dim3(4096), dim3(256), 0, stream,
                     x, cbam_spw, cbam_spb, qkv_dw, qkvlp, ws + OFF_PRE,
                     ws + OFF_A, ws + OFF_CW, ws + OFF_THR,
                     ws + OFF_W96, ws + OFF_CB, out);

  for (int b = 0; b < 4; ++b) {
    hipLaunchKernelGGL(k5_mfma, dim3(1024, 2), dim3(256), 0, stream,
                       ln2_w, ln2_b, ffn_in_w, out, Tb, b);
    hipLaunchKernelGGL(k6a_dw, dim3(256, 16), dim3(256), 0, stream,
                       dw3_w, dw5_w, Tb, Ybuf);
    hipLaunchKernelGGL(k6b_out, dim3(256, 4), dim3(256), 0, stream,
                       ffn_out_w, Ybuf, ws + OFF_FLAG, out, ws + OFF_Z, b);
    hipLaunchKernelGGL(k7_fft, dim3(16384), dim3(256), 0, stream,
                       ws + OFF_FFTW, ws + OFF_FLAG, ws + OFF_Z, out, b);
  }
}

// Round 10
// 1180.826 us; speedup vs baseline: 5.4154x; 1.0032x over previous
//
#include <hip/hip_runtime.h>
#include <hip/hip_bf16.h>
#include <math.h>

#define HW 65536
#define NPIX 262144

// ---- workspace layout (float offsets) ----
#define OFF_FFTW 0            // 64x64 spatial fft kernel
#define OFF_FLAG 4096         // 1
#define OFF_GSUM 4097         // 1    (zeroed in k0)
#define OFF_POOL 4098         // 128  (zeroed in k0)  -- pooled(loc) sums
#define OFF_GRAM 4226         // 1280 (zeroed in k0)
#define OFF_THR  5506         // 32   (written by k4a_red)
#define OFF_BAD  5538         // 1    (zeroed in k0)  -- k1 checker flag
#define OFF_A    5539         // 1024
#define OFF_CW   6563         // 128
#define OFF_QKVL 8192         // 96ch * 262144 px bf16 = 12582912 float-slots (SGSA phase)
#define OFF_MQKV 12591104     // 96*64 fp32 composed qkv matrix
#define OFF_MG1  (OFF_MQKV + 6144)     // 16*64 fp32  (ends 12598272)
#define OFF_MPRE 12598272     // 32*64 fp32 composed pre matrix (ends 12600320)
#define OFF_PREB 12600320     // [4][65536][32] bf16 px-major = 4194304 slots (ends 16794624)
#define OFF_LOCB 16794624     // [4][65536][32] bf16 px-major = 4194304 slots (ends 20988928)
#define OFF_PART 20988928     // 2048 blk * 4 waves * 4 g = 32768 (ends 21021696)
#define OFF_W96  21021696     // 64*96 fp32 composed out_proj|post matrix (SGSA phase only)
#define OFF_CB   (OFF_W96 + 6144)      // 64 fp32 (ends 21027904 < 25174016)
// MFFN phase (per-batch, overlaps QKVL/PREB/LOCB/W96 which are dead by then):
#define OFF_T    8192                      // 256ch * 65536 bf16
#define OFF_Y    (OFF_T + 16777216)        // 128ch * 65536 bf16
#define OFF_Z    (OFF_Y + 4194304)         // 64ch * 65536 fp32
// peak ws usage = 25174016 floats = 100.7 MB (unchanged proven footprint)

typedef __attribute__((ext_vector_type(8))) short short8v;
typedef __attribute__((ext_vector_type(4))) float f32x4;

__device__ __forceinline__ float sigm(float v) { return 1.f / (1.f + expf(-v)); }
__device__ __forceinline__ float wredsum(float v) {
#pragma unroll
  for (int off = 32; off >= 1; off >>= 1) v += __shfl_xor(v, off);
  return v;
}
__device__ __forceinline__ unsigned short f2bf(float f) {
  union { float f; unsigned u; } x; x.f = f;
  unsigned r = x.u + 0x7fffu + ((x.u >> 16) & 1u);
  return (unsigned short)(r >> 16);
}
__device__ __forceinline__ float bf2f(unsigned short u) {
  union { unsigned u; float f; } x; x.u = ((unsigned)u) << 16;
  return x.f;
}

// ---------------- K0: zero accumulators + fft kernel + composed matrices ----------------
__global__ __launch_bounds__(256) void k0_setup(
    const float* __restrict__ fft_W, const float* __restrict__ in_proj_w,
    const float* __restrict__ qkv_w, const float* __restrict__ g1w,
    const float* __restrict__ pre_w, const float* __restrict__ out_proj_w,
    const float* __restrict__ post_w, const float* __restrict__ post_b,
    float* __restrict__ ws)
{
  __shared__ float ct8[8];
  __shared__ int sbad;
  const int tid = threadIdx.x;
  if (tid < 8) ct8[tid] = cosf((float)tid * 0.78539816339744831f); // cos(k*pi/4)
  if (tid == 0) sbad = 0;
  for (int i = tid; i < 1442; i += 256) ws[OFF_GSUM + i] = 0.f;    // gsum,pool,gram,thr,bad
  for (int i = tid; i < 96 * 64; i += 256) {
    int o = i >> 6, c = i & 63;
    float s = 0.f;
    for (int j = 0; j < 32; ++j) s += qkv_w[o * 32 + j] * in_proj_w[(32 + j) * 64 + c];
    ws[OFF_MQKV + i] = s;
  }
  for (int i = tid; i < 16 * 64; i += 256) {
    int o = i >> 6, c = i & 63;
    float s = 0.f;
    for (int j = 0; j < 32; ++j) s += g1w[o * 32 + j] * in_proj_w[(32 + j) * 64 + c];
    ws[OFF_MG1 + i] = s;
  }
  for (int i = tid; i < 32 * 64; i += 256) {
    int o = i >> 6, c = i & 63;
    float s = 0.f;
    for (int j = 0; j < 32; ++j) s += pre_w[o * 32 + j] * in_proj_w[j * 64 + c];
    ws[OFF_MPRE + i] = s;
  }
  for (int i = tid; i < 64 * 96; i += 256) {
    int o = i / 96, c = i - o * 96;
    float s;
    if (c < 32) s = out_proj_w[o * 64 + c];
    else if (c < 64) {
      s = 0.f;
      for (int k = 0; k < 32; ++k) s += out_proj_w[o * 64 + 32 + k] * post_w[k * 32 + (c - 32)];
    } else s = out_proj_w[o * 64 + (c - 32)];
    ws[OFF_W96 + i] = s;
  }
  for (int i = tid; i < 64; i += 256) {
    float s = 0.f;
    for (int k = 0; k < 32; ++k) s += out_proj_w[i * 64 + 32 + k] * post_b[k];
    ws[OFF_CB + i] = s;
  }
  __syncthreads();
  bool ok = true;
  for (int i = tid; i < 64 * 64; i += 256) {
    int ch = i >> 6, ab = i & 63;
    int a = ab >> 3, b2 = ab & 7;
    float s = 0.f;
    for (int u = 0; u < 8; ++u)
      for (int v = 0; v < 8; ++v) {
        float Wf;
        if (v == 0 || v == 4)
          Wf = 0.5f * (fft_W[ch * 40 + u * 5 + v] + fft_W[ch * 40 + ((8 - u) & 7) * 5 + v]);
        else if (v < 5)
          Wf = fft_W[ch * 40 + u * 5 + v];
        else
          Wf = fft_W[ch * 40 + ((8 - u) & 7) * 5 + (8 - v)];
        s += Wf * ct8[(u * a + v * b2) & 7];
      }
    s *= (1.f / 64.f);
    ws[OFF_FFTW + i] = s;
    float expect = ((i & 63) == 0) ? 1.f : 0.f;
    if (fabsf(s - expect) > 1e-4f) ok = false;
  }
  if (!ok) atomicOr(&sbad, 1);
  __syncthreads();
  if (tid == 0) ws[OFF_FLAG] = sbad ? 0.f : 1.f;
}

// ---------------- K1 (MFMA, register-LN): LN1 + [loc|qkv|pre] + gate + pooled ----------------
// 1024 blocks x 256 px. Phase A: per-thread LN in registers -> sXnb bf16.
// Phase B: 10 o-tiles x 4 px-subtiles MFMA with wave-private staging (no barriers).
__global__ __launch_bounds__(256) void k1_mfma(
    const float* __restrict__ x, const float* __restrict__ ln1_w, const float* __restrict__ ln1_b,
    const float* __restrict__ in_proj_w, const float* __restrict__ mqkv, const float* __restrict__ mg1,
    const float* __restrict__ mpre, const float* __restrict__ pre_b,
    const float* __restrict__ g1b, const float* __restrict__ g2w, const float* __restrict__ g2b,
    unsigned short* __restrict__ qkvl, unsigned short* __restrict__ LOCB,
    unsigned short* __restrict__ PREB, float* __restrict__ pooled, float* __restrict__ gsum)
{
  __shared__ unsigned short sXnb[256][72];   // LN'd bf16 activations [px][64ch]
  __shared__ unsigned short sStg[4][16][72]; // per-wave fragment staging [o_l][px_l]
  __shared__ float sPoolL[32];
  __shared__ float sRed[4];
  const int tid = threadIdx.x;
  const int p0 = blockIdx.x * 256;
  const int b = p0 >> 16;
  const int hw0 = p0 & (HW - 1);
  if (tid < 32) sPoolL[tid] = 0.f;
  // ---- Phase A: register LN, one px per thread ----
  {
    const float* xb = x + (size_t)(b * 64) * HW + hw0;
    float xv[64];
    float mu = 0.f;
#pragma unroll
    for (int c = 0; c < 64; ++c) { xv[c] = xb[(size_t)c * HW + tid]; mu += xv[c]; }
    mu *= (1.f / 64.f);
    float var = 0.f;
#pragma unroll
    for (int c = 0; c < 64; ++c) { float d = xv[c] - mu; var += d * d; }
    var *= (1.f / 64.f);
    const float rs = rsqrtf(var + 1e-5f);
#pragma unroll
    for (int ch = 0; ch < 8; ++ch) {
      union { short8v v; unsigned short s[8]; } u;
#pragma unroll
      for (int j = 0; j < 8; ++j) {
        int c = ch * 8 + j;
        u.s[j] = f2bf((xv[c] - mu) * rs * ln1_w[c] + ln1_b[c]);
      }
      *reinterpret_cast<short8v*>(&sXnb[tid][ch * 8]) = u.v;
    }
  }
  __syncthreads();
  // ---- Phase B: MFMA tiles ----
  const int w = tid >> 6, lane = tid & 63;
  const int col = lane & 15, kgrp = lane >> 4;
#pragma unroll
  for (int pass = 0; pass < 3; ++pass) {
    const int tile = pass * 4 + w;
    if (tile >= 10) continue;                 // wave-uniform branch
    const int og = tile * 16 + col;           // 0..159
    const float* wrow = (og < 32) ? (in_proj_w + og * 64)
                      : (og < 128) ? (mqkv + (og - 32) * 64)
                                   : (mpre + (og - 128) * 64);
    union { short8v v; unsigned short s[8]; } bw[2];
#pragma unroll
    for (int kk = 0; kk < 2; ++kk) {
      const int c0 = kk * 32 + kgrp * 8;
#pragma unroll
      for (int j = 0; j < 8; ++j) bw[kk].s[j] = f2bf(wrow[c0 + j]);
    }
    const float bias = (og >= 128) ? pre_b[og - 128] : 0.f;
    float poolAcc = 0.f;
#pragma unroll
    for (int pxsub = 0; pxsub < 4; ++pxsub) {
      f32x4 acc[4];
#pragma unroll
      for (int s = 0; s < 4; ++s) acc[s] = (f32x4){0.f, 0.f, 0.f, 0.f};
#pragma unroll
      for (int kk = 0; kk < 2; ++kk) {
        const int c0 = kk * 32 + kgrp * 8;
#pragma unroll
        for (int s = 0; s < 4; ++s) {
          short8v av = *reinterpret_cast<const short8v*>(&sXnb[pxsub * 64 + s * 16 + col][c0]);
          acc[s] = __builtin_amdgcn_mfma_f32_16x16x32_bf16(av, bw[kk].v, acc[s], 0, 0, 0);
        }
      }
      // write fragments to wave-private staging [o_l=col][px_l]
#pragma unroll
      for (int s = 0; s < 4; ++s) {
#pragma unroll
        for (int r = 0; r < 4; ++r) {
          float v = acc[s][r] + bias;
          sStg[w][col][s * 16 + kgrp * 4 + r] = f2bf(v);
          if (og < 32) poolAcc += v;
        }
      }
      // store (wave-private; DS ops in-order within a wave -> no barrier)
      if (og >= 32 && og < 128) {
        // qkv: channel-major planes
        const int row = lane >> 2, seg = lane & 3;
        const unsigned short* src = &sStg[w][row][seg * 16];
        unsigned short* dst = qkvl + (size_t)(b * 96 + (tile - 2) * 16 + row) * HW
                              + hw0 + pxsub * 64 + seg * 16;
        *reinterpret_cast<short8v*>(dst) = *reinterpret_cast<const short8v*>(src);
        *reinterpret_cast<short8v*>(dst + 8) = *reinterpret_cast<const short8v*>(src + 8);
      } else {
        // loc / pre: px-major [px][32] bf16, transposed via staging
        const int pxl = lane;
        union { short8v v; unsigned short s[8]; } u0, u1;
#pragma unroll
        for (int o = 0; o < 8; ++o) { u0.s[o] = sStg[w][o][pxl]; u1.s[o] = sStg[w][8 + o][pxl]; }
        unsigned short* base = (og < 32) ? LOCB : PREB;
        const int choff = (og < 32) ? (tile * 16) : ((tile - 8) * 16);
        unsigned short* dst = base + ((size_t)b * HW + hw0 + pxsub * 64 + pxl) * 32 + choff;
        *reinterpret_cast<short8v*>(dst) = u0.v;
        *reinterpret_cast<short8v*>(dst + 8) = u1.v;
      }
    }
    if (og < 32) {
      poolAcc += __shfl_xor(poolAcc, 16);
      poolAcc += __shfl_xor(poolAcc, 32);
      if (kgrp == 0) sPoolL[og] = poolAcc;
    }
  }
  // ---- gate (verified scalar path, pxsub-looped) ----
  {
    const int gq = tid & 3;
    float gvtot = 0.f;
#pragma unroll
    for (int pxsub = 0; pxsub < 4; ++pxsub) {
      const int gpx = pxsub * 64 + (tid >> 2);
      float h[4];
#pragma unroll
      for (int i = 0; i < 4; ++i) h[i] = g1b[gq * 4 + i];
#pragma unroll
      for (int cc = 0; cc < 64; cc += 8) {
        union { short8v v; unsigned short s[8]; } xu;
        xu.v = *reinterpret_cast<const short8v*>(&sXnb[gpx][cc]);
#pragma unroll
        for (int j = 0; j < 8; ++j) {
          float xf = bf2f(xu.s[j]);
#pragma unroll
          for (int i = 0; i < 4; ++i) h[i] += mg1[(gq * 4 + i) * 64 + cc + j] * xf;
        }
      }
      float gpart = 0.f;
#pragma unroll
      for (int i = 0; i < 4; ++i) gpart += g2w[gq * 4 + i] * fmaxf(h[i], 0.f);
      gpart += __shfl_xor(gpart, 1);
      gpart += __shfl_xor(gpart, 2);
      if (gq == 0) gvtot += sigm(gpart + g2b[0]);
    }
    float gv = wredsum(gvtot);
    if (lane == 0) sRed[w] = gv;
  }
  __syncthreads();
  if (tid == 0) atomicAdd(gsum, sRed[0] + sRed[1] + sRed[2] + sRed[3]);
  if (tid < 32) atomicAdd(&pooled[b * 32 + tid], sPoolL[tid]);
}

// ---------------- K1 checker: 256 sampled px vs independent fp32 reference ----------------
__global__ __launch_bounds__(256) void k1_check(
    const float* __restrict__ x, const float* __restrict__ ln1_w, const float* __restrict__ ln1_b,
    const float* __restrict__ in_proj_w, const float* __restrict__ qkv_w,
    const float* __restrict__ pre_w, const float* __restrict__ pre_b,
    const unsigned short* __restrict__ LOCB, const unsigned short* __restrict__ qkvl,
    const unsigned short* __restrict__ PREB, float* __restrict__ bad)
{
  const int t = threadIdx.x;
  const int b = t & 3;
  const int px = (t * 1031) & (HW - 1);
  const float* xb = x + (size_t)(b * 64) * HW + px;
  float xv[64];
  float mu = 0.f;
#pragma unroll
  for (int c = 0; c < 64; ++c) { xv[c] = xb[(size_t)c * HW]; mu += xv[c]; }
  mu *= (1.f / 64.f);
  float var = 0.f;
#pragma unroll
  for (int c = 0; c < 64; ++c) { float d = xv[c] - mu; var += d * d; }
  var *= (1.f / 64.f);
  float rs = rsqrtf(var + 1e-5f);
#pragma unroll
  for (int c = 0; c < 64; ++c) xv[c] = (xv[c] - mu) * rs * ln1_w[c] + ln1_b[c];
  bool fail = false;
  float lc[32], gl[32];
  for (int o = 0; o < 32; ++o) {
    float s = 0.f;
#pragma unroll
    for (int c = 0; c < 64; ++c) s += in_proj_w[o * 64 + c] * xv[c];
    lc[o] = s;
    float got = bf2f(LOCB[((size_t)b * HW + px) * 32 + o]);
    if (fabsf(got - s) > 0.05f + 0.05f * fabsf(s)) fail = true;
    float s2 = 0.f;
#pragma unroll
    for (int c = 0; c < 64; ++c) s2 += in_proj_w[(32 + o) * 64 + c] * xv[c];
    gl[o] = s2;
  }
  for (int o = 0; o < 96; ++o) {
    float s = 0.f;
#pragma unroll
    for (int j = 0; j < 32; ++j) s += qkv_w[o * 32 + j] * gl[j];
    float got = bf2f(qkvl[(size_t)(b * 96 + o) * HW + px]);
    if (fabsf(got - s) > 0.05f + 0.05f * fabsf(s)) fail = true;
  }
  for (int o = 0; o < 32; ++o) {
    float s = pre_b[o];
#pragma unroll
    for (int j = 0; j < 32; ++j) s += pre_w[o * 32 + j] * lc[j];
    float got = bf2f(PREB[((size_t)b * HW + px) * 32 + o]);
    if (fabsf(got - s) > 0.05f + 0.05f * fabsf(s)) fail = true;
  }
  if (fail) atomicExch(bad, 1.f);
}

// ---------------- K1 reset (only if checker failed) ----------------
__global__ __launch_bounds__(256) void k1r_reset(const float* __restrict__ bad, float* __restrict__ gsum)
{
  if (bad[0] < 0.5f) return;
  const int tid = threadIdx.x;
  if (tid < 129) gsum[tid] = 0.f;
}

// ---------------- K1 fallback (only if checker failed) ----------------
__global__ __launch_bounds__(256) void k1_fb(
    const float* __restrict__ x, const float* __restrict__ ln1_w, const float* __restrict__ ln1_b,
    const float* __restrict__ in_proj_w, const float* __restrict__ qkv_w,
    const float* __restrict__ pre_w, const float* __restrict__ pre_b,
    const float* __restrict__ g1w, const float* __restrict__ g1b,
    const float* __restrict__ g2w, const float* __restrict__ g2b,
    const float* __restrict__ bad,
    unsigned short* __restrict__ qkvl, unsigned short* __restrict__ LOCB,
    unsigned short* __restrict__ PREB, float* __restrict__ pooled, float* __restrict__ gsum)
{
  if (bad[0] < 0.5f) return;
  __shared__ float sPool[4][32];
  __shared__ float sRed[4];
  const int tid = threadIdx.x;
  const int p = blockIdx.x * 256 + tid;
  const int b = p >> 16;
  const int hw = p & (HW - 1);
  const int wave = tid >> 6, lane = tid & 63;
  const float* xb = x + (size_t)(b * 64) * HW + hw;
  float xv[64];
  float mu = 0.f;
#pragma unroll
  for (int c = 0; c < 64; ++c) { xv[c] = xb[(size_t)c * HW]; mu += xv[c]; }
  mu *= (1.f / 64.f);
  float var = 0.f;
#pragma unroll
  for (int c = 0; c < 64; ++c) { float d = xv[c] - mu; var += d * d; }
  var *= (1.f / 64.f);
  const float rs = rsqrtf(var + 1e-5f);
#pragma unroll
  for (int c = 0; c < 64; ++c) xv[c] = (xv[c] - mu) * rs * ln1_w[c] + ln1_b[c];
  float loc[32];
  for (int o = 0; o < 32; ++o) {
    float s = 0.f;
#pragma unroll
    for (int c = 0; c < 64; ++c) s += in_proj_w[o * 64 + c] * xv[c];
    loc[o] = s;
    LOCB[((size_t)b * HW + hw) * 32 + o] = f2bf(s);
    float r = wredsum(s);
    if (lane == 0) sPool[wave][o] = r;
  }
  for (int o = 0; o < 32; ++o) {
    float s = pre_b[o];
#pragma unroll
    for (int j = 0; j < 32; ++j) s += pre_w[o * 32 + j] * loc[j];
    PREB[((size_t)b * HW + hw) * 32 + o] = f2bf(s);
  }
  float gl[32];
  for (int o = 0; o < 32; ++o) {
    float s = 0.f;
#pragma unroll
    for (int c = 0; c < 64; ++c) s += in_proj_w[(32 + o) * 64 + c] * xv[c];
    gl[o] = s;
  }
  for (int o = 0; o < 96; ++o) {
    float s = 0.f;
#pragma unroll
    for (int j = 0; j < 32; ++j) s += qkv_w[o * 32 + j] * gl[j];
    qkvl[(size_t)(b * 96 + o) * HW + hw] = f2bf(s);
  }
  float gacc = g2b[0];
  for (int o = 0; o < 16; ++o) {
    float h = g1b[o];
#pragma unroll
    for (int j = 0; j < 32; ++j) h += g1w[o * 32 + j] * gl[j];
    gacc += g2w[o] * fmaxf(h, 0.f);
  }
  float gv = wredsum(sigm(gacc));
  if (lane == 0) sRed[wave] = gv;
  __syncthreads();
  if (tid == 0) atomicAdd(gsum, sRed[0] + sRed[1] + sRed[2] + sRed[3]);
  if (tid < 32) {
    float s = sPool[0][tid] + sPool[1][tid] + sPool[2][tid] + sPool[3][tid];
    atomicAdd(&pooled[b * 32 + tid], s);
  }
}

// ---------------- K2 (MFMA): dwconv(q,k) + Gram via V·V^T — vectorized row loads ----------------
__global__ __launch_bounds__(256) void k2_mfma(
    const unsigned short* __restrict__ qkvl, const float* __restrict__ qkv_dw, float* __restrict__ gram)
{
  __shared__ float sred[4][256];
  const int tid = threadIdx.x;
  const int slab = blockIdx.x;
  const int h = blockIdx.y, b = blockIdx.z;
  const int w = tid >> 6, lane = tid & 63;
  const int ch = lane & 15, grp = lane >> 4;
  const int gch = (ch < 8) ? (h * 8 + ch) : (32 + h * 8 + (ch - 8));
  const unsigned short* plane = qkvl + (size_t)(b * 96 + gch) * HW;
  const float* wt = qkv_dw + gch * 9;
  float w9[9];
#pragma unroll
  for (int t = 0; t < 9; ++t) w9[t] = wt[t];
  f32x4 acc = (f32x4){0.f, 0.f, 0.f, 0.f};
#pragma unroll
  for (int iter = 0; iter < 4; ++iter) {
    const int pxbase = slab * 512 + w * 128 + iter * 32 + grp * 8;
    const int y = pxbase >> 8;
    const int x0 = pxbase & 255;
    float row[3][10];
#pragma unroll
    for (int dy = 0; dy < 3; ++dy) {
      const int yy = y + dy - 1;
      if ((unsigned)yy >= 256u) {
#pragma unroll
        for (int j = 0; j < 10; ++j) row[dy][j] = 0.f;
        continue;
      }
      const unsigned short* rp = plane + yy * 256;
      union { short8v v; unsigned short s[8]; } cu;
      cu.v = *reinterpret_cast<const short8v*>(rp + x0);
#pragma unroll
      for (int j = 0; j < 8; ++j) row[dy][j + 1] = bf2f(cu.s[j]);
      row[dy][0] = (x0 > 0) ? bf2f(rp[x0 - 1]) : 0.f;
      row[dy][9] = (x0 < 248) ? bf2f(rp[x0 + 8]) : 0.f;
    }
    union { short8v v; unsigned short s[8]; } frag;
#pragma unroll
    for (int j = 0; j < 8; ++j) {
      float a = 0.f;
#pragma unroll
      for (int dy = 0; dy < 3; ++dy)
#pragma unroll
        for (int dx = 0; dx < 3; ++dx)
          a += row[dy][j + dx] * w9[dy * 3 + dx];
      frag.s[j] = f2bf(a);
    }
    acc = __builtin_amdgcn_mfma_f32_16x16x32_bf16(frag.v, frag.v, acc, 0, 0, 0);
  }
#pragma unroll
  for (int r = 0; r < 4; ++r) sred[w][(grp * 4 + r) * 16 + ch] = acc[r];
  __syncthreads();
  if (tid < 256) {
    float g = sred[0][tid] + sred[1][tid] + sred[2][tid] + sred[3][tid];
    const int row_ = tid >> 4, col_ = tid & 15;
    int idx = -1;
    if (row_ < 8 && col_ >= 8) idx = row_ * 8 + (col_ - 8);
    else if (row_ == col_ && row_ < 8) idx = 64 + row_;
    else if (row_ == col_) idx = 72 + (row_ - 8);
    if (idx >= 0) atomicAdd(&gram[(b * 4 + h) * 80 + idx], g);
  }
}

// ---------------- K3: dk, CBAM weights, attention matrices ----------------
__global__ __launch_bounds__(256) void k3_final(
    const float* __restrict__ m1w, const float* __restrict__ m1b,
    const float* __restrict__ m2w, const float* __restrict__ m2b,
    const float* __restrict__ temperature, const float* __restrict__ attn_scales,
    const float* __restrict__ pre_w, const float* __restrict__ pre_b,
    const float* __restrict__ gsum, const float* __restrict__ pooled,
    const float* __restrict__ gram, float* __restrict__ Abuf, float* __restrict__ cwbuf)
{
  __shared__ int s_dk;
  __shared__ float s_scale;
  const int tid = threadIdx.x;
  if (tid == 0) {
    float gmean = gsum[0] / (float)NPIX;
    int dk = (int)floorf(8.f * gmean);
    if (dk < 1) dk = 1;
    if (dk > 8) dk = 8;
    s_dk = dk;
    s_scale = attn_scales[0] + attn_scales[1] + attn_scales[2] + attn_scales[3];
  }
  __syncthreads();
  if (tid < 128) {
    int b = tid >> 5, ch = tid & 31, g = ch >> 2, c = ch & 3;
    float h1 = m1b[g];
#pragma unroll
    for (int cc = 0; cc < 4; ++cc) {
      int row = g * 4 + cc;
      float pp = pre_b[row];
#pragma unroll
      for (int j = 0; j < 32; ++j)
        pp += pre_w[row * 32 + j] * (pooled[b * 32 + j] * (1.f / 65536.f));
      h1 += pp * m1w[g * 4 + cc];
    }
    h1 = fmaxf(h1, 0.f);
    cwbuf[tid] = sigm(h1 * m2w[g * 4 + c] + m2b[g * 4 + c]);

    int r = tid, h = (r >> 3) & 3, c8 = r & 7;
    const float* gm = gram + (b * 4 + h) * 80;
    float qn = fmaxf(sqrtf(gm[64 + c8]), 1e-12f);
    float temp = temperature[h];
    float a[8];
#pragma unroll
    for (int d = 0; d < 8; ++d) {
      float kn = fmaxf(sqrtf(gm[72 + d]), 1e-12f);
      a[d] = gm[c8 * 8 + d] / (qn * kn) * temp;
    }
    float t[8];
#pragma unroll
    for (int d = 0; d < 8; ++d) t[d] = a[d];
#pragma unroll
    for (int i = 0; i < 8; ++i)
#pragma unroll
      for (int j = 0; j < 8; ++j)
        if (j > i && t[j] > t[i]) { float tmp = t[i]; t[i] = t[j]; t[j] = tmp; }
    float kth = t[s_dk - 1];
    float mx = t[0];
    float e[8]; float sum = 0.f;
#pragma unroll
    for (int d = 0; d < 8; ++d) {
      e[d] = (a[d] >= kth) ? expf(a[d] - mx) : 0.f;
      sum += e[d];
    }
    float inv = s_scale / sum;
#pragma unroll
    for (int d = 0; d < 8; ++d) Abuf[r * 8 + d] = e[d] * inv;
  }
}

// ---------------- K4a: resp partial sums (atomic-free), PREB bf16 ----------------
__global__ __launch_bounds__(256) void k4a_thr(
    const float* __restrict__ spw, const float* __restrict__ spb,
    const float* __restrict__ cwbuf, const unsigned short* __restrict__ PREB,
    float* __restrict__ wpart)
{
  const int tid = threadIdx.x;
  const int pxb = blockIdx.x >> 1;
  const int gh = blockIdx.x & 1;
  const int px = pxb * 256 + tid;
  const int b = px >> 16, hw = px & (HW - 1);
  const int w = tid >> 6, lane = tid & 63;
  const float* cw = cwbuf + b * 32;
  const unsigned short* pp = PREB + ((size_t)b * HW + hw) * 32 + gh * 16;
  union { short8v v; unsigned short s[8]; } u0, u1;
  u0.v = *reinterpret_cast<const short8v*>(pp);
  u1.v = *reinterpret_cast<const short8v*>(pp + 8);
  float pv[16];
#pragma unroll
  for (int k = 0; k < 8; ++k) { pv[k] = bf2f(u0.s[k]); pv[8 + k] = bf2f(u1.s[k]); }
  float racc[4];
#pragma unroll
  for (int g4 = 0; g4 < 4; ++g4) {
    const int g = gh * 4 + g4;
    float xa[4];
    float sdot = spb[g];
#pragma unroll
    for (int c = 0; c < 4; ++c) {
      xa[c] = pv[g4 * 4 + c] * cw[g * 4 + c];
      sdot += xa[c] * spw[g * 4 + c];
    }
    float sgv = sigm(sdot);
    float r = 0.f;
#pragma unroll
    for (int c = 0; c < 4; ++c) r += sigm(xa[c] * sgv);
    racc[g4] = r;
  }
#pragma unroll
  for (int g4 = 0; g4 < 4; ++g4) {
    float v = wredsum(racc[g4]);
    if (lane == 0) wpart[(blockIdx.x * 4 + w) * 4 + g4] = v;
  }
}

// ---------------- K4a_red: reduce wpart -> thrbuf ----------------
__global__ __launch_bounds__(256) void k4a_red(
    const float* __restrict__ wpart, float* __restrict__ thrbuf)
{
  __shared__ float sr[256];
  const int tid = threadIdx.x;
  const int b = blockIdx.x >> 3, g = blockIdx.x & 7;
  const int gh = g >> 2, gl = g & 3;
  float s = 0.f;
#pragma unroll
  for (int w = 0; w < 4; ++w)
    s += wpart[((((size_t)(b * 256 + tid) * 2 + gh) * 4) + w) * 4 + gl];
  sr[tid] = s;
  __syncthreads();
  for (int st = 128; st >= 1; st >>= 1) {
    if (tid < st) sr[tid] += sr[tid + st];
    __syncthreads();
  }
  if (tid == 0) thrbuf[b * 8 + g] = sr[0];
}

// ---------------- K4b (MFMA): LGCE finish + V-dwconv + attn -> A96, W96 MFMA + cb + x -> dout ----------------
__global__ __launch_bounds__(256) void k4b_fuse(
    const float* __restrict__ x, const float* __restrict__ spw, const float* __restrict__ spb,
    const float* __restrict__ qkv_dw, const unsigned short* __restrict__ qkvl,
    const unsigned short* __restrict__ LOCB, const unsigned short* __restrict__ PREB,
    const float* __restrict__ Abuf, const float* __restrict__ cwbuf, const float* __restrict__ thrbuf,
    const float* __restrict__ W96, const float* __restrict__ cb,
    float* __restrict__ dout)
{
  __shared__ unsigned short sA[64][104];
  __shared__ float sOut[64][65];
  const int tid = threadIdx.x;
  const int px_l = tid & 63, q = tid >> 6;
  const int p0 = blockIdx.x * 64;
  const int b = p0 >> 16;
  const int hw0 = p0 & (HW - 1);
  const int hw = hw0 + px_l;
  const int y = hw >> 8, xx = hw & 255;
  const float* cw = cwbuf + b * 32;
  const float* A = Abuf + b * 256;
  // loc (bf16 px-major, copied raw into sA) + pre (bf16 px-major -> fp32)
  union { short8v v; unsigned short s[8]; } lv, pvv;
  lv.v = *reinterpret_cast<const short8v*>(LOCB + ((size_t)b * HW + hw) * 32 + q * 8);
  pvv.v = *reinterpret_cast<const short8v*>(PREB + ((size_t)b * HW + hw) * 32 + q * 8);
  float pre8[8];
#pragma unroll
  for (int j = 0; j < 8; ++j) pre8[j] = bf2f(pvv.s[j]);
  float mx8[8];
#pragma unroll
  for (int g2 = 0; g2 < 2; ++g2) {
    const int g = 2 * q + g2;
    float xa[4];
    float sdot = spb[g];
#pragma unroll
    for (int c = 0; c < 4; ++c) {
      xa[c] = pre8[g2 * 4 + c] * cw[g * 4 + c];
      sdot += xa[c] * spw[g * 4 + c];
    }
    float sgv = sigm(sdot);
    float thr = thrbuf[b * 8 + g] * (1.f / (4.f * 65536.f));
#pragma unroll
    for (int c = 0; c < 4; ++c) {
      float resp = sigm(xa[c] * sgv);
      float m = (resp > thr) ? 1.f : resp;
      mx8[g2 * 4 + c] = pre8[g2 * 4 + c] * m;
    }
  }
  int offs[9]; bool okn[9];
#pragma unroll
  for (int dy = -1; dy <= 1; ++dy)
#pragma unroll
    for (int dx = -1; dx <= 1; ++dx) {
      int i = (dy + 1) * 3 + (dx + 1);
      int yy = y + dy, x2 = xx + dx;
      okn[i] = ((unsigned)yy < 256u) && ((unsigned)x2 < 256u);
      offs[i] = yy * 256 + x2;
    }
  float v8[8];
#pragma unroll
  for (int j = 0; j < 8; ++j) {
    const unsigned short* plane = qkvl + (size_t)(b * 96 + 64 + q * 8 + j) * HW;
    float acc = 0.f;
#pragma unroll
    for (int i = 0; i < 9; ++i)
      if (okn[i]) acc += bf2f(plane[offs[i]]) * qkv_dw[(64 + q * 8 + j) * 9 + i];
    v8[j] = acc;
  }
#pragma unroll
  for (int j = 0; j < 8; ++j) {
    float s = 0.f;
#pragma unroll
    for (int d = 0; d < 8; ++d) s += A[(q * 8 + j) * 8 + d] * v8[d];
    sA[px_l][q * 8 + j] = f2bf(s);
    sA[px_l][32 + q * 8 + j] = f2bf(mx8[j]);
    sA[px_l][64 + q * 8 + j] = lv.s[j];
  }
  __syncthreads();
  const int w = q, lane = tid & 63;
  const int col = lane & 15, kgrp = lane >> 4;
  const int og = w * 16 + col;
  f32x4 acc[4];
#pragma unroll
  for (int s = 0; s < 4; ++s) acc[s] = (f32x4){0.f, 0.f, 0.f, 0.f};
#pragma unroll
  for (int kk = 0; kk < 3; ++kk) {
    const int c0 = kk * 32 + kgrp * 8;
    union { short8v v; unsigned short s[8]; } bw;
    const float* wp = W96 + og * 96 + c0;
#pragma unroll
    for (int j = 0; j < 8; ++j) bw.s[j] = f2bf(wp[j]);
#pragma unroll
    for (int s = 0; s < 4; ++s) {
      short8v av = *reinterpret_cast<const short8v*>(&sA[s * 16 + col][c0]);
      acc[s] = __builtin_amdgcn_mfma_f32_16x16x32_bf16(av, bw.v, acc[s], 0, 0, 0);
    }
  }
#pragma unroll
  for (int s = 0; s < 4; ++s) {
#pragma unroll
    for (int r = 0; r < 4; ++r) {
      int pxl = s * 16 + kgrp * 4 + r;
      sOut[og][pxl] = acc[s][r];
    }
  }
  __syncthreads();
  const float* xb = x + (size_t)(b * 64) * HW + hw0;
  float* db = dout + (size_t)(b * 64) * HW + hw0;
#pragma unroll
  for (int i = 0; i < 16; ++i) {
    int idx = tid + i * 256;
    int o = idx >> 6, px = idx & 63;
    db[(size_t)o * HW + px] = sOut[o][px] + cb[o] + xb[(size_t)o * HW + px];
  }
}

// ---------------- K5 (MFMA): LN2 + ffn_in (64->256), 128 outs/block ----------------
__global__ __launch_bounds__(256) void k5_mfma(
    const float* __restrict__ ln2_w, const float* __restrict__ ln2_b,
    const float* __restrict__ ffn_in_w, const float* __restrict__ dout,
    unsigned short* __restrict__ Tb, int b)
{
  __shared__ float sStage[64][65];
  __shared__ unsigned short sXnb[64][72];
  __shared__ unsigned short sOutB[128][72];
  __shared__ float sMu[64], sRs[64];
  const int tid = threadIdx.x;
  const int px0 = blockIdx.x * 64;
  const int o0base = blockIdx.y * 128;
  const float* db = dout + (size_t)(b * 64) * HW + px0;
#pragma unroll
  for (int i = 0; i < 16; ++i) {
    int idx = tid + i * 256;
    int c = idx >> 6, px = idx & 63;
    sStage[px][c] = db[(size_t)c * HW + px];
  }
  __syncthreads();
  if (tid < 64) {
    float mu = 0.f;
#pragma unroll
    for (int c = 0; c < 64; ++c) mu += sStage[tid][c];
    mu *= (1.f / 64.f);
    float var = 0.f;
#pragma unroll
    for (int c = 0; c < 64; ++c) { float d = sStage[tid][c] - mu; var += d * d; }
    var *= (1.f / 64.f);
    sMu[tid] = mu;
    sRs[tid] = rsqrtf(var + 1e-5f);
  }
  __syncthreads();
#pragma unroll
  for (int i = 0; i < 16; ++i) {
    int idx = tid + i * 256;
    int px = idx >> 6, c = idx & 63;
    float xn = (sStage[px][c] - sMu[px]) * sRs[px] * ln2_w[c] + ln2_b[c];
    sXnb[px][c] = f2bf(xn);
  }
  __syncthreads();
  const int w = tid >> 6, lane = tid & 63;
  const int col = lane & 15, kgrp = lane >> 4;
#pragma unroll
  for (int pass = 0; pass < 2; ++pass) {
    const int o_l = pass * 64 + w * 16 + col;
    const int og = o0base + o_l;
    f32x4 acc[4];
#pragma unroll
    for (int s = 0; s < 4; ++s) acc[s] = (f32x4){0.f, 0.f, 0.f, 0.f};
#pragma unroll
    for (int kk = 0; kk < 2; ++kk) {
      const int c0 = kk * 32 + kgrp * 8;
      union { short8v v; unsigned short s[8]; } bw;
      const float* wp = ffn_in_w + (size_t)og * 64 + c0;
#pragma unroll
      for (int j = 0; j < 8; ++j) bw.s[j] = f2bf(wp[j]);
#pragma unroll
      for (int s = 0; s < 4; ++s) {
        short8v av = *reinterpret_cast<const short8v*>(&sXnb[s * 16 + col][c0]);
        acc[s] = __builtin_amdgcn_mfma_f32_16x16x32_bf16(av, bw.v, acc[s], 0, 0, 0);
      }
    }
#pragma unroll
    for (int s = 0; s < 4; ++s) {
#pragma unroll
      for (int r = 0; r < 4; ++r) {
        int px_l = s * 16 + kgrp * 4 + r;
        sOutB[o_l][px_l] = f2bf(acc[s][r]);
      }
    }
  }
  __syncthreads();
  for (int i = tid; i < 1024; i += 256) {
    int o = i >> 3, seg = i & 7;
    *reinterpret_cast<short8v*>(Tb + (size_t)(o0base + o) * HW + px0 + seg * 8) =
        *reinterpret_cast<const short8v*>(&sOutB[o][seg * 8]);
  }
}

// ---------------- K6a: dwconv3/dwconv5 + gelu*mul -> Y (bf16) ----------------
__global__ __launch_bounds__(256) void k6a_dw(
    const float* __restrict__ dw3_w, const float* __restrict__ dw5_w,
    const unsigned short* __restrict__ T, __hip_bfloat16* __restrict__ Y)
{
  const int tid = threadIdx.x;
  const int px = blockIdx.x * 256 + tid;
  const int j0 = blockIdx.y * 8;
  const int row = px >> 8, col = px & 255;
  bool oky[5], okx[5];
#pragma unroll
  for (int d = 0; d < 5; ++d) {
    oky[d] = ((unsigned)(row + d - 2) < 256u);
    okx[d] = ((unsigned)(col + d - 2) < 256u);
  }
#pragma unroll
  for (int jj = 0; jj < 8; ++jj) {
    const int j = j0 + jj;
    const unsigned short* pl = T + (size_t)j * HW;
    float a = 0.f;
#pragma unroll
    for (int dy = -1; dy <= 1; ++dy) {
      if (!oky[dy + 2]) continue;
#pragma unroll
      for (int dx = -1; dx <= 1; ++dx) {
        if (!okx[dx + 2]) continue;
        a += bf2f(pl[px + dy * 256 + dx]) * dw3_w[j * 9 + (dy + 1) * 3 + (dx + 1)];
      }
    }
    float m = 0.f;
    const unsigned short* pm = T + (size_t)(128 + j) * HW;
    if (j < 64) {
#pragma unroll
      for (int dy = -1; dy <= 1; ++dy) {
        if (!oky[dy + 2]) continue;
#pragma unroll
        for (int dx = -1; dx <= 1; ++dx) {
          if (!okx[dx + 2]) continue;
          m += bf2f(pm[px + dy * 256 + dx]) * dw3_w[(128 + j) * 9 + (dy + 1) * 3 + (dx + 1)];
        }
      }
    } else {
#pragma unroll
      for (int dy = -2; dy <= 2; ++dy) {
        if (!oky[dy + 2]) continue;
#pragma unroll
        for (int dx = -2; dx <= 2; ++dx) {
          if (!okx[dx + 2]) continue;
          m += bf2f(pm[px + dy * 256 + dx]) * dw5_w[(j - 64) * 25 + (dy + 2) * 5 + (dx + 2)];
        }
      }
    }
    float gl = 0.5f * a * (1.f + erff(a * 0.70710678118654752f));
    Y[(size_t)j * HW + px] = __float2bfloat16(gl * m);
  }
}

// ---------------- K6b: ffn_out (128->64) from Y ----------------
__global__ __launch_bounds__(256) void k6b_out(
    const float* __restrict__ ffn_out_w, const __hip_bfloat16* __restrict__ Y,
    const float* __restrict__ flag, float* __restrict__ dout, float* __restrict__ Z, int b)
{
  __shared__ float sW[2048];
  const int tid = threadIdx.x;
  const int o0 = blockIdx.y * 16;
  for (int i = tid; i < 2048; i += 256) sW[i] = ffn_out_w[o0 * 128 + i];
  __syncthreads();
  const int px = blockIdx.x * 256 + tid;
  float z[16];
#pragma unroll
  for (int o = 0; o < 16; ++o) z[o] = 0.f;
  for (int j = 0; j < 128; ++j) {
    float yv = __bfloat162float(Y[(size_t)j * HW + px]);
#pragma unroll
    for (int o = 0; o < 16; ++o) z[o] += sW[o * 128 + j] * yv;
  }
  if (flag[0] > 0.5f) {
    float* ob = dout + (size_t)(b * 64 + o0) * HW + px;
#pragma unroll
    for (int o = 0; o < 16; ++o) ob[(size_t)o * HW] += z[o];
  } else {
    float* zb = Z + (size_t)o0 * HW + px;
#pragma unroll
    for (int o = 0; o < 16; ++o) zb[(size_t)o * HW] = z[o];
  }
}

// ---------------- K7: general fft path (early-exit if identity) ----------------
__global__ __launch_bounds__(256) void k7_fft(
    const float* __restrict__ fftw, const float* __restrict__ flag,
    const float* __restrict__ Z, float* __restrict__ dout, int b)
{
  if (flag[0] > 0.5f) return;
  __shared__ float swv[64];
  __shared__ float spatch[4][64];
  const int tid = threadIdx.x;
  const int c = blockIdx.x >> 8;
  const int pblk = blockIdx.x & 255;
  if (tid < 64) swv[tid] = fftw[c * 64 + tid];
  const int lp = tid >> 6, e = tid & 63;
  const int patch = pblk * 4 + lp;
  const int pi = patch >> 5, pj = patch & 31;
  const int i = e >> 3, jj = e & 7;
  const int gidx = (pi * 8 + i) * 256 + pj * 8 + jj;
  const float zv = Z[(size_t)c * HW + gidx];
  spatch[lp][e] = zv;
  __syncthreads();
  float s = 0.f;
#pragma unroll
  for (int a = 0; a < 8; ++a)
#pragma unroll
    for (int b2 = 0; b2 < 8; ++b2)
      s += swv[a * 8 + b2] * spatch[lp][((i - a) & 7) * 8 + ((jj - b2) & 7)];
  dout[(size_t)(b * 64 + c) * HW + gidx] += s;
}

extern "C" void kernel_launch(void* const* d_in, const int* in_sizes, int n_in,
                              void* d_out, int out_size, void* d_ws, size_t ws_size,
                              hipStream_t stream) {
  const float* x          = (const float*)d_in[0];
  const float* ln1_w      = (const float*)d_in[1];
  const float* ln1_b      = (const float*)d_in[2];
  const float* in_proj_w  = (const float*)d_in[3];
  const float* qkv_w      = (const float*)d_in[4];
  const float* qkv_dw     = (const float*)d_in[5];
  const float* out_proj_w = (const float*)d_in[6];
  const float* temperature= (const float*)d_in[7];
  const float* attn_scales= (const float*)d_in[8];
  const float* gate_w1    = (const float*)d_in[9];
  const float* gate_b1    = (const float*)d_in[10];
  const float* gate_w2    = (const float*)d_in[11];
  const float* gate_b2    = (const float*)d_in[12];
  const float* lgce_pre_w = (const float*)d_in[13];
  const float* lgce_pre_b = (const float*)d_in[14];
  const float* lgce_post_w= (const float*)d_in[15];
  const float* lgce_post_b= (const float*)d_in[16];
  const float* cbam_m1w   = (const float*)d_in[17];
  const float* cbam_m1b   = (const float*)d_in[18];
  const float* cbam_m2w   = (const float*)d_in[19];
  const float* cbam_m2b   = (const float*)d_in[20];
  const float* cbam_spw   = (const float*)d_in[21];
  const float* cbam_spb   = (const float*)d_in[22];
  const float* ln2_w      = (const float*)d_in[23];
  const float* ln2_b      = (const float*)d_in[24];
  const float* ffn_in_w   = (const float*)d_in[25];
  const float* dw3_w      = (const float*)d_in[26];
  const float* dw5_w      = (const float*)d_in[27];
  const float* ffn_out_w  = (const float*)d_in[28];
  const float* fft_W      = (const float*)d_in[29];
  float* ws = (float*)d_ws;
  float* out = (float*)d_out;
  unsigned short* qkvlp = (unsigned short*)(ws + OFF_QKVL);
  unsigned short* LOCB = (unsigned short*)(ws + OFF_LOCB);
  unsigned short* PREB = (unsigned short*)(ws + OFF_PREB);
  unsigned short* Tb = (unsigned short*)(ws + OFF_T);
  __hip_bfloat16* Ybuf = (__hip_bfloat16*)(ws + OFF_Y);

  hipLaunchKernelGGL(k0_setup, dim3(1), dim3(256), 0, stream,
                     fft_W, in_proj_w, qkv_w, gate_w1, lgce_pre_w,
                     out_proj_w, lgce_post_w, lgce_post_b, ws);
  hipLaunchKernelGGL(k1_mfma, dim3(1024), dim3(256), 0, stream,
                     x, ln1_w, ln1_b, in_proj_w, ws + OFF_MQKV, ws + OFF_MG1,
                     ws + OFF_MPRE, lgce_pre_b,
                     gate_b1, gate_w2, gate_b2,
                     qkvlp, LOCB, PREB, ws + OFF_POOL, ws + OFF_GSUM);
  hipLaunchKernelGGL(k1_check, dim3(1), dim3(256), 0, stream,
                     x, ln1_w, ln1_b, in_proj_w, qkv_w, lgce_pre_w, lgce_pre_b,
                     LOCB, qkvlp, PREB, ws + OFF_BAD);
  hipLaunchKernelGGL(k1r_reset, dim3(1), dim3(256), 0, stream,
                     ws + OFF_BAD, ws + OFF_GSUM);
  hipLaunchKernelGGL(k1_fb, dim3(1024), dim3(256), 0, stream,
                     x, ln1_w, ln1_b, in_proj_w, qkv_w, lgce_pre_w, lgce_pre_b,
                     gate_w1, gate_b1, gate_w2, gate_b2,
                     ws + OFF_BAD, qkvlp, LOCB, PREB, ws + OFF_POOL, ws + OFF_GSUM);
  hipLaunchKernelGGL(k2_mfma, dim3(128, 4, 4), dim3(256), 0, stream,
                     qkvlp, qkv_dw, ws + OFF_GRAM);
  hipLaunchKernelGGL(k3_final, dim3(1), dim3(256), 0, stream,
                     cbam_m1w, cbam_m1b, cbam_m2w, cbam_m2b, temperature, attn_scales,
                     lgce_pre_w, lgce_pre_b,
                     ws + OFF_GSUM, ws + OFF_POOL, ws + OFF_GRAM, ws + OFF_A, ws + OFF_CW);
  hipLaunchKernelGGL(k4a_thr, dim3(2048), dim3(256), 0, stream,
                     cbam_spw, cbam_spb, ws + OFF_CW, PREB, ws + OFF_PART);
  hipLaunchKernelGGL(k4a_red, dim3(32), dim3(256), 0, stream,
                     ws + OFF_PART, ws + OFF_THR);
  hipLaunchKernelGGL(k4b_fuse, dim3(4096), dim3(256), 0, stream,
                     x, cbam_spw, cbam_spb, qkv_dw, qkvlp, LOCB, PREB,
                     ws + OFF_A, ws + OFF_CW, ws + OFF_THR,
                     ws + OFF_W96, ws + OFF_CB, out);

  for (int b = 0; b < 4; ++b) {
    hipLaunchKernelGGL(k5_mfma, dim3(1024, 2), dim3(256), 0, stream,
                       ln2_w, ln2_b, ffn_in_w, out, Tb, b);
    hipLaunchKernelGGL(k6a_dw, dim3(256, 16), dim3(256), 0, stream,
                       dw3_w, dw5_w, Tb, Ybuf);
    hipLaunchKernelGGL(k6b_out, dim3(256, 4), dim3(256), 0, stream,
                       ffn_out_w, Ybuf, ws + OFF_FLAG, out, ws + OFF_Z, b);
    hipLaunchKernelGGL(k7_fft, dim3(16384), dim3(256), 0, stream,
                       ws + OFF_FFTW, ws + OFF_FLAG, ws + OFF_Z, out, b);
  }
}

// Round 11
// 1132.279 us; speedup vs baseline: 5.6476x; 1.0429x over previous
//
#include <hip/hip_runtime.h>
#include <hip/hip_bf16.h>
#include <math.h>

#define HW 65536
#define NPIX 262144

// ---- workspace layout (float offsets) ----
#define OFF_FFTW 0            // 64x64 spatial fft kernel
#define OFF_FLAG 4096         // 1
#define OFF_GSUM 4097         // 1    (zeroed in k0)
#define OFF_POOL 4098         // 128  (zeroed in k0)  -- pooled(loc) sums
#define OFF_GRAM 4226         // 1280 (zeroed in k0)
#define OFF_THR  5506         // 32   (written by k4a_red)
#define OFF_BAD  5538         // 1    (zeroed in k0)  -- k1 checker flag
#define OFF_A    5539         // 1024
#define OFF_CW   6563         // 128
#define OFF_QKVL 8192         // 96ch * 262144 px bf16 = 12582912 float-slots (SGSA phase)
#define OFF_MQKV 12591104     // 96*64 fp32 composed qkv matrix
#define OFF_MG1  (OFF_MQKV + 6144)     // 16*64 fp32  (ends 12598272)
#define OFF_MPRE 12598272     // 32*64 fp32 composed pre matrix (ends 12600320)
#define OFF_PREB 12600320     // [4][65536][32] bf16 px-major = 4194304 slots (ends 16794624)
#define OFF_LOCB 16794624     // [4][65536][32] bf16 px-major = 4194304 slots (ends 20988928)
#define OFF_PART 20988928     // 2048 blk * 4 waves * 4 g = 32768 (ends 21021696)
#define OFF_W96  21021696     // 64*96 fp32 composed out_proj|post matrix (SGSA phase only)
#define OFF_CB   (OFF_W96 + 6144)      // 64 fp32 (ends 21027904 < 25174016)
// MFFN phase (per-batch, overlaps QKVL/PREB/LOCB/W96 which are dead by then):
#define OFF_T    8192                      // 256ch * 65536 bf16
#define OFF_Y    (OFF_T + 16777216)        // 128ch * 65536 bf16
#define OFF_Z    (OFF_Y + 4194304)         // 64ch * 65536 fp32
// peak ws usage = 25174016 floats = 100.7 MB (unchanged proven footprint)

typedef __attribute__((ext_vector_type(8))) short short8v;
typedef __attribute__((ext_vector_type(4))) float f32x4;

__device__ __forceinline__ float sigm(float v) { return 1.f / (1.f + expf(-v)); }
__device__ __forceinline__ float wredsum(float v) {
#pragma unroll
  for (int off = 32; off >= 1; off >>= 1) v += __shfl_xor(v, off);
  return v;
}
__device__ __forceinline__ unsigned short f2bf(float f) {
  union { float f; unsigned u; } x; x.f = f;
  unsigned r = x.u + 0x7fffu + ((x.u >> 16) & 1u);
  return (unsigned short)(r >> 16);
}
__device__ __forceinline__ float bf2f(unsigned short u) {
  union { unsigned u; float f; } x; x.u = ((unsigned)u) << 16;
  return x.f;
}

// ---------------- K0: zero accumulators + fft kernel + composed matrices ----------------
__global__ __launch_bounds__(256) void k0_setup(
    const float* __restrict__ fft_W, const float* __restrict__ in_proj_w,
    const float* __restrict__ qkv_w, const float* __restrict__ g1w,
    const float* __restrict__ pre_w, const float* __restrict__ out_proj_w,
    const float* __restrict__ post_w, const float* __restrict__ post_b,
    float* __restrict__ ws)
{
  __shared__ float ct8[8];
  __shared__ int sbad;
  const int tid = threadIdx.x;
  if (tid < 8) ct8[tid] = cosf((float)tid * 0.78539816339744831f); // cos(k*pi/4)
  if (tid == 0) sbad = 0;
  for (int i = tid; i < 1442; i += 256) ws[OFF_GSUM + i] = 0.f;    // gsum,pool,gram,thr,bad
  for (int i = tid; i < 96 * 64; i += 256) {
    int o = i >> 6, c = i & 63;
    float s = 0.f;
    for (int j = 0; j < 32; ++j) s += qkv_w[o * 32 + j] * in_proj_w[(32 + j) * 64 + c];
    ws[OFF_MQKV + i] = s;
  }
  for (int i = tid; i < 16 * 64; i += 256) {
    int o = i >> 6, c = i & 63;
    float s = 0.f;
    for (int j = 0; j < 32; ++j) s += g1w[o * 32 + j] * in_proj_w[(32 + j) * 64 + c];
    ws[OFF_MG1 + i] = s;
  }
  for (int i = tid; i < 32 * 64; i += 256) {
    int o = i >> 6, c = i & 63;
    float s = 0.f;
    for (int j = 0; j < 32; ++j) s += pre_w[o * 32 + j] * in_proj_w[j * 64 + c];
    ws[OFF_MPRE + i] = s;
  }
  for (int i = tid; i < 64 * 96; i += 256) {
    int o = i / 96, c = i - o * 96;
    float s;
    if (c < 32) s = out_proj_w[o * 64 + c];
    else if (c < 64) {
      s = 0.f;
      for (int k = 0; k < 32; ++k) s += out_proj_w[o * 64 + 32 + k] * post_w[k * 32 + (c - 32)];
    } else s = out_proj_w[o * 64 + (c - 32)];
    ws[OFF_W96 + i] = s;
  }
  for (int i = tid; i < 64; i += 256) {
    float s = 0.f;
    for (int k = 0; k < 32; ++k) s += out_proj_w[i * 64 + 32 + k] * post_b[k];
    ws[OFF_CB + i] = s;
  }
  __syncthreads();
  bool ok = true;
  for (int i = tid; i < 64 * 64; i += 256) {
    int ch = i >> 6, ab = i & 63;
    int a = ab >> 3, b2 = ab & 7;
    float s = 0.f;
    for (int u = 0; u < 8; ++u)
      for (int v = 0; v < 8; ++v) {
        float Wf;
        if (v == 0 || v == 4)
          Wf = 0.5f * (fft_W[ch * 40 + u * 5 + v] + fft_W[ch * 40 + ((8 - u) & 7) * 5 + v]);
        else if (v < 5)
          Wf = fft_W[ch * 40 + u * 5 + v];
        else
          Wf = fft_W[ch * 40 + ((8 - u) & 7) * 5 + (8 - v)];
        s += Wf * ct8[(u * a + v * b2) & 7];
      }
    s *= (1.f / 64.f);
    ws[OFF_FFTW + i] = s;
    float expect = ((i & 63) == 0) ? 1.f : 0.f;
    if (fabsf(s - expect) > 1e-4f) ok = false;
  }
  if (!ok) atomicOr(&sbad, 1);
  __syncthreads();
  if (tid == 0) ws[OFF_FLAG] = sbad ? 0.f : 1.f;
}

// ---------------- K1 (MFMA, 128px blocks): LN1 + [loc|qkv|pre] + gate + pooled ----------------
// 2048 blocks x 128 px. Phase A: 2 threads/px register LN. Phase B: 10 o-tiles x 2 px-subtiles.
// LDS ~28 KB -> 5 blocks/CU.
__global__ __launch_bounds__(256) void k1_mfma(
    const float* __restrict__ x, const float* __restrict__ ln1_w, const float* __restrict__ ln1_b,
    const float* __restrict__ in_proj_w, const float* __restrict__ mqkv, const float* __restrict__ mg1,
    const float* __restrict__ mpre, const float* __restrict__ pre_b,
    const float* __restrict__ g1b, const float* __restrict__ g2w, const float* __restrict__ g2b,
    unsigned short* __restrict__ qkvl, unsigned short* __restrict__ LOCB,
    unsigned short* __restrict__ PREB, float* __restrict__ pooled, float* __restrict__ gsum)
{
  __shared__ unsigned short sXnb[128][72];   // LN'd bf16 activations [px][64ch]  (18.4 KB)
  __shared__ unsigned short sStg[4][16][76]; // per-wave staging, padded stride 76 (9.7 KB)
  __shared__ float sPoolL[32];
  __shared__ float sRed[4];
  const int tid = threadIdx.x;
  const int p0 = blockIdx.x * 128;
  const int b = p0 >> 16;
  const int hw0 = p0 & (HW - 1);
  if (tid < 32) sPoolL[tid] = 0.f;
  // ---- Phase A: register LN, 2 threads per px (each 32 channels) ----
  {
    const int px_l = tid >> 1, half = tid & 1;
    const float* xb = x + (size_t)(b * 64 + half * 32) * HW + hw0 + px_l;
    float xv[32];
    float mu = 0.f;
#pragma unroll
    for (int c = 0; c < 32; ++c) { xv[c] = xb[(size_t)c * HW]; mu += xv[c]; }
    mu += __shfl_xor(mu, 1);
    mu *= (1.f / 64.f);
    float var = 0.f;
#pragma unroll
    for (int c = 0; c < 32; ++c) { float d = xv[c] - mu; var += d * d; }
    var += __shfl_xor(var, 1);
    var *= (1.f / 64.f);
    const float rs = rsqrtf(var + 1e-5f);
#pragma unroll
    for (int ch = 0; ch < 4; ++ch) {
      union { short8v v; unsigned short s[8]; } u;
#pragma unroll
      for (int j = 0; j < 8; ++j) {
        int cg = half * 32 + ch * 8 + j;
        u.s[j] = f2bf(xv[ch * 8 + j] * rs - mu * rs * ln1_w[cg] / ln1_w[cg] * ln1_w[cg] + 0.f); // placeholder
      }
      (void)u;
    }
    // correct form (no cleverness): xn = (xv - mu) * rs * w + b
#pragma unroll
    for (int ch = 0; ch < 4; ++ch) {
      union { short8v v; unsigned short s[8]; } u;
#pragma unroll
      for (int j = 0; j < 8; ++j) {
        int cg = half * 32 + ch * 8 + j;
        u.s[j] = f2bf((xv[ch * 8 + j] - mu) * rs * ln1_w[cg] + ln1_b[cg]);
      }
      *reinterpret_cast<short8v*>(&sXnb[px_l][half * 32 + ch * 8]) = u.v;
    }
  }
  __syncthreads();
  // ---- Phase B: MFMA tiles ----
  const int w = tid >> 6, lane = tid & 63;
  const int col = lane & 15, kgrp = lane >> 4;
#pragma unroll
  for (int pass = 0; pass < 3; ++pass) {
    const int tile = pass * 4 + w;
    if (tile >= 10) continue;                 // wave-uniform
    const int og = tile * 16 + col;           // 0..159
    const float* wrow = (og < 32) ? (in_proj_w + og * 64)
                      : (og < 128) ? (mqkv + (og - 32) * 64)
                                   : (mpre + (og - 128) * 64);
    union { short8v v; unsigned short s[8]; } bw[2];
#pragma unroll
    for (int kk = 0; kk < 2; ++kk) {
      const int c0 = kk * 32 + kgrp * 8;
#pragma unroll
      for (int j = 0; j < 8; ++j) bw[kk].s[j] = f2bf(wrow[c0 + j]);
    }
    const float bias = (og >= 128) ? pre_b[og - 128] : 0.f;
    float poolAcc = 0.f;
#pragma unroll
    for (int pxsub = 0; pxsub < 2; ++pxsub) {
      f32x4 acc[4];
#pragma unroll
      for (int s = 0; s < 4; ++s) acc[s] = (f32x4){0.f, 0.f, 0.f, 0.f};
#pragma unroll
      for (int kk = 0; kk < 2; ++kk) {
        const int c0 = kk * 32 + kgrp * 8;
#pragma unroll
        for (int s = 0; s < 4; ++s) {
          short8v av = *reinterpret_cast<const short8v*>(&sXnb[pxsub * 64 + s * 16 + col][c0]);
          acc[s] = __builtin_amdgcn_mfma_f32_16x16x32_bf16(av, bw[kk].v, acc[s], 0, 0, 0);
        }
      }
#pragma unroll
      for (int s = 0; s < 4; ++s) {
#pragma unroll
        for (int r = 0; r < 4; ++r) {
          float v = acc[s][r] + bias;
          sStg[w][col][s * 16 + kgrp * 4 + r] = f2bf(v);
          if (og < 32) poolAcc += v;
        }
      }
      if (og >= 32 && og < 128) {
        const int row = lane >> 2, seg = lane & 3;
        const unsigned short* src = &sStg[w][row][seg * 16];
        unsigned short* dst = qkvl + (size_t)(b * 96 + (tile - 2) * 16 + row) * HW
                              + hw0 + pxsub * 64 + seg * 16;
        *reinterpret_cast<short8v*>(dst) = *reinterpret_cast<const short8v*>(src);
        *reinterpret_cast<short8v*>(dst + 8) = *reinterpret_cast<const short8v*>(src + 8);
      } else {
        const int pxl = lane;
        union { short8v v; unsigned short s[8]; } u0, u1;
#pragma unroll
        for (int o = 0; o < 8; ++o) { u0.s[o] = sStg[w][o][pxl]; u1.s[o] = sStg[w][8 + o][pxl]; }
        unsigned short* base = (og < 32) ? LOCB : PREB;
        const int choff = (og < 32) ? (tile * 16) : ((tile - 8) * 16);
        unsigned short* dst = base + ((size_t)b * HW + hw0 + pxsub * 64 + pxl) * 32 + choff;
        *reinterpret_cast<short8v*>(dst) = u0.v;
        *reinterpret_cast<short8v*>(dst + 8) = u1.v;
      }
    }
    if (og < 32) {
      poolAcc += __shfl_xor(poolAcc, 16);
      poolAcc += __shfl_xor(poolAcc, 32);
      if (kgrp == 0) sPoolL[og] = poolAcc;
    }
  }
  // ---- gate: 2 threads/px, 8 h-rows each ----
  {
    const int gpx = tid >> 1, gq = tid & 1;
    float h[8];
#pragma unroll
    for (int i = 0; i < 8; ++i) h[i] = g1b[gq * 8 + i];
#pragma unroll
    for (int cc = 0; cc < 64; cc += 8) {
      union { short8v v; unsigned short s[8]; } xu;
      xu.v = *reinterpret_cast<const short8v*>(&sXnb[gpx][cc]);
#pragma unroll
      for (int j = 0; j < 8; ++j) {
        float xf = bf2f(xu.s[j]);
#pragma unroll
        for (int i = 0; i < 8; ++i) h[i] += mg1[(gq * 8 + i) * 64 + cc + j] * xf;
      }
    }
    float gpart = 0.f;
#pragma unroll
    for (int i = 0; i < 8; ++i) gpart += g2w[gq * 8 + i] * fmaxf(h[i], 0.f);
    gpart += __shfl_xor(gpart, 1);
    float gv = (gq == 0) ? sigm(gpart + g2b[0]) : 0.f;
    gv = wredsum(gv);
    if (lane == 0) sRed[w] = gv;
  }
  __syncthreads();
  if (tid == 0) atomicAdd(gsum, sRed[0] + sRed[1] + sRed[2] + sRed[3]);
  if (tid < 32) atomicAdd(&pooled[b * 32 + tid], sPoolL[tid]);
}

// ---------------- K1 checker: 256 sampled px vs independent fp32 reference ----------------
__global__ __launch_bounds__(256) void k1_check(
    const float* __restrict__ x, const float* __restrict__ ln1_w, const float* __restrict__ ln1_b,
    const float* __restrict__ in_proj_w, const float* __restrict__ qkv_w,
    const float* __restrict__ pre_w, const float* __restrict__ pre_b,
    const unsigned short* __restrict__ LOCB, const unsigned short* __restrict__ qkvl,
    const unsigned short* __restrict__ PREB, float* __restrict__ bad)
{
  const int t = threadIdx.x;
  const int b = t & 3;
  const int px = (t * 1031) & (HW - 1);
  const float* xb = x + (size_t)(b * 64) * HW + px;
  float xv[64];
  float mu = 0.f;
#pragma unroll
  for (int c = 0; c < 64; ++c) { xv[c] = xb[(size_t)c * HW]; mu += xv[c]; }
  mu *= (1.f / 64.f);
  float var = 0.f;
#pragma unroll
  for (int c = 0; c < 64; ++c) { float d = xv[c] - mu; var += d * d; }
  var *= (1.f / 64.f);
  float rs = rsqrtf(var + 1e-5f);
#pragma unroll
  for (int c = 0; c < 64; ++c) xv[c] = (xv[c] - mu) * rs * ln1_w[c] + ln1_b[c];
  bool fail = false;
  float lc[32], gl[32];
  for (int o = 0; o < 32; ++o) {
    float s = 0.f;
#pragma unroll
    for (int c = 0; c < 64; ++c) s += in_proj_w[o * 64 + c] * xv[c];
    lc[o] = s;
    float got = bf2f(LOCB[((size_t)b * HW + px) * 32 + o]);
    if (fabsf(got - s) > 0.05f + 0.05f * fabsf(s)) fail = true;
    float s2 = 0.f;
#pragma unroll
    for (int c = 0; c < 64; ++c) s2 += in_proj_w[(32 + o) * 64 + c] * xv[c];
    gl[o] = s2;
  }
  for (int o = 0; o < 96; ++o) {
    float s = 0.f;
#pragma unroll
    for (int j = 0; j < 32; ++j) s += qkv_w[o * 32 + j] * gl[j];
    float got = bf2f(qkvl[(size_t)(b * 96 + o) * HW + px]);
    if (fabsf(got - s) > 0.05f + 0.05f * fabsf(s)) fail = true;
  }
  for (int o = 0; o < 32; ++o) {
    float s = pre_b[o];
#pragma unroll
    for (int j = 0; j < 32; ++j) s += pre_w[o * 32 + j] * lc[j];
    float got = bf2f(PREB[((size_t)b * HW + px) * 32 + o]);
    if (fabsf(got - s) > 0.05f + 0.05f * fabsf(s)) fail = true;
  }
  if (fail) atomicExch(bad, 1.f);
}

// ---------------- K1 reset (only if checker failed) ----------------
__global__ __launch_bounds__(256) void k1r_reset(const float* __restrict__ bad, float* __restrict__ gsum)
{
  if (bad[0] < 0.5f) return;
  const int tid = threadIdx.x;
  if (tid < 129) gsum[tid] = 0.f;
}

// ---------------- K1 fallback (only if checker failed) ----------------
__global__ __launch_bounds__(256) void k1_fb(
    const float* __restrict__ x, const float* __restrict__ ln1_w, const float* __restrict__ ln1_b,
    const float* __restrict__ in_proj_w, const float* __restrict__ qkv_w,
    const float* __restrict__ pre_w, const float* __restrict__ pre_b,
    const float* __restrict__ g1w, const float* __restrict__ g1b,
    const float* __restrict__ g2w, const float* __restrict__ g2b,
    const float* __restrict__ bad,
    unsigned short* __restrict__ qkvl, unsigned short* __restrict__ LOCB,
    unsigned short* __restrict__ PREB, float* __restrict__ pooled, float* __restrict__ gsum)
{
  if (bad[0] < 0.5f) return;
  __shared__ float sPool[4][32];
  __shared__ float sRed[4];
  const int tid = threadIdx.x;
  const int p = blockIdx.x * 256 + tid;
  const int b = p >> 16;
  const int hw = p & (HW - 1);
  const int wave = tid >> 6, lane = tid & 63;
  const float* xb = x + (size_t)(b * 64) * HW + hw;
  float xv[64];
  float mu = 0.f;
#pragma unroll
  for (int c = 0; c < 64; ++c) { xv[c] = xb[(size_t)c * HW]; mu += xv[c]; }
  mu *= (1.f / 64.f);
  float var = 0.f;
#pragma unroll
  for (int c = 0; c < 64; ++c) { float d = xv[c] - mu; var += d * d; }
  var *= (1.f / 64.f);
  const float rs = rsqrtf(var + 1e-5f);
#pragma unroll
  for (int c = 0; c < 64; ++c) xv[c] = (xv[c] - mu) * rs * ln1_w[c] + ln1_b[c];
  float loc[32];
  for (int o = 0; o < 32; ++o) {
    float s = 0.f;
#pragma unroll
    for (int c = 0; c < 64; ++c) s += in_proj_w[o * 64 + c] * xv[c];
    loc[o] = s;
    LOCB[((size_t)b * HW + hw) * 32 + o] = f2bf(s);
    float r = wredsum(s);
    if (lane == 0) sPool[wave][o] = r;
  }
  for (int o = 0; o < 32; ++o) {
    float s = pre_b[o];
#pragma unroll
    for (int j = 0; j < 32; ++j) s += pre_w[o * 32 + j] * loc[j];
    PREB[((size_t)b * HW + hw) * 32 + o] = f2bf(s);
  }
  float gl[32];
  for (int o = 0; o < 32; ++o) {
    float s = 0.f;
#pragma unroll
    for (int c = 0; c < 64; ++c) s += in_proj_w[(32 + o) * 64 + c] * xv[c];
    gl[o] = s;
  }
  for (int o = 0; o < 96; ++o) {
    float s = 0.f;
#pragma unroll
    for (int j = 0; j < 32; ++j) s += qkv_w[o * 32 + j] * gl[j];
    qkvl[(size_t)(b * 96 + o) * HW + hw] = f2bf(s);
  }
  float gacc = g2b[0];
  for (int o = 0; o < 16; ++o) {
    float h = g1b[o];
#pragma unroll
    for (int j = 0; j < 32; ++j) h += g1w[o * 32 + j] * gl[j];
    gacc += g2w[o] * fmaxf(h, 0.f);
  }
  float gv = wredsum(sigm(gacc));
  if (lane == 0) sRed[wave] = gv;
  __syncthreads();
  if (tid == 0) atomicAdd(gsum, sRed[0] + sRed[1] + sRed[2] + sRed[3]);
  if (tid < 32) {
    float s = sPool[0][tid] + sPool[1][tid] + sPool[2][tid] + sPool[3][tid];
    atomicAdd(&pooled[b * 32 + tid], s);
  }
}

// ---------------- K2 (MFMA): dwconv(q,k) + Gram via V·V^T — vectorized row loads ----------------
__global__ __launch_bounds__(256) void k2_mfma(
    const unsigned short* __restrict__ qkvl, const float* __restrict__ qkv_dw, float* __restrict__ gram)
{
  __shared__ float sred[4][256];
  const int tid = threadIdx.x;
  const int slab = blockIdx.x;
  const int h = blockIdx.y, b = blockIdx.z;
  const int w = tid >> 6, lane = tid & 63;
  const int ch = lane & 15, grp = lane >> 4;
  const int gch = (ch < 8) ? (h * 8 + ch) : (32 + h * 8 + (ch - 8));
  const unsigned short* plane = qkvl + (size_t)(b * 96 + gch) * HW;
  const float* wt = qkv_dw + gch * 9;
  float w9[9];
#pragma unroll
  for (int t = 0; t < 9; ++t) w9[t] = wt[t];
  f32x4 acc = (f32x4){0.f, 0.f, 0.f, 0.f};
#pragma unroll
  for (int iter = 0; iter < 4; ++iter) {
    const int pxbase = slab * 512 + w * 128 + iter * 32 + grp * 8;
    const int y = pxbase >> 8;
    const int x0 = pxbase & 255;
    float row[3][10];
#pragma unroll
    for (int dy = 0; dy < 3; ++dy) {
      const int yy = y + dy - 1;
      if ((unsigned)yy >= 256u) {
#pragma unroll
        for (int j = 0; j < 10; ++j) row[dy][j] = 0.f;
        continue;
      }
      const unsigned short* rp = plane + yy * 256;
      union { short8v v; unsigned short s[8]; } cu;
      cu.v = *reinterpret_cast<const short8v*>(rp + x0);
#pragma unroll
      for (int j = 0; j < 8; ++j) row[dy][j + 1] = bf2f(cu.s[j]);
      row[dy][0] = (x0 > 0) ? bf2f(rp[x0 - 1]) : 0.f;
      row[dy][9] = (x0 < 248) ? bf2f(rp[x0 + 8]) : 0.f;
    }
    union { short8v v; unsigned short s[8]; } frag;
#pragma unroll
    for (int j = 0; j < 8; ++j) {
      float a = 0.f;
#pragma unroll
      for (int dy = 0; dy < 3; ++dy)
#pragma unroll
        for (int dx = 0; dx < 3; ++dx)
          a += row[dy][j + dx] * w9[dy * 3 + dx];
      frag.s[j] = f2bf(a);
    }
    acc = __builtin_amdgcn_mfma_f32_16x16x32_bf16(frag.v, frag.v, acc, 0, 0, 0);
  }
#pragma unroll
  for (int r = 0; r < 4; ++r) sred[w][(grp * 4 + r) * 16 + ch] = acc[r];
  __syncthreads();
  if (tid < 256) {
    float g = sred[0][tid] + sred[1][tid] + sred[2][tid] + sred[3][tid];
    const int row_ = tid >> 4, col_ = tid & 15;
    int idx = -1;
    if (row_ < 8 && col_ >= 8) idx = row_ * 8 + (col_ - 8);
    else if (row_ == col_ && row_ < 8) idx = 64 + row_;
    else if (row_ == col_) idx = 72 + (row_ - 8);
    if (idx >= 0) atomicAdd(&gram[(b * 4 + h) * 80 + idx], g);
  }
}

// ---------------- K3: dk, CBAM weights, attention matrices ----------------
__global__ __launch_bounds__(256) void k3_final(
    const float* __restrict__ m1w, const float* __restrict__ m1b,
    const float* __restrict__ m2w, const float* __restrict__ m2b,
    const float* __restrict__ temperature, const float* __restrict__ attn_scales,
    const float* __restrict__ pre_w, const float* __restrict__ pre_b,
    const float* __restrict__ gsum, const float* __restrict__ pooled,
    const float* __restrict__ gram, float* __restrict__ Abuf, float* __restrict__ cwbuf)
{
  __shared__ int s_dk;
  __shared__ float s_scale;
  const int tid = threadIdx.x;
  if (tid == 0) {
    float gmean = gsum[0] / (float)NPIX;
    int dk = (int)floorf(8.f * gmean);
    if (dk < 1) dk = 1;
    if (dk > 8) dk = 8;
    s_dk = dk;
    s_scale = attn_scales[0] + attn_scales[1] + attn_scales[2] + attn_scales[3];
  }
  __syncthreads();
  if (tid < 128) {
    int b = tid >> 5, ch = tid & 31, g = ch >> 2, c = ch & 3;
    float h1 = m1b[g];
#pragma unroll
    for (int cc = 0; cc < 4; ++cc) {
      int row = g * 4 + cc;
      float pp = pre_b[row];
#pragma unroll
      for (int j = 0; j < 32; ++j)
        pp += pre_w[row * 32 + j] * (pooled[b * 32 + j] * (1.f / 65536.f));
      h1 += pp * m1w[g * 4 + cc];
    }
    h1 = fmaxf(h1, 0.f);
    cwbuf[tid] = sigm(h1 * m2w[g * 4 + c] + m2b[g * 4 + c]);

    int r = tid, h = (r >> 3) & 3, c8 = r & 7;
    const float* gm = gram + (b * 4 + h) * 80;
    float qn = fmaxf(sqrtf(gm[64 + c8]), 1e-12f);
    float temp = temperature[h];
    float a[8];
#pragma unroll
    for (int d = 0; d < 8; ++d) {
      float kn = fmaxf(sqrtf(gm[72 + d]), 1e-12f);
      a[d] = gm[c8 * 8 + d] / (qn * kn) * temp;
    }
    float t[8];
#pragma unroll
    for (int d = 0; d < 8; ++d) t[d] = a[d];
#pragma unroll
    for (int i = 0; i < 8; ++i)
#pragma unroll
      for (int j = 0; j < 8; ++j)
        if (j > i && t[j] > t[i]) { float tmp = t[i]; t[i] = t[j]; t[j] = tmp; }
    float kth = t[s_dk - 1];
    float mx = t[0];
    float e[8]; float sum = 0.f;
#pragma unroll
    for (int d = 0; d < 8; ++d) {
      e[d] = (a[d] >= kth) ? expf(a[d] - mx) : 0.f;
      sum += e[d];
    }
    float inv = s_scale / sum;
#pragma unroll
    for (int d = 0; d < 8; ++d) Abuf[r * 8 + d] = e[d] * inv;
  }
}

// ---------------- K4a: resp partial sums (atomic-free), PREB bf16 ----------------
__global__ __launch_bounds__(256) void k4a_thr(
    const float* __restrict__ spw, const float* __restrict__ spb,
    const float* __restrict__ cwbuf, const unsigned short* __restrict__ PREB,
    float* __restrict__ wpart)
{
  const int tid = threadIdx.x;
  const int pxb = blockIdx.x >> 1;
  const int gh = blockIdx.x & 1;
  const int px = pxb * 256 + tid;
  const int b = px >> 16, hw = px & (HW - 1);
  const int w = tid >> 6, lane = tid & 63;
  const float* cw = cwbuf + b * 32;
  const unsigned short* pp = PREB + ((size_t)b * HW + hw) * 32 + gh * 16;
  union { short8v v; unsigned short s[8]; } u0, u1;
  u0.v = *reinterpret_cast<const short8v*>(pp);
  u1.v = *reinterpret_cast<const short8v*>(pp + 8);
  float pv[16];
#pragma unroll
  for (int k = 0; k < 8; ++k) { pv[k] = bf2f(u0.s[k]); pv[8 + k] = bf2f(u1.s[k]); }
  float racc[4];
#pragma unroll
  for (int g4 = 0; g4 < 4; ++g4) {
    const int g = gh * 4 + g4;
    float xa[4];
    float sdot = spb[g];
#pragma unroll
    for (int c = 0; c < 4; ++c) {
      xa[c] = pv[g4 * 4 + c] * cw[g * 4 + c];
      sdot += xa[c] * spw[g * 4 + c];
    }
    float sgv = sigm(sdot);
    float r = 0.f;
#pragma unroll
    for (int c = 0; c < 4; ++c) r += sigm(xa[c] * sgv);
    racc[g4] = r;
  }
#pragma unroll
  for (int g4 = 0; g4 < 4; ++g4) {
    float v = wredsum(racc[g4]);
    if (lane == 0) wpart[(blockIdx.x * 4 + w) * 4 + g4] = v;
  }
}

// ---------------- K4a_red: reduce wpart -> thrbuf ----------------
__global__ __launch_bounds__(256) void k4a_red(
    const float* __restrict__ wpart, float* __restrict__ thrbuf)
{
  __shared__ float sr[256];
  const int tid = threadIdx.x;
  const int b = blockIdx.x >> 3, g = blockIdx.x & 7;
  const int gh = g >> 2, gl = g & 3;
  float s = 0.f;
#pragma unroll
  for (int w = 0; w < 4; ++w)
    s += wpart[((((size_t)(b * 256 + tid) * 2 + gh) * 4) + w) * 4 + gl];
  sr[tid] = s;
  __syncthreads();
  for (int st = 128; st >= 1; st >>= 1) {
    if (tid < st) sr[tid] += sr[tid + st];
    __syncthreads();
  }
  if (tid == 0) thrbuf[b * 8 + g] = sr[0];
}

// ---------------- K4b (MFMA): LGCE finish + V-dwconv + attn -> A96, W96 MFMA + cb + x -> dout ----------------
__global__ __launch_bounds__(256) void k4b_fuse(
    const float* __restrict__ x, const float* __restrict__ spw, const float* __restrict__ spb,
    const float* __restrict__ qkv_dw, const unsigned short* __restrict__ qkvl,
    const unsigned short* __restrict__ LOCB, const unsigned short* __restrict__ PREB,
    const float* __restrict__ Abuf, const float* __restrict__ cwbuf, const float* __restrict__ thrbuf,
    const float* __restrict__ W96, const float* __restrict__ cb,
    float* __restrict__ dout)
{
  __shared__ unsigned short sA[64][104];
  __shared__ float sOut[64][65];
  const int tid = threadIdx.x;
  const int px_l = tid & 63, q = tid >> 6;
  const int p0 = blockIdx.x * 64;
  const int b = p0 >> 16;
  const int hw0 = p0 & (HW - 1);
  const int hw = hw0 + px_l;
  const int y = hw >> 8, xx = hw & 255;
  const float* cw = cwbuf + b * 32;
  const float* A = Abuf + b * 256;
  union { short8v v; unsigned short s[8]; } lv, pvv;
  lv.v = *reinterpret_cast<const short8v*>(LOCB + ((size_t)b * HW + hw) * 32 + q * 8);
  pvv.v = *reinterpret_cast<const short8v*>(PREB + ((size_t)b * HW + hw) * 32 + q * 8);
  float pre8[8];
#pragma unroll
  for (int j = 0; j < 8; ++j) pre8[j] = bf2f(pvv.s[j]);
  float mx8[8];
#pragma unroll
  for (int g2 = 0; g2 < 2; ++g2) {
    const int g = 2 * q + g2;
    float xa[4];
    float sdot = spb[g];
#pragma unroll
    for (int c = 0; c < 4; ++c) {
      xa[c] = pre8[g2 * 4 + c] * cw[g * 4 + c];
      sdot += xa[c] * spw[g * 4 + c];
    }
    float sgv = sigm(sdot);
    float thr = thrbuf[b * 8 + g] * (1.f / (4.f * 65536.f));
#pragma unroll
    for (int c = 0; c < 4; ++c) {
      float resp = sigm(xa[c] * sgv);
      float m = (resp > thr) ? 1.f : resp;
      mx8[g2 * 4 + c] = pre8[g2 * 4 + c] * m;
    }
  }
  int offs[9]; bool okn[9];
#pragma unroll
  for (int dy = -1; dy <= 1; ++dy)
#pragma unroll
    for (int dx = -1; dx <= 1; ++dx) {
      int i = (dy + 1) * 3 + (dx + 1);
      int yy = y + dy, x2 = xx + dx;
      okn[i] = ((unsigned)yy < 256u) && ((unsigned)x2 < 256u);
      offs[i] = yy * 256 + x2;
    }
  float v8[8];
#pragma unroll
  for (int j = 0; j < 8; ++j) {
    const unsigned short* plane = qkvl + (size_t)(b * 96 + 64 + q * 8 + j) * HW;
    float acc = 0.f;
#pragma unroll
    for (int i = 0; i < 9; ++i)
      if (okn[i]) acc += bf2f(plane[offs[i]]) * qkv_dw[(64 + q * 8 + j) * 9 + i];
    v8[j] = acc;
  }
#pragma unroll
  for (int j = 0; j < 8; ++j) {
    float s = 0.f;
#pragma unroll
    for (int d = 0; d < 8; ++d) s += A[(q * 8 + j) * 8 + d] * v8[d];
    sA[px_l][q * 8 + j] = f2bf(s);
    sA[px_l][32 + q * 8 + j] = f2bf(mx8[j]);
    sA[px_l][64 + q * 8 + j] = lv.s[j];
  }
  __syncthreads();
  const int w = q, lane = tid & 63;
  const int col = lane & 15, kgrp = lane >> 4;
  const int og = w * 16 + col;
  f32x4 acc[4];
#pragma unroll
  for (int s = 0; s < 4; ++s) acc[s] = (f32x4){0.f, 0.f, 0.f, 0.f};
#pragma unroll
  for (int kk = 0; kk < 3; ++kk) {
    const int c0 = kk * 32 + kgrp * 8;
    union { short8v v; unsigned short s[8]; } bw;
    const float* wp = W96 + og * 96 + c0;
#pragma unroll
    for (int j = 0; j < 8; ++j) bw.s[j] = f2bf(wp[j]);
#pragma unroll
    for (int s = 0; s < 4; ++s) {
      short8v av = *reinterpret_cast<const short8v*>(&sA[s * 16 + col][c0]);
      acc[s] = __builtin_amdgcn_mfma_f32_16x16x32_bf16(av, bw.v, acc[s], 0, 0, 0);
    }
  }
#pragma unroll
  for (int s = 0; s < 4; ++s) {
#pragma unroll
    for (int r = 0; r < 4; ++r) {
      int pxl = s * 16 + kgrp * 4 + r;
      sOut[og][pxl] = acc[s][r];
    }
  }
  __syncthreads();
  const float* xb = x + (size_t)(b * 64) * HW + hw0;
  float* db = dout + (size_t)(b * 64) * HW + hw0;
#pragma unroll
  for (int i = 0; i < 16; ++i) {
    int idx = tid + i * 256;
    int o = idx >> 6, px = idx & 63;
    db[(size_t)o * HW + px] = sOut[o][px] + cb[o] + xb[(size_t)o * HW + px];
  }
}

// ---------------- K5 (MFMA): LN2 + ffn_in (64->256), 128 outs/block ----------------
__global__ __launch_bounds__(256) void k5_mfma(
    const float* __restrict__ ln2_w, const float* __restrict__ ln2_b,
    const float* __restrict__ ffn_in_w, const float* __restrict__ dout,
    unsigned short* __restrict__ Tb, int b)
{
  __shared__ float sStage[64][65];
  __shared__ unsigned short sXnb[64][72];
  __shared__ unsigned short sOutB[128][72];
  __shared__ float sMu[64], sRs[64];
  const int tid = threadIdx.x;
  const int px0 = blockIdx.x * 64;
  const int o0base = blockIdx.y * 128;
  const float* db = dout + (size_t)(b * 64) * HW + px0;
#pragma unroll
  for (int i = 0; i < 16; ++i) {
    int idx = tid + i * 256;
    int c = idx >> 6, px = idx & 63;
    sStage[px][c] = db[(size_t)c * HW + px];
  }
  __syncthreads();
  if (tid < 64) {
    float mu = 0.f;
#pragma unroll
    for (int c = 0; c < 64; ++c) mu += sStage[tid][c];
    mu *= (1.f / 64.f);
    float var = 0.f;
#pragma unroll
    for (int c = 0; c < 64; ++c) { float d = sStage[tid][c] - mu; var += d * d; }
    var *= (1.f / 64.f);
    sMu[tid] = mu;
    sRs[tid] = rsqrtf(var + 1e-5f);
  }
  __syncthreads();
#pragma unroll
  for (int i = 0; i < 16; ++i) {
    int idx = tid + i * 256;
    int px = idx >> 6, c = idx & 63;
    float xn = (sStage[px][c] - sMu[px]) * sRs[px] * ln2_w[c] + ln2_b[c];
    sXnb[px][c] = f2bf(xn);
  }
  __syncthreads();
  const int w = tid >> 6, lane = tid & 63;
  const int col = lane & 15, kgrp = lane >> 4;
#pragma unroll
  for (int pass = 0; pass < 2; ++pass) {
    const int o_l = pass * 64 + w * 16 + col;
    const int og = o0base + o_l;
    f32x4 acc[4];
#pragma unroll
    for (int s = 0; s < 4; ++s) acc[s] = (f32x4){0.f, 0.f, 0.f, 0.f};
#pragma unroll
    for (int kk = 0; kk < 2; ++kk) {
      const int c0 = kk * 32 + kgrp * 8;
      union { short8v v; unsigned short s[8]; } bw;
      const float* wp = ffn_in_w + (size_t)og * 64 + c0;
#pragma unroll
      for (int j = 0; j < 8; ++j) bw.s[j] = f2bf(wp[j]);
#pragma unroll
      for (int s = 0; s < 4; ++s) {
        short8v av = *reinterpret_cast<const short8v*>(&sXnb[s * 16 + col][c0]);
        acc[s] = __builtin_amdgcn_mfma_f32_16x16x32_bf16(av, bw.v, acc[s], 0, 0, 0);
      }
    }
#pragma unroll
    for (int s = 0; s < 4; ++s) {
#pragma unroll
      for (int r = 0; r < 4; ++r) {
        int px_l = s * 16 + kgrp * 4 + r;
        sOutB[o_l][px_l] = f2bf(acc[s][r]);
      }
    }
  }
  __syncthreads();
  for (int i = tid; i < 1024; i += 256) {
    int o = i >> 3, seg = i & 7;
    *reinterpret_cast<short8v*>(Tb + (size_t)(o0base + o) * HW + px0 + seg * 8) =
        *reinterpret_cast<const short8v*>(&sOutB[o][seg * 8]);
  }
}

// ---------------- K6a: dwconv3/dwconv5 + gelu*mul -> Y (bf16) ----------------
__global__ __launch_bounds__(256) void k6a_dw(
    const float* __restrict__ dw3_w, const float* __restrict__ dw5_w,
    const unsigned short* __restrict__ T, __hip_bfloat16* __restrict__ Y)
{
  const int tid = threadIdx.x;
  const int px = blockIdx.x * 256 + tid;
  const int j0 = blockIdx.y * 8;
  const int row = px >> 8, col = px & 255;
  bool oky[5], okx[5];
#pragma unroll
  for (int d = 0; d < 5; ++d) {
    oky[d] = ((unsigned)(row + d - 2) < 256u);
    okx[d] = ((unsigned)(col + d - 2) < 256u);
  }
#pragma unroll
  for (int jj = 0; jj < 8; ++jj) {
    const int j = j0 + jj;
    const unsigned short* pl = T + (size_t)j * HW;
    float a = 0.f;
#pragma unroll
    for (int dy = -1; dy <= 1; ++dy) {
      if (!oky[dy + 2]) continue;
#pragma unroll
      for (int dx = -1; dx <= 1; ++dx) {
        if (!okx[dx + 2]) continue;
        a += bf2f(pl[px + dy * 256 + dx]) * dw3_w[j * 9 + (dy + 1) * 3 + (dx + 1)];
      }
    }
    float m = 0.f;
    const unsigned short* pm = T + (size_t)(128 + j) * HW;
    if (j < 64) {
#pragma unroll
      for (int dy = -1; dy <= 1; ++dy) {
        if (!oky[dy + 2]) continue;
#pragma unroll
        for (int dx = -1; dx <= 1; ++dx) {
          if (!okx[dx + 2]) continue;
          m += bf2f(pm[px + dy * 256 + dx]) * dw3_w[(128 + j) * 9 + (dy + 1) * 3 + (dx + 1)];
        }
      }
    } else {
#pragma unroll
      for (int dy = -2; dy <= 2; ++dy) {
        if (!oky[dy + 2]) continue;
#pragma unroll
        for (int dx = -2; dx <= 2; ++dx) {
          if (!okx[dx + 2]) continue;
          m += bf2f(pm[px + dy * 256 + dx]) * dw5_w[(j - 64) * 25 + (dy + 2) * 5 + (dx + 2)];
        }
      }
    }
    float gl = 0.5f * a * (1.f + erff(a * 0.70710678118654752f));
    Y[(size_t)j * HW + px] = __float2bfloat16(gl * m);
  }
}

// ---------------- K6b: ffn_out (128->64) from Y ----------------
__global__ __launch_bounds__(256) void k6b_out(
    const float* __restrict__ ffn_out_w, const __hip_bfloat16* __restrict__ Y,
    const float* __restrict__ flag, float* __restrict__ dout, float* __restrict__ Z, int b)
{
  __shared__ float sW[2048];
  const int tid = threadIdx.x;
  const int o0 = blockIdx.y * 16;
  for (int i = tid; i < 2048; i += 256) sW[i] = ffn_out_w[o0 * 128 + i];
  __syncthreads();
  const int px = blockIdx.x * 256 + tid;
  float z[16];
#pragma unroll
  for (int o = 0; o < 16; ++o) z[o] = 0.f;
  for (int j = 0; j < 128; ++j) {
    float yv = __bfloat162float(Y[(size_t)j * HW + px]);
#pragma unroll
    for (int o = 0; o < 16; ++o) z[o] += sW[o * 128 + j] * yv;
  }
  if (flag[0] > 0.5f) {
    float* ob = dout + (size_t)(b * 64 + o0) * HW + px;
#pragma unroll
    for (int o = 0; o < 16; ++o) ob[(size_t)o * HW] += z[o];
  } else {
    float* zb = Z + (size_t)o0 * HW + px;
#pragma unroll
    for (int o = 0; o < 16; ++o) zb[(size_t)o * HW] = z[o];
  }
}

// ---------------- K7: general fft path (early-exit if identity) ----------------
__global__ __launch_bounds__(256) void k7_fft(
    const float* __restrict__ fftw, const float* __restrict__ flag,
    const float* __restrict__ Z, float* __restrict__ dout, int b)
{
  if (flag[0] > 0.5f) return;
  __shared__ float swv[64];
  __shared__ float spatch[4][64];
  const int tid = threadIdx.x;
  const int c = blockIdx.x >> 8;
  const int pblk = blockIdx.x & 255;
  if (tid < 64) swv[tid] = fftw[c * 64 + tid];
  const int lp = tid >> 6, e = tid & 63;
  const int patch = pblk * 4 + lp;
  const int pi = patch >> 5, pj = patch & 31;
  const int i = e >> 3, jj = e & 7;
  const int gidx = (pi * 8 + i) * 256 + pj * 8 + jj;
  const float zv = Z[(size_t)c * HW + gidx];
  spatch[lp][e] = zv;
  __syncthreads();
  float s = 0.f;
#pragma unroll
  for (int a = 0; a < 8; ++a)
#pragma unroll
    for (int b2 = 0; b2 < 8; ++b2)
      s += swv[a * 8 + b2] * spatch[lp][((i - a) & 7) * 8 + ((jj - b2) & 7)];
  dout[(size_t)(b * 64 + c) * HW + gidx] += s;
}

extern "C" void kernel_launch(void* const* d_in, const int* in_sizes, int n_in,
                              void* d_out, int out_size, void* d_ws, size_t ws_size,
                              hipStream_t stream) {
  const float* x          = (const float*)d_in[0];
  const float* ln1_w      = (const float*)d_in[1];
  const float* ln1_b      = (const float*)d_in[2];
  const float* in_proj_w  = (const float*)d_in[3];
  const float* qkv_w      = (const float*)d_in[4];
  const float* qkv_dw     = (const float*)d_in[5];
  const float* out_proj_w = (const float*)d_in[6];
  const float* temperature= (const float*)d_in[7];
  const float* attn_scales= (const float*)d_in[8];
  const float* gate_w1    = (const float*)d_in[9];
  const float* gate_b1    = (const float*)d_in[10];
  const float* gate_w2    = (const float*)d_in[11];
  const float* gate_b2    = (const float*)d_in[12];
  const float* lgce_pre_w = (const float*)d_in[13];
  const float* lgce_pre_b = (const float*)d_in[14];
  const float* lgce_post_w= (const float*)d_in[15];
  const float* lgce_post_b= (const float*)d_in[16];
  const float* cbam_m1w   = (const float*)d_in[17];
  const float* cbam_m1b   = (const float*)d_in[18];
  const float* cbam_m2w   = (const float*)d_in[19];
  const float* cbam_m2b   = (const float*)d_in[20];
  const float* cbam_spw   = (const float*)d_in[21];
  const float* cbam_spb   = (const float*)d_in[22];
  const float* ln2_w      = (const float*)d_in[23];
  const float* ln2_b      = (const float*)d_in[24];
  const float* ffn_in_w   = (const float*)d_in[25];
  const float* dw3_w      = (const float*)d_in[26];
  const float* dw5_w      = (const float*)d_in[27];
  const float* ffn_out_w  = (const float*)d_in[28];
  const float* fft_W      = (const float*)d_in[29];
  float* ws = (float*)d_ws;
  float* out = (float*)d_out;
  unsigned short* qkvlp = (unsigned short*)(ws + OFF_QKVL);
  unsigned short* LOCB = (unsigned short*)(ws + OFF_LOCB);
  unsigned short* PREB = (unsigned short*)(ws + OFF_PREB);
  unsigned short* Tb = (unsigned short*)(ws + OFF_T);
  __hip_bfloat16* Ybuf = (__hip_bfloat16*)(ws + OFF_Y);

  hipLaunchKernelGGL(k0_setup, dim3(1), dim3(256), 0, stream,
                     fft_W, in_proj_w, qkv_w, gate_w1, lgce_pre_w,
                     out_proj_w, lgce_post_w, lgce_post_b, ws);
  hipLaunchKernelGGL(k1_mfma, dim3(2048), dim3(256), 0, stream,
                     x, ln1_w, ln1_b, in_proj_w, ws + OFF_MQKV, ws + OFF_MG1,
                     ws + OFF_MPRE, lgce_pre_b,
                     gate_b1, gate_w2, gate_b2,
                     qkvlp, LOCB, PREB, ws + OFF_POOL, ws + OFF_GSUM);
  hipLaunchKernelGGL(k1_check, dim3(1), dim3(256), 0, stream,
                     x, ln1_w, ln1_b, in_proj_w, qkv_w, lgce_pre_w, lgce_pre_b,
                     LOCB, qkvlp, PREB, ws + OFF_BAD);
  hipLaunchKernelGGL(k1r_reset, dim3(1), dim3(256), 0, stream,
                     ws + OFF_BAD, ws + OFF_GSUM);
  hipLaunchKernelGGL(k1_fb, dim3(1024), dim3(256), 0, stream,
                     x, ln1_w, ln1_b, in_proj_w, qkv_w, lgce_pre_w, lgce_pre_b,
                     gate_w1, gate_b1, gate_w2, gate_b2,
                     ws + OFF_BAD, qkvlp, LOCB, PREB, ws + OFF_POOL, ws + OFF_GSUM);
  hipLaunchKernelGGL(k2_mfma, dim3(128, 4, 4), dim3(256), 0, stream,
                     qkvlp, qkv_dw, ws + OFF_GRAM);
  hipLaunchKernelGGL(k3_final, dim3(1), dim3(256), 0, stream,
                     cbam_m1w, cbam_m1b, cbam_m2w, cbam_m2b, temperature, attn_scales,
                     lgce_pre_w, lgce_pre_b,
                     ws + OFF_GSUM, ws + OFF_POOL, ws + OFF_GRAM, ws + OFF_A, ws + OFF_CW);
  hipLaunchKernelGGL(k4a_thr, dim3(2048), dim3(256), 0, stream,
                     cbam_spw, cbam_spb, ws + OFF_CW, PREB, ws + OFF_PART);
  hipLaunchKernelGGL(k4a_red, dim3(32), dim3(256), 0, stream,
                     ws + OFF_PART, ws + OFF_THR);
  hipLaunchKernelGGL(k4b_fuse, dim3(4096), dim3(256), 0, stream,
                     x, cbam_spw, cbam_spb, qkv_dw, qkvlp, LOCB, PREB,
                     ws + OFF_A, ws + OFF_CW, ws + OFF_THR,
                     ws + OFF_W96, ws + OFF_CB, out);

  for (int b = 0; b < 4; ++b) {
    hipLaunchKernelGGL(k5_mfma, dim3(1024, 2), dim3(256), 0, stream,
                       ln2_w, ln2_b, ffn_in_w, out, Tb, b);
    hipLaunchKernelGGL(k6a_dw, dim3(256, 16), dim3(256), 0, stream,
                       dw3_w, dw5_w, Tb, Ybuf);
    hipLaunchKernelGGL(k6b_out, dim3(256, 4), dim3(256), 0, stream,
                       ffn_out_w, Ybuf, ws + OFF_FLAG, out, ws + OFF_Z, b);
    hipLaunchKernelGGL(k7_fft, dim3(16384), dim3(256), 0, stream,
                       ws + OFF_FFTW, ws + OFF_FLAG, ws + OFF_Z, out, b);
  }
}

// Round 12
// 1006.925 us; speedup vs baseline: 6.3507x; 1.1245x over previous
//
#include <hip/hip_runtime.h>
#include <hip/hip_bf16.h>
#include <math.h>

#define HW 65536
#define NPIX 262144

// ---- workspace layout (float offsets) ----
#define OFF_FFTW 0            // 64x64 spatial fft kernel
#define OFF_FLAG 4096         // 1
#define OFF_GSUM 4097         // 1    (zeroed in k0)
#define OFF_POOL 4098         // 128  (zeroed in k0)  -- pooled(loc) sums
#define OFF_GRAM 4226         // 1280 (zeroed in k0)
#define OFF_THR  5506         // 32   (written by k4a_red)
#define OFF_BAD  5538         // 1    (zeroed in k0)  -- k1 checker flag
#define OFF_A    5539         // 1024
#define OFF_CW   6563         // 128
#define OFF_QKVL 8192         // 96ch * 262144 px bf16 = 12582912 float-slots (SGSA phase)
#define OFF_MQKV 12591104     // 96*64 fp32 composed qkv matrix
#define OFF_MG1  (OFF_MQKV + 6144)     // 16*64 fp32  (ends 12598272)
#define OFF_MPRE 12598272     // 32*64 fp32 composed pre matrix (ends 12600320)
#define OFF_PREB 12600320     // [4][65536][32] bf16 px-major = 4194304 slots (ends 16794624)
#define OFF_LOCB 16794624     // [4][65536][32] bf16 px-major = 4194304 slots (ends 20988928)
#define OFF_PART 20988928     // 2048 blk * 4 waves * 4 g = 32768 (ends 21021696)
#define OFF_W96  21021696     // 64*96 fp32 composed out_proj|post matrix (SGSA phase only)
#define OFF_CB   (OFF_W96 + 6144)      // 64 fp32 (ends 21027904 < 25174016)
// MFFN phase (per-batch, overlaps QKVL/PREB/LOCB/W96 which are dead by then):
#define OFF_T    8192                      // 256ch * 65536 bf16
#define OFF_Y    (OFF_T + 16777216)        // 128ch * 65536 bf16
#define OFF_Z    (OFF_Y + 4194304)         // 64ch * 65536 fp32
// peak ws usage = 25174016 floats = 100.7 MB (unchanged proven footprint)

typedef __attribute__((ext_vector_type(8))) short short8v;
typedef __attribute__((ext_vector_type(4))) float f32x4;

__device__ __forceinline__ float sigm(float v) { return 1.f / (1.f + expf(-v)); }
__device__ __forceinline__ float wredsum(float v) {
#pragma unroll
  for (int off = 32; off >= 1; off >>= 1) v += __shfl_xor(v, off);
  return v;
}
__device__ __forceinline__ unsigned short f2bf(float f) {
  union { float f; unsigned u; } x; x.f = f;
  unsigned r = x.u + 0x7fffu + ((x.u >> 16) & 1u);
  return (unsigned short)(r >> 16);
}
__device__ __forceinline__ float bf2f(unsigned short u) {
  union { unsigned u; float f; } x; x.u = ((unsigned)u) << 16;
  return x.f;
}

// ---------------- K0: zero accumulators + fft kernel + composed matrices ----------------
__global__ __launch_bounds__(256) void k0_setup(
    const float* __restrict__ fft_W, const float* __restrict__ in_proj_w,
    const float* __restrict__ qkv_w, const float* __restrict__ g1w,
    const float* __restrict__ pre_w, const float* __restrict__ out_proj_w,
    const float* __restrict__ post_w, const float* __restrict__ post_b,
    float* __restrict__ ws)
{
  __shared__ float ct8[8];
  __shared__ int sbad;
  const int tid = threadIdx.x;
  if (tid < 8) ct8[tid] = cosf((float)tid * 0.78539816339744831f); // cos(k*pi/4)
  if (tid == 0) sbad = 0;
  for (int i = tid; i < 1442; i += 256) ws[OFF_GSUM + i] = 0.f;    // gsum,pool,gram,thr,bad
  for (int i = tid; i < 96 * 64; i += 256) {
    int o = i >> 6, c = i & 63;
    float s = 0.f;
    for (int j = 0; j < 32; ++j) s += qkv_w[o * 32 + j] * in_proj_w[(32 + j) * 64 + c];
    ws[OFF_MQKV + i] = s;
  }
  for (int i = tid; i < 16 * 64; i += 256) {
    int o = i >> 6, c = i & 63;
    float s = 0.f;
    for (int j = 0; j < 32; ++j) s += g1w[o * 32 + j] * in_proj_w[(32 + j) * 64 + c];
    ws[OFF_MG1 + i] = s;
  }
  for (int i = tid; i < 32 * 64; i += 256) {
    int o = i >> 6, c = i & 63;
    float s = 0.f;
    for (int j = 0; j < 32; ++j) s += pre_w[o * 32 + j] * in_proj_w[j * 64 + c];
    ws[OFF_MPRE + i] = s;
  }
  for (int i = tid; i < 64 * 96; i += 256) {
    int o = i / 96, c = i - o * 96;
    float s;
    if (c < 32) s = out_proj_w[o * 64 + c];
    else if (c < 64) {
      s = 0.f;
      for (int k = 0; k < 32; ++k) s += out_proj_w[o * 64 + 32 + k] * post_w[k * 32 + (c - 32)];
    } else s = out_proj_w[o * 64 + (c - 32)];
    ws[OFF_W96 + i] = s;
  }
  for (int i = tid; i < 64; i += 256) {
    float s = 0.f;
    for (int k = 0; k < 32; ++k) s += out_proj_w[i * 64 + 32 + k] * post_b[k];
    ws[OFF_CB + i] = s;
  }
  __syncthreads();
  bool ok = true;
  for (int i = tid; i < 64 * 64; i += 256) {
    int ch = i >> 6, ab = i & 63;
    int a = ab >> 3, b2 = ab & 7;
    float s = 0.f;
    for (int u = 0; u < 8; ++u)
      for (int v = 0; v < 8; ++v) {
        float Wf;
        if (v == 0 || v == 4)
          Wf = 0.5f * (fft_W[ch * 40 + u * 5 + v] + fft_W[ch * 40 + ((8 - u) & 7) * 5 + v]);
        else if (v < 5)
          Wf = fft_W[ch * 40 + u * 5 + v];
        else
          Wf = fft_W[ch * 40 + ((8 - u) & 7) * 5 + (8 - v)];
        s += Wf * ct8[(u * a + v * b2) & 7];
      }
    s *= (1.f / 64.f);
    ws[OFF_FFTW + i] = s;
    float expect = ((i & 63) == 0) ? 1.f : 0.f;
    if (fabsf(s - expect) > 1e-4f) ok = false;
  }
  if (!ok) atomicOr(&sbad, 1);
  __syncthreads();
  if (tid == 0) ws[OFF_FLAG] = sbad ? 0.f : 1.f;
}

// ---------------- K1 (MFMA, 128px blocks): LN1 + [loc|qkv|pre] + gate + pooled ----------------
__global__ __launch_bounds__(256) void k1_mfma(
    const float* __restrict__ x, const float* __restrict__ ln1_w, const float* __restrict__ ln1_b,
    const float* __restrict__ in_proj_w, const float* __restrict__ mqkv, const float* __restrict__ mg1,
    const float* __restrict__ mpre, const float* __restrict__ pre_b,
    const float* __restrict__ g1b, const float* __restrict__ g2w, const float* __restrict__ g2b,
    unsigned short* __restrict__ qkvl, unsigned short* __restrict__ LOCB,
    unsigned short* __restrict__ PREB, float* __restrict__ pooled, float* __restrict__ gsum)
{
  __shared__ unsigned short sXnb[128][72];   // LN'd bf16 activations [px][64ch]  (18.4 KB)
  __shared__ unsigned short sStg[4][16][76]; // per-wave staging, padded stride 76 (9.7 KB)
  __shared__ float sPoolL[32];
  __shared__ float sRed[4];
  const int tid = threadIdx.x;
  const int p0 = blockIdx.x * 128;
  const int b = p0 >> 16;
  const int hw0 = p0 & (HW - 1);
  if (tid < 32) sPoolL[tid] = 0.f;
  // ---- Phase A: register LN, 2 threads per px (each 32 channels) ----
  {
    const int px_l = tid >> 1, half = tid & 1;
    const float* xb = x + (size_t)(b * 64 + half * 32) * HW + hw0 + px_l;
    float xv[32];
    float mu = 0.f;
#pragma unroll
    for (int c = 0; c < 32; ++c) { xv[c] = xb[(size_t)c * HW]; mu += xv[c]; }
    mu += __shfl_xor(mu, 1);
    mu *= (1.f / 64.f);
    float var = 0.f;
#pragma unroll
    for (int c = 0; c < 32; ++c) { float d = xv[c] - mu; var += d * d; }
    var += __shfl_xor(var, 1);
    var *= (1.f / 64.f);
    const float rs = rsqrtf(var + 1e-5f);
#pragma unroll
    for (int ch = 0; ch < 4; ++ch) {
      union { short8v v; unsigned short s[8]; } u;
#pragma unroll
      for (int j = 0; j < 8; ++j) {
        int cg = half * 32 + ch * 8 + j;
        u.s[j] = f2bf((xv[ch * 8 + j] - mu) * rs * ln1_w[cg] + ln1_b[cg]);
      }
      *reinterpret_cast<short8v*>(&sXnb[px_l][half * 32 + ch * 8]) = u.v;
    }
  }
  __syncthreads();
  // ---- Phase B: MFMA tiles ----
  const int w = tid >> 6, lane = tid & 63;
  const int col = lane & 15, kgrp = lane >> 4;
#pragma unroll
  for (int pass = 0; pass < 3; ++pass) {
    const int tile = pass * 4 + w;
    if (tile >= 10) continue;                 // wave-uniform
    const int og = tile * 16 + col;           // 0..159
    const float* wrow = (og < 32) ? (in_proj_w + og * 64)
                      : (og < 128) ? (mqkv + (og - 32) * 64)
                                   : (mpre + (og - 128) * 64);
    union { short8v v; unsigned short s[8]; } bw[2];
#pragma unroll
    for (int kk = 0; kk < 2; ++kk) {
      const int c0 = kk * 32 + kgrp * 8;
#pragma unroll
      for (int j = 0; j < 8; ++j) bw[kk].s[j] = f2bf(wrow[c0 + j]);
    }
    const float bias = (og >= 128) ? pre_b[og - 128] : 0.f;
    float poolAcc = 0.f;
#pragma unroll
    for (int pxsub = 0; pxsub < 2; ++pxsub) {
      f32x4 acc[4];
#pragma unroll
      for (int s = 0; s < 4; ++s) acc[s] = (f32x4){0.f, 0.f, 0.f, 0.f};
#pragma unroll
      for (int kk = 0; kk < 2; ++kk) {
        const int c0 = kk * 32 + kgrp * 8;
#pragma unroll
        for (int s = 0; s < 4; ++s) {
          short8v av = *reinterpret_cast<const short8v*>(&sXnb[pxsub * 64 + s * 16 + col][c0]);
          acc[s] = __builtin_amdgcn_mfma_f32_16x16x32_bf16(av, bw[kk].v, acc[s], 0, 0, 0);
        }
      }
#pragma unroll
      for (int s = 0; s < 4; ++s) {
#pragma unroll
        for (int r = 0; r < 4; ++r) {
          float v = acc[s][r] + bias;
          sStg[w][col][s * 16 + kgrp * 4 + r] = f2bf(v);
          if (og < 32) poolAcc += v;
        }
      }
      if (og >= 32 && og < 128) {
        const int row = lane >> 2, seg = lane & 3;
        const unsigned short* src = &sStg[w][row][seg * 16];
        unsigned short* dst = qkvl + (size_t)(b * 96 + (tile - 2) * 16 + row) * HW
                              + hw0 + pxsub * 64 + seg * 16;
        *reinterpret_cast<short8v*>(dst) = *reinterpret_cast<const short8v*>(src);
        *reinterpret_cast<short8v*>(dst + 8) = *reinterpret_cast<const short8v*>(src + 8);
      } else {
        const int pxl = lane;
        union { short8v v; unsigned short s[8]; } u0, u1;
#pragma unroll
        for (int o = 0; o < 8; ++o) { u0.s[o] = sStg[w][o][pxl]; u1.s[o] = sStg[w][8 + o][pxl]; }
        unsigned short* base = (og < 32) ? LOCB : PREB;
        const int choff = (og < 32) ? (tile * 16) : ((tile - 8) * 16);
        unsigned short* dst = base + ((size_t)b * HW + hw0 + pxsub * 64 + pxl) * 32 + choff;
        *reinterpret_cast<short8v*>(dst) = u0.v;
        *reinterpret_cast<short8v*>(dst + 8) = u1.v;
      }
    }
    if (og < 32) {
      poolAcc += __shfl_xor(poolAcc, 16);
      poolAcc += __shfl_xor(poolAcc, 32);
      if (kgrp == 0) sPoolL[og] = poolAcc;
    }
  }
  // ---- gate: 2 threads/px, 8 h-rows each ----
  {
    const int gpx = tid >> 1, gq = tid & 1;
    float h[8];
#pragma unroll
    for (int i = 0; i < 8; ++i) h[i] = g1b[gq * 8 + i];
#pragma unroll
    for (int cc = 0; cc < 64; cc += 8) {
      union { short8v v; unsigned short s[8]; } xu;
      xu.v = *reinterpret_cast<const short8v*>(&sXnb[gpx][cc]);
#pragma unroll
      for (int j = 0; j < 8; ++j) {
        float xf = bf2f(xu.s[j]);
#pragma unroll
        for (int i = 0; i < 8; ++i) h[i] += mg1[(gq * 8 + i) * 64 + cc + j] * xf;
      }
    }
    float gpart = 0.f;
#pragma unroll
    for (int i = 0; i < 8; ++i) gpart += g2w[gq * 8 + i] * fmaxf(h[i], 0.f);
    gpart += __shfl_xor(gpart, 1);
    float gv = (gq == 0) ? sigm(gpart + g2b[0]) : 0.f;
    gv = wredsum(gv);
    if (lane == 0) sRed[w] = gv;
  }
  __syncthreads();
  if (tid == 0) atomicAdd(gsum, sRed[0] + sRed[1] + sRed[2] + sRed[3]);
  if (tid < 32) atomicAdd(&pooled[b * 32 + tid], sPoolL[tid]);
}

// ---------------- K1 checker (parallel): 256 blocks x 1 sampled px ----------------
__global__ __launch_bounds__(256) void k1_check(
    const float* __restrict__ x, const float* __restrict__ ln1_w, const float* __restrict__ ln1_b,
    const float* __restrict__ in_proj_w, const float* __restrict__ qkv_w,
    const float* __restrict__ pre_w, const float* __restrict__ pre_b,
    const unsigned short* __restrict__ LOCB, const unsigned short* __restrict__ qkvl,
    const unsigned short* __restrict__ PREB, float* __restrict__ bad)
{
  __shared__ float sXv[64];
  __shared__ float sLc[32], sGl[32];
  const int blk = blockIdx.x;
  const int b = blk & 3;
  const int px = (blk * 1031) & (HW - 1);
  const int tid = threadIdx.x;
  if (tid < 64) sXv[tid] = x[(size_t)(b * 64 + tid) * HW + px];
  __syncthreads();
  if (tid < 64) {
    float v = sXv[tid];
    float mu = wredsum(v) * (1.f / 64.f);
    float d = v - mu;
    float var = wredsum(d * d) * (1.f / 64.f);
    float rs = rsqrtf(var + 1e-5f);
    sXv[tid] = d * rs * ln1_w[tid] + ln1_b[tid];
  }
  __syncthreads();
  if (tid < 64) {
    const int o = tid & 31;
    const int hi = tid >> 5;
    float s = 0.f;
#pragma unroll
    for (int c = 0; c < 64; ++c) s += in_proj_w[(hi * 32 + o) * 64 + c] * sXv[c];
    if (hi) sGl[o] = s; else sLc[o] = s;
  }
  __syncthreads();
  bool fail = false;
  if (tid < 32) {
    float s = sLc[tid];
    float got = bf2f(LOCB[((size_t)b * HW + px) * 32 + tid]);
    if (fabsf(got - s) > 0.05f + 0.05f * fabsf(s)) fail = true;
  } else if (tid < 128) {
    const int o = tid - 32;             // qkv rows 0..95 (first 96 of tid 32..127)
    float s = 0.f;
#pragma unroll
    for (int j = 0; j < 32; ++j) s += qkv_w[o * 32 + j] * sGl[j];
    float got = bf2f(qkvl[(size_t)(b * 96 + o) * HW + px]);
    if (fabsf(got - s) > 0.05f + 0.05f * fabsf(s)) fail = true;
  } else if (tid < 160) {
    const int o = tid - 128;            // pre rows 0..31
    float s = pre_b[o];
#pragma unroll
    for (int j = 0; j < 32; ++j) s += pre_w[o * 32 + j] * sLc[j];
    float got = bf2f(PREB[((size_t)b * HW + px) * 32 + o]);
    if (fabsf(got - s) > 0.05f + 0.05f * fabsf(s)) fail = true;
  }
  if (fail) atomicExch(bad, 1.f);
}

// ---------------- K1 reset (only if checker failed) ----------------
__global__ __launch_bounds__(256) void k1r_reset(const float* __restrict__ bad, float* __restrict__ gsum)
{
  if (bad[0] < 0.5f) return;
  const int tid = threadIdx.x;
  if (tid < 129) gsum[tid] = 0.f;
}

// ---------------- K1 fallback (only if checker failed) ----------------
__global__ __launch_bounds__(256) void k1_fb(
    const float* __restrict__ x, const float* __restrict__ ln1_w, const float* __restrict__ ln1_b,
    const float* __restrict__ in_proj_w, const float* __restrict__ qkv_w,
    const float* __restrict__ pre_w, const float* __restrict__ pre_b,
    const float* __restrict__ g1w, const float* __restrict__ g1b,
    const float* __restrict__ g2w, const float* __restrict__ g2b,
    const float* __restrict__ bad,
    unsigned short* __restrict__ qkvl, unsigned short* __restrict__ LOCB,
    unsigned short* __restrict__ PREB, float* __restrict__ pooled, float* __restrict__ gsum)
{
  if (bad[0] < 0.5f) return;
  __shared__ float sPool[4][32];
  __shared__ float sRed[4];
  const int tid = threadIdx.x;
  const int p = blockIdx.x * 256 + tid;
  const int b = p >> 16;
  const int hw = p & (HW - 1);
  const int wave = tid >> 6, lane = tid & 63;
  const float* xb = x + (size_t)(b * 64) * HW + hw;
  float xv[64];
  float mu = 0.f;
#pragma unroll
  for (int c = 0; c < 64; ++c) { xv[c] = xb[(size_t)c * HW]; mu += xv[c]; }
  mu *= (1.f / 64.f);
  float var = 0.f;
#pragma unroll
  for (int c = 0; c < 64; ++c) { float d = xv[c] - mu; var += d * d; }
  var *= (1.f / 64.f);
  const float rs = rsqrtf(var + 1e-5f);
#pragma unroll
  for (int c = 0; c < 64; ++c) xv[c] = (xv[c] - mu) * rs * ln1_w[c] + ln1_b[c];
  float loc[32];
  for (int o = 0; o < 32; ++o) {
    float s = 0.f;
#pragma unroll
    for (int c = 0; c < 64; ++c) s += in_proj_w[o * 64 + c] * xv[c];
    loc[o] = s;
    LOCB[((size_t)b * HW + hw) * 32 + o] = f2bf(s);
    float r = wredsum(s);
    if (lane == 0) sPool[wave][o] = r;
  }
  for (int o = 0; o < 32; ++o) {
    float s = pre_b[o];
#pragma unroll
    for (int j = 0; j < 32; ++j) s += pre_w[o * 32 + j] * loc[j];
    PREB[((size_t)b * HW + hw) * 32 + o] = f2bf(s);
  }
  float gl[32];
  for (int o = 0; o < 32; ++o) {
    float s = 0.f;
#pragma unroll
    for (int c = 0; c < 64; ++c) s += in_proj_w[(32 + o) * 64 + c] * xv[c];
    gl[o] = s;
  }
  for (int o = 0; o < 96; ++o) {
    float s = 0.f;
#pragma unroll
    for (int j = 0; j < 32; ++j) s += qkv_w[o * 32 + j] * gl[j];
    qkvl[(size_t)(b * 96 + o) * HW + hw] = f2bf(s);
  }
  float gacc = g2b[0];
  for (int o = 0; o < 16; ++o) {
    float h = g1b[o];
#pragma unroll
    for (int j = 0; j < 32; ++j) h += g1w[o * 32 + j] * gl[j];
    gacc += g2w[o] * fmaxf(h, 0.f);
  }
  float gv = wredsum(sigm(gacc));
  if (lane == 0) sRed[wave] = gv;
  __syncthreads();
  if (tid == 0) atomicAdd(gsum, sRed[0] + sRed[1] + sRed[2] + sRed[3]);
  if (tid < 32) {
    float s = sPool[0][tid] + sPool[1][tid] + sPool[2][tid] + sPool[3][tid];
    atomicAdd(&pooled[b * 32 + tid], s);
  }
}

// ---------------- K2 (MFMA): dwconv(q,k) + Gram via V·V^T — vectorized row loads ----------------
__global__ __launch_bounds__(256) void k2_mfma(
    const unsigned short* __restrict__ qkvl, const float* __restrict__ qkv_dw, float* __restrict__ gram)
{
  __shared__ float sred[4][256];
  const int tid = threadIdx.x;
  const int slab = blockIdx.x;
  const int h = blockIdx.y, b = blockIdx.z;
  const int w = tid >> 6, lane = tid & 63;
  const int ch = lane & 15, grp = lane >> 4;
  const int gch = (ch < 8) ? (h * 8 + ch) : (32 + h * 8 + (ch - 8));
  const unsigned short* plane = qkvl + (size_t)(b * 96 + gch) * HW;
  const float* wt = qkv_dw + gch * 9;
  float w9[9];
#pragma unroll
  for (int t = 0; t < 9; ++t) w9[t] = wt[t];
  f32x4 acc = (f32x4){0.f, 0.f, 0.f, 0.f};
#pragma unroll
  for (int iter = 0; iter < 4; ++iter) {
    const int pxbase = slab * 512 + w * 128 + iter * 32 + grp * 8;
    const int y = pxbase >> 8;
    const int x0 = pxbase & 255;
    float row[3][10];
#pragma unroll
    for (int dy = 0; dy < 3; ++dy) {
      const int yy = y + dy - 1;
      if ((unsigned)yy >= 256u) {
#pragma unroll
        for (int j = 0; j < 10; ++j) row[dy][j] = 0.f;
        continue;
      }
      const unsigned short* rp = plane + yy * 256;
      union { short8v v; unsigned short s[8]; } cu;
      cu.v = *reinterpret_cast<const short8v*>(rp + x0);
#pragma unroll
      for (int j = 0; j < 8; ++j) row[dy][j + 1] = bf2f(cu.s[j]);
      row[dy][0] = (x0 > 0) ? bf2f(rp[x0 - 1]) : 0.f;
      row[dy][9] = (x0 < 248) ? bf2f(rp[x0 + 8]) : 0.f;
    }
    union { short8v v; unsigned short s[8]; } frag;
#pragma unroll
    for (int j = 0; j < 8; ++j) {
      float a = 0.f;
#pragma unroll
      for (int dy = 0; dy < 3; ++dy)
#pragma unroll
        for (int dx = 0; dx < 3; ++dx)
          a += row[dy][j + dx] * w9[dy * 3 + dx];
      frag.s[j] = f2bf(a);
    }
    acc = __builtin_amdgcn_mfma_f32_16x16x32_bf16(frag.v, frag.v, acc, 0, 0, 0);
  }
#pragma unroll
  for (int r = 0; r < 4; ++r) sred[w][(grp * 4 + r) * 16 + ch] = acc[r];
  __syncthreads();
  if (tid < 256) {
    float g = sred[0][tid] + sred[1][tid] + sred[2][tid] + sred[3][tid];
    const int row_ = tid >> 4, col_ = tid & 15;
    int idx = -1;
    if (row_ < 8 && col_ >= 8) idx = row_ * 8 + (col_ - 8);
    else if (row_ == col_ && row_ < 8) idx = 64 + row_;
    else if (row_ == col_) idx = 72 + (row_ - 8);
    if (idx >= 0) atomicAdd(&gram[(b * 4 + h) * 80 + idx], g);
  }
}

// ---------------- K3: dk, CBAM weights, attention matrices ----------------
__global__ __launch_bounds__(256) void k3_final(
    const float* __restrict__ m1w, const float* __restrict__ m1b,
    const float* __restrict__ m2w, const float* __restrict__ m2b,
    const float* __restrict__ temperature, const float* __restrict__ attn_scales,
    const float* __restrict__ pre_w, const float* __restrict__ pre_b,
    const float* __restrict__ gsum, const float* __restrict__ pooled,
    const float* __restrict__ gram, float* __restrict__ Abuf, float* __restrict__ cwbuf)
{
  __shared__ int s_dk;
  __shared__ float s_scale;
  const int tid = threadIdx.x;
  if (tid == 0) {
    float gmean = gsum[0] / (float)NPIX;
    int dk = (int)floorf(8.f * gmean);
    if (dk < 1) dk = 1;
    if (dk > 8) dk = 8;
    s_dk = dk;
    s_scale = attn_scales[0] + attn_scales[1] + attn_scales[2] + attn_scales[3];
  }
  __syncthreads();
  if (tid < 128) {
    int b = tid >> 5, ch = tid & 31, g = ch >> 2, c = ch & 3;
    float h1 = m1b[g];
#pragma unroll
    for (int cc = 0; cc < 4; ++cc) {
      int row = g * 4 + cc;
      float pp = pre_b[row];
#pragma unroll
      for (int j = 0; j < 32; ++j)
        pp += pre_w[row * 32 + j] * (pooled[b * 32 + j] * (1.f / 65536.f));
      h1 += pp * m1w[g * 4 + cc];
    }
    h1 = fmaxf(h1, 0.f);
    cwbuf[tid] = sigm(h1 * m2w[g * 4 + c] + m2b[g * 4 + c]);

    int r = tid, h = (r >> 3) & 3, c8 = r & 7;
    const float* gm = gram + (b * 4 + h) * 80;
    float qn = fmaxf(sqrtf(gm[64 + c8]), 1e-12f);
    float temp = temperature[h];
    float a[8];
#pragma unroll
    for (int d = 0; d < 8; ++d) {
      float kn = fmaxf(sqrtf(gm[72 + d]), 1e-12f);
      a[d] = gm[c8 * 8 + d] / (qn * kn) * temp;
    }
    float t[8];
#pragma unroll
    for (int d = 0; d < 8; ++d) t[d] = a[d];
#pragma unroll
    for (int i = 0; i < 8; ++i)
#pragma unroll
      for (int j = 0; j < 8; ++j)
        if (j > i && t[j] > t[i]) { float tmp = t[i]; t[i] = t[j]; t[j] = tmp; }
    float kth = t[s_dk - 1];
    float mx = t[0];
    float e[8]; float sum = 0.f;
#pragma unroll
    for (int d = 0; d < 8; ++d) {
      e[d] = (a[d] >= kth) ? expf(a[d] - mx) : 0.f;
      sum += e[d];
    }
    float inv = s_scale / sum;
#pragma unroll
    for (int d = 0; d < 8; ++d) Abuf[r * 8 + d] = e[d] * inv;
  }
}

// ---------------- K4a: resp partial sums (atomic-free), PREB bf16 ----------------
__global__ __launch_bounds__(256) void k4a_thr(
    const float* __restrict__ spw, const float* __restrict__ spb,
    const float* __restrict__ cwbuf, const unsigned short* __restrict__ PREB,
    float* __restrict__ wpart)
{
  const int tid = threadIdx.x;
  const int pxb = blockIdx.x >> 1;
  const int gh = blockIdx.x & 1;
  const int px = pxb * 256 + tid;
  const int b = px >> 16, hw = px & (HW - 1);
  const int w = tid >> 6, lane = tid & 63;
  const float* cw = cwbuf + b * 32;
  const unsigned short* pp = PREB + ((size_t)b * HW + hw) * 32 + gh * 16;
  union { short8v v; unsigned short s[8]; } u0, u1;
  u0.v = *reinterpret_cast<const short8v*>(pp);
  u1.v = *reinterpret_cast<const short8v*>(pp + 8);
  float pv[16];
#pragma unroll
  for (int k = 0; k < 8; ++k) { pv[k] = bf2f(u0.s[k]); pv[8 + k] = bf2f(u1.s[k]); }
  float racc[4];
#pragma unroll
  for (int g4 = 0; g4 < 4; ++g4) {
    const int g = gh * 4 + g4;
    float xa[4];
    float sdot = spb[g];
#pragma unroll
    for (int c = 0; c < 4; ++c) {
      xa[c] = pv[g4 * 4 + c] * cw[g * 4 + c];
      sdot += xa[c] * spw[g * 4 + c];
    }
    float sgv = sigm(sdot);
    float r = 0.f;
#pragma unroll
    for (int c = 0; c < 4; ++c) r += sigm(xa[c] * sgv);
    racc[g4] = r;
  }
#pragma unroll
  for (int g4 = 0; g4 < 4; ++g4) {
    float v = wredsum(racc[g4]);
    if (lane == 0) wpart[(blockIdx.x * 4 + w) * 4 + g4] = v;
  }
}

// ---------------- K4a_red: reduce wpart -> thrbuf ----------------
__global__ __launch_bounds__(256) void k4a_red(
    const float* __restrict__ wpart, float* __restrict__ thrbuf)
{
  __shared__ float sr[256];
  const int tid = threadIdx.x;
  const int b = blockIdx.x >> 3, g = blockIdx.x & 7;
  const int gh = g >> 2, gl = g & 3;
  float s = 0.f;
#pragma unroll
  for (int w = 0; w < 4; ++w)
    s += wpart[((((size_t)(b * 256 + tid) * 2 + gh) * 4) + w) * 4 + gl];
  sr[tid] = s;
  __syncthreads();
  for (int st = 128; st >= 1; st >>= 1) {
    if (tid < st) sr[tid] += sr[tid + st];
    __syncthreads();
  }
  if (tid == 0) thrbuf[b * 8 + g] = sr[0];
}

// ---------------- K4b (MFMA): LGCE finish + V-dwconv + attn -> A96, W96 MFMA + cb + x -> dout ----------------
__global__ __launch_bounds__(256) void k4b_fuse(
    const float* __restrict__ x, const float* __restrict__ spw, const float* __restrict__ spb,
    const float* __restrict__ qkv_dw, const unsigned short* __restrict__ qkvl,
    const unsigned short* __restrict__ LOCB, const unsigned short* __restrict__ PREB,
    const float* __restrict__ Abuf, const float* __restrict__ cwbuf, const float* __restrict__ thrbuf,
    const float* __restrict__ W96, const float* __restrict__ cb,
    float* __restrict__ dout)
{
  __shared__ unsigned short sA[64][104];
  __shared__ float sOut[64][65];
  const int tid = threadIdx.x;
  const int px_l = tid & 63, q = tid >> 6;
  const int p0 = blockIdx.x * 64;
  const int b = p0 >> 16;
  const int hw0 = p0 & (HW - 1);
  const int hw = hw0 + px_l;
  const int y = hw >> 8, xx = hw & 255;
  const float* cw = cwbuf + b * 32;
  const float* A = Abuf + b * 256;
  union { short8v v; unsigned short s[8]; } lv, pvv;
  lv.v = *reinterpret_cast<const short8v*>(LOCB + ((size_t)b * HW + hw) * 32 + q * 8);
  pvv.v = *reinterpret_cast<const short8v*>(PREB + ((size_t)b * HW + hw) * 32 + q * 8);
  float pre8[8];
#pragma unroll
  for (int j = 0; j < 8; ++j) pre8[j] = bf2f(pvv.s[j]);
  float mx8[8];
#pragma unroll
  for (int g2 = 0; g2 < 2; ++g2) {
    const int g = 2 * q + g2;
    float xa[4];
    float sdot = spb[g];
#pragma unroll
    for (int c = 0; c < 4; ++c) {
      xa[c] = pre8[g2 * 4 + c] * cw[g * 4 + c];
      sdot += xa[c] * spw[g * 4 + c];
    }
    float sgv = sigm(sdot);
    float thr = thrbuf[b * 8 + g] * (1.f / (4.f * 65536.f));
#pragma unroll
    for (int c = 0; c < 4; ++c) {
      float resp = sigm(xa[c] * sgv);
      float m = (resp > thr) ? 1.f : resp;
      mx8[g2 * 4 + c] = pre8[g2 * 4 + c] * m;
    }
  }
  int offs[9]; bool okn[9];
#pragma unroll
  for (int dy = -1; dy <= 1; ++dy)
#pragma unroll
    for (int dx = -1; dx <= 1; ++dx) {
      int i = (dy + 1) * 3 + (dx + 1);
      int yy = y + dy, x2 = xx + dx;
      okn[i] = ((unsigned)yy < 256u) && ((unsigned)x2 < 256u);
      offs[i] = yy * 256 + x2;
    }
  float v8[8];
#pragma unroll
  for (int j = 0; j < 8; ++j) {
    const unsigned short* plane = qkvl + (size_t)(b * 96 + 64 + q * 8 + j) * HW;
    float acc = 0.f;
#pragma unroll
    for (int i = 0; i < 9; ++i)
      if (okn[i]) acc += bf2f(plane[offs[i]]) * qkv_dw[(64 + q * 8 + j) * 9 + i];
    v8[j] = acc;
  }
#pragma unroll
  for (int j = 0; j < 8; ++j) {
    float s = 0.f;
#pragma unroll
    for (int d = 0; d < 8; ++d) s += A[(q * 8 + j) * 8 + d] * v8[d];
    sA[px_l][q * 8 + j] = f2bf(s);
    sA[px_l][32 + q * 8 + j] = f2bf(mx8[j]);
    sA[px_l][64 + q * 8 + j] = lv.s[j];
  }
  __syncthreads();
  const int w = q, lane = tid & 63;
  const int col = lane & 15, kgrp = lane >> 4;
  const int og = w * 16 + col;
  f32x4 acc[4];
#pragma unroll
  for (int s = 0; s < 4; ++s) acc[s] = (f32x4){0.f, 0.f, 0.f, 0.f};
#pragma unroll
  for (int kk = 0; kk < 3; ++kk) {
    const int c0 = kk * 32 + kgrp * 8;
    union { short8v v; unsigned short s[8]; } bw;
    const float* wp = W96 + og * 96 + c0;
#pragma unroll
    for (int j = 0; j < 8; ++j) bw.s[j] = f2bf(wp[j]);
#pragma unroll
    for (int s = 0; s < 4; ++s) {
      short8v av = *reinterpret_cast<const short8v*>(&sA[s * 16 + col][c0]);
      acc[s] = __builtin_amdgcn_mfma_f32_16x16x32_bf16(av, bw.v, acc[s], 0, 0, 0);
    }
  }
#pragma unroll
  for (int s = 0; s < 4; ++s) {
#pragma unroll
    for (int r = 0; r < 4; ++r) {
      int pxl = s * 16 + kgrp * 4 + r;
      sOut[og][pxl] = acc[s][r];
    }
  }
  __syncthreads();
  const float* xb = x + (size_t)(b * 64) * HW + hw0;
  float* db = dout + (size_t)(b * 64) * HW + hw0;
#pragma unroll
  for (int i = 0; i < 16; ++i) {
    int idx = tid + i * 256;
    int o = idx >> 6, px = idx & 63;
    db[(size_t)o * HW + px] = sOut[o][px] + cb[o] + xb[(size_t)o * HW + px];
  }
}

// ---------------- K5 (MFMA): LN2 + ffn_in (64->256), 128 outs/block ----------------
__global__ __launch_bounds__(256) void k5_mfma(
    const float* __restrict__ ln2_w, const float* __restrict__ ln2_b,
    const float* __restrict__ ffn_in_w, const float* __restrict__ dout,
    unsigned short* __restrict__ Tb, int b)
{
  __shared__ float sStage[64][65];
  __shared__ unsigned short sXnb[64][72];
  __shared__ unsigned short sOutB[128][72];
  __shared__ float sMu[64], sRs[64];
  const int tid = threadIdx.x;
  const int px0 = blockIdx.x * 64;
  const int o0base = blockIdx.y * 128;
  const float* db = dout + (size_t)(b * 64) * HW + px0;
#pragma unroll
  for (int i = 0; i < 16; ++i) {
    int idx = tid + i * 256;
    int c = idx >> 6, px = idx & 63;
    sStage[px][c] = db[(size_t)c * HW + px];
  }
  __syncthreads();
  if (tid < 64) {
    float mu = 0.f;
#pragma unroll
    for (int c = 0; c < 64; ++c) mu += sStage[tid][c];
    mu *= (1.f / 64.f);
    float var = 0.f;
#pragma unroll
    for (int c = 0; c < 64; ++c) { float d = sStage[tid][c] - mu; var += d * d; }
    var *= (1.f / 64.f);
    sMu[tid] = mu;
    sRs[tid] = rsqrtf(var + 1e-5f);
  }
  __syncthreads();
#pragma unroll
  for (int i = 0; i < 16; ++i) {
    int idx = tid + i * 256;
    int px = idx >> 6, c = idx & 63;
    float xn = (sStage[px][c] - sMu[px]) * sRs[px] * ln2_w[c] + ln2_b[c];
    sXnb[px][c] = f2bf(xn);
  }
  __syncthreads();
  const int w = tid >> 6, lane = tid & 63;
  const int col = lane & 15, kgrp = lane >> 4;
#pragma unroll
  for (int pass = 0; pass < 2; ++pass) {
    const int o_l = pass * 64 + w * 16 + col;
    const int og = o0base + o_l;
    f32x4 acc[4];
#pragma unroll
    for (int s = 0; s < 4; ++s) acc[s] = (f32x4){0.f, 0.f, 0.f, 0.f};
#pragma unroll
    for (int kk = 0; kk < 2; ++kk) {
      const int c0 = kk * 32 + kgrp * 8;
      union { short8v v; unsigned short s[8]; } bw;
      const float* wp = ffn_in_w + (size_t)og * 64 + c0;
#pragma unroll
      for (int j = 0; j < 8; ++j) bw.s[j] = f2bf(wp[j]);
#pragma unroll
      for (int s = 0; s < 4; ++s) {
        short8v av = *reinterpret_cast<const short8v*>(&sXnb[s * 16 + col][c0]);
        acc[s] = __builtin_amdgcn_mfma_f32_16x16x32_bf16(av, bw.v, acc[s], 0, 0, 0);
      }
    }
#pragma unroll
    for (int s = 0; s < 4; ++s) {
#pragma unroll
      for (int r = 0; r < 4; ++r) {
        int px_l = s * 16 + kgrp * 4 + r;
        sOutB[o_l][px_l] = f2bf(acc[s][r]);
      }
    }
  }
  __syncthreads();
  for (int i = tid; i < 1024; i += 256) {
    int o = i >> 3, seg = i & 7;
    *reinterpret_cast<short8v*>(Tb + (size_t)(o0base + o) * HW + px0 + seg * 8) =
        *reinterpret_cast<const short8v*>(&sOutB[o][seg * 8]);
  }
}

// ---------------- K6a: dwconv3/dwconv5 + gelu*mul -> Y (bf16) ----------------
__global__ __launch_bounds__(256) void k6a_dw(
    const float* __restrict__ dw3_w, const float* __restrict__ dw5_w,
    const unsigned short* __restrict__ T, __hip_bfloat16* __restrict__ Y)
{
  const int tid = threadIdx.x;
  const int px = blockIdx.x * 256 + tid;
  const int j0 = blockIdx.y * 8;
  const int row = px >> 8, col = px & 255;
  bool oky[5], okx[5];
#pragma unroll
  for (int d = 0; d < 5; ++d) {
    oky[d] = ((unsigned)(row + d - 2) < 256u);
    okx[d] = ((unsigned)(col + d - 2) < 256u);
  }
#pragma unroll
  for (int jj = 0; jj < 8; ++jj) {
    const int j = j0 + jj;
    const unsigned short* pl = T + (size_t)j * HW;
    float a = 0.f;
#pragma unroll
    for (int dy = -1; dy <= 1; ++dy) {
      if (!oky[dy + 2]) continue;
#pragma unroll
      for (int dx = -1; dx <= 1; ++dx) {
        if (!okx[dx + 2]) continue;
        a += bf2f(pl[px + dy * 256 + dx]) * dw3_w[j * 9 + (dy + 1) * 3 + (dx + 1)];
      }
    }
    float m = 0.f;
    const unsigned short* pm = T + (size_t)(128 + j) * HW;
    if (j < 64) {
#pragma unroll
      for (int dy = -1; dy <= 1; ++dy) {
        if (!oky[dy + 2]) continue;
#pragma unroll
        for (int dx = -1; dx <= 1; ++dx) {
          if (!okx[dx + 2]) continue;
          m += bf2f(pm[px + dy * 256 + dx]) * dw3_w[(128 + j) * 9 + (dy + 1) * 3 + (dx + 1)];
        }
      }
    } else {
#pragma unroll
      for (int dy = -2; dy <= 2; ++dy) {
        if (!oky[dy + 2]) continue;
#pragma unroll
        for (int dx = -2; dx <= 2; ++dx) {
          if (!okx[dx + 2]) continue;
          m += bf2f(pm[px + dy * 256 + dx]) * dw5_w[(j - 64) * 25 + (dy + 2) * 5 + (dx + 2)];
        }
      }
    }
    float gl = 0.5f * a * (1.f + erff(a * 0.70710678118654752f));
    Y[(size_t)j * HW + px] = __float2bfloat16(gl * m);
  }
}

// ---------------- K6b: ffn_out (128->64) from Y ----------------
__global__ __launch_bounds__(256) void k6b_out(
    const float* __restrict__ ffn_out_w, const __hip_bfloat16* __restrict__ Y,
    const float* __restrict__ flag, float* __restrict__ dout, float* __restrict__ Z, int b)
{
  __shared__ float sW[2048];
  const int tid = threadIdx.x;
  const int o0 = blockIdx.y * 16;
  for (int i = tid; i < 2048; i += 256) sW[i] = ffn_out_w[o0 * 128 + i];
  __syncthreads();
  const int px = blockIdx.x * 256 + tid;
  float z[16];
#pragma unroll
  for (int o = 0; o < 16; ++o) z[o] = 0.f;
  for (int j = 0; j < 128; ++j) {
    float yv = __bfloat162float(Y[(size_t)j * HW + px]);
#pragma unroll
    for (int o = 0; o < 16; ++o) z[o] += sW[o * 128 + j] * yv;
  }
  if (flag[0] > 0.5f) {
    float* ob = dout + (size_t)(b * 64 + o0) * HW + px;
#pragma unroll
    for (int o = 0; o < 16; ++o) ob[(size_t)o * HW] += z[o];
  } else {
    float* zb = Z + (size_t)o0 * HW + px;
#pragma unroll
    for (int o = 0; o < 16; ++o) zb[(size_t)o * HW] = z[o];
  }
}

// ---------------- K7: general fft path (early-exit if identity) ----------------
__global__ __launch_bounds__(256) void k7_fft(
    const float* __restrict__ fftw, const float* __restrict__ flag,
    const float* __restrict__ Z, float* __restrict__ dout, int b)
{
  if (flag[0] > 0.5f) return;
  __shared__ float swv[64];
  __shared__ float spatch[4][64];
  const int tid = threadIdx.x;
  const int c = blockIdx.x >> 8;
  const int pblk = blockIdx.x & 255;
  if (tid < 64) swv[tid] = fftw[c * 64 + tid];
  const int lp = tid >> 6, e = tid & 63;
  const int patch = pblk * 4 + lp;
  const int pi = patch >> 5, pj = patch & 31;
  const int i = e >> 3, jj = e & 7;
  const int gidx = (pi * 8 + i) * 256 + pj * 8 + jj;
  const float zv = Z[(size_t)c * HW + gidx];
  spatch[lp][e] = zv;
  __syncthreads();
  float s = 0.f;
#pragma unroll
  for (int a = 0; a < 8; ++a)
#pragma unroll
    for (int b2 = 0; b2 < 8; ++b2)
      s += swv[a * 8 + b2] * spatch[lp][((i - a) & 7) * 8 + ((jj - b2) & 7)];
  dout[(size_t)(b * 64 + c) * HW + gidx] += s;
}

extern "C" void kernel_launch(void* const* d_in, const int* in_sizes, int n_in,
                              void* d_out, int out_size, void* d_ws, size_t ws_size,
                              hipStream_t stream) {
  const float* x          = (const float*)d_in[0];
  const float* ln1_w      = (const float*)d_in[1];
  const float* ln1_b      = (const float*)d_in[2];
  const float* in_proj_w  = (const float*)d_in[3];
  const float* qkv_w      = (const float*)d_in[4];
  const float* qkv_dw     = (const float*)d_in[5];
  const float* out_proj_w = (const float*)d_in[6];
  const float* temperature= (const float*)d_in[7];
  const float* attn_scales= (const float*)d_in[8];
  const float* gate_w1    = (const float*)d_in[9];
  const float* gate_b1    = (const float*)d_in[10];
  const float* gate_w2    = (const float*)d_in[11];
  const float* gate_b2    = (const float*)d_in[12];
  const float* lgce_pre_w = (const float*)d_in[13];
  const float* lgce_pre_b = (const float*)d_in[14];
  const float* lgce_post_w= (const float*)d_in[15];
  const float* lgce_post_b= (const float*)d_in[16];
  const float* cbam_m1w   = (const float*)d_in[17];
  const float* cbam_m1b   = (const float*)d_in[18];
  const float* cbam_m2w   = (const float*)d_in[19];
  const float* cbam_m2b   = (const float*)d_in[20];
  const float* cbam_spw   = (const float*)d_in[21];
  const float* cbam_spb   = (const float*)d_in[22];
  const float* ln2_w      = (const float*)d_in[23];
  const float* ln2_b      = (const float*)d_in[24];
  const float* ffn_in_w   = (const float*)d_in[25];
  const float* dw3_w      = (const float*)d_in[26];
  const float* dw5_w      = (const float*)d_in[27];
  const float* ffn_out_w  = (const float*)d_in[28];
  const float* fft_W      = (const float*)d_in[29];
  float* ws = (float*)d_ws;
  float* out = (float*)d_out;
  unsigned short* qkvlp = (unsigned short*)(ws + OFF_QKVL);
  unsigned short* LOCB = (unsigned short*)(ws + OFF_LOCB);
  unsigned short* PREB = (unsigned short*)(ws + OFF_PREB);
  unsigned short* Tb = (unsigned short*)(ws + OFF_T);
  __hip_bfloat16* Ybuf = (__hip_bfloat16*)(ws + OFF_Y);

  hipLaunchKernelGGL(k0_setup, dim3(1), dim3(256), 0, stream,
                     fft_W, in_proj_w, qkv_w, gate_w1, lgce_pre_w,
                     out_proj_w, lgce_post_w, lgce_post_b, ws);
  hipLaunchKernelGGL(k1_mfma, dim3(2048), dim3(256), 0, stream,
                     x, ln1_w, ln1_b, in_proj_w, ws + OFF_MQKV, ws + OFF_MG1,
                     ws + OFF_MPRE, lgce_pre_b,
                     gate_b1, gate_w2, gate_b2,
                     qkvlp, LOCB, PREB, ws + OFF_POOL, ws + OFF_GSUM);
  hipLaunchKernelGGL(k1_check, dim3(256), dim3(256), 0, stream,
                     x, ln1_w, ln1_b, in_proj_w, qkv_w, lgce_pre_w, lgce_pre_b,
                     LOCB, qkvlp, PREB, ws + OFF_BAD);
  hipLaunchKernelGGL(k1r_reset, dim3(1), dim3(256), 0, stream,
                     ws + OFF_BAD, ws + OFF_GSUM);
  hipLaunchKernelGGL(k1_fb, dim3(1024), dim3(256), 0, stream,
                     x, ln1_w, ln1_b, in_proj_w, qkv_w, lgce_pre_w, lgce_pre_b,
                     gate_w1, gate_b1, gate_w2, gate_b2,
                     ws + OFF_BAD, qkvlp, LOCB, PREB, ws + OFF_POOL, ws + OFF_GSUM);
  hipLaunchKernelGGL(k2_mfma, dim3(128, 4, 4), dim3(256), 0, stream,
                     qkvlp, qkv_dw, ws + OFF_GRAM);
  hipLaunchKernelGGL(k3_final, dim3(1), dim3(256), 0, stream,
                     cbam_m1w, cbam_m1b, cbam_m2w, cbam_m2b, temperature, attn_scales,
                     lgce_pre_w, lgce_pre_b,
                     ws + OFF_GSUM, ws + OFF_POOL, ws + OFF_GRAM, ws + OFF_A, ws + OFF_CW);
  hipLaunchKernelGGL(k4a_thr, dim3(2048), dim3(256), 0, stream,
                     cbam_spw, cbam_spb, ws + OFF_CW, PREB, ws + OFF_PART);
  hipLaunchKernelGGL(k4a_red, dim3(32), dim3(256), 0, stream,
                     ws + OFF_PART, ws + OFF_THR);
  hipLaunchKernelGGL(k4b_fuse, dim3(4096), dim3(256), 0, stream,
                     x, cbam_spw, cbam_spb, qkv_dw, qkvlp, LOCB, PREB,
                     ws + OFF_A, ws + OFF_CW, ws + OFF_THR,
                     ws + OFF_W96, ws + OFF_CB, out);

  for (int b = 0; b < 4; ++b) {
    hipLaunchKernelGGL(k5_mfma, dim3(1024, 2), dim3(256), 0, stream,
                       ln2_w, ln2_b, ffn_in_w, out, Tb, b);
    hipLaunchKernelGGL(k6a_dw, dim3(256, 16), dim3(256), 0, stream,
                       dw3_w, dw5_w, Tb, Ybuf);
    hipLaunchKernelGGL(k6b_out, dim3(256, 4), dim3(256), 0, stream,
                       ffn_out_w, Ybuf, ws + OFF_FLAG, out, ws + OFF_Z, b);
    hipLaunchKernelGGL(k7_fft, dim3(16384), dim3(256), 0, stream,
                       ws + OFF_FFTW, ws + OFF_FLAG, ws + OFF_Z, out, b);
  }
}